// Round 1
// baseline (1886.530 us; speedup 1.0000x reference)
//
#include <hip/hip_runtime.h>

// ---------------- problem constants ----------------
constexpr int NN = 32768;      // nodes
constexpr int EE = 524288;     // edges
constexpr int NB = 256;        // graphs / batch
constexpr int EN = EE + NN;    // edges + self loops

// ---------------- workspace layout (bytes) ----------------
constexpr size_t MB = 1ull << 20;
constexpr size_t OFF_A    = 0;        // 48MB: conv y1 (drug/target), later h1 [N,320]
constexpr size_t OFF_B    = 48*MB;    // 68MB: conv y2, later g1o [N,320]
constexpr size_t OFF_C    = 116*MB;   // 14MB: a1 [EN,5], later h2 [N,96]
constexpr size_t OFF_CSRS = 130*MB;   // csr_src [EN]
constexpr size_t OFF_CSRE = 133*MB;   // csr_eid [EN]
constexpr size_t OFF_ROWP = 136*MB;   // rowptr [N+1]
constexpr size_t OFF_DEG  = 137*MB;   // deg [N]
constexpr size_t OFF_CUR  = 138*MB;   // cursor [N]
constexpr size_t OFF_A2   = 139*MB;   // a2 [EN]
constexpr size_t OFF_G2O  = 142*MB;   // g2o [N,96]
constexpr size_t OFF_AS1  = 155*MB;   // [N,5]
constexpr size_t OFF_AD1  = 156*MB;
constexpr size_t OFF_AS2  = 157*MB;   // [N]
constexpr size_t OFF_AD2  = 158*MB;
constexpr size_t OFF_CD   = 159*MB;   // [256,96] pooled drug conv
constexpr size_t OFF_CT   = 160*MB;   // [256,96] pooled target conv
constexpr size_t OFF_POOL = 161*MB;   // [256,96] graph pool
constexpr size_t OFF_GFC  = 162*MB;   // [256,96]
constexpr size_t OFF_XC   = 163*MB;   // [256,288]
constexpr size_t OFF_M1B  = 164*MB;   // [256,1024]
constexpr size_t OFF_M2B  = 165*MB;   // wait 1MB each -> [256,1024] = 1MB exactly
constexpr size_t OFF_M3B  = 166*MB;   // [256,512]
constexpr size_t OFF_FD   = 167*MB;   // F table drug [32][4][65]
constexpr size_t OFF_FT   = 168*MB;   // F table target [32][8][26]
constexpr size_t OFF_WD2T = 169*MB;
constexpr size_t OFF_WD3T = 170*MB;
constexpr size_t OFF_WT2T = 171*MB;
constexpr size_t OFF_WT3T = 172*MB;
constexpr size_t OFF_CB   = 173*MB;   // const block: [0:25]=M1, [25:30]=M2, [30:35]=easum,
                                      // [35:40]=aeself1, [40]=ae2self, [41:46]=eamean

// =================================================================
// Tiny precompute tables: F_drug, F_target, M1[j][h], M2[j]
// =================================================================
__global__ void k_tables(const float* __restrict__ wd1, const float* __restrict__ emb_xd,
                         const float* __restrict__ wt1, const float* __restrict__ emb_xt,
                         const float* __restrict__ g1we, const float* __restrict__ g1ae,
                         const float* __restrict__ g2we, const float* __restrict__ g2ae,
                         float* __restrict__ Fd, float* __restrict__ Ft,
                         float* __restrict__ CB) {
  int t = blockIdx.x * 256 + threadIdx.x;
  const int NFd = 32*4*65, NFt = 32*8*26;
  if (t < NFd) {                       // Fd[co][k][v]
    int v = t % 65; int ck = t / 65; int k = ck & 3; int co = ck >> 2;
    float s = 0.f;
    for (int ci = 0; ci < 128; ++ci)
      s = fmaf(wd1[(co*128 + ci)*4 + k], emb_xd[v*128 + ci], s);
    Fd[t] = s;
  } else if (t < NFd + NFt) {          // Ft[co][k][v]
    int u = t - NFd;
    int v = u % 26; int ck = u / 26; int k = ck & 7; int co = ck >> 3;
    float s = 0.f;
    for (int ci = 0; ci < 128; ++ci)
      s = fmaf(wt1[(co*128 + ci)*8 + k], emb_xt[v*128 + ci], s);
    Ft[u] = s;
  } else if (t < NFd + NFt + 25) {     // M1[j][h]
    int u = t - NFd - NFt; int h = u % 5, j = u / 5;
    float s = 0.f;
    for (int c = 0; c < 64; ++c)
      s = fmaf(g1we[j*320 + h*64 + c], g1ae[h*64 + c], s);
    CB[j*5 + h] = s;
  } else if (t < NFd + NFt + 30) {     // M2[j]
    int j = t - NFd - NFt - 25;
    float s = 0.f;
    for (int c = 0; c < 96; ++c)
      s = fmaf(g2we[j*96 + c], g2ae[c], s);
    CB[25 + j] = s;
  }
}

// sum of ea columns -> CB[30..34] (pre-zeroed)
__global__ void k_easum(const float* __restrict__ ea, float* __restrict__ CB) {
  float acc[5] = {0,0,0,0,0};
  for (long e = blockIdx.x*256L + threadIdx.x; e < EE; e += 256L*gridDim.x) {
    #pragma unroll
    for (int j = 0; j < 5; ++j) acc[j] += ea[e*5 + j];
  }
  #pragma unroll
  for (int j = 0; j < 5; ++j)
    for (int off = 1; off < 64; off <<= 1) acc[j] += __shfl_xor(acc[j], off, 64);
  if ((threadIdx.x & 63) == 0) {
    #pragma unroll
    for (int j = 0; j < 5; ++j) atomicAdd(&CB[30 + j], acc[j]);
  }
}

// eamean, aeself1[h], ae2self
__global__ void k_finalize(float* __restrict__ CB) {
  if (blockIdx.x == 0 && threadIdx.x == 0) {
    float em[5];
    for (int j = 0; j < 5; ++j) { em[j] = CB[30 + j] / (float)EE; CB[41 + j] = em[j]; }
    for (int h = 0; h < 5; ++h) {
      float s = 0.f;
      for (int j = 0; j < 5; ++j) s = fmaf(em[j], CB[j*5 + h], s);
      CB[35 + h] = s;
    }
    float s = 0.f;
    for (int j = 0; j < 5; ++j) s = fmaf(em[j], CB[25 + j], s);
    CB[40] = s;
  }
}

// =================================================================
// conv1 via lookup table: y[b,co,l] = relu(b[co] + sum_k F[co,k,idx[b,l+k]])
// =================================================================
template<int K, int V, int COUT>
__global__ void k_conv1_lut(const int* __restrict__ idx, const float* __restrict__ F,
                            const float* __restrict__ bias, float* __restrict__ y,
                            int L, int Lout) {
  __shared__ float Fs[COUT*K*V];
  __shared__ float bs[COUT];
  int b = blockIdx.y;
  for (int i = threadIdx.x; i < COUT*K*V; i += blockDim.x) Fs[i] = F[i];
  for (int i = threadIdx.x; i < COUT; i += blockDim.x) bs[i] = bias[i];
  __syncthreads();
  int o = blockIdx.x * blockDim.x + threadIdx.x;
  if (o >= COUT * Lout) return;
  int co = o / Lout, l = o % Lout;
  const int* ib = idx + b*L + l;
  float acc = bs[co];
  #pragma unroll
  for (int k = 0; k < K; ++k) acc += Fs[(co*K + k)*V + ib[k]];
  y[(b*COUT + co)*Lout + l] = fmaxf(acc, 0.f);
}

// weight transpose [co][ci][k] -> [ci][k][co]
__global__ void k_wtrans(const float* __restrict__ w, float* __restrict__ wt,
                         int COUT, int CIN, int K) {
  int t = blockIdx.x*256 + threadIdx.x;
  if (t >= COUT*CIN*K) return;
  int k = t % K; int ci = (t / K) % CIN; int co = t / (K*CIN);
  wt[(ci*K + k)*COUT + co] = w[t];
}

// =================================================================
// direct conv, register-tiled; optional fused global-max-pool (relu >= 0)
// block = COUT*G threads; each thread: fixed co, LG consecutive l positions
// =================================================================
template<int CIN, int K, int COUT, int G, int LG, bool POOL>
__global__ void k_conv(const float* __restrict__ x, const float* __restrict__ wt,
                       const float* __restrict__ bias, float* __restrict__ y,
                       int Lin, int Lout) {
  constexpr int LT = G * LG;
  __shared__ float xs[CIN][LT + K - 1];
  int b = blockIdx.y;
  int l0 = blockIdx.x * LT;
  const int nth = COUT * G;
  const float* xb = x + b*CIN*Lin;
  for (int i = threadIdx.x; i < CIN*(LT + K - 1); i += nth) {
    int ci = i / (LT + K - 1), dl = i % (LT + K - 1);
    int l = l0 + dl;
    xs[ci][dl] = (l < Lin) ? xb[ci*Lin + l] : 0.f;
  }
  __syncthreads();
  int co = threadIdx.x % COUT;
  int gg = threadIdx.x / COUT;
  float acc[LG];
  #pragma unroll
  for (int j = 0; j < LG; ++j) acc[j] = 0.f;
  for (int ci = 0; ci < CIN; ++ci) {
    float xr[LG + K - 1];
    #pragma unroll
    for (int t = 0; t < LG + K - 1; ++t) xr[t] = xs[ci][gg*LG + t];
    #pragma unroll
    for (int k = 0; k < K; ++k) {
      float wv = wt[(ci*K + k)*COUT + co];
      #pragma unroll
      for (int j = 0; j < LG; ++j) acc[j] = fmaf(wv, xr[j + k], acc[j]);
    }
  }
  float bv = bias[co];
  if (!POOL) {
    float* yb = y + (b*COUT + co)*Lout;
    #pragma unroll
    for (int j = 0; j < LG; ++j) {
      int l = l0 + gg*LG + j;
      if (l < Lout) yb[l] = fmaxf(acc[j] + bv, 0.f);
    }
  } else {
    float m = 0.f;
    #pragma unroll
    for (int j = 0; j < LG; ++j) {
      int l = l0 + gg*LG + j;
      if (l < Lout) m = fmaxf(m, fmaxf(acc[j] + bv, 0.f));
    }
    atomicMax((unsigned int*)&y[b*COUT + co], __float_as_uint(m));
  }
}

// =================================================================
// generic row GEMM: y[n,c] = sum_k x[n,k] * W[k,c]
// =================================================================
__global__ void k_rowgemm(const float* __restrict__ x, const float* __restrict__ W,
                          float* __restrict__ y, long nrows, int K, int C) {
  long o = blockIdx.x*256L + threadIdx.x;
  if (o >= nrows * C) return;
  int n = (int)(o / C), c = (int)(o % C);
  const float* xr = x + (long)n * K;
  float acc = 0.f;
  for (int k = 0; k < K; ++k) acc = fmaf(xr[k], W[(long)k*C + c], acc);
  y[o] = acc;
}

// per-node attention terms: as[n,h] = sum_c h[n,h,c]*a_s[h,c]; same for ad
__global__ void k_attn_nodeterms(const float* __restrict__ h, const float* __restrict__ a_s,
                                 const float* __restrict__ a_d, float* __restrict__ as_o,
                                 float* __restrict__ ad_o, int H, int CH) {
  long t = blockIdx.x*256L + threadIdx.x;
  if (t >= (long)NN * H) return;
  int n = (int)(t / H), hh = (int)(t % H);
  const float* hr = h + ((long)n*H + hh)*CH;
  float s1 = 0.f, s2 = 0.f;
  for (int c = 0; c < CH; ++c) {
    float v = hr[c];
    s1 = fmaf(v, a_s[hh*CH + c], s1);
    s2 = fmaf(v, a_d[hh*CH + c], s2);
  }
  as_o[t] = s1; ad_o[t] = s2;
}

// per-edge attention logit with leaky_relu(0.2). e >= EE are self loops.
template<int H>
__global__ void k_edge_attn(const int* __restrict__ ei, const float* __restrict__ ea,
                            const float* __restrict__ asb, const float* __restrict__ adb,
                            const float* __restrict__ M, const float* __restrict__ aeself,
                            float* __restrict__ a_out) {
  long e = blockIdx.x*256L + threadIdx.x;
  if (e >= (long)EN) return;
  int s, d;
  float av[H];
  if (e < EE) {
    s = ei[e]; d = ei[EE + e];
    float er[5];
    #pragma unroll
    for (int j = 0; j < 5; ++j) er[j] = ea[e*5 + j];
    #pragma unroll
    for (int h = 0; h < H; ++h) {
      float t = 0.f;
      #pragma unroll
      for (int j = 0; j < 5; ++j) t = fmaf(er[j], M[j*H + h], t);
      av[h] = t;
    }
  } else {
    s = d = (int)(e - EE);
    #pragma unroll
    for (int h = 0; h < H; ++h) av[h] = aeself[h];
  }
  #pragma unroll
  for (int h = 0; h < H; ++h) {
    float v = asb[s*H + h] + adb[d*H + h] + av[h];
    a_out[e*H + h] = (v > 0.f) ? v : 0.2f * v;
  }
}

// ------------- CSR build -------------
__global__ void k_deg(const int* __restrict__ ei, int* __restrict__ deg) {
  long e = blockIdx.x*256L + threadIdx.x;
  if (e >= (long)EN) return;
  int d = (e < EE) ? ei[EE + e] : (int)(e - EE);
  atomicAdd(&deg[d], 1);
}

__global__ void k_scan(const int* __restrict__ deg, int* __restrict__ rowptr,
                       int* __restrict__ cursor) {
  __shared__ int ps[256];
  int tid = threadIdx.x;
  int base = tid * 128;           // 256*128 = 32768 = NN
  int s = 0;
  for (int i = 0; i < 128; ++i) s += deg[base + i];
  ps[tid] = s;
  __syncthreads();
  for (int off = 1; off < 256; off <<= 1) {
    int v = (tid >= off) ? ps[tid - off] : 0;
    __syncthreads();
    ps[tid] += v;
    __syncthreads();
  }
  int run = ps[tid] - s;          // exclusive prefix
  for (int i = 0; i < 128; ++i) {
    rowptr[base + i] = run;
    cursor[base + i] = run;
    run += deg[base + i];
  }
  if (tid == 255) rowptr[NN] = run;
}

__global__ void k_scatter(const int* __restrict__ ei, int* __restrict__ cursor,
                          int* __restrict__ csr_src, int* __restrict__ csr_eid) {
  long e = blockIdx.x*256L + threadIdx.x;
  if (e >= (long)EN) return;
  int s, d;
  if (e < EE) { s = ei[e]; d = ei[EE + e]; }
  else        { s = d = (int)(e - EE); }
  int p = atomicAdd(&cursor[d], 1);
  csr_src[p] = s;
  csr_eid[p] = (int)e;
}

// =================================================================
// GAT aggregation: wave per destination node. ACT: 0=elu, 1=relu
// =================================================================
template<int H, int CH, int ACT>
__global__ void k_gat_aggr(const int* __restrict__ rowptr, const int* __restrict__ csr_src,
                           const int* __restrict__ csr_eid, const float* __restrict__ a,
                           const float* __restrict__ hfeat, const float* __restrict__ bias,
                           float* __restrict__ out) {
  int wid = (int)((blockIdx.x*(long)blockDim.x + threadIdx.x) >> 6);
  int lane = threadIdx.x & 63;
  if (wid >= NN) return;
  int row0 = rowptr[wid], row1 = rowptr[wid + 1];
  constexpr int F = H * CH;
  constexpr int NJ = (F + 63) / 64;
  float amax[H], asum[H], rinv[H];
  #pragma unroll
  for (int h = 0; h < H; ++h) amax[h] = -1e30f;
  for (int p = row0 + lane; p < row1; p += 64) {
    int e = csr_eid[p];
    #pragma unroll
    for (int h = 0; h < H; ++h) amax[h] = fmaxf(amax[h], a[(long)e*H + h]);
  }
  #pragma unroll
  for (int h = 0; h < H; ++h)
    for (int off = 1; off < 64; off <<= 1) amax[h] = fmaxf(amax[h], __shfl_xor(amax[h], off, 64));
  #pragma unroll
  for (int h = 0; h < H; ++h) asum[h] = 0.f;
  for (int p = row0 + lane; p < row1; p += 64) {
    int e = csr_eid[p];
    #pragma unroll
    for (int h = 0; h < H; ++h) asum[h] += __expf(a[(long)e*H + h] - amax[h]);
  }
  #pragma unroll
  for (int h = 0; h < H; ++h) {
    for (int off = 1; off < 64; off <<= 1) asum[h] += __shfl_xor(asum[h], off, 64);
    rinv[h] = 1.f / (asum[h] + 1e-16f);
  }
  float acc[NJ];
  #pragma unroll
  for (int j = 0; j < NJ; ++j) acc[j] = 0.f;
  for (int p = row0; p < row1; ++p) {
    int e = csr_eid[p];
    int s = csr_src[p];
    const float* hr = hfeat + (long)s * F;
    #pragma unroll
    for (int j = 0; j < NJ; ++j) {
      int idx = j*64 + lane;
      if ((F % 64 == 0) || idx < F) {
        int h = idx / CH;
        float al = __expf(a[(long)e*H + h] - amax[h]) * rinv[h];
        acc[j] = fmaf(al, hr[idx], acc[j]);
      }
    }
  }
  float* orow = out + (long)wid * F;
  #pragma unroll
  for (int j = 0; j < NJ; ++j) {
    int idx = j*64 + lane;
    if ((F % 64 == 0) || idx < F) {
      float v = acc[j] + bias[idx];
      if (ACT == 0) v = (v > 0.f) ? v : expm1f(v);
      else          v = fmaxf(v, 0.f);
      orow[idx] = v;
    }
  }
}

// graph max pool (relu'd input >= 0, pooled pre-zeroed)
__global__ void k_pool(const float* __restrict__ g2o, const int* __restrict__ batch,
                       unsigned int* __restrict__ pooled) {
  long o = blockIdx.x*256L + threadIdx.x;
  if (o >= (long)NN * 96) return;
  int n = (int)(o / 96), c = (int)(o % 96);
  atomicMax(&pooled[batch[n]*96 + c], __float_as_uint(g2o[o]));
}

// =================================================================
// tiled GEMM with bias + optional relu: y[r,c] = act(b[c] + sum_k x[r,k]W[k,c])
// block: 256 threads (one col each), RT rows per block; dyn LDS = RT*K floats
// =================================================================
template<int RT>
__global__ void k_gemm_bias_act(const float* __restrict__ x, const float* __restrict__ W,
                                const float* __restrict__ bias, float* __restrict__ y,
                                int K, int C, int act) {
  extern __shared__ float xs[];
  int c0 = blockIdx.x * 256;
  int r0 = blockIdx.y * RT;
  for (int i = threadIdx.x; i < RT*K; i += 256) {
    int r = i / K, k = i % K;
    xs[i] = x[(long)(r0 + r)*K + k];
  }
  __syncthreads();
  int c = c0 + threadIdx.x;
  if (c >= C) return;
  float acc[RT];
  #pragma unroll
  for (int r = 0; r < RT; ++r) acc[r] = 0.f;
  for (int k = 0; k < K; ++k) {
    float wv = W[(long)k*C + c];
    #pragma unroll
    for (int r = 0; r < RT; ++r) acc[r] = fmaf(xs[r*K + k], wv, acc[r]);
  }
  float bv = bias[c];
  #pragma unroll
  for (int r = 0; r < RT; ++r) {
    float v = acc[r] + bv;
    if (act) v = fmaxf(v, 0.f);
    y[(long)(r0 + r)*C + c] = v;
  }
}

__global__ void k_concat(const float* __restrict__ cd, const float* __restrict__ ct,
                         const float* __restrict__ gfc, float* __restrict__ xc) {
  int t = blockIdx.x*256 + threadIdx.x;
  if (t >= NB*288) return;
  int b = t / 288, c = t % 288;
  float v = (c < 96) ? cd[b*96 + c] : (c < 192) ? ct[b*96 + (c-96)] : gfc[b*96 + (c-192)];
  xc[t] = v;
}

// final 512-dot per row: out[b] = sum_k x[b,k]*w[k] + b0
__global__ void k_final(const float* __restrict__ x, const float* __restrict__ w,
                        const float* __restrict__ b, float* __restrict__ out) {
  int wid = (int)((blockIdx.x*256L + threadIdx.x) >> 6);
  int lane = threadIdx.x & 63;
  if (wid >= NB) return;
  const float* xr = x + (long)wid*512;
  float s = 0.f;
  for (int k = lane; k < 512; k += 64) s = fmaf(xr[k], w[k], s);
  for (int off = 1; off < 64; off <<= 1) s += __shfl_xor(s, off, 64);
  if (lane == 0) out[wid] = s + b[0];
}

// =================================================================
extern "C" void kernel_launch(void* const* d_in, const int* in_sizes, int n_in,
                              void* d_out, int out_size, void* d_ws, size_t ws_size,
                              hipStream_t stream) {
  const int*   xd     = (const int*)  d_in[0];
  const int*   xt     = (const int*)  d_in[1];
  const float* ax     = (const float*)d_in[2];
  const int*   ei     = (const int*)  d_in[3];
  const float* ea     = (const float*)d_in[4];
  const int*   batch  = (const int*)  d_in[5];
  const float* emb_xd = (const float*)d_in[6];
  const float* emb_xt = (const float*)d_in[7];
  const float* wd1 = (const float*)d_in[8];  const float* bd1 = (const float*)d_in[9];
  const float* wd2 = (const float*)d_in[10]; const float* bd2 = (const float*)d_in[11];
  const float* wd3 = (const float*)d_in[12]; const float* bd3 = (const float*)d_in[13];
  const float* wt1 = (const float*)d_in[14]; const float* bt1 = (const float*)d_in[15];
  const float* wt2 = (const float*)d_in[16]; const float* bt2 = (const float*)d_in[17];
  const float* wt3 = (const float*)d_in[18]; const float* bt3 = (const float*)d_in[19];
  const float* g1_w  = (const float*)d_in[20]; const float* g1_as = (const float*)d_in[21];
  const float* g1_ad = (const float*)d_in[22]; const float* g1_we = (const float*)d_in[23];
  const float* g1_ae = (const float*)d_in[24]; const float* g1_b  = (const float*)d_in[25];
  const float* g2_w  = (const float*)d_in[26]; const float* g2_as = (const float*)d_in[27];
  const float* g2_ad = (const float*)d_in[28]; const float* g2_we = (const float*)d_in[29];
  const float* g2_ae = (const float*)d_in[30]; const float* g2_b  = (const float*)d_in[31];
  const float* fc1_w = (const float*)d_in[32]; const float* fc1_b = (const float*)d_in[33];
  const float* c1_w = (const float*)d_in[34]; const float* c1_b = (const float*)d_in[35];
  const float* c2_w = (const float*)d_in[36]; const float* c2_b = (const float*)d_in[37];
  const float* c3_w = (const float*)d_in[38]; const float* c3_b = (const float*)d_in[39];
  const float* c4_w = (const float*)d_in[40]; const float* c4_b = (const float*)d_in[41];
  float* out = (float*)d_out;

  char* ws = (char*)d_ws;
  auto F = [&](size_t off) { return (float*)(ws + off); };
  auto I = [&](size_t off) { return (int*)(ws + off); };
  auto U = [&](size_t off) { return (unsigned int*)(ws + off); };

  // ---- zero-init the atomically-updated buffers ----
  hipMemsetAsync(ws + OFF_CB,   0, 64*sizeof(float), stream);
  hipMemsetAsync(ws + OFF_DEG,  0, NN*sizeof(int),   stream);
  hipMemsetAsync(ws + OFF_CD,   0, NB*96*sizeof(float), stream);
  hipMemsetAsync(ws + OFF_CT,   0, NB*96*sizeof(float), stream);
  hipMemsetAsync(ws + OFF_POOL, 0, NB*96*sizeof(float), stream);

  // ---- tables ----
  k_tables<<<(8320 + 6656 + 30 + 255)/256, 256, 0, stream>>>(
      wd1, emb_xd, wt1, emb_xt, g1_we, g1_ae, g2_we, g2_ae,
      F(OFF_FD), F(OFF_FT), F(OFF_CB));
  k_easum<<<256, 256, 0, stream>>>(ea, F(OFF_CB));
  k_finalize<<<1, 64, 0, stream>>>(F(OFF_CB));

  // ---- weight transposes ----
  k_wtrans<<<(8192 + 255)/256, 256, 0, stream>>>(wd2, F(OFF_WD2T), 64, 32, 4);
  k_wtrans<<<(24576 + 255)/256, 256, 0, stream>>>(wd3, F(OFF_WD3T), 96, 64, 4);
  k_wtrans<<<(16384 + 255)/256, 256, 0, stream>>>(wt2, F(OFF_WT2T), 64, 32, 8);
  k_wtrans<<<(49152 + 255)/256, 256, 0, stream>>>(wt3, F(OFF_WT3T), 96, 64, 8);

  // ---- drug conv branch: L=100 -> 97 -> 94 -> 91 -> maxpool ----
  k_conv1_lut<4,65,32><<<dim3((32*97 + 255)/256, NB), 256, 0, stream>>>(
      xd, F(OFF_FD), bd1, F(OFF_A), 100, 97);
  k_conv<32,4,64,4,16,false><<<dim3((94 + 63)/64, NB), 256, 0, stream>>>(
      F(OFF_A), F(OFF_WD2T), bd2, F(OFF_B), 97, 94);
  k_conv<64,4,96,2,16,true><<<dim3((91 + 31)/32, NB), 192, 0, stream>>>(
      F(OFF_B), F(OFF_WD3T), bd3, F(OFF_CD), 94, 91);

  // ---- target conv branch: L=1000 -> 993 -> 986 -> 979 -> maxpool ----
  k_conv1_lut<8,26,32><<<dim3((32*993 + 255)/256, NB), 256, 0, stream>>>(
      xt, F(OFF_FT), bt1, F(OFF_A), 1000, 993);
  k_conv<32,8,64,4,16,false><<<dim3((986 + 63)/64, NB), 256, 0, stream>>>(
      F(OFF_A), F(OFF_WT2T), bt2, F(OFF_B), 993, 986);
  k_conv<64,8,96,2,16,true><<<dim3((979 + 31)/32, NB), 192, 0, stream>>>(
      F(OFF_B), F(OFF_WT3T), bt3, F(OFF_CT), 986, 979);

  // ---- GAT layer 1 ----
  k_rowgemm<<<(int)(((long)NN*320 + 255)/256), 256, 0, stream>>>(
      ax, g1_w, F(OFF_A), NN, 24, 320);                       // h1 -> A
  k_attn_nodeterms<<<(NN*5 + 255)/256, 256, 0, stream>>>(
      F(OFF_A), g1_as, g1_ad, F(OFF_AS1), F(OFF_AD1), 5, 64);
  k_edge_attn<5><<<(EN + 255)/256, 256, 0, stream>>>(
      ei, ea, F(OFF_AS1), F(OFF_AD1), F(OFF_CB), F(OFF_CB) + 35, F(OFF_C));  // a1 -> C

  k_deg<<<(EN + 255)/256, 256, 0, stream>>>(ei, I(OFF_DEG));
  k_scan<<<1, 256, 0, stream>>>(I(OFF_DEG), I(OFF_ROWP), I(OFF_CUR));
  k_scatter<<<(EN + 255)/256, 256, 0, stream>>>(ei, I(OFF_CUR), I(OFF_CSRS), I(OFF_CSRE));

  k_gat_aggr<5,64,0><<<NN/4, 256, 0, stream>>>(
      I(OFF_ROWP), I(OFF_CSRS), I(OFF_CSRE), F(OFF_C), F(OFF_A), g1_b, F(OFF_B)); // g1o -> B

  // ---- GAT layer 2 ----
  k_rowgemm<<<(int)(((long)NN*96 + 255)/256), 256, 0, stream>>>(
      F(OFF_B), g2_w, F(OFF_C), NN, 320, 96);                 // h2 -> C (a1 dead)
  k_attn_nodeterms<<<(NN + 255)/256, 256, 0, stream>>>(
      F(OFF_C), g2_as, g2_ad, F(OFF_AS2), F(OFF_AD2), 1, 96);
  k_edge_attn<1><<<(EN + 255)/256, 256, 0, stream>>>(
      ei, ea, F(OFF_AS2), F(OFF_AD2), F(OFF_CB) + 25, F(OFF_CB) + 40, F(OFF_A2));
  k_gat_aggr<1,96,1><<<NN/4, 256, 0, stream>>>(
      I(OFF_ROWP), I(OFF_CSRS), I(OFF_CSRE), F(OFF_A2), F(OFF_C), g2_b, F(OFF_G2O));

  // ---- graph pool + fc1 ----
  k_pool<<<(int)(((long)NN*96 + 255)/256), 256, 0, stream>>>(
      F(OFF_G2O), batch, U(OFF_POOL));
  k_gemm_bias_act<8><<<dim3(1, NB/8), 256, 8*96*4, stream>>>(
      F(OFF_POOL), fc1_w, fc1_b, F(OFF_GFC), 96, 96, 1);

  // ---- concat + MLP head ----
  k_concat<<<(NB*288 + 255)/256, 256, 0, stream>>>(
      F(OFF_CD), F(OFF_CT), F(OFF_GFC), F(OFF_XC));
  k_gemm_bias_act<8><<<dim3(4, NB/8), 256, 8*288*4, stream>>>(
      F(OFF_XC), c1_w, c1_b, F(OFF_M1B), 288, 1024, 1);
  k_gemm_bias_act<8><<<dim3(4, NB/8), 256, 8*1024*4, stream>>>(
      F(OFF_M1B), c2_w, c2_b, F(OFF_M2B), 1024, 1024, 1);
  k_gemm_bias_act<8><<<dim3(2, NB/8), 256, 8*1024*4, stream>>>(
      F(OFF_M2B), c3_w, c3_b, F(OFF_M3B), 1024, 512, 1);
  k_final<<<(NB*64 + 255)/256, 256, 0, stream>>>(F(OFF_M3B), c4_w, c4_b, out);
}

// Round 2
// 1550.326 us; speedup vs baseline: 1.2169x; 1.2169x over previous
//
#include <hip/hip_runtime.h>

// ---------------- problem constants ----------------
constexpr int NN = 32768;      // nodes
constexpr int EE = 524288;     // edges
constexpr int NB = 256;        // graphs / batch
constexpr int EN = EE + NN;    // edges + self loops

// ---------------- workspace layout (bytes) ----------------
constexpr size_t MB = 1ull << 20;
constexpr size_t OFF_A    = 0;        // 48MB: conv y1 (drug/target), later h1 [N,320]
constexpr size_t OFF_B    = 48*MB;    // 68MB: conv y2, later g1o [N,320]
constexpr size_t OFF_C    = 116*MB;   // 14MB: a1 [EN,5], later h2 [N,96]
constexpr size_t OFF_CSRS = 130*MB;   // csr_src [EN]
constexpr size_t OFF_CSRE = 133*MB;   // csr_eid [EN]
constexpr size_t OFF_ROWP = 136*MB;   // rowptr [N+1]
constexpr size_t OFF_DEG  = 137*MB;   // deg [N]
constexpr size_t OFF_CUR  = 138*MB;   // cursor [N]
constexpr size_t OFF_A2   = 139*MB;   // a2 [EN]
constexpr size_t OFF_G2O  = 142*MB;   // g2o [N,96]
constexpr size_t OFF_AS1  = 155*MB;   // [N,5]
constexpr size_t OFF_AD1  = 156*MB;
constexpr size_t OFF_AS2  = 157*MB;   // [N]
constexpr size_t OFF_AD2  = 158*MB;
constexpr size_t OFF_CD   = 159*MB;   // [256,96] pooled drug conv
constexpr size_t OFF_CT   = 160*MB;   // [256,96] pooled target conv
constexpr size_t OFF_POOL = 161*MB;   // [256,96] graph pool
constexpr size_t OFF_GFC  = 162*MB;   // [256,96]
constexpr size_t OFF_XC   = 163*MB;   // [256,288]
constexpr size_t OFF_M1B  = 164*MB;   // [256,1024]
constexpr size_t OFF_M2B  = 165*MB;   // [256,1024]
constexpr size_t OFF_M3B  = 166*MB;   // [256,512]
constexpr size_t OFF_FD   = 167*MB;   // F table drug [32][4][65]
constexpr size_t OFF_FT   = 168*MB;   // F table target [32][8][26]
constexpr size_t OFF_WD2T = 169*MB;
constexpr size_t OFF_WD3T = 170*MB;
constexpr size_t OFF_WT2T = 171*MB;
constexpr size_t OFF_WT3T = 172*MB;
constexpr size_t OFF_CB   = 173*MB;   // const block: [0:25]=M1, [25:30]=M2, [30:35]=easum,
                                      // [35:40]=aeself1, [40]=ae2self, [41:46]=eamean

// =================================================================
// Tiny precompute tables: F_drug, F_target, M1[j][h], M2[j]
// =================================================================
__global__ void k_tables(const float* __restrict__ wd1, const float* __restrict__ emb_xd,
                         const float* __restrict__ wt1, const float* __restrict__ emb_xt,
                         const float* __restrict__ g1we, const float* __restrict__ g1ae,
                         const float* __restrict__ g2we, const float* __restrict__ g2ae,
                         float* __restrict__ Fd, float* __restrict__ Ft,
                         float* __restrict__ CB) {
  int t = blockIdx.x * 256 + threadIdx.x;
  const int NFd = 32*4*65, NFt = 32*8*26;
  if (t < NFd) {                       // Fd[co][k][v]
    int v = t % 65; int ck = t / 65; int k = ck & 3; int co = ck >> 2;
    float s = 0.f;
    for (int ci = 0; ci < 128; ++ci)
      s = fmaf(wd1[(co*128 + ci)*4 + k], emb_xd[v*128 + ci], s);
    Fd[t] = s;
  } else if (t < NFd + NFt) {          // Ft[co][k][v]
    int u = t - NFd;
    int v = u % 26; int ck = u / 26; int k = ck & 7; int co = ck >> 3;
    float s = 0.f;
    for (int ci = 0; ci < 128; ++ci)
      s = fmaf(wt1[(co*128 + ci)*8 + k], emb_xt[v*128 + ci], s);
    Ft[u] = s;
  } else if (t < NFd + NFt + 25) {     // M1[j][h]
    int u = t - NFd - NFt; int h = u % 5, j = u / 5;
    float s = 0.f;
    for (int c = 0; c < 64; ++c)
      s = fmaf(g1we[j*320 + h*64 + c], g1ae[h*64 + c], s);
    CB[j*5 + h] = s;
  } else if (t < NFd + NFt + 30) {     // M2[j]
    int j = t - NFd - NFt - 25;
    float s = 0.f;
    for (int c = 0; c < 96; ++c)
      s = fmaf(g2we[j*96 + c], g2ae[c], s);
    CB[25 + j] = s;
  }
}

// sum of ea columns -> CB[30..34] (pre-zeroed)
__global__ void k_easum(const float* __restrict__ ea, float* __restrict__ CB) {
  float acc[5] = {0,0,0,0,0};
  for (long e = blockIdx.x*256L + threadIdx.x; e < EE; e += 256L*gridDim.x) {
    #pragma unroll
    for (int j = 0; j < 5; ++j) acc[j] += ea[e*5 + j];
  }
  #pragma unroll
  for (int j = 0; j < 5; ++j)
    for (int off = 1; off < 64; off <<= 1) acc[j] += __shfl_xor(acc[j], off, 64);
  if ((threadIdx.x & 63) == 0) {
    #pragma unroll
    for (int j = 0; j < 5; ++j) atomicAdd(&CB[30 + j], acc[j]);
  }
}

// eamean, aeself1[h], ae2self
__global__ void k_finalize(float* __restrict__ CB) {
  if (blockIdx.x == 0 && threadIdx.x == 0) {
    float em[5];
    for (int j = 0; j < 5; ++j) { em[j] = CB[30 + j] / (float)EE; CB[41 + j] = em[j]; }
    for (int h = 0; h < 5; ++h) {
      float s = 0.f;
      for (int j = 0; j < 5; ++j) s = fmaf(em[j], CB[j*5 + h], s);
      CB[35 + h] = s;
    }
    float s = 0.f;
    for (int j = 0; j < 5; ++j) s = fmaf(em[j], CB[25 + j], s);
    CB[40] = s;
  }
}

// =================================================================
// conv1 via lookup table: y[b,co,l] = relu(b[co] + sum_k F[co,k,idx[b,l+k]])
// =================================================================
template<int K, int V, int COUT>
__global__ void k_conv1_lut(const int* __restrict__ idx, const float* __restrict__ F,
                            const float* __restrict__ bias, float* __restrict__ y,
                            int L, int Lout) {
  __shared__ float Fs[COUT*K*V];
  __shared__ float bs[COUT];
  int b = blockIdx.y;
  for (int i = threadIdx.x; i < COUT*K*V; i += blockDim.x) Fs[i] = F[i];
  for (int i = threadIdx.x; i < COUT; i += blockDim.x) bs[i] = bias[i];
  __syncthreads();
  int o = blockIdx.x * blockDim.x + threadIdx.x;
  if (o >= COUT * Lout) return;
  int co = o / Lout, l = o % Lout;
  const int* ib = idx + b*L + l;
  float acc = bs[co];
  #pragma unroll
  for (int k = 0; k < K; ++k) acc += Fs[(co*K + k)*V + ib[k]];
  y[(b*COUT + co)*Lout + l] = fmaxf(acc, 0.f);
}

// weight transpose [co][ci][k] -> [ci][k][co]
__global__ void k_wtrans(const float* __restrict__ w, float* __restrict__ wt,
                         int COUT, int CIN, int K) {
  int t = blockIdx.x*256 + threadIdx.x;
  if (t >= COUT*CIN*K) return;
  int k = t % K; int ci = (t / K) % CIN; int co = t / (K*CIN);
  wt[(ci*K + k)*COUT + co] = w[t];
}

// =================================================================
// direct conv, register-tiled; optional fused global-max-pool (relu >= 0)
// =================================================================
template<int CIN, int K, int COUT, int G, int LG, bool POOL>
__global__ void k_conv(const float* __restrict__ x, const float* __restrict__ wt,
                       const float* __restrict__ bias, float* __restrict__ y,
                       int Lin, int Lout) {
  constexpr int LT = G * LG;
  __shared__ float xs[CIN][LT + K - 1];
  int b = blockIdx.y;
  int l0 = blockIdx.x * LT;
  const int nth = COUT * G;
  const float* xb = x + b*CIN*Lin;
  for (int i = threadIdx.x; i < CIN*(LT + K - 1); i += nth) {
    int ci = i / (LT + K - 1), dl = i % (LT + K - 1);
    int l = l0 + dl;
    xs[ci][dl] = (l < Lin) ? xb[ci*Lin + l] : 0.f;
  }
  __syncthreads();
  int co = threadIdx.x % COUT;
  int gg = threadIdx.x / COUT;
  float acc[LG];
  #pragma unroll
  for (int j = 0; j < LG; ++j) acc[j] = 0.f;
  for (int ci = 0; ci < CIN; ++ci) {
    float xr[LG + K - 1];
    #pragma unroll
    for (int t = 0; t < LG + K - 1; ++t) xr[t] = xs[ci][gg*LG + t];
    #pragma unroll
    for (int k = 0; k < K; ++k) {
      float wv = wt[(ci*K + k)*COUT + co];
      #pragma unroll
      for (int j = 0; j < LG; ++j) acc[j] = fmaf(wv, xr[j + k], acc[j]);
    }
  }
  float bv = bias[co];
  if (!POOL) {
    float* yb = y + (b*COUT + co)*Lout;
    #pragma unroll
    for (int j = 0; j < LG; ++j) {
      int l = l0 + gg*LG + j;
      if (l < Lout) yb[l] = fmaxf(acc[j] + bv, 0.f);
    }
  } else {
    float m = 0.f;
    #pragma unroll
    for (int j = 0; j < LG; ++j) {
      int l = l0 + gg*LG + j;
      if (l < Lout) m = fmaxf(m, fmaxf(acc[j] + bv, 0.f));
    }
    atomicMax((unsigned int*)&y[b*COUT + co], __float_as_uint(m));
  }
}

// =================================================================
// register-tiled GEMM: Y[m,c] = act(bias[c] + sum_k X[m,k]*W[k,c])
// grid (C/BN, M/BM), 256 threads = (BM/TM) x (BN/TN). Requires M%BM==0, C%BN==0.
// =================================================================
template<int BM, int BN, int BK, int TM, int TN, bool BIAS, bool RELU>
__global__ void k_gemm(const float* __restrict__ X, const float* __restrict__ W,
                       const float* __restrict__ bias, float* __restrict__ Y,
                       int K, int C) {
  constexpr int NTH = (BM/TM)*(BN/TN);
  static_assert(NTH == 256, "block must be 256 threads");
  __shared__ float xs[BK][BM + 1];
  __shared__ float wsm[BK][BN];
  const int m0 = blockIdx.y * BM;
  const int c0 = blockIdx.x * BN;
  const int tn = threadIdx.x % (BN/TN);
  const int tm = threadIdx.x / (BN/TN);
  float acc[TM][TN];
  #pragma unroll
  for (int i = 0; i < TM; ++i)
    #pragma unroll
    for (int j = 0; j < TN; ++j) acc[i][j] = 0.f;

  for (int k0 = 0; k0 < K; k0 += BK) {
    #pragma unroll
    for (int i = threadIdx.x; i < BM*BK; i += NTH) {
      int m = i / BK, k = i % BK;
      xs[k][m] = X[(long)(m0 + m)*K + k0 + k];
    }
    #pragma unroll
    for (int i = threadIdx.x; i < BK*BN; i += NTH) {
      int k = i / BN, c = i % BN;
      wsm[k][c] = W[(long)(k0 + k)*C + c0 + c];
    }
    __syncthreads();
    #pragma unroll
    for (int k = 0; k < BK; ++k) {
      float xv[TM], wv[TN];
      #pragma unroll
      for (int i = 0; i < TM; ++i) xv[i] = xs[k][tm*TM + i];
      #pragma unroll
      for (int j = 0; j < TN; ++j) wv[j] = wsm[k][tn*TN + j];
      #pragma unroll
      for (int i = 0; i < TM; ++i)
        #pragma unroll
        for (int j = 0; j < TN; ++j) acc[i][j] = fmaf(xv[i], wv[j], acc[i][j]);
    }
    __syncthreads();
  }
  #pragma unroll
  for (int i = 0; i < TM; ++i) {
    float* yr = Y + (long)(m0 + tm*TM + i)*C + c0 + tn*TN;
    #pragma unroll
    for (int j = 0; j < TN; ++j) {
      float v = acc[i][j];
      if (BIAS) v += bias[c0 + tn*TN + j];
      if (RELU) v = fmaxf(v, 0.f);
      yr[j] = v;
    }
  }
}

// per-node attention terms: as[n,h] = sum_c h[n,h,c]*a_s[h,c]; same for ad
__global__ void k_attn_nodeterms(const float* __restrict__ h, const float* __restrict__ a_s,
                                 const float* __restrict__ a_d, float* __restrict__ as_o,
                                 float* __restrict__ ad_o, int H, int CH) {
  long t = blockIdx.x*256L + threadIdx.x;
  if (t >= (long)NN * H) return;
  int n = (int)(t / H), hh = (int)(t % H);
  const float* hr = h + ((long)n*H + hh)*CH;
  float s1 = 0.f, s2 = 0.f;
  for (int c = 0; c < CH; ++c) {
    float v = hr[c];
    s1 = fmaf(v, a_s[hh*CH + c], s1);
    s2 = fmaf(v, a_d[hh*CH + c], s2);
  }
  as_o[t] = s1; ad_o[t] = s2;
}

// per-edge attention logit with leaky_relu(0.2). e >= EE are self loops.
template<int H>
__global__ void k_edge_attn(const int* __restrict__ ei, const float* __restrict__ ea,
                            const float* __restrict__ asb, const float* __restrict__ adb,
                            const float* __restrict__ M, const float* __restrict__ aeself,
                            float* __restrict__ a_out) {
  long e = blockIdx.x*256L + threadIdx.x;
  if (e >= (long)EN) return;
  int s, d;
  float av[H];
  if (e < EE) {
    s = ei[e]; d = ei[EE + e];
    float er[5];
    #pragma unroll
    for (int j = 0; j < 5; ++j) er[j] = ea[e*5 + j];
    #pragma unroll
    for (int h = 0; h < H; ++h) {
      float t = 0.f;
      #pragma unroll
      for (int j = 0; j < 5; ++j) t = fmaf(er[j], M[j*H + h], t);
      av[h] = t;
    }
  } else {
    s = d = (int)(e - EE);
    #pragma unroll
    for (int h = 0; h < H; ++h) av[h] = aeself[h];
  }
  #pragma unroll
  for (int h = 0; h < H; ++h) {
    float v = asb[s*H + h] + adb[d*H + h] + av[h];
    a_out[e*H + h] = (v > 0.f) ? v : 0.2f * v;
  }
}

// ------------- CSR build -------------
__global__ void k_deg(const int* __restrict__ ei, int* __restrict__ deg) {
  long e = blockIdx.x*256L + threadIdx.x;
  if (e >= (long)EN) return;
  int d = (e < EE) ? ei[EE + e] : (int)(e - EE);
  atomicAdd(&deg[d], 1);
}

__global__ void k_scan(const int* __restrict__ deg, int* __restrict__ rowptr,
                       int* __restrict__ cursor) {
  __shared__ int ps[256];
  int tid = threadIdx.x;
  int base = tid * 128;           // 256*128 = 32768 = NN
  int s = 0;
  for (int i = 0; i < 128; ++i) s += deg[base + i];
  ps[tid] = s;
  __syncthreads();
  for (int off = 1; off < 256; off <<= 1) {
    int v = (tid >= off) ? ps[tid - off] : 0;
    __syncthreads();
    ps[tid] += v;
    __syncthreads();
  }
  int run = ps[tid] - s;          // exclusive prefix
  for (int i = 0; i < 128; ++i) {
    rowptr[base + i] = run;
    cursor[base + i] = run;
    run += deg[base + i];
  }
  if (tid == 255) rowptr[NN] = run;
}

__global__ void k_scatter(const int* __restrict__ ei, int* __restrict__ cursor,
                          int* __restrict__ csr_src, int* __restrict__ csr_eid) {
  long e = blockIdx.x*256L + threadIdx.x;
  if (e >= (long)EN) return;
  int s, d;
  if (e < EE) { s = ei[e]; d = ei[EE + e]; }
  else        { s = d = (int)(e - EE); }
  int p = atomicAdd(&cursor[d], 1);
  csr_src[p] = s;
  csr_eid[p] = (int)e;
}

// =================================================================
// GAT aggregation: wave per destination node. ACT: 0=elu, 1=relu
// =================================================================
template<int H, int CH, int ACT>
__global__ void k_gat_aggr(const int* __restrict__ rowptr, const int* __restrict__ csr_src,
                           const int* __restrict__ csr_eid, const float* __restrict__ a,
                           const float* __restrict__ hfeat, const float* __restrict__ bias,
                           float* __restrict__ out) {
  int wid = (int)((blockIdx.x*(long)blockDim.x + threadIdx.x) >> 6);
  int lane = threadIdx.x & 63;
  if (wid >= NN) return;
  int row0 = rowptr[wid], row1 = rowptr[wid + 1];
  constexpr int F = H * CH;
  constexpr int NJ = (F + 63) / 64;
  float amax[H], asum[H], rinv[H];
  #pragma unroll
  for (int h = 0; h < H; ++h) amax[h] = -1e30f;
  for (int p = row0 + lane; p < row1; p += 64) {
    int e = csr_eid[p];
    #pragma unroll
    for (int h = 0; h < H; ++h) amax[h] = fmaxf(amax[h], a[(long)e*H + h]);
  }
  #pragma unroll
  for (int h = 0; h < H; ++h)
    for (int off = 1; off < 64; off <<= 1) amax[h] = fmaxf(amax[h], __shfl_xor(amax[h], off, 64));
  #pragma unroll
  for (int h = 0; h < H; ++h) asum[h] = 0.f;
  for (int p = row0 + lane; p < row1; p += 64) {
    int e = csr_eid[p];
    #pragma unroll
    for (int h = 0; h < H; ++h) asum[h] += __expf(a[(long)e*H + h] - amax[h]);
  }
  #pragma unroll
  for (int h = 0; h < H; ++h) {
    for (int off = 1; off < 64; off <<= 1) asum[h] += __shfl_xor(asum[h], off, 64);
    rinv[h] = 1.f / (asum[h] + 1e-16f);
  }
  float acc[NJ];
  #pragma unroll
  for (int j = 0; j < NJ; ++j) acc[j] = 0.f;
  for (int p = row0; p < row1; ++p) {
    int e = csr_eid[p];
    int s = csr_src[p];
    const float* hr = hfeat + (long)s * F;
    #pragma unroll
    for (int j = 0; j < NJ; ++j) {
      int idx = j*64 + lane;
      if ((F % 64 == 0) || idx < F) {
        int h = idx / CH;
        float al = __expf(a[(long)e*H + h] - amax[h]) * rinv[h];
        acc[j] = fmaf(al, hr[idx], acc[j]);
      }
    }
  }
  float* orow = out + (long)wid * F;
  #pragma unroll
  for (int j = 0; j < NJ; ++j) {
    int idx = j*64 + lane;
    if ((F % 64 == 0) || idx < F) {
      float v = acc[j] + bias[idx];
      if (ACT == 0) v = (v > 0.f) ? v : expm1f(v);
      else          v = fmaxf(v, 0.f);
      orow[idx] = v;
    }
  }
}

// graph max pool (relu'd input >= 0, pooled pre-zeroed)
__global__ void k_pool(const float* __restrict__ g2o, const int* __restrict__ batch,
                       unsigned int* __restrict__ pooled) {
  long o = blockIdx.x*256L + threadIdx.x;
  if (o >= (long)NN * 96) return;
  int n = (int)(o / 96), c = (int)(o % 96);
  atomicMax(&pooled[batch[n]*96 + c], __float_as_uint(g2o[o]));
}

__global__ void k_concat(const float* __restrict__ cd, const float* __restrict__ ct,
                         const float* __restrict__ gfc, float* __restrict__ xc) {
  int t = blockIdx.x*256 + threadIdx.x;
  if (t >= NB*288) return;
  int b = t / 288, c = t % 288;
  float v = (c < 96) ? cd[b*96 + c] : (c < 192) ? ct[b*96 + (c-96)] : gfc[b*96 + (c-192)];
  xc[t] = v;
}

// final 512-dot per row: out[b] = sum_k x[b,k]*w[k] + b0
__global__ void k_final(const float* __restrict__ x, const float* __restrict__ w,
                        const float* __restrict__ b, float* __restrict__ out) {
  int wid = (int)((blockIdx.x*256L + threadIdx.x) >> 6);
  int lane = threadIdx.x & 63;
  if (wid >= NB) return;
  const float* xr = x + (long)wid*512;
  float s = 0.f;
  for (int k = lane; k < 512; k += 64) s = fmaf(xr[k], w[k], s);
  for (int off = 1; off < 64; off <<= 1) s += __shfl_xor(s, off, 64);
  if (lane == 0) out[wid] = s + b[0];
}

// =================================================================
extern "C" void kernel_launch(void* const* d_in, const int* in_sizes, int n_in,
                              void* d_out, int out_size, void* d_ws, size_t ws_size,
                              hipStream_t stream) {
  const int*   xd     = (const int*)  d_in[0];
  const int*   xt     = (const int*)  d_in[1];
  const float* ax     = (const float*)d_in[2];
  const int*   ei     = (const int*)  d_in[3];
  const float* ea     = (const float*)d_in[4];
  const int*   batch  = (const int*)  d_in[5];
  const float* emb_xd = (const float*)d_in[6];
  const float* emb_xt = (const float*)d_in[7];
  const float* wd1 = (const float*)d_in[8];  const float* bd1 = (const float*)d_in[9];
  const float* wd2 = (const float*)d_in[10]; const float* bd2 = (const float*)d_in[11];
  const float* wd3 = (const float*)d_in[12]; const float* bd3 = (const float*)d_in[13];
  const float* wt1 = (const float*)d_in[14]; const float* bt1 = (const float*)d_in[15];
  const float* wt2 = (const float*)d_in[16]; const float* bt2 = (const float*)d_in[17];
  const float* wt3 = (const float*)d_in[18]; const float* bt3 = (const float*)d_in[19];
  const float* g1_w  = (const float*)d_in[20]; const float* g1_as = (const float*)d_in[21];
  const float* g1_ad = (const float*)d_in[22]; const float* g1_we = (const float*)d_in[23];
  const float* g1_ae = (const float*)d_in[24]; const float* g1_b  = (const float*)d_in[25];
  const float* g2_w  = (const float*)d_in[26]; const float* g2_as = (const float*)d_in[27];
  const float* g2_ad = (const float*)d_in[28]; const float* g2_we = (const float*)d_in[29];
  const float* g2_ae = (const float*)d_in[30]; const float* g2_b  = (const float*)d_in[31];
  const float* fc1_w = (const float*)d_in[32]; const float* fc1_b = (const float*)d_in[33];
  const float* c1_w = (const float*)d_in[34]; const float* c1_b = (const float*)d_in[35];
  const float* c2_w = (const float*)d_in[36]; const float* c2_b = (const float*)d_in[37];
  const float* c3_w = (const float*)d_in[38]; const float* c3_b = (const float*)d_in[39];
  const float* c4_w = (const float*)d_in[40]; const float* c4_b = (const float*)d_in[41];
  float* out = (float*)d_out;

  char* ws = (char*)d_ws;
  auto F = [&](size_t off) { return (float*)(ws + off); };
  auto I = [&](size_t off) { return (int*)(ws + off); };
  auto U = [&](size_t off) { return (unsigned int*)(ws + off); };

  // ---- zero-init the atomically-updated buffers ----
  hipMemsetAsync(ws + OFF_CB,   0, 64*sizeof(float), stream);
  hipMemsetAsync(ws + OFF_DEG,  0, NN*sizeof(int),   stream);
  hipMemsetAsync(ws + OFF_CD,   0, NB*96*sizeof(float), stream);
  hipMemsetAsync(ws + OFF_CT,   0, NB*96*sizeof(float), stream);
  hipMemsetAsync(ws + OFF_POOL, 0, NB*96*sizeof(float), stream);

  // ---- tables ----
  k_tables<<<(8320 + 6656 + 30 + 255)/256, 256, 0, stream>>>(
      wd1, emb_xd, wt1, emb_xt, g1_we, g1_ae, g2_we, g2_ae,
      F(OFF_FD), F(OFF_FT), F(OFF_CB));
  k_easum<<<256, 256, 0, stream>>>(ea, F(OFF_CB));
  k_finalize<<<1, 64, 0, stream>>>(F(OFF_CB));

  // ---- weight transposes ----
  k_wtrans<<<(8192 + 255)/256, 256, 0, stream>>>(wd2, F(OFF_WD2T), 64, 32, 4);
  k_wtrans<<<(24576 + 255)/256, 256, 0, stream>>>(wd3, F(OFF_WD3T), 96, 64, 4);
  k_wtrans<<<(16384 + 255)/256, 256, 0, stream>>>(wt2, F(OFF_WT2T), 64, 32, 8);
  k_wtrans<<<(49152 + 255)/256, 256, 0, stream>>>(wt3, F(OFF_WT3T), 96, 64, 8);

  // ---- drug conv branch: L=100 -> 97 -> 94 -> 91 -> maxpool ----
  k_conv1_lut<4,65,32><<<dim3((32*97 + 255)/256, NB), 256, 0, stream>>>(
      xd, F(OFF_FD), bd1, F(OFF_A), 100, 97);
  k_conv<32,4,64,4,16,false><<<dim3((94 + 63)/64, NB), 256, 0, stream>>>(
      F(OFF_A), F(OFF_WD2T), bd2, F(OFF_B), 97, 94);
  k_conv<64,4,96,2,16,true><<<dim3((91 + 31)/32, NB), 192, 0, stream>>>(
      F(OFF_B), F(OFF_WD3T), bd3, F(OFF_CD), 94, 91);

  // ---- target conv branch: L=1000 -> 993 -> 986 -> 979 -> maxpool ----
  k_conv1_lut<8,26,32><<<dim3((32*993 + 255)/256, NB), 256, 0, stream>>>(
      xt, F(OFF_FT), bt1, F(OFF_A), 1000, 993);
  k_conv<32,8,64,4,16,false><<<dim3((986 + 63)/64, NB), 256, 0, stream>>>(
      F(OFF_A), F(OFF_WT2T), bt2, F(OFF_B), 993, 986);
  k_conv<64,8,96,2,16,true><<<dim3((979 + 31)/32, NB), 192, 0, stream>>>(
      F(OFF_B), F(OFF_WT3T), bt3, F(OFF_CT), 986, 979);

  // ---- GAT layer 1 ----
  // h1 = ax @ g1_w : [32768,24]@[24,320]
  k_gemm<64,64,24,4,4,false,false><<<dim3(320/64, NN/64), 256, 0, stream>>>(
      ax, g1_w, nullptr, F(OFF_A), 24, 320);
  k_attn_nodeterms<<<(NN*5 + 255)/256, 256, 0, stream>>>(
      F(OFF_A), g1_as, g1_ad, F(OFF_AS1), F(OFF_AD1), 5, 64);
  k_edge_attn<5><<<(EN + 255)/256, 256, 0, stream>>>(
      ei, ea, F(OFF_AS1), F(OFF_AD1), F(OFF_CB), F(OFF_CB) + 35, F(OFF_C));  // a1 -> C

  k_deg<<<(EN + 255)/256, 256, 0, stream>>>(ei, I(OFF_DEG));
  k_scan<<<1, 256, 0, stream>>>(I(OFF_DEG), I(OFF_ROWP), I(OFF_CUR));
  k_scatter<<<(EN + 255)/256, 256, 0, stream>>>(ei, I(OFF_CUR), I(OFF_CSRS), I(OFF_CSRE));

  k_gat_aggr<5,64,0><<<NN/4, 256, 0, stream>>>(
      I(OFF_ROWP), I(OFF_CSRS), I(OFF_CSRE), F(OFF_C), F(OFF_A), g1_b, F(OFF_B)); // g1o -> B

  // ---- GAT layer 2 ----
  // h2 = g1o @ g2_w : [32768,320]@[320,96]
  k_gemm<32,96,32,2,6,false,false><<<dim3(96/96, NN/32), 256, 0, stream>>>(
      F(OFF_B), g2_w, nullptr, F(OFF_C), 320, 96);
  k_attn_nodeterms<<<(NN + 255)/256, 256, 0, stream>>>(
      F(OFF_C), g2_as, g2_ad, F(OFF_AS2), F(OFF_AD2), 1, 96);
  k_edge_attn<1><<<(EN + 255)/256, 256, 0, stream>>>(
      ei, ea, F(OFF_AS2), F(OFF_AD2), F(OFF_CB) + 25, F(OFF_CB) + 40, F(OFF_A2));
  k_gat_aggr<1,96,1><<<NN/4, 256, 0, stream>>>(
      I(OFF_ROWP), I(OFF_CSRS), I(OFF_CSRE), F(OFF_A2), F(OFF_C), g2_b, F(OFF_G2O));

  // ---- graph pool + fc1 ----
  k_pool<<<(int)(((long)NN*96 + 255)/256), 256, 0, stream>>>(
      F(OFF_G2O), batch, U(OFF_POOL));
  k_gemm<64,96,32,4,6,true,true><<<dim3(96/96, NB/64), 256, 0, stream>>>(
      F(OFF_POOL), fc1_w, fc1_b, F(OFF_GFC), 96, 96);

  // ---- concat + MLP head ----
  k_concat<<<(NB*288 + 255)/256, 256, 0, stream>>>(
      F(OFF_CD), F(OFF_CT), F(OFF_GFC), F(OFF_XC));
  k_gemm<64,64,32,4,4,true,true><<<dim3(1024/64, NB/64), 256, 0, stream>>>(
      F(OFF_XC), c1_w, c1_b, F(OFF_M1B), 288, 1024);
  k_gemm<64,64,32,4,4,true,true><<<dim3(1024/64, NB/64), 256, 0, stream>>>(
      F(OFF_M1B), c2_w, c2_b, F(OFF_M2B), 1024, 1024);
  k_gemm<64,64,32,4,4,true,true><<<dim3(512/64, NB/64), 256, 0, stream>>>(
      F(OFF_M2B), c3_w, c3_b, F(OFF_M3B), 1024, 512);
  k_final<<<(NB*64 + 255)/256, 256, 0, stream>>>(F(OFF_M3B), c4_w, c4_b, out);
}

// Round 5
// 1151.948 us; speedup vs baseline: 1.6377x; 1.3458x over previous
//
#include <hip/hip_runtime.h>

// ---------------- problem constants ----------------
constexpr int NN = 32768;      // nodes
constexpr int EE = 524288;     // edges
constexpr int NB = 256;        // graphs / batch
constexpr int EN = EE + NN;    // edges + self loops

typedef unsigned short u16;
typedef short bh8 __attribute__((ext_vector_type(8)));    // 8 bf16 (4 VGPRs)
typedef float f32x4 __attribute__((ext_vector_type(4)));  // MFMA accumulator

__device__ inline u16 f2b(float f) {   // f32 -> bf16 round-to-nearest-even
  unsigned u = __float_as_uint(f);
  return (u16)((u + 0x7fffu + ((u >> 16) & 1u)) >> 16);
}

// ---------------- workspace layout (bytes) ----------------
constexpr size_t MB = 1ull << 20;
constexpr size_t OFF_A    = 0;        // conv y1 (drug f32 / target bf16-T), later h1 [N,320]
constexpr size_t OFF_B    = 48*MB;    // conv y2, later g1o [N,320]
constexpr size_t OFF_C    = 116*MB;   // a1 [EN,5], later h2 [N,96]
constexpr size_t OFF_CSRS = 130*MB;   // csr_src [EN]
constexpr size_t OFF_CSRE = 133*MB;   // csr_eid [EN]
constexpr size_t OFF_ROWP = 136*MB;   // rowptr [N+1]
constexpr size_t OFF_DEG  = 137*MB;   // deg [N]
constexpr size_t OFF_CUR  = 138*MB;   // cursor [N]
constexpr size_t OFF_A2   = 139*MB;   // a2 [EN]
constexpr size_t OFF_G2O  = 142*MB;   // g2o [N,96]
constexpr size_t OFF_AS1  = 155*MB;   // [N,5]
constexpr size_t OFF_AD1  = 156*MB;
constexpr size_t OFF_AS2  = 157*MB;   // [N]
constexpr size_t OFF_AD2  = 158*MB;
constexpr size_t OFF_CD   = 159*MB;   // [256,96] pooled drug conv
constexpr size_t OFF_CT   = 160*MB;   // [256,96] pooled target conv
constexpr size_t OFF_POOL = 161*MB;   // [256,96] graph pool
constexpr size_t OFF_GFC  = 162*MB;   // [256,96]
constexpr size_t OFF_XC   = 163*MB;   // [256,288]
constexpr size_t OFF_M1B  = 164*MB;   // [256,1024]
constexpr size_t OFF_M2B  = 165*MB;   // [256,1024]
constexpr size_t OFF_M3B  = 166*MB;   // [256,512]
constexpr size_t OFF_FD   = 167*MB;   // F table drug [32][4][65] f32
constexpr size_t OFF_FT   = 168*MB;   // F table target [8][26][32] f32 (k,v,co layout!)
constexpr size_t OFF_WD2T = 169*MB;   // drug w2 [ci][k][co] f32
constexpr size_t OFF_WD3T = 170*MB;   // drug w3 [ci][k][co] f32
constexpr size_t OFF_WT2B = 171*MB;   // target w2 bf16 [co][kk*32+ci]  (64x256)
constexpr size_t OFF_WT3B = 172*MB;   // target w3 bf16 [co][kk*64+ci]  (96x512)
constexpr size_t OFF_CB   = 173*MB;   // const block: [0:25]=M1, [25:30]=M2, [30:35]=easum,
                                      // [35:40]=aeself1, [40]=ae2self, [41:46]=eamean

// =================================================================
// Tiny precompute tables: F_drug [co][k][v], F_target [k][v][co], M1, M2
// =================================================================
__global__ void k_tables(const float* __restrict__ wd1, const float* __restrict__ emb_xd,
                         const float* __restrict__ wt1, const float* __restrict__ emb_xt,
                         const float* __restrict__ g1we, const float* __restrict__ g1ae,
                         const float* __restrict__ g2we, const float* __restrict__ g2ae,
                         float* __restrict__ Fd, float* __restrict__ Ft,
                         float* __restrict__ CB) {
  int t = blockIdx.x * 256 + threadIdx.x;
  const int NFd = 32*4*65, NFt = 32*8*26;
  if (t < NFd) {                       // Fd[co][k][v]
    int v = t % 65; int ck = t / 65; int k = ck & 3; int co = ck >> 2;
    float s = 0.f;
    for (int ci = 0; ci < 128; ++ci)
      s = fmaf(wd1[(co*128 + ci)*4 + k], emb_xd[v*128 + ci], s);
    Fd[t] = s;
  } else if (t < NFd + NFt) {          // Ft stored [k][v][co] for conflict-free LDS
    int u = t - NFd;
    int v = u % 26; int ck = u / 26; int k = ck & 7; int co = ck >> 3;
    float s = 0.f;
    for (int ci = 0; ci < 128; ++ci)
      s = fmaf(wt1[(co*128 + ci)*8 + k], emb_xt[v*128 + ci], s);
    Ft[(k*26 + v)*32 + co] = s;
  } else if (t < NFd + NFt + 25) {     // M1[j][h]
    int u = t - NFd - NFt; int h = u % 5, j = u / 5;
    float s = 0.f;
    for (int c = 0; c < 64; ++c)
      s = fmaf(g1we[j*320 + h*64 + c], g1ae[h*64 + c], s);
    CB[j*5 + h] = s;
  } else if (t < NFd + NFt + 30) {     // M2[j]
    int j = t - NFd - NFt - 25;
    float s = 0.f;
    for (int c = 0; c < 96; ++c)
      s = fmaf(g2we[j*96 + c], g2ae[c], s);
    CB[25 + j] = s;
  }
}

// target conv2/conv3 weights -> bf16, layout [co][k] with k = kk*CIN + ci
__global__ void k_wcvt(const float* __restrict__ w2, const float* __restrict__ w3,
                       u16* __restrict__ o2, u16* __restrict__ o3) {
  int t = blockIdx.x*256 + threadIdx.x;
  if (t < 64*256) {
    int co = t >> 8, k = t & 255, kk = k >> 5, ci = k & 31;
    o2[t] = f2b(w2[(co*32 + ci)*8 + kk]);
  } else if (t < 64*256 + 96*512) {
    int u = t - 64*256;
    int co = u >> 9, k = u & 511, kk = k >> 6, ci = k & 63;
    o3[u] = f2b(w3[(co*64 + ci)*8 + kk]);
  }
}

// sum of ea columns -> CB[30..34] (pre-zeroed)
__global__ void k_easum(const float* __restrict__ ea, float* __restrict__ CB) {
  float acc[5] = {0,0,0,0,0};
  for (long e = blockIdx.x*256L + threadIdx.x; e < EE; e += 256L*gridDim.x) {
    #pragma unroll
    for (int j = 0; j < 5; ++j) acc[j] += ea[e*5 + j];
  }
  #pragma unroll
  for (int j = 0; j < 5; ++j)
    for (int off = 1; off < 64; off <<= 1) acc[j] += __shfl_xor(acc[j], off, 64);
  if ((threadIdx.x & 63) == 0) {
    #pragma unroll
    for (int j = 0; j < 5; ++j) atomicAdd(&CB[30 + j], acc[j]);
  }
}

// eamean, aeself1[h], ae2self
__global__ void k_finalize(float* __restrict__ CB) {
  if (blockIdx.x == 0 && threadIdx.x == 0) {
    float em[5];
    for (int j = 0; j < 5; ++j) { em[j] = CB[30 + j] / (float)EE; CB[41 + j] = em[j]; }
    for (int h = 0; h < 5; ++h) {
      float s = 0.f;
      for (int j = 0; j < 5; ++j) s = fmaf(em[j], CB[j*5 + h], s);
      CB[35 + h] = s;
    }
    float s = 0.f;
    for (int j = 0; j < 5; ++j) s = fmaf(em[j], CB[25 + j], s);
    CB[40] = s;
  }
}

// =================================================================
// drug conv1 via LUT (unchanged, f32 [b][co][l] out)
// =================================================================
template<int K, int V, int COUT>
__global__ void k_conv1_lut(const int* __restrict__ idx, const float* __restrict__ F,
                            const float* __restrict__ bias, float* __restrict__ y,
                            int L, int Lout) {
  __shared__ float Fs[COUT*K*V];
  __shared__ float bs[COUT];
  int b = blockIdx.y;
  for (int i = threadIdx.x; i < COUT*K*V; i += blockDim.x) Fs[i] = F[i];
  for (int i = threadIdx.x; i < COUT; i += blockDim.x) bs[i] = bias[i];
  __syncthreads();
  int o = blockIdx.x * blockDim.x + threadIdx.x;
  if (o >= COUT * Lout) return;
  int co = o / Lout, l = o % Lout;
  const int* ib = idx + b*L + l;
  float acc = bs[co];
  #pragma unroll
  for (int k = 0; k < K; ++k) acc += Fs[(co*K + k)*V + ib[k]];
  y[(b*COUT + co)*Lout + l] = fmaxf(acc, 0.f);
}

// =================================================================
// target conv1 via LUT -> bf16 transposed out y[b][l][co]
// 512 threads: co = tid&31, p = tid>>5 (16 positions/block)
// =================================================================
__global__ __launch_bounds__(512) void k_conv1t(
    const int* __restrict__ idx, const float* __restrict__ Ftab,
    const float* __restrict__ bias, u16* __restrict__ y, int L, int Lout) {
  constexpr int K = 8, V = 26, CO = 32;
  __shared__ float Fs[K*V*CO];
  __shared__ float bs[CO];
  __shared__ int sq[16 + K];
  int b = blockIdx.y, l0 = blockIdx.x * 16;
  for (int i = threadIdx.x; i < K*V*CO; i += 512) Fs[i] = Ftab[i];
  if (threadIdx.x < CO) bs[threadIdx.x] = bias[threadIdx.x];
  if (threadIdx.x < 16 + K - 1) {
    int l = l0 + (int)threadIdx.x;
    sq[threadIdx.x] = (l < L) ? idx[b*L + l] : 0;
  }
  __syncthreads();
  int co = threadIdx.x & 31;
  int p = threadIdx.x >> 5;
  int l = l0 + p;
  if (l >= Lout) return;
  float acc = bs[co];
  #pragma unroll
  for (int k = 0; k < K; ++k) acc += Fs[(k*V + sq[p + k])*CO + co];
  y[((size_t)b*Lout + l)*CO + co] = f2b(fmaxf(acc, 0.f));
}

// weight transpose [co][ci][k] -> [ci][k][co] (drug branch, f32)
__global__ void k_wtrans(const float* __restrict__ w, float* __restrict__ wt,
                         int COUT, int CIN, int K) {
  int t = blockIdx.x*256 + threadIdx.x;
  if (t >= COUT*CIN*K) return;
  int k = t % K; int ci = (t / K) % CIN; int co = t / (K*CIN);
  wt[(ci*K + k)*COUT + co] = w[t];
}

// =================================================================
// drug direct conv (unchanged)
// =================================================================
template<int CIN, int K, int COUT, int G, int LG, bool POOL>
__global__ void k_conv(const float* __restrict__ x, const float* __restrict__ wt,
                       const float* __restrict__ bias, float* __restrict__ y,
                       int Lin, int Lout) {
  constexpr int LT = G * LG;
  __shared__ float xs[CIN][LT + K - 1];
  int b = blockIdx.y;
  int l0 = blockIdx.x * LT;
  const int nth = COUT * G;
  const float* xb = x + b*CIN*Lin;
  for (int i = threadIdx.x; i < CIN*(LT + K - 1); i += nth) {
    int ci = i / (LT + K - 1), dl = i % (LT + K - 1);
    int l = l0 + dl;
    xs[ci][dl] = (l < Lin) ? xb[ci*Lin + l] : 0.f;
  }
  __syncthreads();
  int co = threadIdx.x % COUT;
  int gg = threadIdx.x / COUT;
  float acc[LG];
  #pragma unroll
  for (int j = 0; j < LG; ++j) acc[j] = 0.f;
  for (int ci = 0; ci < CIN; ++ci) {
    float xr[LG + K - 1];
    #pragma unroll
    for (int t = 0; t < LG + K - 1; ++t) xr[t] = xs[ci][gg*LG + t];
    #pragma unroll
    for (int k = 0; k < K; ++k) {
      float wv = wt[(ci*K + k)*COUT + co];
      #pragma unroll
      for (int j = 0; j < LG; ++j) acc[j] = fmaf(wv, xr[j + k], acc[j]);
    }
  }
  float bv = bias[co];
  if (!POOL) {
    float* yb = y + (b*COUT + co)*Lout;
    #pragma unroll
    for (int j = 0; j < LG; ++j) {
      int l = l0 + gg*LG + j;
      if (l < Lout) yb[l] = fmaxf(acc[j] + bv, 0.f);
    }
  } else {
    float m = 0.f;
    #pragma unroll
    for (int j = 0; j < LG; ++j) {
      int l = l0 + gg*LG + j;
      if (l < Lout) m = fmaxf(m, fmaxf(acc[j] + bv, 0.f));
    }
    atomicMax((unsigned int*)&y[b*COUT + co], __float_as_uint(m));
  }
}

// =================================================================
// target conv2/conv3: implicit-GEMM via MFMA bf16.
// x: [B][Lin][CIN] bf16, w: [COUT][KD] bf16 (k = kk*CIN+ci), out either
// y [B][Lout][COUT] bf16 or fused relu+maxpool -> pool[B][COUT].
// 512 thr = 8 waves; M-tile 256 (16 m-subtiles); wave (ng=w>>2, mg=w&3):
// m-subs mg*4..+3, n-tiles ng*NT2..+NT2-1. K-loop barrier-free (all LDS staged).
// =================================================================
template<int CIN, int COUT, int NT2, bool POOL>
__global__ __launch_bounds__(512) void k_convmfma(
    const u16* __restrict__ xin, const u16* __restrict__ wtb,
    const float* __restrict__ bias, u16* __restrict__ yout,
    unsigned int* __restrict__ pool, int Lin, int Lout) {
  constexpr int KD = CIN*8;
  constexpr int NCH = KD/32;
  constexpr int MT = 256, ROWS = MT + 7;
  constexpr int XPAD = CIN + 8;     // halves; keeps 16B align, 2-way max conflict
  constexpr int WPAD = KD + 8;
  __shared__ u16 xs[ROWS*XPAD];
  __shared__ u16 wsd[COUT*WPAD];
  int b = blockIdx.y;
  int l0 = blockIdx.x * MT;
  int tid = threadIdx.x;
  { // stage weights (uint copies, coalesced)
    const unsigned* wg = (const unsigned*)wtb;
    unsigned* wl = (unsigned*)wsd;
    constexpr int KD2 = KD/2, WP2 = WPAD/2;
    for (int i = tid; i < COUT*KD2; i += 512) {
      int co = i / KD2, c = i % KD2;
      wl[co*WP2 + c] = wg[i];
    }
  }
  { // stage x rows [l0, l0+ROWS), zero beyond Lin
    const unsigned* xg = (const unsigned*)(xin + (size_t)b*Lin*CIN);
    unsigned* xl = (unsigned*)xs;
    constexpr int C2 = CIN/2, XP2 = XPAD/2;
    for (int i = tid; i < ROWS*C2; i += 512) {
      int r = i / C2, c = i % C2;
      unsigned v = 0;
      if (l0 + r < Lin) v = xg[(size_t)l0*C2 + i];
      xl[r*XP2 + c] = v;
    }
  }
  __syncthreads();
  int lane = tid & 63;
  int w = tid >> 6;
  int mg = w & 3, ng = w >> 2;
  int l15 = lane & 15, l4 = lane >> 4;
  f32x4 acc[4][NT2];
  #pragma unroll
  for (int mi = 0; mi < 4; ++mi)
    #pragma unroll
    for (int nj = 0; nj < NT2; ++nj) acc[mi][nj] = (f32x4){0.f, 0.f, 0.f, 0.f};

  #pragma unroll
  for (int ch = 0; ch < NCH; ++ch) {
    const int kk = (ch*32) / CIN;
    const int cib = (ch*32) % CIN + l4*8;
    bh8 a[4], bb[NT2];
    #pragma unroll
    for (int mi = 0; mi < 4; ++mi) {
      int row = mg*64 + mi*16 + l15 + kk;
      a[mi] = *(const bh8*)&xs[row*XPAD + cib];
    }
    #pragma unroll
    for (int nj = 0; nj < NT2; ++nj) {
      int co = (ng*NT2 + nj)*16 + l15;
      bb[nj] = *(const bh8*)&wsd[co*WPAD + ch*32 + l4*8];
    }
    #pragma unroll
    for (int mi = 0; mi < 4; ++mi)
      #pragma unroll
      for (int nj = 0; nj < NT2; ++nj)
        acc[mi][nj] = __builtin_amdgcn_mfma_f32_16x16x32_bf16(a[mi], bb[nj], acc[mi][nj], 0, 0, 0);
  }

  if (!POOL) {
    #pragma unroll
    for (int nj = 0; nj < NT2; ++nj) {
      int co = (ng*NT2 + nj)*16 + l15;
      float bv = bias[co];
      #pragma unroll
      for (int mi = 0; mi < 4; ++mi)
        #pragma unroll
        for (int r = 0; r < 4; ++r) {
          int m = mg*64 + mi*16 + l4*4 + r;
          if (l0 + m < Lout)
            yout[((size_t)b*Lout + l0 + m)*COUT + co] = f2b(fmaxf(acc[mi][nj][r] + bv, 0.f));
        }
    }
  } else {
    #pragma unroll
    for (int nj = 0; nj < NT2; ++nj) {
      int co = (ng*NT2 + nj)*16 + l15;
      float bv = bias[co];
      float mx = 0.f;
      #pragma unroll
      for (int mi = 0; mi < 4; ++mi)
        #pragma unroll
        for (int r = 0; r < 4; ++r) {
          int m = mg*64 + mi*16 + l4*4 + r;
          if (l0 + m < Lout) mx = fmaxf(mx, fmaxf(acc[mi][nj][r] + bv, 0.f));
        }
      mx = fmaxf(mx, __shfl_xor(mx, 16, 64));
      mx = fmaxf(mx, __shfl_xor(mx, 32, 64));
      if (l4 == 0) atomicMax(&pool[b*COUT + co], __float_as_uint(mx));
    }
  }
}

// =================================================================
// register-tiled f32 GEMM (unchanged)
// =================================================================
template<int BM, int BN, int BK, int TM, int TN, bool BIAS, bool RELU>
__global__ void k_gemm(const float* __restrict__ X, const float* __restrict__ W,
                       const float* __restrict__ bias, float* __restrict__ Y,
                       int K, int C) {
  constexpr int NTH = (BM/TM)*(BN/TN);
  static_assert(NTH == 256, "block must be 256 threads");
  __shared__ float xs[BK][BM + 1];
  __shared__ float wsm[BK][BN];
  const int m0 = blockIdx.y * BM;
  const int c0 = blockIdx.x * BN;
  const int tn = threadIdx.x % (BN/TN);
  const int tm = threadIdx.x / (BN/TN);
  float acc[TM][TN];
  #pragma unroll
  for (int i = 0; i < TM; ++i)
    #pragma unroll
    for (int j = 0; j < TN; ++j) acc[i][j] = 0.f;

  for (int k0 = 0; k0 < K; k0 += BK) {
    #pragma unroll
    for (int i = threadIdx.x; i < BM*BK; i += NTH) {
      int m = i / BK, k = i % BK;
      xs[k][m] = X[(long)(m0 + m)*K + k0 + k];
    }
    #pragma unroll
    for (int i = threadIdx.x; i < BK*BN; i += NTH) {
      int k = i / BN, c = i % BN;
      wsm[k][c] = W[(long)(k0 + k)*C + c0 + c];
    }
    __syncthreads();
    #pragma unroll
    for (int k = 0; k < BK; ++k) {
      float xv[TM], wv[TN];
      #pragma unroll
      for (int i = 0; i < TM; ++i) xv[i] = xs[k][tm*TM + i];
      #pragma unroll
      for (int j = 0; j < TN; ++j) wv[j] = wsm[k][tn*TN + j];
      #pragma unroll
      for (int i = 0; i < TM; ++i)
        #pragma unroll
        for (int j = 0; j < TN; ++j) acc[i][j] = fmaf(xv[i], wv[j], acc[i][j]);
    }
    __syncthreads();
  }
  #pragma unroll
  for (int i = 0; i < TM; ++i) {
    float* yr = Y + (long)(m0 + tm*TM + i)*C + c0 + tn*TN;
    #pragma unroll
    for (int j = 0; j < TN; ++j) {
      float v = acc[i][j];
      if (BIAS) v += bias[c0 + tn*TN + j];
      if (RELU) v = fmaxf(v, 0.f);
      yr[j] = v;
    }
  }
}

// per-node attention terms
__global__ void k_attn_nodeterms(const float* __restrict__ h, const float* __restrict__ a_s,
                                 const float* __restrict__ a_d, float* __restrict__ as_o,
                                 float* __restrict__ ad_o, int H, int CH) {
  long t = blockIdx.x*256L + threadIdx.x;
  if (t >= (long)NN * H) return;
  int n = (int)(t / H), hh = (int)(t % H);
  const float* hr = h + ((long)n*H + hh)*CH;
  float s1 = 0.f, s2 = 0.f;
  for (int c = 0; c < CH; ++c) {
    float v = hr[c];
    s1 = fmaf(v, a_s[hh*CH + c], s1);
    s2 = fmaf(v, a_d[hh*CH + c], s2);
  }
  as_o[t] = s1; ad_o[t] = s2;
}

// per-edge attention logit with leaky_relu(0.2). e >= EE are self loops.
template<int H>
__global__ void k_edge_attn(const int* __restrict__ ei, const float* __restrict__ ea,
                            const float* __restrict__ asb, const float* __restrict__ adb,
                            const float* __restrict__ M, const float* __restrict__ aeself,
                            float* __restrict__ a_out) {
  long e = blockIdx.x*256L + threadIdx.x;
  if (e >= (long)EN) return;
  int s, d;
  float av[H];
  if (e < EE) {
    s = ei[e]; d = ei[EE + e];
    float er[5];
    #pragma unroll
    for (int j = 0; j < 5; ++j) er[j] = ea[e*5 + j];
    #pragma unroll
    for (int h = 0; h < H; ++h) {
      float t = 0.f;
      #pragma unroll
      for (int j = 0; j < 5; ++j) t = fmaf(er[j], M[j*H + h], t);
      av[h] = t;
    }
  } else {
    s = d = (int)(e - EE);
    #pragma unroll
    for (int h = 0; h < H; ++h) av[h] = aeself[h];
  }
  #pragma unroll
  for (int h = 0; h < H; ++h) {
    float v = asb[s*H + h] + adb[d*H + h] + av[h];
    a_out[e*H + h] = (v > 0.f) ? v : 0.2f * v;
  }
}

// ------------- CSR build -------------
__global__ void k_deg(const int* __restrict__ ei, int* __restrict__ deg) {
  long e = blockIdx.x*256L + threadIdx.x;
  if (e >= (long)EN) return;
  int d = (e < EE) ? ei[EE + e] : (int)(e - EE);
  atomicAdd(&deg[d], 1);
}

__global__ void k_scan(const int* __restrict__ deg, int* __restrict__ rowptr,
                       int* __restrict__ cursor) {
  __shared__ int ps[256];
  int tid = threadIdx.x;
  int base = tid * 128;           // 256*128 = 32768 = NN
  int s = 0;
  for (int i = 0; i < 128; ++i) s += deg[base + i];
  ps[tid] = s;
  __syncthreads();
  for (int off = 1; off < 256; off <<= 1) {
    int v = (tid >= off) ? ps[tid - off] : 0;
    __syncthreads();
    ps[tid] += v;
    __syncthreads();
  }
  int run = ps[tid] - s;          // exclusive prefix
  for (int i = 0; i < 128; ++i) {
    rowptr[base + i] = run;
    cursor[base + i] = run;
    run += deg[base + i];
  }
  if (tid == 255) rowptr[NN] = run;
}

__global__ void k_scatter(const int* __restrict__ ei, int* __restrict__ cursor,
                          int* __restrict__ csr_src, int* __restrict__ csr_eid) {
  long e = blockIdx.x*256L + threadIdx.x;
  if (e >= (long)EN) return;
  int s, d;
  if (e < EE) { s = ei[e]; d = ei[EE + e]; }
  else        { s = d = (int)(e - EE); }
  int p = atomicAdd(&cursor[d], 1);
  csr_src[p] = s;
  csr_eid[p] = (int)e;
}

// =================================================================
// GAT aggregation: wave per destination node. ACT: 0=elu, 1=relu
// =================================================================
template<int H, int CH, int ACT>
__global__ void k_gat_aggr(const int* __restrict__ rowptr, const int* __restrict__ csr_src,
                           const int* __restrict__ csr_eid, const float* __restrict__ a,
                           const float* __restrict__ hfeat, const float* __restrict__ bias,
                           float* __restrict__ out) {
  int wid = (int)((blockIdx.x*(long)blockDim.x + threadIdx.x) >> 6);
  int lane = threadIdx.x & 63;
  if (wid >= NN) return;
  int row0 = rowptr[wid], row1 = rowptr[wid + 1];
  constexpr int F = H * CH;
  constexpr int NJ = (F + 63) / 64;
  float amax[H], asum[H], rinv[H];
  #pragma unroll
  for (int h = 0; h < H; ++h) amax[h] = -1e30f;
  for (int p = row0 + lane; p < row1; p += 64) {
    int e = csr_eid[p];
    #pragma unroll
    for (int h = 0; h < H; ++h) amax[h] = fmaxf(amax[h], a[(long)e*H + h]);
  }
  #pragma unroll
  for (int h = 0; h < H; ++h)
    for (int off = 1; off < 64; off <<= 1) amax[h] = fmaxf(amax[h], __shfl_xor(amax[h], off, 64));
  #pragma unroll
  for (int h = 0; h < H; ++h) asum[h] = 0.f;
  for (int p = row0 + lane; p < row1; p += 64) {
    int e = csr_eid[p];
    #pragma unroll
    for (int h = 0; h < H; ++h) asum[h] += __expf(a[(long)e*H + h] - amax[h]);
  }
  #pragma unroll
  for (int h = 0; h < H; ++h) {
    for (int off = 1; off < 64; off <<= 1) asum[h] += __shfl_xor(asum[h], off, 64);
    rinv[h] = 1.f / (asum[h] + 1e-16f);
  }
  float acc[NJ];
  #pragma unroll
  for (int j = 0; j < NJ; ++j) acc[j] = 0.f;
  for (int p = row0; p < row1; ++p) {
    int e = csr_eid[p];
    int s = csr_src[p];
    const float* hr = hfeat + (long)s * F;
    #pragma unroll
    for (int j = 0; j < NJ; ++j) {
      int idx = j*64 + lane;
      if ((F % 64 == 0) || idx < F) {
        int h = idx / CH;
        float al = __expf(a[(long)e*H + h] - amax[h]) * rinv[h];
        acc[j] = fmaf(al, hr[idx], acc[j]);
      }
    }
  }
  float* orow = out + (long)wid * F;
  #pragma unroll
  for (int j = 0; j < NJ; ++j) {
    int idx = j*64 + lane;
    if ((F % 64 == 0) || idx < F) {
      float v = acc[j] + bias[idx];
      if (ACT == 0) v = (v > 0.f) ? v : expm1f(v);
      else          v = fmaxf(v, 0.f);
      orow[idx] = v;
    }
  }
}

// graph max pool (relu'd input >= 0, pooled pre-zeroed)
__global__ void k_pool(const float* __restrict__ g2o, const int* __restrict__ batch,
                       unsigned int* __restrict__ pooled) {
  long o = blockIdx.x*256L + threadIdx.x;
  if (o >= (long)NN * 96) return;
  int n = (int)(o / 96), c = (int)(o % 96);
  atomicMax(&pooled[batch[n]*96 + c], __float_as_uint(g2o[o]));
}

__global__ void k_concat(const float* __restrict__ cd, const float* __restrict__ ct,
                         const float* __restrict__ gfc, float* __restrict__ xc) {
  int t = blockIdx.x*256 + threadIdx.x;
  if (t >= NB*288) return;
  int b = t / 288, c = t % 288;
  float v = (c < 96) ? cd[b*96 + c] : (c < 192) ? ct[b*96 + (c-96)] : gfc[b*96 + (c-192)];
  xc[t] = v;
}

// final 512-dot per row
__global__ void k_final(const float* __restrict__ x, const float* __restrict__ w,
                        const float* __restrict__ b, float* __restrict__ out) {
  int wid = (int)((blockIdx.x*256L + threadIdx.x) >> 6);
  int lane = threadIdx.x & 63;
  if (wid >= NB) return;
  const float* xr = x + (long)wid*512;
  float s = 0.f;
  for (int k = lane; k < 512; k += 64) s = fmaf(xr[k], w[k], s);
  for (int off = 1; off < 64; off <<= 1) s += __shfl_xor(s, off, 64);
  if (lane == 0) out[wid] = s + b[0];
}

// =================================================================
extern "C" void kernel_launch(void* const* d_in, const int* in_sizes, int n_in,
                              void* d_out, int out_size, void* d_ws, size_t ws_size,
                              hipStream_t stream) {
  const int*   xd     = (const int*)  d_in[0];
  const int*   xt     = (const int*)  d_in[1];
  const float* ax     = (const float*)d_in[2];
  const int*   ei     = (const int*)  d_in[3];
  const float* ea     = (const float*)d_in[4];
  const int*   batch  = (const int*)  d_in[5];
  const float* emb_xd = (const float*)d_in[6];
  const float* emb_xt = (const float*)d_in[7];
  const float* wd1 = (const float*)d_in[8];  const float* bd1 = (const float*)d_in[9];
  const float* wd2 = (const float*)d_in[10]; const float* bd2 = (const float*)d_in[11];
  const float* wd3 = (const float*)d_in[12]; const float* bd3 = (const float*)d_in[13];
  const float* wt1 = (const float*)d_in[14]; const float* bt1 = (const float*)d_in[15];
  const float* wt2 = (const float*)d_in[16]; const float* bt2 = (const float*)d_in[17];
  const float* wt3 = (const float*)d_in[18]; const float* bt3 = (const float*)d_in[19];
  const float* g1_w  = (const float*)d_in[20]; const float* g1_as = (const float*)d_in[21];
  const float* g1_ad = (const float*)d_in[22]; const float* g1_we = (const float*)d_in[23];
  const float* g1_ae = (const float*)d_in[24]; const float* g1_b  = (const float*)d_in[25];
  const float* g2_w  = (const float*)d_in[26]; const float* g2_as = (const float*)d_in[27];
  const float* g2_ad = (const float*)d_in[28]; const float* g2_we = (const float*)d_in[29];
  const float* g2_ae = (const float*)d_in[30]; const float* g2_b  = (const float*)d_in[31];
  const float* fc1_w = (const float*)d_in[32]; const float* fc1_b = (const float*)d_in[33];
  const float* c1_w = (const float*)d_in[34]; const float* c1_b = (const float*)d_in[35];
  const float* c2_w = (const float*)d_in[36]; const float* c2_b = (const float*)d_in[37];
  const float* c3_w = (const float*)d_in[38]; const float* c3_b = (const float*)d_in[39];
  const float* c4_w = (const float*)d_in[40]; const float* c4_b = (const float*)d_in[41];
  float* out = (float*)d_out;

  char* ws = (char*)d_ws;
  auto F = [&](size_t off) { return (float*)(ws + off); };
  auto I = [&](size_t off) { return (int*)(ws + off); };
  auto U = [&](size_t off) { return (unsigned int*)(ws + off); };
  auto H = [&](size_t off) { return (u16*)(ws + off); };

  // ---- zero-init the atomically-updated buffers ----
  hipMemsetAsync(ws + OFF_CB,   0, 64*sizeof(float), stream);
  hipMemsetAsync(ws + OFF_DEG,  0, NN*sizeof(int),   stream);
  hipMemsetAsync(ws + OFF_CD,   0, NB*96*sizeof(float), stream);
  hipMemsetAsync(ws + OFF_CT,   0, NB*96*sizeof(float), stream);
  hipMemsetAsync(ws + OFF_POOL, 0, NB*96*sizeof(float), stream);

  // ---- tables / weight converts ----
  k_tables<<<(8320 + 6656 + 30 + 255)/256, 256, 0, stream>>>(
      wd1, emb_xd, wt1, emb_xt, g1_we, g1_ae, g2_we, g2_ae,
      F(OFF_FD), F(OFF_FT), F(OFF_CB));
  k_wcvt<<<(64*256 + 96*512 + 255)/256, 256, 0, stream>>>(
      wt2, wt3, H(OFF_WT2B), H(OFF_WT3B));
  k_easum<<<256, 256, 0, stream>>>(ea, F(OFF_CB));
  k_finalize<<<1, 64, 0, stream>>>(F(OFF_CB));

  // ---- drug weight transposes (f32 path) ----
  k_wtrans<<<(8192 + 255)/256, 256, 0, stream>>>(wd2, F(OFF_WD2T), 64, 32, 4);
  k_wtrans<<<(24576 + 255)/256, 256, 0, stream>>>(wd3, F(OFF_WD3T), 96, 64, 4);

  // ---- drug conv branch (f32 direct): L=100 -> 97 -> 94 -> 91 -> maxpool ----
  k_conv1_lut<4,65,32><<<dim3((32*97 + 255)/256, NB), 256, 0, stream>>>(
      xd, F(OFF_FD), bd1, F(OFF_A), 100, 97);
  k_conv<32,4,64,4,16,false><<<dim3((94 + 63)/64, NB), 256, 0, stream>>>(
      F(OFF_A), F(OFF_WD2T), bd2, F(OFF_B), 97, 94);
  k_conv<64,4,96,2,16,true><<<dim3((91 + 31)/32, NB), 192, 0, stream>>>(
      F(OFF_B), F(OFF_WD3T), bd3, F(OFF_CD), 94, 91);

  // ---- target conv branch (bf16 MFMA): 1000 -> 993 -> 986 -> 979 -> maxpool ----
  k_conv1t<<<dim3((993 + 15)/16, NB), 512, 0, stream>>>(
      xt, F(OFF_FT), bt1, H(OFF_A), 1000, 993);
  k_convmfma<32,64,2,false><<<dim3(4, NB), 512, 0, stream>>>(
      H(OFF_A), H(OFF_WT2B), bt2, H(OFF_B), nullptr, 993, 986);
  k_convmfma<64,96,3,true><<<dim3(4, NB), 512, 0, stream>>>(
      H(OFF_B), H(OFF_WT3B), bt3, nullptr, U(OFF_CT), 986, 979);

  // ---- GAT layer 1 ----
  k_gemm<64,64,24,4,4,false,false><<<dim3(320/64, NN/64), 256, 0, stream>>>(
      ax, g1_w, nullptr, F(OFF_A), 24, 320);
  k_attn_nodeterms<<<(NN*5 + 255)/256, 256, 0, stream>>>(
      F(OFF_A), g1_as, g1_ad, F(OFF_AS1), F(OFF_AD1), 5, 64);
  k_edge_attn<5><<<(EN + 255)/256, 256, 0, stream>>>(
      ei, ea, F(OFF_AS1), F(OFF_AD1), F(OFF_CB), F(OFF_CB) + 35, F(OFF_C));

  k_deg<<<(EN + 255)/256, 256, 0, stream>>>(ei, I(OFF_DEG));
  k_scan<<<1, 256, 0, stream>>>(I(OFF_DEG), I(OFF_ROWP), I(OFF_CUR));
  k_scatter<<<(EN + 255)/256, 256, 0, stream>>>(ei, I(OFF_CUR), I(OFF_CSRS), I(OFF_CSRE));

  k_gat_aggr<5,64,0><<<NN/4, 256, 0, stream>>>(
      I(OFF_ROWP), I(OFF_CSRS), I(OFF_CSRE), F(OFF_C), F(OFF_A), g1_b, F(OFF_B));

  // ---- GAT layer 2 ----
  k_gemm<32,96,32,2,6,false,false><<<dim3(96/96, NN/32), 256, 0, stream>>>(
      F(OFF_B), g2_w, nullptr, F(OFF_C), 320, 96);
  k_attn_nodeterms<<<(NN + 255)/256, 256, 0, stream>>>(
      F(OFF_C), g2_as, g2_ad, F(OFF_AS2), F(OFF_AD2), 1, 96);
  k_edge_attn<1><<<(EN + 255)/256, 256, 0, stream>>>(
      ei, ea, F(OFF_AS2), F(OFF_AD2), F(OFF_CB) + 25, F(OFF_CB) + 40, F(OFF_A2));
  k_gat_aggr<1,96,1><<<NN/4, 256, 0, stream>>>(
      I(OFF_ROWP), I(OFF_CSRS), I(OFF_CSRE), F(OFF_A2), F(OFF_C), g2_b, F(OFF_G2O));

  // ---- graph pool + fc1 ----
  k_pool<<<(int)(((long)NN*96 + 255)/256), 256, 0, stream>>>(
      F(OFF_G2O), batch, U(OFF_POOL));
  k_gemm<64,96,32,4,6,true,true><<<dim3(96/96, NB/64), 256, 0, stream>>>(
      F(OFF_POOL), fc1_w, fc1_b, F(OFF_GFC), 96, 96);

  // ---- concat + MLP head ----
  k_concat<<<(NB*288 + 255)/256, 256, 0, stream>>>(
      F(OFF_CD), F(OFF_CT), F(OFF_GFC), F(OFF_XC));
  k_gemm<64,64,32,4,4,true,true><<<dim3(1024/64, NB/64), 256, 0, stream>>>(
      F(OFF_XC), c1_w, c1_b, F(OFF_M1B), 288, 1024);
  k_gemm<64,64,32,4,4,true,true><<<dim3(1024/64, NB/64), 256, 0, stream>>>(
      F(OFF_M1B), c2_w, c2_b, F(OFF_M2B), 1024, 1024);
  k_gemm<64,64,32,4,4,true,true><<<dim3(512/64, NB/64), 256, 0, stream>>>(
      F(OFF_M2B), c3_w, c3_b, F(OFF_M3B), 1024, 512);
  k_final<<<(NB*64 + 255)/256, 256, 0, stream>>>(F(OFF_M3B), c4_w, c4_b, out);
}

// Round 6
// 1008.277 us; speedup vs baseline: 1.8710x; 1.1425x over previous
//
#include <hip/hip_runtime.h>

// ---------------- problem constants ----------------
constexpr int NN = 32768;      // nodes
constexpr int EE = 524288;     // edges
constexpr int NB = 256;        // graphs / batch
constexpr int EN = EE + NN;    // edges + self loops

typedef unsigned short u16;
typedef short bh8 __attribute__((ext_vector_type(8)));    // 8 bf16 (4 VGPRs)
typedef float f32x4 __attribute__((ext_vector_type(4)));  // MFMA accumulator

__device__ inline u16 f2b(float f) {   // f32 -> bf16 round-to-nearest-even
  unsigned u = __float_as_uint(f);
  return (u16)((u + 0x7fffu + ((u >> 16) & 1u)) >> 16);
}

// ---------------- workspace layout (bytes) ----------------
constexpr size_t MB = 1ull << 20;
constexpr size_t OFF_A    = 0;        // conv y1 (drug f32 / target bf16-T), later h1 [N,320]
constexpr size_t OFF_B    = 48*MB;    // conv y2, later g1o [N,320]
constexpr size_t OFF_C    = 116*MB;   // a1 [EN,5], later h2 [N,96]
constexpr size_t OFF_CSRS = 130*MB;   // csr_src [EN]
constexpr size_t OFF_CSRE = 133*MB;   // csr_eid [EN]
constexpr size_t OFF_ROWP = 136*MB;   // rowptr [N+1]
constexpr size_t OFF_DEG  = 137*MB;   // deg [N]
constexpr size_t OFF_CUR  = 138*MB;   // cursor [N]
constexpr size_t OFF_A2   = 139*MB;   // a2 [EN]
constexpr size_t OFF_G2O  = 142*MB;   // g2o [N,96]
constexpr size_t OFF_AS1  = 155*MB;   // [N,5]
constexpr size_t OFF_AD1  = 156*MB;
constexpr size_t OFF_AS2  = 157*MB;   // [N]
constexpr size_t OFF_AD2  = 158*MB;
constexpr size_t OFF_CD   = 159*MB;   // [256,96] pooled drug conv
constexpr size_t OFF_CT   = 160*MB;   // [256,96] pooled target conv
constexpr size_t OFF_POOL = 161*MB;   // [256,96] graph pool
constexpr size_t OFF_GFC  = 162*MB;   // [256,96]
constexpr size_t OFF_XC   = 163*MB;   // [256,288]
constexpr size_t OFF_M1B  = 164*MB;   // [256,1024]
constexpr size_t OFF_M2B  = 165*MB;   // [256,1024]
constexpr size_t OFF_M3B  = 166*MB;   // [256,512]
constexpr size_t OFF_FD   = 167*MB;   // F table drug [32][4][65] f32
constexpr size_t OFF_FT   = 168*MB;   // F table target [8][26][32] f32 (k,v,co layout!)
constexpr size_t OFF_WD2T = 169*MB;   // drug w2 [ci][k][co] f32
constexpr size_t OFF_WD3T = 170*MB;   // drug w3 [ci][k][co] f32
constexpr size_t OFF_WT2B = 171*MB;   // target w2 bf16 [co][kk*32+ci]  (64x256)
constexpr size_t OFF_WT3B = 172*MB;   // target w3 bf16 [co][kk*64+ci]  (96x512)
constexpr size_t OFF_CB   = 173*MB;   // const block: [0:25]=M1, [25:30]=M2, [30:35]=easum,
                                      // [35:40]=aeself1, [40]=ae2self, [41:46]=eamean

// =================================================================
// Tiny precompute tables: F_drug [co][k][v], F_target [k][v][co], M1, M2
// =================================================================
__global__ void k_tables(const float* __restrict__ wd1, const float* __restrict__ emb_xd,
                         const float* __restrict__ wt1, const float* __restrict__ emb_xt,
                         const float* __restrict__ g1we, const float* __restrict__ g1ae,
                         const float* __restrict__ g2we, const float* __restrict__ g2ae,
                         float* __restrict__ Fd, float* __restrict__ Ft,
                         float* __restrict__ CB) {
  int t = blockIdx.x * 256 + threadIdx.x;
  const int NFd = 32*4*65, NFt = 32*8*26;
  if (t < NFd) {                       // Fd[co][k][v]
    int v = t % 65; int ck = t / 65; int k = ck & 3; int co = ck >> 2;
    float s = 0.f;
    for (int ci = 0; ci < 128; ++ci)
      s = fmaf(wd1[(co*128 + ci)*4 + k], emb_xd[v*128 + ci], s);
    Fd[t] = s;
  } else if (t < NFd + NFt) {          // Ft stored [k][v][co] for conflict-free LDS
    int u = t - NFd;
    int v = u % 26; int ck = u / 26; int k = ck & 7; int co = ck >> 3;
    float s = 0.f;
    for (int ci = 0; ci < 128; ++ci)
      s = fmaf(wt1[(co*128 + ci)*8 + k], emb_xt[v*128 + ci], s);
    Ft[(k*26 + v)*32 + co] = s;
  } else if (t < NFd + NFt + 25) {     // M1[j][h]
    int u = t - NFd - NFt; int h = u % 5, j = u / 5;
    float s = 0.f;
    for (int c = 0; c < 64; ++c)
      s = fmaf(g1we[j*320 + h*64 + c], g1ae[h*64 + c], s);
    CB[j*5 + h] = s;
  } else if (t < NFd + NFt + 30) {     // M2[j]
    int j = t - NFd - NFt - 25;
    float s = 0.f;
    for (int c = 0; c < 96; ++c)
      s = fmaf(g2we[j*96 + c], g2ae[c], s);
    CB[25 + j] = s;
  }
}

// target conv2/conv3 weights -> bf16, layout [co][k] with k = kk*CIN + ci
__global__ void k_wcvt(const float* __restrict__ w2, const float* __restrict__ w3,
                       u16* __restrict__ o2, u16* __restrict__ o3) {
  int t = blockIdx.x*256 + threadIdx.x;
  if (t < 64*256) {
    int co = t >> 8, k = t & 255, kk = k >> 5, ci = k & 31;
    o2[t] = f2b(w2[(co*32 + ci)*8 + kk]);
  } else if (t < 64*256 + 96*512) {
    int u = t - 64*256;
    int co = u >> 9, k = u & 511, kk = k >> 6, ci = k & 63;
    o3[u] = f2b(w3[(co*64 + ci)*8 + kk]);
  }
}

// sum of ea columns -> CB[30..34] (pre-zeroed)
__global__ void k_easum(const float* __restrict__ ea, float* __restrict__ CB) {
  float acc[5] = {0,0,0,0,0};
  for (long e = blockIdx.x*256L + threadIdx.x; e < EE; e += 256L*gridDim.x) {
    #pragma unroll
    for (int j = 0; j < 5; ++j) acc[j] += ea[e*5 + j];
  }
  #pragma unroll
  for (int j = 0; j < 5; ++j)
    for (int off = 1; off < 64; off <<= 1) acc[j] += __shfl_xor(acc[j], off, 64);
  if ((threadIdx.x & 63) == 0) {
    #pragma unroll
    for (int j = 0; j < 5; ++j) atomicAdd(&CB[30 + j], acc[j]);
  }
}

// eamean, aeself1[h], ae2self
__global__ void k_finalize(float* __restrict__ CB) {
  if (blockIdx.x == 0 && threadIdx.x == 0) {
    float em[5];
    for (int j = 0; j < 5; ++j) { em[j] = CB[30 + j] / (float)EE; CB[41 + j] = em[j]; }
    for (int h = 0; h < 5; ++h) {
      float s = 0.f;
      for (int j = 0; j < 5; ++j) s = fmaf(em[j], CB[j*5 + h], s);
      CB[35 + h] = s;
    }
    float s = 0.f;
    for (int j = 0; j < 5; ++j) s = fmaf(em[j], CB[25 + j], s);
    CB[40] = s;
  }
}

// =================================================================
// drug conv1 via LUT (unchanged, f32 [b][co][l] out)
// =================================================================
template<int K, int V, int COUT>
__global__ void k_conv1_lut(const int* __restrict__ idx, const float* __restrict__ F,
                            const float* __restrict__ bias, float* __restrict__ y,
                            int L, int Lout) {
  __shared__ float Fs[COUT*K*V];
  __shared__ float bs[COUT];
  int b = blockIdx.y;
  for (int i = threadIdx.x; i < COUT*K*V; i += blockDim.x) Fs[i] = F[i];
  for (int i = threadIdx.x; i < COUT; i += blockDim.x) bs[i] = bias[i];
  __syncthreads();
  int o = blockIdx.x * blockDim.x + threadIdx.x;
  if (o >= COUT * Lout) return;
  int co = o / Lout, l = o % Lout;
  const int* ib = idx + b*L + l;
  float acc = bs[co];
  #pragma unroll
  for (int k = 0; k < K; ++k) acc += Fs[(co*K + k)*V + ib[k]];
  y[(b*COUT + co)*Lout + l] = fmaxf(acc, 0.f);
}

// =================================================================
// target conv1 via LUT -> bf16 transposed out y[b][l][co]
// =================================================================
__global__ __launch_bounds__(512) void k_conv1t(
    const int* __restrict__ idx, const float* __restrict__ Ftab,
    const float* __restrict__ bias, u16* __restrict__ y, int L, int Lout) {
  constexpr int K = 8, V = 26, CO = 32;
  __shared__ float Fs[K*V*CO];
  __shared__ float bs[CO];
  __shared__ int sq[16 + K];
  int b = blockIdx.y, l0 = blockIdx.x * 16;
  for (int i = threadIdx.x; i < K*V*CO; i += 512) Fs[i] = Ftab[i];
  if (threadIdx.x < CO) bs[threadIdx.x] = bias[threadIdx.x];
  if (threadIdx.x < 16 + K - 1) {
    int l = l0 + (int)threadIdx.x;
    sq[threadIdx.x] = (l < L) ? idx[b*L + l] : 0;
  }
  __syncthreads();
  int co = threadIdx.x & 31;
  int p = threadIdx.x >> 5;
  int l = l0 + p;
  if (l >= Lout) return;
  float acc = bs[co];
  #pragma unroll
  for (int k = 0; k < K; ++k) acc += Fs[(k*V + sq[p + k])*CO + co];
  y[((size_t)b*Lout + l)*CO + co] = f2b(fmaxf(acc, 0.f));
}

// weight transpose [co][ci][k] -> [ci][k][co] (drug branch, f32)
__global__ void k_wtrans(const float* __restrict__ w, float* __restrict__ wt,
                         int COUT, int CIN, int K) {
  int t = blockIdx.x*256 + threadIdx.x;
  if (t >= COUT*CIN*K) return;
  int k = t % K; int ci = (t / K) % CIN; int co = t / (K*CIN);
  wt[(ci*K + k)*COUT + co] = w[t];
}

// =================================================================
// drug direct conv (unchanged)
// =================================================================
template<int CIN, int K, int COUT, int G, int LG, bool POOL>
__global__ void k_conv(const float* __restrict__ x, const float* __restrict__ wt,
                       const float* __restrict__ bias, float* __restrict__ y,
                       int Lin, int Lout) {
  constexpr int LT = G * LG;
  __shared__ float xs[CIN][LT + K - 1];
  int b = blockIdx.y;
  int l0 = blockIdx.x * LT;
  const int nth = COUT * G;
  const float* xb = x + b*CIN*Lin;
  for (int i = threadIdx.x; i < CIN*(LT + K - 1); i += nth) {
    int ci = i / (LT + K - 1), dl = i % (LT + K - 1);
    int l = l0 + dl;
    xs[ci][dl] = (l < Lin) ? xb[ci*Lin + l] : 0.f;
  }
  __syncthreads();
  int co = threadIdx.x % COUT;
  int gg = threadIdx.x / COUT;
  float acc[LG];
  #pragma unroll
  for (int j = 0; j < LG; ++j) acc[j] = 0.f;
  for (int ci = 0; ci < CIN; ++ci) {
    float xr[LG + K - 1];
    #pragma unroll
    for (int t = 0; t < LG + K - 1; ++t) xr[t] = xs[ci][gg*LG + t];
    #pragma unroll
    for (int k = 0; k < K; ++k) {
      float wv = wt[(ci*K + k)*COUT + co];
      #pragma unroll
      for (int j = 0; j < LG; ++j) acc[j] = fmaf(wv, xr[j + k], acc[j]);
    }
  }
  float bv = bias[co];
  if (!POOL) {
    float* yb = y + (b*COUT + co)*Lout;
    #pragma unroll
    for (int j = 0; j < LG; ++j) {
      int l = l0 + gg*LG + j;
      if (l < Lout) yb[l] = fmaxf(acc[j] + bv, 0.f);
    }
  } else {
    float m = 0.f;
    #pragma unroll
    for (int j = 0; j < LG; ++j) {
      int l = l0 + gg*LG + j;
      if (l < Lout) m = fmaxf(m, fmaxf(acc[j] + bv, 0.f));
    }
    atomicMax((unsigned int*)&y[b*COUT + co], __float_as_uint(m));
  }
}

// =================================================================
// target conv2/conv3: implicit-GEMM via MFMA bf16 (unchanged)
// =================================================================
template<int CIN, int COUT, int NT2, bool POOL>
__global__ __launch_bounds__(512) void k_convmfma(
    const u16* __restrict__ xin, const u16* __restrict__ wtb,
    const float* __restrict__ bias, u16* __restrict__ yout,
    unsigned int* __restrict__ pool, int Lin, int Lout) {
  constexpr int KD = CIN*8;
  constexpr int NCH = KD/32;
  constexpr int MT = 256, ROWS = MT + 7;
  constexpr int XPAD = CIN + 8;
  constexpr int WPAD = KD + 8;
  __shared__ u16 xs[ROWS*XPAD];
  __shared__ u16 wsd[COUT*WPAD];
  int b = blockIdx.y;
  int l0 = blockIdx.x * MT;
  int tid = threadIdx.x;
  {
    const unsigned* wg = (const unsigned*)wtb;
    unsigned* wl = (unsigned*)wsd;
    constexpr int KD2 = KD/2, WP2 = WPAD/2;
    for (int i = tid; i < COUT*KD2; i += 512) {
      int co = i / KD2, c = i % KD2;
      wl[co*WP2 + c] = wg[i];
    }
  }
  {
    const unsigned* xg = (const unsigned*)(xin + (size_t)b*Lin*CIN);
    unsigned* xl = (unsigned*)xs;
    constexpr int C2 = CIN/2, XP2 = XPAD/2;
    for (int i = tid; i < ROWS*C2; i += 512) {
      int r = i / C2, c = i % C2;
      unsigned v = 0;
      if (l0 + r < Lin) v = xg[(size_t)l0*C2 + i];
      xl[r*XP2 + c] = v;
    }
  }
  __syncthreads();
  int lane = tid & 63;
  int w = tid >> 6;
  int mg = w & 3, ng = w >> 2;
  int l15 = lane & 15, l4 = lane >> 4;
  f32x4 acc[4][NT2];
  #pragma unroll
  for (int mi = 0; mi < 4; ++mi)
    #pragma unroll
    for (int nj = 0; nj < NT2; ++nj) acc[mi][nj] = (f32x4){0.f, 0.f, 0.f, 0.f};

  #pragma unroll
  for (int ch = 0; ch < NCH; ++ch) {
    const int kk = (ch*32) / CIN;
    const int cib = (ch*32) % CIN + l4*8;
    bh8 a[4], bb[NT2];
    #pragma unroll
    for (int mi = 0; mi < 4; ++mi) {
      int row = mg*64 + mi*16 + l15 + kk;
      a[mi] = *(const bh8*)&xs[row*XPAD + cib];
    }
    #pragma unroll
    for (int nj = 0; nj < NT2; ++nj) {
      int co = (ng*NT2 + nj)*16 + l15;
      bb[nj] = *(const bh8*)&wsd[co*WPAD + ch*32 + l4*8];
    }
    #pragma unroll
    for (int mi = 0; mi < 4; ++mi)
      #pragma unroll
      for (int nj = 0; nj < NT2; ++nj)
        acc[mi][nj] = __builtin_amdgcn_mfma_f32_16x16x32_bf16(a[mi], bb[nj], acc[mi][nj], 0, 0, 0);
  }

  if (!POOL) {
    #pragma unroll
    for (int nj = 0; nj < NT2; ++nj) {
      int co = (ng*NT2 + nj)*16 + l15;
      float bv = bias[co];
      #pragma unroll
      for (int mi = 0; mi < 4; ++mi)
        #pragma unroll
        for (int r = 0; r < 4; ++r) {
          int m = mg*64 + mi*16 + l4*4 + r;
          if (l0 + m < Lout)
            yout[((size_t)b*Lout + l0 + m)*COUT + co] = f2b(fmaxf(acc[mi][nj][r] + bv, 0.f));
        }
    }
  } else {
    #pragma unroll
    for (int nj = 0; nj < NT2; ++nj) {
      int co = (ng*NT2 + nj)*16 + l15;
      float bv = bias[co];
      float mx = 0.f;
      #pragma unroll
      for (int mi = 0; mi < 4; ++mi)
        #pragma unroll
        for (int r = 0; r < 4; ++r) {
          int m = mg*64 + mi*16 + l4*4 + r;
          if (l0 + m < Lout) mx = fmaxf(mx, fmaxf(acc[mi][nj][r] + bv, 0.f));
        }
      mx = fmaxf(mx, __shfl_xor(mx, 16, 64));
      mx = fmaxf(mx, __shfl_xor(mx, 32, 64));
      if (l4 == 0) atomicMax(&pool[b*COUT + co], __float_as_uint(mx));
    }
  }
}

// =================================================================
// register-tiled f32 GEMM (no split; used for large-M h1/h2)
// =================================================================
template<int BM, int BN, int BK, int TM, int TN, bool BIAS, bool RELU>
__global__ void k_gemm(const float* __restrict__ X, const float* __restrict__ W,
                       const float* __restrict__ bias, float* __restrict__ Y,
                       int K, int C) {
  constexpr int NTH = (BM/TM)*(BN/TN);
  static_assert(NTH == 256, "block must be 256 threads");
  __shared__ float xs[BK][BM + 1];
  __shared__ float wsm[BK][BN];
  const int m0 = blockIdx.y * BM;
  const int c0 = blockIdx.x * BN;
  const int tn = threadIdx.x % (BN/TN);
  const int tm = threadIdx.x / (BN/TN);
  float acc[TM][TN];
  #pragma unroll
  for (int i = 0; i < TM; ++i)
    #pragma unroll
    for (int j = 0; j < TN; ++j) acc[i][j] = 0.f;

  for (int k0 = 0; k0 < K; k0 += BK) {
    #pragma unroll
    for (int i = threadIdx.x; i < BM*BK; i += NTH) {
      int m = i / BK, k = i % BK;
      xs[k][m] = X[(long)(m0 + m)*K + k0 + k];
    }
    #pragma unroll
    for (int i = threadIdx.x; i < BK*BN; i += NTH) {
      int k = i / BN, c = i % BN;
      wsm[k][c] = W[(long)(k0 + k)*C + c0 + c];
    }
    __syncthreads();
    #pragma unroll
    for (int k = 0; k < BK; ++k) {
      float xv[TM], wv[TN];
      #pragma unroll
      for (int i = 0; i < TM; ++i) xv[i] = xs[k][tm*TM + i];
      #pragma unroll
      for (int j = 0; j < TN; ++j) wv[j] = wsm[k][tn*TN + j];
      #pragma unroll
      for (int i = 0; i < TM; ++i)
        #pragma unroll
        for (int j = 0; j < TN; ++j) acc[i][j] = fmaf(xv[i], wv[j], acc[i][j]);
    }
    __syncthreads();
  }
  #pragma unroll
  for (int i = 0; i < TM; ++i) {
    float* yr = Y + (long)(m0 + tm*TM + i)*C + c0 + tn*TN;
    #pragma unroll
    for (int j = 0; j < TN; ++j) {
      float v = acc[i][j];
      if (BIAS) v += bias[c0 + tn*TN + j];
      if (RELU) v = fmaxf(v, 0.f);
      yr[j] = v;
    }
  }
}

// =================================================================
// split-K f32 GEMM for skinny-M (M=256) MLP layers.
// grid (C/BN, M/BM, K/KS); each block accumulates its K-chunk and
// atomicAdds into pre-zeroed Y. Bias/relu applied by k_bias_relu after.
// =================================================================
template<int BM, int BN, int BK, int TM, int TN>
__global__ void k_gemm_sk(const float* __restrict__ X, const float* __restrict__ W,
                          float* __restrict__ Y, int K, int C, int KS) {
  constexpr int NTH = (BM/TM)*(BN/TN);
  static_assert(NTH == 256, "block must be 256 threads");
  __shared__ float xs[BK][BM + 1];
  __shared__ float wsm[BK][BN];
  const int m0 = blockIdx.y * BM;
  const int c0 = blockIdx.x * BN;
  const int kbeg = blockIdx.z * KS;
  const int kend = min(K, kbeg + KS);
  const int tn = threadIdx.x % (BN/TN);
  const int tm = threadIdx.x / (BN/TN);
  float acc[TM][TN];
  #pragma unroll
  for (int i = 0; i < TM; ++i)
    #pragma unroll
    for (int j = 0; j < TN; ++j) acc[i][j] = 0.f;

  for (int k0 = kbeg; k0 < kend; k0 += BK) {
    #pragma unroll
    for (int i = threadIdx.x; i < BM*BK; i += NTH) {
      int m = i / BK, k = i % BK;
      xs[k][m] = X[(long)(m0 + m)*K + k0 + k];
    }
    #pragma unroll
    for (int i = threadIdx.x; i < BK*BN; i += NTH) {
      int k = i / BN, c = i % BN;
      wsm[k][c] = W[(long)(k0 + k)*C + c0 + c];
    }
    __syncthreads();
    #pragma unroll
    for (int k = 0; k < BK; ++k) {
      float xv[TM], wv[TN];
      #pragma unroll
      for (int i = 0; i < TM; ++i) xv[i] = xs[k][tm*TM + i];
      #pragma unroll
      for (int j = 0; j < TN; ++j) wv[j] = wsm[k][tn*TN + j];
      #pragma unroll
      for (int i = 0; i < TM; ++i)
        #pragma unroll
        for (int j = 0; j < TN; ++j) acc[i][j] = fmaf(xv[i], wv[j], acc[i][j]);
    }
    __syncthreads();
  }
  #pragma unroll
  for (int i = 0; i < TM; ++i) {
    float* yr = Y + (long)(m0 + tm*TM + i)*C + c0 + tn*TN;
    #pragma unroll
    for (int j = 0; j < TN; ++j) atomicAdd(&yr[j], acc[i][j]);
  }
}

// bias + optional relu, in place over [rows*C]
__global__ void k_bias_relu(float* __restrict__ Y, const float* __restrict__ bias,
                            long total, int C, int relu) {
  long o = blockIdx.x*256L + threadIdx.x;
  if (o >= total) return;
  int c = (int)(o % C);
  float v = Y[o] + bias[c];
  if (relu) v = fmaxf(v, 0.f);
  Y[o] = v;
}

// per-node attention terms
__global__ void k_attn_nodeterms(const float* __restrict__ h, const float* __restrict__ a_s,
                                 const float* __restrict__ a_d, float* __restrict__ as_o,
                                 float* __restrict__ ad_o, int H, int CH) {
  long t = blockIdx.x*256L + threadIdx.x;
  if (t >= (long)NN * H) return;
  int n = (int)(t / H), hh = (int)(t % H);
  const float* hr = h + ((long)n*H + hh)*CH;
  float s1 = 0.f, s2 = 0.f;
  for (int c = 0; c < CH; ++c) {
    float v = hr[c];
    s1 = fmaf(v, a_s[hh*CH + c], s1);
    s2 = fmaf(v, a_d[hh*CH + c], s2);
  }
  as_o[t] = s1; ad_o[t] = s2;
}

// per-edge attention logit with leaky_relu(0.2). e >= EE are self loops.
template<int H>
__global__ void k_edge_attn(const int* __restrict__ ei, const float* __restrict__ ea,
                            const float* __restrict__ asb, const float* __restrict__ adb,
                            const float* __restrict__ M, const float* __restrict__ aeself,
                            float* __restrict__ a_out) {
  long e = blockIdx.x*256L + threadIdx.x;
  if (e >= (long)EN) return;
  int s, d;
  float av[H];
  if (e < EE) {
    s = ei[e]; d = ei[EE + e];
    float er[5];
    #pragma unroll
    for (int j = 0; j < 5; ++j) er[j] = ea[e*5 + j];
    #pragma unroll
    for (int h = 0; h < H; ++h) {
      float t = 0.f;
      #pragma unroll
      for (int j = 0; j < 5; ++j) t = fmaf(er[j], M[j*H + h], t);
      av[h] = t;
    }
  } else {
    s = d = (int)(e - EE);
    #pragma unroll
    for (int h = 0; h < H; ++h) av[h] = aeself[h];
  }
  #pragma unroll
  for (int h = 0; h < H; ++h) {
    float v = asb[s*H + h] + adb[d*H + h] + av[h];
    a_out[e*H + h] = (v > 0.f) ? v : 0.2f * v;
  }
}

// ------------- CSR build -------------
__global__ void k_deg(const int* __restrict__ ei, int* __restrict__ deg) {
  long e = blockIdx.x*256L + threadIdx.x;
  if (e >= (long)EN) return;
  int d = (e < EE) ? ei[EE + e] : (int)(e - EE);
  atomicAdd(&deg[d], 1);
}

__global__ void k_scan(const int* __restrict__ deg, int* __restrict__ rowptr,
                       int* __restrict__ cursor) {
  __shared__ int ps[256];
  int tid = threadIdx.x;
  int base = tid * 128;           // 256*128 = 32768 = NN
  int s = 0;
  for (int i = 0; i < 128; ++i) s += deg[base + i];
  ps[tid] = s;
  __syncthreads();
  for (int off = 1; off < 256; off <<= 1) {
    int v = (tid >= off) ? ps[tid - off] : 0;
    __syncthreads();
    ps[tid] += v;
    __syncthreads();
  }
  int run = ps[tid] - s;          // exclusive prefix
  for (int i = 0; i < 128; ++i) {
    rowptr[base + i] = run;
    cursor[base + i] = run;
    run += deg[base + i];
  }
  if (tid == 255) rowptr[NN] = run;
}

__global__ void k_scatter(const int* __restrict__ ei, int* __restrict__ cursor,
                          int* __restrict__ csr_src, int* __restrict__ csr_eid) {
  long e = blockIdx.x*256L + threadIdx.x;
  if (e >= (long)EN) return;
  int s, d;
  if (e < EE) { s = ei[e]; d = ei[EE + e]; }
  else        { s = d = (int)(e - EE); }
  int p = atomicAdd(&cursor[d], 1);
  csr_src[p] = s;
  csr_eid[p] = (int)e;
}

// =================================================================
// GAT aggregation: wave per destination node. ACT: 0=elu, 1=relu
// =================================================================
template<int H, int CH, int ACT>
__global__ void k_gat_aggr(const int* __restrict__ rowptr, const int* __restrict__ csr_src,
                           const int* __restrict__ csr_eid, const float* __restrict__ a,
                           const float* __restrict__ hfeat, const float* __restrict__ bias,
                           float* __restrict__ out) {
  int wid = (int)((blockIdx.x*(long)blockDim.x + threadIdx.x) >> 6);
  int lane = threadIdx.x & 63;
  if (wid >= NN) return;
  int row0 = rowptr[wid], row1 = rowptr[wid + 1];
  constexpr int F = H * CH;
  constexpr int NJ = (F + 63) / 64;
  float amax[H], asum[H], rinv[H];
  #pragma unroll
  for (int h = 0; h < H; ++h) amax[h] = -1e30f;
  for (int p = row0 + lane; p < row1; p += 64) {
    int e = csr_eid[p];
    #pragma unroll
    for (int h = 0; h < H; ++h) amax[h] = fmaxf(amax[h], a[(long)e*H + h]);
  }
  #pragma unroll
  for (int h = 0; h < H; ++h)
    for (int off = 1; off < 64; off <<= 1) amax[h] = fmaxf(amax[h], __shfl_xor(amax[h], off, 64));
  #pragma unroll
  for (int h = 0; h < H; ++h) asum[h] = 0.f;
  for (int p = row0 + lane; p < row1; p += 64) {
    int e = csr_eid[p];
    #pragma unroll
    for (int h = 0; h < H; ++h) asum[h] += __expf(a[(long)e*H + h] - amax[h]);
  }
  #pragma unroll
  for (int h = 0; h < H; ++h) {
    for (int off = 1; off < 64; off <<= 1) asum[h] += __shfl_xor(asum[h], off, 64);
    rinv[h] = 1.f / (asum[h] + 1e-16f);
  }
  float acc[NJ];
  #pragma unroll
  for (int j = 0; j < NJ; ++j) acc[j] = 0.f;
  for (int p = row0; p < row1; ++p) {
    int e = csr_eid[p];
    int s = csr_src[p];
    const float* hr = hfeat + (long)s * F;
    #pragma unroll
    for (int j = 0; j < NJ; ++j) {
      int idx = j*64 + lane;
      if ((F % 64 == 0) || idx < F) {
        int h = idx / CH;
        float al = __expf(a[(long)e*H + h] - amax[h]) * rinv[h];
        acc[j] = fmaf(al, hr[idx], acc[j]);
      }
    }
  }
  float* orow = out + (long)wid * F;
  #pragma unroll
  for (int j = 0; j < NJ; ++j) {
    int idx = j*64 + lane;
    if ((F % 64 == 0) || idx < F) {
      float v = acc[j] + bias[idx];
      if (ACT == 0) v = (v > 0.f) ? v : expm1f(v);
      else          v = fmaxf(v, 0.f);
      orow[idx] = v;
    }
  }
}

// graph max pool (relu'd input >= 0, pooled pre-zeroed)
__global__ void k_pool(const float* __restrict__ g2o, const int* __restrict__ batch,
                       unsigned int* __restrict__ pooled) {
  long o = blockIdx.x*256L + threadIdx.x;
  if (o >= (long)NN * 96) return;
  int n = (int)(o / 96), c = (int)(o % 96);
  atomicMax(&pooled[batch[n]*96 + c], __float_as_uint(g2o[o]));
}

__global__ void k_concat(const float* __restrict__ cd, const float* __restrict__ ct,
                         const float* __restrict__ gfc, float* __restrict__ xc) {
  int t = blockIdx.x*256 + threadIdx.x;
  if (t >= NB*288) return;
  int b = t / 288, c = t % 288;
  float v = (c < 96) ? cd[b*96 + c] : (c < 192) ? ct[b*96 + (c-96)] : gfc[b*96 + (c-192)];
  xc[t] = v;
}

// final 512-dot per row
__global__ void k_final(const float* __restrict__ x, const float* __restrict__ w,
                        const float* __restrict__ b, float* __restrict__ out) {
  int wid = (int)((blockIdx.x*256L + threadIdx.x) >> 6);
  int lane = threadIdx.x & 63;
  if (wid >= NB) return;
  const float* xr = x + (long)wid*512;
  float s = 0.f;
  for (int k = lane; k < 512; k += 64) s = fmaf(xr[k], w[k], s);
  for (int off = 1; off < 64; off <<= 1) s += __shfl_xor(s, off, 64);
  if (lane == 0) out[wid] = s + b[0];
}

// =================================================================
extern "C" void kernel_launch(void* const* d_in, const int* in_sizes, int n_in,
                              void* d_out, int out_size, void* d_ws, size_t ws_size,
                              hipStream_t stream) {
  const int*   xd     = (const int*)  d_in[0];
  const int*   xt     = (const int*)  d_in[1];
  const float* ax     = (const float*)d_in[2];
  const int*   ei     = (const int*)  d_in[3];
  const float* ea     = (const float*)d_in[4];
  const int*   batch  = (const int*)  d_in[5];
  const float* emb_xd = (const float*)d_in[6];
  const float* emb_xt = (const float*)d_in[7];
  const float* wd1 = (const float*)d_in[8];  const float* bd1 = (const float*)d_in[9];
  const float* wd2 = (const float*)d_in[10]; const float* bd2 = (const float*)d_in[11];
  const float* wd3 = (const float*)d_in[12]; const float* bd3 = (const float*)d_in[13];
  const float* wt1 = (const float*)d_in[14]; const float* bt1 = (const float*)d_in[15];
  const float* wt2 = (const float*)d_in[16]; const float* bt2 = (const float*)d_in[17];
  const float* wt3 = (const float*)d_in[18]; const float* bt3 = (const float*)d_in[19];
  const float* g1_w  = (const float*)d_in[20]; const float* g1_as = (const float*)d_in[21];
  const float* g1_ad = (const float*)d_in[22]; const float* g1_we = (const float*)d_in[23];
  const float* g1_ae = (const float*)d_in[24]; const float* g1_b  = (const float*)d_in[25];
  const float* g2_w  = (const float*)d_in[26]; const float* g2_as = (const float*)d_in[27];
  const float* g2_ad = (const float*)d_in[28]; const float* g2_we = (const float*)d_in[29];
  const float* g2_ae = (const float*)d_in[30]; const float* g2_b  = (const float*)d_in[31];
  const float* fc1_w = (const float*)d_in[32]; const float* fc1_b = (const float*)d_in[33];
  const float* c1_w = (const float*)d_in[34]; const float* c1_b = (const float*)d_in[35];
  const float* c2_w = (const float*)d_in[36]; const float* c2_b = (const float*)d_in[37];
  const float* c3_w = (const float*)d_in[38]; const float* c3_b = (const float*)d_in[39];
  const float* c4_w = (const float*)d_in[40]; const float* c4_b = (const float*)d_in[41];
  float* out = (float*)d_out;

  char* ws = (char*)d_ws;
  auto F = [&](size_t off) { return (float*)(ws + off); };
  auto I = [&](size_t off) { return (int*)(ws + off); };
  auto U = [&](size_t off) { return (unsigned int*)(ws + off); };
  auto H = [&](size_t off) { return (u16*)(ws + off); };

  // ---- zero-init the atomically-updated buffers ----
  hipMemsetAsync(ws + OFF_CB,   0, 64*sizeof(float), stream);
  hipMemsetAsync(ws + OFF_DEG,  0, NN*sizeof(int),   stream);
  hipMemsetAsync(ws + OFF_CD,   0, NB*96*sizeof(float), stream);
  hipMemsetAsync(ws + OFF_CT,   0, NB*96*sizeof(float), stream);
  hipMemsetAsync(ws + OFF_POOL, 0, NB*96*sizeof(float), stream);
  // split-K accumulators
  hipMemsetAsync(ws + OFF_GFC,  0, NB*96*sizeof(float),   stream);
  hipMemsetAsync(ws + OFF_M1B,  0, NB*1024*sizeof(float), stream);
  hipMemsetAsync(ws + OFF_M2B,  0, NB*1024*sizeof(float), stream);
  hipMemsetAsync(ws + OFF_M3B,  0, NB*512*sizeof(float),  stream);

  // ---- tables / weight converts ----
  k_tables<<<(8320 + 6656 + 30 + 255)/256, 256, 0, stream>>>(
      wd1, emb_xd, wt1, emb_xt, g1_we, g1_ae, g2_we, g2_ae,
      F(OFF_FD), F(OFF_FT), F(OFF_CB));
  k_wcvt<<<(64*256 + 96*512 + 255)/256, 256, 0, stream>>>(
      wt2, wt3, H(OFF_WT2B), H(OFF_WT3B));
  k_easum<<<256, 256, 0, stream>>>(ea, F(OFF_CB));
  k_finalize<<<1, 64, 0, stream>>>(F(OFF_CB));

  // ---- drug weight transposes (f32 path) ----
  k_wtrans<<<(8192 + 255)/256, 256, 0, stream>>>(wd2, F(OFF_WD2T), 64, 32, 4);
  k_wtrans<<<(24576 + 255)/256, 256, 0, stream>>>(wd3, F(OFF_WD3T), 96, 64, 4);

  // ---- drug conv branch (f32 direct): L=100 -> 97 -> 94 -> 91 -> maxpool ----
  k_conv1_lut<4,65,32><<<dim3((32*97 + 255)/256, NB), 256, 0, stream>>>(
      xd, F(OFF_FD), bd1, F(OFF_A), 100, 97);
  k_conv<32,4,64,4,16,false><<<dim3((94 + 63)/64, NB), 256, 0, stream>>>(
      F(OFF_A), F(OFF_WD2T), bd2, F(OFF_B), 97, 94);
  k_conv<64,4,96,2,16,true><<<dim3((91 + 31)/32, NB), 192, 0, stream>>>(
      F(OFF_B), F(OFF_WD3T), bd3, F(OFF_CD), 94, 91);

  // ---- target conv branch (bf16 MFMA): 1000 -> 993 -> 986 -> 979 -> maxpool ----
  k_conv1t<<<dim3((993 + 15)/16, NB), 512, 0, stream>>>(
      xt, F(OFF_FT), bt1, H(OFF_A), 1000, 993);
  k_convmfma<32,64,2,false><<<dim3(4, NB), 512, 0, stream>>>(
      H(OFF_A), H(OFF_WT2B), bt2, H(OFF_B), nullptr, 993, 986);
  k_convmfma<64,96,3,true><<<dim3(4, NB), 512, 0, stream>>>(
      H(OFF_B), H(OFF_WT3B), bt3, nullptr, U(OFF_CT), 986, 979);

  // ---- GAT layer 1 ----
  k_gemm<64,64,24,4,4,false,false><<<dim3(320/64, NN/64), 256, 0, stream>>>(
      ax, g1_w, nullptr, F(OFF_A), 24, 320);
  k_attn_nodeterms<<<(NN*5 + 255)/256, 256, 0, stream>>>(
      F(OFF_A), g1_as, g1_ad, F(OFF_AS1), F(OFF_AD1), 5, 64);
  k_edge_attn<5><<<(EN + 255)/256, 256, 0, stream>>>(
      ei, ea, F(OFF_AS1), F(OFF_AD1), F(OFF_CB), F(OFF_CB) + 35, F(OFF_C));

  k_deg<<<(EN + 255)/256, 256, 0, stream>>>(ei, I(OFF_DEG));
  k_scan<<<1, 256, 0, stream>>>(I(OFF_DEG), I(OFF_ROWP), I(OFF_CUR));
  k_scatter<<<(EN + 255)/256, 256, 0, stream>>>(ei, I(OFF_CUR), I(OFF_CSRS), I(OFF_CSRE));

  k_gat_aggr<5,64,0><<<NN/4, 256, 0, stream>>>(
      I(OFF_ROWP), I(OFF_CSRS), I(OFF_CSRE), F(OFF_C), F(OFF_A), g1_b, F(OFF_B));

  // ---- GAT layer 2 ----
  k_gemm<32,96,32,2,6,false,false><<<dim3(96/96, NN/32), 256, 0, stream>>>(
      F(OFF_B), g2_w, nullptr, F(OFF_C), 320, 96);
  k_attn_nodeterms<<<(NN + 255)/256, 256, 0, stream>>>(
      F(OFF_C), g2_as, g2_ad, F(OFF_AS2), F(OFF_AD2), 1, 96);
  k_edge_attn<1><<<(EN + 255)/256, 256, 0, stream>>>(
      ei, ea, F(OFF_AS2), F(OFF_AD2), F(OFF_CB) + 25, F(OFF_CB) + 40, F(OFF_A2));
  k_gat_aggr<1,96,1><<<NN/4, 256, 0, stream>>>(
      I(OFF_ROWP), I(OFF_CSRS), I(OFF_CSRE), F(OFF_A2), F(OFF_C), g2_b, F(OFF_G2O));

  // ---- graph pool + fc1 (split-K) ----
  k_pool<<<(int)(((long)NN*96 + 255)/256), 256, 0, stream>>>(
      F(OFF_G2O), batch, U(OFF_POOL));
  k_gemm_sk<64,32,32,4,2><<<dim3(96/32, NB/64, 3), 256, 0, stream>>>(
      F(OFF_POOL), fc1_w, F(OFF_GFC), 96, 96, 32);
  k_bias_relu<<<(NB*96 + 255)/256, 256, 0, stream>>>(
      F(OFF_GFC), fc1_b, (long)NB*96, 96, 1);

  // ---- concat + MLP head (split-K GEMMs) ----
  k_concat<<<(NB*288 + 255)/256, 256, 0, stream>>>(
      F(OFF_CD), F(OFF_CT), F(OFF_GFC), F(OFF_XC));

  k_gemm_sk<64,64,32,4,4><<<dim3(1024/64, NB/64, 3), 256, 0, stream>>>(
      F(OFF_XC), c1_w, F(OFF_M1B), 288, 1024, 96);
  k_bias_relu<<<(NB*1024 + 255)/256, 256, 0, stream>>>(
      F(OFF_M1B), c1_b, (long)NB*1024, 1024, 1);

  k_gemm_sk<64,64,32,4,4><<<dim3(1024/64, NB/64, 8), 256, 0, stream>>>(
      F(OFF_M1B), c2_w, F(OFF_M2B), 1024, 1024, 128);
  k_bias_relu<<<(NB*1024 + 255)/256, 256, 0, stream>>>(
      F(OFF_M2B), c2_b, (long)NB*1024, 1024, 1);

  k_gemm_sk<64,64,32,4,4><<<dim3(512/64, NB/64, 8), 256, 0, stream>>>(
      F(OFF_M2B), c3_w, F(OFF_M3B), 1024, 512, 128);
  k_bias_relu<<<(NB*512 + 255)/256, 256, 0, stream>>>(
      F(OFF_M3B), c3_b, (long)NB*512, 512, 1);

  k_final<<<(NB*64 + 255)/256, 256, 0, stream>>>(F(OFF_M3B), c4_w, c4_b, out);
}

// Round 7
// 961.630 us; speedup vs baseline: 1.9618x; 1.0485x over previous
//
#include <hip/hip_runtime.h>

// ---------------- problem constants ----------------
constexpr int NN = 32768;      // nodes
constexpr int EE = 524288;     // edges
constexpr int NB = 256;        // graphs / batch
constexpr int EN = EE + NN;    // edges + self loops

typedef unsigned short u16;
typedef short bh8 __attribute__((ext_vector_type(8)));    // 8 bf16 (4 VGPRs)
typedef float f32x4 __attribute__((ext_vector_type(4)));  // MFMA accumulator

__device__ inline u16 f2b(float f) {   // f32 -> bf16 round-to-nearest-even
  unsigned u = __float_as_uint(f);
  return (u16)((u + 0x7fffu + ((u >> 16) & 1u)) >> 16);
}

// ---------------- workspace layout (bytes) ----------------
constexpr size_t MB = 1ull << 20;
constexpr size_t OFF_A    = 0;        // conv y1 (drug f32 / target bf16-T), later h1 [N,320]
constexpr size_t OFF_B    = 48*MB;    // conv y2 (<=33MB), later g1o [N,320] (42MB: 48..90)
constexpr size_t OFF_AC   = 100*MB;   // a_csr [EN,5] f32 (11.2MB: 100..111.2) reused layer2
constexpr size_t OFF_C    = 116*MB;   // a1 [EN,5], later h2 [N,96]
constexpr size_t OFF_CSRS = 130*MB;   // csr_src [EN]
constexpr size_t OFF_CSRE = 133*MB;   // csr_eid [EN]
constexpr size_t OFF_ROWP = 136*MB;   // rowptr [N+1]
constexpr size_t OFF_DEG  = 137*MB;   // deg [N]
constexpr size_t OFF_CUR  = 138*MB;   // cursor [N]
constexpr size_t OFF_A2   = 139*MB;   // a2 [EN]
constexpr size_t OFF_G2O  = 142*MB;   // g2o [N,96]
constexpr size_t OFF_AS1  = 155*MB;   // [N,5]
constexpr size_t OFF_AD1  = 156*MB;
constexpr size_t OFF_AS2  = 157*MB;   // [N]
constexpr size_t OFF_AD2  = 158*MB;
constexpr size_t OFF_CD   = 159*MB;   // [256,96] pooled drug conv
constexpr size_t OFF_CT   = 160*MB;   // [256,96] pooled target conv
constexpr size_t OFF_POOL = 161*MB;   // [256,96] graph pool
constexpr size_t OFF_GFC  = 162*MB;   // [256,96]
constexpr size_t OFF_XC   = 163*MB;   // [256,288]
constexpr size_t OFF_M1B  = 164*MB;   // [256,1024]
constexpr size_t OFF_M2B  = 165*MB;   // [256,1024]
constexpr size_t OFF_M3B  = 166*MB;   // [256,512]
constexpr size_t OFF_FD   = 167*MB;   // F table drug [32][4][65] f32
constexpr size_t OFF_FT   = 168*MB;   // F table target [8][26][32] f32 (k,v,co layout!)
constexpr size_t OFF_WD2T = 169*MB;   // drug w2 [ci][k][co] f32
constexpr size_t OFF_WD3T = 170*MB;   // drug w3 [ci][k][co] f32
constexpr size_t OFF_WT2B = 171*MB;   // target w2 bf16 [co][kk*32+ci]  (64x256)
constexpr size_t OFF_WT3B = 172*MB;   // target w3 bf16 [co][kk*64+ci]  (96x512)
constexpr size_t OFF_CB   = 173*MB;   // const block: [0:25]=M1, [25:30]=M2, [30:35]=easum,
                                      // [35:40]=aeself1, [40]=ae2self, [41:46]=eamean

// =================================================================
// Tiny precompute tables: F_drug [co][k][v], F_target [k][v][co], M1, M2
// =================================================================
__global__ void k_tables(const float* __restrict__ wd1, const float* __restrict__ emb_xd,
                         const float* __restrict__ wt1, const float* __restrict__ emb_xt,
                         const float* __restrict__ g1we, const float* __restrict__ g1ae,
                         const float* __restrict__ g2we, const float* __restrict__ g2ae,
                         float* __restrict__ Fd, float* __restrict__ Ft,
                         float* __restrict__ CB) {
  int t = blockIdx.x * 256 + threadIdx.x;
  const int NFd = 32*4*65, NFt = 32*8*26;
  if (t < NFd) {                       // Fd[co][k][v]
    int v = t % 65; int ck = t / 65; int k = ck & 3; int co = ck >> 2;
    float s = 0.f;
    for (int ci = 0; ci < 128; ++ci)
      s = fmaf(wd1[(co*128 + ci)*4 + k], emb_xd[v*128 + ci], s);
    Fd[t] = s;
  } else if (t < NFd + NFt) {          // Ft stored [k][v][co] for conflict-free LDS
    int u = t - NFd;
    int v = u % 26; int ck = u / 26; int k = ck & 7; int co = ck >> 3;
    float s = 0.f;
    for (int ci = 0; ci < 128; ++ci)
      s = fmaf(wt1[(co*128 + ci)*8 + k], emb_xt[v*128 + ci], s);
    Ft[(k*26 + v)*32 + co] = s;
  } else if (t < NFd + NFt + 25) {     // M1[j][h]
    int u = t - NFd - NFt; int h = u % 5, j = u / 5;
    float s = 0.f;
    for (int c = 0; c < 64; ++c)
      s = fmaf(g1we[j*320 + h*64 + c], g1ae[h*64 + c], s);
    CB[j*5 + h] = s;
  } else if (t < NFd + NFt + 30) {     // M2[j]
    int j = t - NFd - NFt - 25;
    float s = 0.f;
    for (int c = 0; c < 96; ++c)
      s = fmaf(g2we[j*96 + c], g2ae[c], s);
    CB[25 + j] = s;
  }
}

// target conv2/conv3 weights -> bf16, layout [co][k] with k = kk*CIN + ci
__global__ void k_wcvt(const float* __restrict__ w2, const float* __restrict__ w3,
                       u16* __restrict__ o2, u16* __restrict__ o3) {
  int t = blockIdx.x*256 + threadIdx.x;
  if (t < 64*256) {
    int co = t >> 8, k = t & 255, kk = k >> 5, ci = k & 31;
    o2[t] = f2b(w2[(co*32 + ci)*8 + kk]);
  } else if (t < 64*256 + 96*512) {
    int u = t - 64*256;
    int co = u >> 9, k = u & 511, kk = k >> 6, ci = k & 63;
    o3[u] = f2b(w3[(co*64 + ci)*8 + kk]);
  }
}

// sum of ea columns -> CB[30..34] (pre-zeroed)
__global__ void k_easum(const float* __restrict__ ea, float* __restrict__ CB) {
  float acc[5] = {0,0,0,0,0};
  for (long e = blockIdx.x*256L + threadIdx.x; e < EE; e += 256L*gridDim.x) {
    #pragma unroll
    for (int j = 0; j < 5; ++j) acc[j] += ea[e*5 + j];
  }
  #pragma unroll
  for (int j = 0; j < 5; ++j)
    for (int off = 1; off < 64; off <<= 1) acc[j] += __shfl_xor(acc[j], off, 64);
  if ((threadIdx.x & 63) == 0) {
    #pragma unroll
    for (int j = 0; j < 5; ++j) atomicAdd(&CB[30 + j], acc[j]);
  }
}

// eamean, aeself1[h], ae2self
__global__ void k_finalize(float* __restrict__ CB) {
  if (blockIdx.x == 0 && threadIdx.x == 0) {
    float em[5];
    for (int j = 0; j < 5; ++j) { em[j] = CB[30 + j] / (float)EE; CB[41 + j] = em[j]; }
    for (int h = 0; h < 5; ++h) {
      float s = 0.f;
      for (int j = 0; j < 5; ++j) s = fmaf(em[j], CB[j*5 + h], s);
      CB[35 + h] = s;
    }
    float s = 0.f;
    for (int j = 0; j < 5; ++j) s = fmaf(em[j], CB[25 + j], s);
    CB[40] = s;
  }
}

// =================================================================
// drug conv1 via LUT (unchanged, f32 [b][co][l] out)
// =================================================================
template<int K, int V, int COUT>
__global__ void k_conv1_lut(const int* __restrict__ idx, const float* __restrict__ F,
                            const float* __restrict__ bias, float* __restrict__ y,
                            int L, int Lout) {
  __shared__ float Fs[COUT*K*V];
  __shared__ float bs[COUT];
  int b = blockIdx.y;
  for (int i = threadIdx.x; i < COUT*K*V; i += blockDim.x) Fs[i] = F[i];
  for (int i = threadIdx.x; i < COUT; i += blockDim.x) bs[i] = bias[i];
  __syncthreads();
  int o = blockIdx.x * blockDim.x + threadIdx.x;
  if (o >= COUT * Lout) return;
  int co = o / Lout, l = o % Lout;
  const int* ib = idx + b*L + l;
  float acc = bs[co];
  #pragma unroll
  for (int k = 0; k < K; ++k) acc += Fs[(co*K + k)*V + ib[k]];
  y[(b*COUT + co)*Lout + l] = fmaxf(acc, 0.f);
}

// =================================================================
// target conv1 via LUT -> bf16 transposed out y[b][l][co]
// =================================================================
__global__ __launch_bounds__(512) void k_conv1t(
    const int* __restrict__ idx, const float* __restrict__ Ftab,
    const float* __restrict__ bias, u16* __restrict__ y, int L, int Lout) {
  constexpr int K = 8, V = 26, CO = 32;
  __shared__ float Fs[K*V*CO];
  __shared__ float bs[CO];
  __shared__ int sq[16 + K];
  int b = blockIdx.y, l0 = blockIdx.x * 16;
  for (int i = threadIdx.x; i < K*V*CO; i += 512) Fs[i] = Ftab[i];
  if (threadIdx.x < CO) bs[threadIdx.x] = bias[threadIdx.x];
  if (threadIdx.x < 16 + K - 1) {
    int l = l0 + (int)threadIdx.x;
    sq[threadIdx.x] = (l < L) ? idx[b*L + l] : 0;
  }
  __syncthreads();
  int co = threadIdx.x & 31;
  int p = threadIdx.x >> 5;
  int l = l0 + p;
  if (l >= Lout) return;
  float acc = bs[co];
  #pragma unroll
  for (int k = 0; k < K; ++k) acc += Fs[(k*V + sq[p + k])*CO + co];
  y[((size_t)b*Lout + l)*CO + co] = f2b(fmaxf(acc, 0.f));
}

// weight transpose [co][ci][k] -> [ci][k][co] (drug branch, f32)
__global__ void k_wtrans(const float* __restrict__ w, float* __restrict__ wt,
                         int COUT, int CIN, int K) {
  int t = blockIdx.x*256 + threadIdx.x;
  if (t >= COUT*CIN*K) return;
  int k = t % K; int ci = (t / K) % CIN; int co = t / (K*CIN);
  wt[(ci*K + k)*COUT + co] = w[t];
}

// =================================================================
// drug direct conv (unchanged)
// =================================================================
template<int CIN, int K, int COUT, int G, int LG, bool POOL>
__global__ void k_conv(const float* __restrict__ x, const float* __restrict__ wt,
                       const float* __restrict__ bias, float* __restrict__ y,
                       int Lin, int Lout) {
  constexpr int LT = G * LG;
  __shared__ float xs[CIN][LT + K - 1];
  int b = blockIdx.y;
  int l0 = blockIdx.x * LT;
  const int nth = COUT * G;
  const float* xb = x + b*CIN*Lin;
  for (int i = threadIdx.x; i < CIN*(LT + K - 1); i += nth) {
    int ci = i / (LT + K - 1), dl = i % (LT + K - 1);
    int l = l0 + dl;
    xs[ci][dl] = (l < Lin) ? xb[ci*Lin + l] : 0.f;
  }
  __syncthreads();
  int co = threadIdx.x % COUT;
  int gg = threadIdx.x / COUT;
  float acc[LG];
  #pragma unroll
  for (int j = 0; j < LG; ++j) acc[j] = 0.f;
  for (int ci = 0; ci < CIN; ++ci) {
    float xr[LG + K - 1];
    #pragma unroll
    for (int t = 0; t < LG + K - 1; ++t) xr[t] = xs[ci][gg*LG + t];
    #pragma unroll
    for (int k = 0; k < K; ++k) {
      float wv = wt[(ci*K + k)*COUT + co];
      #pragma unroll
      for (int j = 0; j < LG; ++j) acc[j] = fmaf(wv, xr[j + k], acc[j]);
    }
  }
  float bv = bias[co];
  if (!POOL) {
    float* yb = y + (b*COUT + co)*Lout;
    #pragma unroll
    for (int j = 0; j < LG; ++j) {
      int l = l0 + gg*LG + j;
      if (l < Lout) yb[l] = fmaxf(acc[j] + bv, 0.f);
    }
  } else {
    float m = 0.f;
    #pragma unroll
    for (int j = 0; j < LG; ++j) {
      int l = l0 + gg*LG + j;
      if (l < Lout) m = fmaxf(m, fmaxf(acc[j] + bv, 0.f));
    }
    atomicMax((unsigned int*)&y[b*COUT + co], __float_as_uint(m));
  }
}

// =================================================================
// target conv2/conv3: implicit-GEMM via MFMA bf16 (unchanged)
// =================================================================
template<int CIN, int COUT, int NT2, bool POOL>
__global__ __launch_bounds__(512) void k_convmfma(
    const u16* __restrict__ xin, const u16* __restrict__ wtb,
    const float* __restrict__ bias, u16* __restrict__ yout,
    unsigned int* __restrict__ pool, int Lin, int Lout) {
  constexpr int KD = CIN*8;
  constexpr int NCH = KD/32;
  constexpr int MT = 256, ROWS = MT + 7;
  constexpr int XPAD = CIN + 8;
  constexpr int WPAD = KD + 8;
  __shared__ u16 xs[ROWS*XPAD];
  __shared__ u16 wsd[COUT*WPAD];
  int b = blockIdx.y;
  int l0 = blockIdx.x * MT;
  int tid = threadIdx.x;
  {
    const unsigned* wg = (const unsigned*)wtb;
    unsigned* wl = (unsigned*)wsd;
    constexpr int KD2 = KD/2, WP2 = WPAD/2;
    for (int i = tid; i < COUT*KD2; i += 512) {
      int co = i / KD2, c = i % KD2;
      wl[co*WP2 + c] = wg[i];
    }
  }
  {
    const unsigned* xg = (const unsigned*)(xin + (size_t)b*Lin*CIN);
    unsigned* xl = (unsigned*)xs;
    constexpr int C2 = CIN/2, XP2 = XPAD/2;
    for (int i = tid; i < ROWS*C2; i += 512) {
      int r = i / C2, c = i % C2;
      unsigned v = 0;
      if (l0 + r < Lin) v = xg[(size_t)l0*C2 + i];
      xl[r*XP2 + c] = v;
    }
  }
  __syncthreads();
  int lane = tid & 63;
  int w = tid >> 6;
  int mg = w & 3, ng = w >> 2;
  int l15 = lane & 15, l4 = lane >> 4;
  f32x4 acc[4][NT2];
  #pragma unroll
  for (int mi = 0; mi < 4; ++mi)
    #pragma unroll
    for (int nj = 0; nj < NT2; ++nj) acc[mi][nj] = (f32x4){0.f, 0.f, 0.f, 0.f};

  #pragma unroll
  for (int ch = 0; ch < NCH; ++ch) {
    const int kk = (ch*32) / CIN;
    const int cib = (ch*32) % CIN + l4*8;
    bh8 a[4], bb[NT2];
    #pragma unroll
    for (int mi = 0; mi < 4; ++mi) {
      int row = mg*64 + mi*16 + l15 + kk;
      a[mi] = *(const bh8*)&xs[row*XPAD + cib];
    }
    #pragma unroll
    for (int nj = 0; nj < NT2; ++nj) {
      int co = (ng*NT2 + nj)*16 + l15;
      bb[nj] = *(const bh8*)&wsd[co*WPAD + ch*32 + l4*8];
    }
    #pragma unroll
    for (int mi = 0; mi < 4; ++mi)
      #pragma unroll
      for (int nj = 0; nj < NT2; ++nj)
        acc[mi][nj] = __builtin_amdgcn_mfma_f32_16x16x32_bf16(a[mi], bb[nj], acc[mi][nj], 0, 0, 0);
  }

  if (!POOL) {
    #pragma unroll
    for (int nj = 0; nj < NT2; ++nj) {
      int co = (ng*NT2 + nj)*16 + l15;
      float bv = bias[co];
      #pragma unroll
      for (int mi = 0; mi < 4; ++mi)
        #pragma unroll
        for (int r = 0; r < 4; ++r) {
          int m = mg*64 + mi*16 + l4*4 + r;
          if (l0 + m < Lout)
            yout[((size_t)b*Lout + l0 + m)*COUT + co] = f2b(fmaxf(acc[mi][nj][r] + bv, 0.f));
        }
    }
  } else {
    #pragma unroll
    for (int nj = 0; nj < NT2; ++nj) {
      int co = (ng*NT2 + nj)*16 + l15;
      float bv = bias[co];
      float mx = 0.f;
      #pragma unroll
      for (int mi = 0; mi < 4; ++mi)
        #pragma unroll
        for (int r = 0; r < 4; ++r) {
          int m = mg*64 + mi*16 + l4*4 + r;
          if (l0 + m < Lout) mx = fmaxf(mx, fmaxf(acc[mi][nj][r] + bv, 0.f));
        }
      mx = fmaxf(mx, __shfl_xor(mx, 16, 64));
      mx = fmaxf(mx, __shfl_xor(mx, 32, 64));
      if (l4 == 0) atomicMax(&pool[b*COUT + co], __float_as_uint(mx));
    }
  }
}

// =================================================================
// register-tiled f32 GEMM (no split; used for large-M h1/h2)
// =================================================================
template<int BM, int BN, int BK, int TM, int TN, bool BIAS, bool RELU>
__global__ void k_gemm(const float* __restrict__ X, const float* __restrict__ W,
                       const float* __restrict__ bias, float* __restrict__ Y,
                       int K, int C) {
  constexpr int NTH = (BM/TM)*(BN/TN);
  static_assert(NTH == 256, "block must be 256 threads");
  __shared__ float xs[BK][BM + 1];
  __shared__ float wsm[BK][BN];
  const int m0 = blockIdx.y * BM;
  const int c0 = blockIdx.x * BN;
  const int tn = threadIdx.x % (BN/TN);
  const int tm = threadIdx.x / (BN/TN);
  float acc[TM][TN];
  #pragma unroll
  for (int i = 0; i < TM; ++i)
    #pragma unroll
    for (int j = 0; j < TN; ++j) acc[i][j] = 0.f;

  for (int k0 = 0; k0 < K; k0 += BK) {
    #pragma unroll
    for (int i = threadIdx.x; i < BM*BK; i += NTH) {
      int m = i / BK, k = i % BK;
      xs[k][m] = X[(long)(m0 + m)*K + k0 + k];
    }
    #pragma unroll
    for (int i = threadIdx.x; i < BK*BN; i += NTH) {
      int k = i / BN, c = i % BN;
      wsm[k][c] = W[(long)(k0 + k)*C + c0 + c];
    }
    __syncthreads();
    #pragma unroll
    for (int k = 0; k < BK; ++k) {
      float xv[TM], wv[TN];
      #pragma unroll
      for (int i = 0; i < TM; ++i) xv[i] = xs[k][tm*TM + i];
      #pragma unroll
      for (int j = 0; j < TN; ++j) wv[j] = wsm[k][tn*TN + j];
      #pragma unroll
      for (int i = 0; i < TM; ++i)
        #pragma unroll
        for (int j = 0; j < TN; ++j) acc[i][j] = fmaf(xv[i], wv[j], acc[i][j]);
    }
    __syncthreads();
  }
  #pragma unroll
  for (int i = 0; i < TM; ++i) {
    float* yr = Y + (long)(m0 + tm*TM + i)*C + c0 + tn*TN;
    #pragma unroll
    for (int j = 0; j < TN; ++j) {
      float v = acc[i][j];
      if (BIAS) v += bias[c0 + tn*TN + j];
      if (RELU) v = fmaxf(v, 0.f);
      yr[j] = v;
    }
  }
}

// =================================================================
// split-K f32 GEMM for skinny-M (M=256) MLP layers.
// =================================================================
template<int BM, int BN, int BK, int TM, int TN>
__global__ void k_gemm_sk(const float* __restrict__ X, const float* __restrict__ W,
                          float* __restrict__ Y, int K, int C, int KS) {
  constexpr int NTH = (BM/TM)*(BN/TN);
  static_assert(NTH == 256, "block must be 256 threads");
  __shared__ float xs[BK][BM + 1];
  __shared__ float wsm[BK][BN];
  const int m0 = blockIdx.y * BM;
  const int c0 = blockIdx.x * BN;
  const int kbeg = blockIdx.z * KS;
  const int kend = min(K, kbeg + KS);
  const int tn = threadIdx.x % (BN/TN);
  const int tm = threadIdx.x / (BN/TN);
  float acc[TM][TN];
  #pragma unroll
  for (int i = 0; i < TM; ++i)
    #pragma unroll
    for (int j = 0; j < TN; ++j) acc[i][j] = 0.f;

  for (int k0 = kbeg; k0 < kend; k0 += BK) {
    #pragma unroll
    for (int i = threadIdx.x; i < BM*BK; i += NTH) {
      int m = i / BK, k = i % BK;
      xs[k][m] = X[(long)(m0 + m)*K + k0 + k];
    }
    #pragma unroll
    for (int i = threadIdx.x; i < BK*BN; i += NTH) {
      int k = i / BN, c = i % BN;
      wsm[k][c] = W[(long)(k0 + k)*C + c0 + c];
    }
    __syncthreads();
    #pragma unroll
    for (int k = 0; k < BK; ++k) {
      float xv[TM], wv[TN];
      #pragma unroll
      for (int i = 0; i < TM; ++i) xv[i] = xs[k][tm*TM + i];
      #pragma unroll
      for (int j = 0; j < TN; ++j) wv[j] = wsm[k][tn*TN + j];
      #pragma unroll
      for (int i = 0; i < TM; ++i)
        #pragma unroll
        for (int j = 0; j < TN; ++j) acc[i][j] = fmaf(xv[i], wv[j], acc[i][j]);
    }
    __syncthreads();
  }
  #pragma unroll
  for (int i = 0; i < TM; ++i) {
    float* yr = Y + (long)(m0 + tm*TM + i)*C + c0 + tn*TN;
    #pragma unroll
    for (int j = 0; j < TN; ++j) atomicAdd(&yr[j], acc[i][j]);
  }
}

// bias + optional relu, in place over [rows*C]
__global__ void k_bias_relu(float* __restrict__ Y, const float* __restrict__ bias,
                            long total, int C, int relu) {
  long o = blockIdx.x*256L + threadIdx.x;
  if (o >= total) return;
  int c = (int)(o % C);
  float v = Y[o] + bias[c];
  if (relu) v = fmaxf(v, 0.f);
  Y[o] = v;
}

// per-node attention terms
__global__ void k_attn_nodeterms(const float* __restrict__ h, const float* __restrict__ a_s,
                                 const float* __restrict__ a_d, float* __restrict__ as_o,
                                 float* __restrict__ ad_o, int H, int CH) {
  long t = blockIdx.x*256L + threadIdx.x;
  if (t >= (long)NN * H) return;
  int n = (int)(t / H), hh = (int)(t % H);
  const float* hr = h + ((long)n*H + hh)*CH;
  float s1 = 0.f, s2 = 0.f;
  for (int c = 0; c < CH; ++c) {
    float v = hr[c];
    s1 = fmaf(v, a_s[hh*CH + c], s1);
    s2 = fmaf(v, a_d[hh*CH + c], s2);
  }
  as_o[t] = s1; ad_o[t] = s2;
}

// per-edge attention logit with leaky_relu(0.2). e >= EE are self loops.
template<int H>
__global__ void k_edge_attn(const int* __restrict__ ei, const float* __restrict__ ea,
                            const float* __restrict__ asb, const float* __restrict__ adb,
                            const float* __restrict__ M, const float* __restrict__ aeself,
                            float* __restrict__ a_out) {
  long e = blockIdx.x*256L + threadIdx.x;
  if (e >= (long)EN) return;
  int s, d;
  float av[H];
  if (e < EE) {
    s = ei[e]; d = ei[EE + e];
    float er[5];
    #pragma unroll
    for (int j = 0; j < 5; ++j) er[j] = ea[e*5 + j];
    #pragma unroll
    for (int h = 0; h < H; ++h) {
      float t = 0.f;
      #pragma unroll
      for (int j = 0; j < 5; ++j) t = fmaf(er[j], M[j*H + h], t);
      av[h] = t;
    }
  } else {
    s = d = (int)(e - EE);
    #pragma unroll
    for (int h = 0; h < H; ++h) av[h] = aeself[h];
  }
  #pragma unroll
  for (int h = 0; h < H; ++h) {
    float v = asb[s*H + h] + adb[d*H + h] + av[h];
    a_out[e*H + h] = (v > 0.f) ? v : 0.2f * v;
  }
}

// gather edge attn into CSR order: ac[p][h] = a[csr_eid[p]][h]
template<int H>
__global__ void k_acsr(const int* __restrict__ csr_eid, const float* __restrict__ a,
                       float* __restrict__ ac) {
  long p = blockIdx.x*256L + threadIdx.x;
  if (p >= (long)EN) return;
  long e = csr_eid[p];
  #pragma unroll
  for (int h = 0; h < H; ++h) ac[p*H + h] = a[e*H + h];
}

// ------------- CSR build -------------
__global__ void k_deg(const int* __restrict__ ei, int* __restrict__ deg) {
  long e = blockIdx.x*256L + threadIdx.x;
  if (e >= (long)EN) return;
  int d = (e < EE) ? ei[EE + e] : (int)(e - EE);
  atomicAdd(&deg[d], 1);
}

__global__ void k_scan(const int* __restrict__ deg, int* __restrict__ rowptr,
                       int* __restrict__ cursor) {
  __shared__ int ps[256];
  int tid = threadIdx.x;
  int base = tid * 128;           // 256*128 = 32768 = NN
  int s = 0;
  for (int i = 0; i < 128; ++i) s += deg[base + i];
  ps[tid] = s;
  __syncthreads();
  for (int off = 1; off < 256; off <<= 1) {
    int v = (tid >= off) ? ps[tid - off] : 0;
    __syncthreads();
    ps[tid] += v;
    __syncthreads();
  }
  int run = ps[tid] - s;          // exclusive prefix
  for (int i = 0; i < 128; ++i) {
    rowptr[base + i] = run;
    cursor[base + i] = run;
    run += deg[base + i];
  }
  if (tid == 255) rowptr[NN] = run;
}

__global__ void k_scatter(const int* __restrict__ ei, int* __restrict__ cursor,
                          int* __restrict__ csr_src, int* __restrict__ csr_eid) {
  long e = blockIdx.x*256L + threadIdx.x;
  if (e >= (long)EN) return;
  int s, d;
  if (e < EE) { s = ei[e]; d = ei[EE + e]; }
  else        { s = d = (int)(e - EE); }
  int p = atomicAdd(&cursor[d], 1);
  csr_src[p] = s;
  csr_eid[p] = (int)e;
}

// =================================================================
// GAT aggregation: wave per destination node, XCD-pinned graph swizzle.
// ac is attn logits in CSR order. ACT: 0=elu, 1=relu.
// Requires grid = NN/4 blocks of 256 threads.
// =================================================================
template<int H, int CH, int ACT>
__global__ void k_gat_aggr(const int* __restrict__ rowptr, const int* __restrict__ csr_src,
                           const float* __restrict__ ac,
                           const float* __restrict__ hfeat, const float* __restrict__ bias,
                           float* __restrict__ out) {
  // bid -> (graph g, slice s): x=bid&7 pins graph to XCD (round-robin dispatch),
  // c=bid>>8 walks one graph per XCD at a time (L2-resident 164KB panel).
  int bid = blockIdx.x;
  int x = bid & 7;
  int r = bid >> 3;
  int s = r & 31;
  int c = r >> 5;
  int g = c*8 + x;
  int wid = g*128 + s*4 + (int)(threadIdx.x >> 6);
  int lane = threadIdx.x & 63;
  int row0 = rowptr[wid], row1 = rowptr[wid + 1];
  constexpr int F = H * CH;
  constexpr int NJ = (F + 63) / 64;
  float amax[H], asum[H], rinv[H];
  #pragma unroll
  for (int h = 0; h < H; ++h) amax[h] = -1e30f;
  for (int p = row0 + lane; p < row1; p += 64) {
    #pragma unroll
    for (int h = 0; h < H; ++h) amax[h] = fmaxf(amax[h], ac[(long)p*H + h]);
  }
  #pragma unroll
  for (int h = 0; h < H; ++h)
    for (int off = 1; off < 64; off <<= 1) amax[h] = fmaxf(amax[h], __shfl_xor(amax[h], off, 64));
  #pragma unroll
  for (int h = 0; h < H; ++h) asum[h] = 0.f;
  for (int p = row0 + lane; p < row1; p += 64) {
    #pragma unroll
    for (int h = 0; h < H; ++h) asum[h] += __expf(ac[(long)p*H + h] - amax[h]);
  }
  #pragma unroll
  for (int h = 0; h < H; ++h) {
    for (int off = 1; off < 64; off <<= 1) asum[h] += __shfl_xor(asum[h], off, 64);
    rinv[h] = 1.f / (asum[h] + 1e-16f);
  }
  float acc[NJ];
  #pragma unroll
  for (int j = 0; j < NJ; ++j) acc[j] = 0.f;
  for (int p = row0; p < row1; ++p) {
    int src = csr_src[p];
    const float* hr = hfeat + (long)src * F;
    #pragma unroll
    for (int j = 0; j < NJ; ++j) {
      int idx = j*64 + lane;
      if ((F % 64 == 0) || idx < F) {
        int h = idx / CH;
        float al = __expf(ac[(long)p*H + h] - amax[h]) * rinv[h];
        acc[j] = fmaf(al, hr[idx], acc[j]);
      }
    }
  }
  float* orow = out + (long)wid * F;
  #pragma unroll
  for (int j = 0; j < NJ; ++j) {
    int idx = j*64 + lane;
    if ((F % 64 == 0) || idx < F) {
      float v = acc[j] + bias[idx];
      if (ACT == 0) v = (v > 0.f) ? v : expm1f(v);
      else          v = fmaxf(v, 0.f);
      orow[idx] = v;
    }
  }
}

// graph max pool (relu'd input >= 0, pooled pre-zeroed)
__global__ void k_pool(const float* __restrict__ g2o, const int* __restrict__ batch,
                       unsigned int* __restrict__ pooled) {
  long o = blockIdx.x*256L + threadIdx.x;
  if (o >= (long)NN * 96) return;
  int n = (int)(o / 96), c = (int)(o % 96);
  atomicMax(&pooled[batch[n]*96 + c], __float_as_uint(g2o[o]));
}

__global__ void k_concat(const float* __restrict__ cd, const float* __restrict__ ct,
                         const float* __restrict__ gfc, float* __restrict__ xc) {
  int t = blockIdx.x*256 + threadIdx.x;
  if (t >= NB*288) return;
  int b = t / 288, c = t % 288;
  float v = (c < 96) ? cd[b*96 + c] : (c < 192) ? ct[b*96 + (c-96)] : gfc[b*96 + (c-192)];
  xc[t] = v;
}

// final 512-dot per row
__global__ void k_final(const float* __restrict__ x, const float* __restrict__ w,
                        const float* __restrict__ b, float* __restrict__ out) {
  int wid = (int)((blockIdx.x*256L + threadIdx.x) >> 6);
  int lane = threadIdx.x & 63;
  if (wid >= NB) return;
  const float* xr = x + (long)wid*512;
  float s = 0.f;
  for (int k = lane; k < 512; k += 64) s = fmaf(xr[k], w[k], s);
  for (int off = 1; off < 64; off <<= 1) s += __shfl_xor(s, off, 64);
  if (lane == 0) out[wid] = s + b[0];
}

// =================================================================
extern "C" void kernel_launch(void* const* d_in, const int* in_sizes, int n_in,
                              void* d_out, int out_size, void* d_ws, size_t ws_size,
                              hipStream_t stream) {
  const int*   xd     = (const int*)  d_in[0];
  const int*   xt     = (const int*)  d_in[1];
  const float* ax     = (const float*)d_in[2];
  const int*   ei     = (const int*)  d_in[3];
  const float* ea     = (const float*)d_in[4];
  const int*   batch  = (const int*)  d_in[5];
  const float* emb_xd = (const float*)d_in[6];
  const float* emb_xt = (const float*)d_in[7];
  const float* wd1 = (const float*)d_in[8];  const float* bd1 = (const float*)d_in[9];
  const float* wd2 = (const float*)d_in[10]; const float* bd2 = (const float*)d_in[11];
  const float* wd3 = (const float*)d_in[12]; const float* bd3 = (const float*)d_in[13];
  const float* wt1 = (const float*)d_in[14]; const float* bt1 = (const float*)d_in[15];
  const float* wt2 = (const float*)d_in[16]; const float* bt2 = (const float*)d_in[17];
  const float* wt3 = (const float*)d_in[18]; const float* bt3 = (const float*)d_in[19];
  const float* g1_w  = (const float*)d_in[20]; const float* g1_as = (const float*)d_in[21];
  const float* g1_ad = (const float*)d_in[22]; const float* g1_we = (const float*)d_in[23];
  const float* g1_ae = (const float*)d_in[24]; const float* g1_b  = (const float*)d_in[25];
  const float* g2_w  = (const float*)d_in[26]; const float* g2_as = (const float*)d_in[27];
  const float* g2_ad = (const float*)d_in[28]; const float* g2_we = (const float*)d_in[29];
  const float* g2_ae = (const float*)d_in[30]; const float* g2_b  = (const float*)d_in[31];
  const float* fc1_w = (const float*)d_in[32]; const float* fc1_b = (const float*)d_in[33];
  const float* c1_w = (const float*)d_in[34]; const float* c1_b = (const float*)d_in[35];
  const float* c2_w = (const float*)d_in[36]; const float* c2_b = (const float*)d_in[37];
  const float* c3_w = (const float*)d_in[38]; const float* c3_b = (const float*)d_in[39];
  const float* c4_w = (const float*)d_in[40]; const float* c4_b = (const float*)d_in[41];
  float* out = (float*)d_out;

  char* ws = (char*)d_ws;
  auto F = [&](size_t off) { return (float*)(ws + off); };
  auto I = [&](size_t off) { return (int*)(ws + off); };
  auto U = [&](size_t off) { return (unsigned int*)(ws + off); };
  auto H = [&](size_t off) { return (u16*)(ws + off); };

  // ---- zero-init the atomically-updated buffers ----
  hipMemsetAsync(ws + OFF_CB,   0, 64*sizeof(float), stream);
  hipMemsetAsync(ws + OFF_DEG,  0, NN*sizeof(int),   stream);
  hipMemsetAsync(ws + OFF_CD,   0, NB*96*sizeof(float), stream);
  hipMemsetAsync(ws + OFF_CT,   0, NB*96*sizeof(float), stream);
  hipMemsetAsync(ws + OFF_POOL, 0, NB*96*sizeof(float), stream);
  // split-K accumulators
  hipMemsetAsync(ws + OFF_GFC,  0, NB*96*sizeof(float),   stream);
  hipMemsetAsync(ws + OFF_M1B,  0, NB*1024*sizeof(float), stream);
  hipMemsetAsync(ws + OFF_M2B,  0, NB*1024*sizeof(float), stream);
  hipMemsetAsync(ws + OFF_M3B,  0, NB*512*sizeof(float),  stream);

  // ---- tables / weight converts ----
  k_tables<<<(8320 + 6656 + 30 + 255)/256, 256, 0, stream>>>(
      wd1, emb_xd, wt1, emb_xt, g1_we, g1_ae, g2_we, g2_ae,
      F(OFF_FD), F(OFF_FT), F(OFF_CB));
  k_wcvt<<<(64*256 + 96*512 + 255)/256, 256, 0, stream>>>(
      wt2, wt3, H(OFF_WT2B), H(OFF_WT3B));
  k_easum<<<256, 256, 0, stream>>>(ea, F(OFF_CB));
  k_finalize<<<1, 64, 0, stream>>>(F(OFF_CB));

  // ---- drug weight transposes (f32 path) ----
  k_wtrans<<<(8192 + 255)/256, 256, 0, stream>>>(wd2, F(OFF_WD2T), 64, 32, 4);
  k_wtrans<<<(24576 + 255)/256, 256, 0, stream>>>(wd3, F(OFF_WD3T), 96, 64, 4);

  // ---- drug conv branch (f32 direct): L=100 -> 97 -> 94 -> 91 -> maxpool ----
  k_conv1_lut<4,65,32><<<dim3((32*97 + 255)/256, NB), 256, 0, stream>>>(
      xd, F(OFF_FD), bd1, F(OFF_A), 100, 97);
  k_conv<32,4,64,4,16,false><<<dim3((94 + 63)/64, NB), 256, 0, stream>>>(
      F(OFF_A), F(OFF_WD2T), bd2, F(OFF_B), 97, 94);
  k_conv<64,4,96,2,16,true><<<dim3((91 + 31)/32, NB), 192, 0, stream>>>(
      F(OFF_B), F(OFF_WD3T), bd3, F(OFF_CD), 94, 91);

  // ---- target conv branch (bf16 MFMA): 1000 -> 993 -> 986 -> 979 -> maxpool ----
  k_conv1t<<<dim3((993 + 15)/16, NB), 512, 0, stream>>>(
      xt, F(OFF_FT), bt1, H(OFF_A), 1000, 993);
  k_convmfma<32,64,2,false><<<dim3(4, NB), 512, 0, stream>>>(
      H(OFF_A), H(OFF_WT2B), bt2, H(OFF_B), nullptr, 993, 986);
  k_convmfma<64,96,3,true><<<dim3(4, NB), 512, 0, stream>>>(
      H(OFF_B), H(OFF_WT3B), bt3, nullptr, U(OFF_CT), 986, 979);

  // ---- CSR build (independent of h1) ----
  k_deg<<<(EN + 255)/256, 256, 0, stream>>>(ei, I(OFF_DEG));
  k_scan<<<1, 256, 0, stream>>>(I(OFF_DEG), I(OFF_ROWP), I(OFF_CUR));
  k_scatter<<<(EN + 255)/256, 256, 0, stream>>>(ei, I(OFF_CUR), I(OFF_CSRS), I(OFF_CSRE));

  // ---- GAT layer 1 ----
  k_gemm<64,64,24,4,4,false,false><<<dim3(320/64, NN/64), 256, 0, stream>>>(
      ax, g1_w, nullptr, F(OFF_A), 24, 320);
  k_attn_nodeterms<<<(NN*5 + 255)/256, 256, 0, stream>>>(
      F(OFF_A), g1_as, g1_ad, F(OFF_AS1), F(OFF_AD1), 5, 64);
  k_edge_attn<5><<<(EN + 255)/256, 256, 0, stream>>>(
      ei, ea, F(OFF_AS1), F(OFF_AD1), F(OFF_CB), F(OFF_CB) + 35, F(OFF_C));
  k_acsr<5><<<(EN + 255)/256, 256, 0, stream>>>(
      I(OFF_CSRE), F(OFF_C), F(OFF_AC));
  k_gat_aggr<5,64,0><<<NN/4, 256, 0, stream>>>(
      I(OFF_ROWP), I(OFF_CSRS), F(OFF_AC), F(OFF_A), g1_b, F(OFF_B));

  // ---- GAT layer 2 ----
  k_gemm<32,96,32,2,6,false,false><<<dim3(96/96, NN/32), 256, 0, stream>>>(
      F(OFF_B), g2_w, nullptr, F(OFF_C), 320, 96);
  k_attn_nodeterms<<<(NN + 255)/256, 256, 0, stream>>>(
      F(OFF_C), g2_as, g2_ad, F(OFF_AS2), F(OFF_AD2), 1, 96);
  k_edge_attn<1><<<(EN + 255)/256, 256, 0, stream>>>(
      ei, ea, F(OFF_AS2), F(OFF_AD2), F(OFF_CB) + 25, F(OFF_CB) + 40, F(OFF_A2));
  k_acsr<1><<<(EN + 255)/256, 256, 0, stream>>>(
      I(OFF_CSRE), F(OFF_A2), F(OFF_AC));
  k_gat_aggr<1,96,1><<<NN/4, 256, 0, stream>>>(
      I(OFF_ROWP), I(OFF_CSRS), F(OFF_AC), F(OFF_C), g2_b, F(OFF_G2O));

  // ---- graph pool + fc1 (split-K) ----
  k_pool<<<(int)(((long)NN*96 + 255)/256), 256, 0, stream>>>(
      F(OFF_G2O), batch, U(OFF_POOL));
  k_gemm_sk<64,32,32,4,2><<<dim3(96/32, NB/64, 3), 256, 0, stream>>>(
      F(OFF_POOL), fc1_w, F(OFF_GFC), 96, 96, 32);
  k_bias_relu<<<(NB*96 + 255)/256, 256, 0, stream>>>(
      F(OFF_GFC), fc1_b, (long)NB*96, 96, 1);

  // ---- concat + MLP head (split-K GEMMs) ----
  k_concat<<<(NB*288 + 255)/256, 256, 0, stream>>>(
      F(OFF_CD), F(OFF_CT), F(OFF_GFC), F(OFF_XC));

  k_gemm_sk<64,64,32,4,4><<<dim3(1024/64, NB/64, 3), 256, 0, stream>>>(
      F(OFF_XC), c1_w, F(OFF_M1B), 288, 1024, 96);
  k_bias_relu<<<(NB*1024 + 255)/256, 256, 0, stream>>>(
      F(OFF_M1B), c1_b, (long)NB*1024, 1024, 1);

  k_gemm_sk<64,64,32,4,4><<<dim3(1024/64, NB/64, 8), 256, 0, stream>>>(
      F(OFF_M1B), c2_w, F(OFF_M2B), 1024, 1024, 128);
  k_bias_relu<<<(NB*1024 + 255)/256, 256, 0, stream>>>(
      F(OFF_M2B), c2_b, (long)NB*1024, 1024, 1);

  k_gemm_sk<64,64,32,4,4><<<dim3(512/64, NB/64, 8), 256, 0, stream>>>(
      F(OFF_M2B), c3_w, F(OFF_M3B), 1024, 512, 128);
  k_bias_relu<<<(NB*512 + 255)/256, 256, 0, stream>>>(
      F(OFF_M3B), c3_b, (long)NB*512, 512, 1);

  k_final<<<(NB*64 + 255)/256, 256, 0, stream>>>(F(OFF_M3B), c4_w, c4_b, out);
}

// Round 9
// 882.365 us; speedup vs baseline: 2.1380x; 1.0898x over previous
//
#include <hip/hip_runtime.h>

// ---------------- problem constants ----------------
constexpr int NN = 32768;      // nodes
constexpr int EE = 524288;     // edges
constexpr int NB = 256;        // graphs / batch
constexpr int EN = EE + NN;    // edges + self loops

typedef unsigned short u16;
typedef short bh8 __attribute__((ext_vector_type(8)));    // 8 bf16 (4 VGPRs)
typedef float f32x4 __attribute__((ext_vector_type(4)));  // MFMA accumulator

__device__ inline u16 f2b(float f) {   // f32 -> bf16 round-to-nearest-even
  unsigned u = __float_as_uint(f);
  return (u16)((u + 0x7fffu + ((u >> 16) & 1u)) >> 16);
}

// ---------------- workspace layout (bytes) ----------------
constexpr size_t MB = 1ull << 20;
constexpr size_t OFF_A    = 0;        // conv y1, later h1 [N,320] f32
constexpr size_t OFF_B    = 48*MB;    // conv y2, later g1o [N,320] bf16 (21MB)
constexpr size_t OFF_AC   = 100*MB;   // a_csr [EN,5] f32 (11.2MB) reused layer2
constexpr size_t OFF_C    = 116*MB;   // a1 [EN,5], later h2 [N,96] f32
constexpr size_t OFF_CSRS = 130*MB;   // csr_src [EN]
constexpr size_t OFF_CSRE = 133*MB;   // csr_eid [EN]
constexpr size_t OFF_ROWP = 136*MB;   // rowptr [N+1]
constexpr size_t OFF_DEG  = 137*MB;   // deg [N]
constexpr size_t OFF_CUR  = 138*MB;   // cursor [N]
constexpr size_t OFF_A2   = 139*MB;   // a2 [EN]
constexpr size_t OFF_G2O  = 142*MB;   // g2o [N,96]
constexpr size_t OFF_AS1  = 155*MB;   // [N,5]
constexpr size_t OFF_AD1  = 156*MB;
constexpr size_t OFF_AS2  = 157*MB;   // [N]
constexpr size_t OFF_AD2  = 158*MB;
constexpr size_t OFF_CD   = 159*MB;   // [256,96] pooled drug conv
constexpr size_t OFF_CT   = 160*MB;   // [256,96] pooled target conv
constexpr size_t OFF_POOL = 161*MB;   // [256,96] graph pool
constexpr size_t OFF_GFC  = 162*MB;   // [256,96]
constexpr size_t OFF_XC   = 163*MB;   // [256,288]
constexpr size_t OFF_M1B  = 164*MB;   // [256,1024]
constexpr size_t OFF_M2B  = 165*MB;   // [256,1024]
constexpr size_t OFF_M3B  = 166*MB;   // [256,512]
constexpr size_t OFF_FD   = 167*MB;   // F table drug [32][4][65] f32
constexpr size_t OFF_FT   = 168*MB;   // F table target [8][26][32] f32
constexpr size_t OFF_WD2T = 169*MB;   // drug w2 [ci][k][co] f32
constexpr size_t OFF_WD3T = 170*MB;   // drug w3 [ci][k][co] f32
constexpr size_t OFF_WT2B = 171*MB;   // target w2 bf16 [co][kk*32+ci]  (64x256)
constexpr size_t OFF_WT3B = 172*MB;   // target w3 bf16 [co][kk*64+ci]  (96x512)
constexpr size_t OFF_W2GB = 174*MB;   // g2_w bf16 [co][k] (96x320)
constexpr size_t OFF_CB   = 173*MB;   // const block: [0:25]=M1, [25:30]=M2, [30:35]=easum,
                                      // [35:40]=aeself1, [40]=ae2self, [41:46]=eamean

// =================================================================
// Tiny precompute tables: F_drug [co][k][v], F_target [k][v][co], M1, M2
// =================================================================
__global__ void k_tables(const float* __restrict__ wd1, const float* __restrict__ emb_xd,
                         const float* __restrict__ wt1, const float* __restrict__ emb_xt,
                         const float* __restrict__ g1we, const float* __restrict__ g1ae,
                         const float* __restrict__ g2we, const float* __restrict__ g2ae,
                         float* __restrict__ Fd, float* __restrict__ Ft,
                         float* __restrict__ CB) {
  int t = blockIdx.x * 256 + threadIdx.x;
  const int NFd = 32*4*65, NFt = 32*8*26;
  if (t < NFd) {                       // Fd[co][k][v]
    int v = t % 65; int ck = t / 65; int k = ck & 3; int co = ck >> 2;
    float s = 0.f;
    for (int ci = 0; ci < 128; ++ci)
      s = fmaf(wd1[(co*128 + ci)*4 + k], emb_xd[v*128 + ci], s);
    Fd[t] = s;
  } else if (t < NFd + NFt) {          // Ft stored [k][v][co]
    int u = t - NFd;
    int v = u % 26; int ck = u / 26; int k = ck & 7; int co = ck >> 3;
    float s = 0.f;
    for (int ci = 0; ci < 128; ++ci)
      s = fmaf(wt1[(co*128 + ci)*8 + k], emb_xt[v*128 + ci], s);
    Ft[(k*26 + v)*32 + co] = s;
  } else if (t < NFd + NFt + 25) {     // M1[j][h]
    int u = t - NFd - NFt; int h = u % 5, j = u / 5;
    float s = 0.f;
    for (int c = 0; c < 64; ++c)
      s = fmaf(g1we[j*320 + h*64 + c], g1ae[h*64 + c], s);
    CB[j*5 + h] = s;
  } else if (t < NFd + NFt + 30) {     // M2[j]
    int j = t - NFd - NFt - 25;
    float s = 0.f;
    for (int c = 0; c < 96; ++c)
      s = fmaf(g2we[j*96 + c], g2ae[c], s);
    CB[25 + j] = s;
  }
}

// weight converts to bf16: target conv2/conv3 ([co][kk*CIN+ci]) and g2_w ([co][k])
__global__ void k_wcvt(const float* __restrict__ w2, const float* __restrict__ w3,
                       const float* __restrict__ g2w,
                       u16* __restrict__ o2, u16* __restrict__ o3,
                       u16* __restrict__ og2) {
  int t = blockIdx.x*256 + threadIdx.x;
  if (t < 64*256) {
    int co = t >> 8, k = t & 255, kk = k >> 5, ci = k & 31;
    o2[t] = f2b(w2[(co*32 + ci)*8 + kk]);
  } else if (t < 64*256 + 96*512) {
    int u = t - 64*256;
    int co = u >> 9, k = u & 511, kk = k >> 6, ci = k & 63;
    o3[u] = f2b(w3[(co*64 + ci)*8 + kk]);
  } else if (t < 64*256 + 96*512 + 96*320) {
    int u = t - 64*256 - 96*512;
    int co = u / 320, k = u % 320;
    og2[u] = f2b(g2w[k*96 + co]);
  }
}

// sum of ea columns -> CB[30..34] (pre-zeroed)
__global__ void k_easum(const float* __restrict__ ea, float* __restrict__ CB) {
  float acc[5] = {0,0,0,0,0};
  for (long e = blockIdx.x*256L + threadIdx.x; e < EE; e += 256L*gridDim.x) {
    #pragma unroll
    for (int j = 0; j < 5; ++j) acc[j] += ea[e*5 + j];
  }
  #pragma unroll
  for (int j = 0; j < 5; ++j)
    for (int off = 1; off < 64; off <<= 1) acc[j] += __shfl_xor(acc[j], off, 64);
  if ((threadIdx.x & 63) == 0) {
    #pragma unroll
    for (int j = 0; j < 5; ++j) atomicAdd(&CB[30 + j], acc[j]);
  }
}

// eamean, aeself1[h], ae2self
__global__ void k_finalize(float* __restrict__ CB) {
  if (blockIdx.x == 0 && threadIdx.x == 0) {
    float em[5];
    for (int j = 0; j < 5; ++j) { em[j] = CB[30 + j] / (float)EE; CB[41 + j] = em[j]; }
    for (int h = 0; h < 5; ++h) {
      float s = 0.f;
      for (int j = 0; j < 5; ++j) s = fmaf(em[j], CB[j*5 + h], s);
      CB[35 + h] = s;
    }
    float s = 0.f;
    for (int j = 0; j < 5; ++j) s = fmaf(em[j], CB[25 + j], s);
    CB[40] = s;
  }
}

// =================================================================
// drug conv1 via LUT (f32 [b][co][l] out)
// =================================================================
template<int K, int V, int COUT>
__global__ void k_conv1_lut(const int* __restrict__ idx, const float* __restrict__ F,
                            const float* __restrict__ bias, float* __restrict__ y,
                            int L, int Lout) {
  __shared__ float Fs[COUT*K*V];
  __shared__ float bs[COUT];
  int b = blockIdx.y;
  for (int i = threadIdx.x; i < COUT*K*V; i += blockDim.x) Fs[i] = F[i];
  for (int i = threadIdx.x; i < COUT; i += blockDim.x) bs[i] = bias[i];
  __syncthreads();
  int o = blockIdx.x * blockDim.x + threadIdx.x;
  if (o >= COUT * Lout) return;
  int co = o / Lout, l = o % Lout;
  const int* ib = idx + b*L + l;
  float acc = bs[co];
  #pragma unroll
  for (int k = 0; k < K; ++k) acc += Fs[(co*K + k)*V + ib[k]];
  y[(b*COUT + co)*Lout + l] = fmaxf(acc, 0.f);
}

// =================================================================
// target conv1 via LUT -> bf16 transposed out y[b][l][co]
// =================================================================
__global__ __launch_bounds__(512) void k_conv1t(
    const int* __restrict__ idx, const float* __restrict__ Ftab,
    const float* __restrict__ bias, u16* __restrict__ y, int L, int Lout) {
  constexpr int K = 8, V = 26, CO = 32;
  __shared__ float Fs[K*V*CO];
  __shared__ float bs[CO];
  __shared__ int sq[16 + K];
  int b = blockIdx.y, l0 = blockIdx.x * 16;
  for (int i = threadIdx.x; i < K*V*CO; i += 512) Fs[i] = Ftab[i];
  if (threadIdx.x < CO) bs[threadIdx.x] = bias[threadIdx.x];
  if (threadIdx.x < 16 + K - 1) {
    int l = l0 + (int)threadIdx.x;
    sq[threadIdx.x] = (l < L) ? idx[b*L + l] : 0;
  }
  __syncthreads();
  int co = threadIdx.x & 31;
  int p = threadIdx.x >> 5;
  int l = l0 + p;
  if (l >= Lout) return;
  float acc = bs[co];
  #pragma unroll
  for (int k = 0; k < K; ++k) acc += Fs[(k*V + sq[p + k])*CO + co];
  y[((size_t)b*Lout + l)*CO + co] = f2b(fmaxf(acc, 0.f));
}

// weight transpose [co][ci][k] -> [ci][k][co] (drug branch, f32)
__global__ void k_wtrans(const float* __restrict__ w, float* __restrict__ wt,
                         int COUT, int CIN, int K) {
  int t = blockIdx.x*256 + threadIdx.x;
  if (t >= COUT*CIN*K) return;
  int k = t % K; int ci = (t / K) % CIN; int co = t / (K*CIN);
  wt[(ci*K + k)*COUT + co] = w[t];
}

// =================================================================
// drug direct conv
// =================================================================
template<int CIN, int K, int COUT, int G, int LG, bool POOL>
__global__ void k_conv(const float* __restrict__ x, const float* __restrict__ wt,
                       const float* __restrict__ bias, float* __restrict__ y,
                       int Lin, int Lout) {
  constexpr int LT = G * LG;
  __shared__ float xs[CIN][LT + K - 1];
  int b = blockIdx.y;
  int l0 = blockIdx.x * LT;
  const int nth = COUT * G;
  const float* xb = x + b*CIN*Lin;
  for (int i = threadIdx.x; i < CIN*(LT + K - 1); i += nth) {
    int ci = i / (LT + K - 1), dl = i % (LT + K - 1);
    int l = l0 + dl;
    xs[ci][dl] = (l < Lin) ? xb[ci*Lin + l] : 0.f;
  }
  __syncthreads();
  int co = threadIdx.x % COUT;
  int gg = threadIdx.x / COUT;
  float acc[LG];
  #pragma unroll
  for (int j = 0; j < LG; ++j) acc[j] = 0.f;
  for (int ci = 0; ci < CIN; ++ci) {
    float xr[LG + K - 1];
    #pragma unroll
    for (int t = 0; t < LG + K - 1; ++t) xr[t] = xs[ci][gg*LG + t];
    #pragma unroll
    for (int k = 0; k < K; ++k) {
      float wv = wt[(ci*K + k)*COUT + co];
      #pragma unroll
      for (int j = 0; j < LG; ++j) acc[j] = fmaf(wv, xr[j + k], acc[j]);
    }
  }
  float bv = bias[co];
  if (!POOL) {
    float* yb = y + (b*COUT + co)*Lout;
    #pragma unroll
    for (int j = 0; j < LG; ++j) {
      int l = l0 + gg*LG + j;
      if (l < Lout) yb[l] = fmaxf(acc[j] + bv, 0.f);
    }
  } else {
    float m = 0.f;
    #pragma unroll
    for (int j = 0; j < LG; ++j) {
      int l = l0 + gg*LG + j;
      if (l < Lout) m = fmaxf(m, fmaxf(acc[j] + bv, 0.f));
    }
    atomicMax((unsigned int*)&y[b*COUT + co], __float_as_uint(m));
  }
}

// =================================================================
// target conv2/conv3: implicit-GEMM via MFMA bf16
// =================================================================
template<int CIN, int COUT, int NT2, bool POOL>
__global__ __launch_bounds__(512) void k_convmfma(
    const u16* __restrict__ xin, const u16* __restrict__ wtb,
    const float* __restrict__ bias, u16* __restrict__ yout,
    unsigned int* __restrict__ pool, int Lin, int Lout) {
  constexpr int KD = CIN*8;
  constexpr int NCH = KD/32;
  constexpr int MT = 256, ROWS = MT + 7;
  constexpr int XPAD = CIN + 8;
  constexpr int WPAD = KD + 8;
  __shared__ u16 xs[ROWS*XPAD];
  __shared__ u16 wsd[COUT*WPAD];
  int b = blockIdx.y;
  int l0 = blockIdx.x * MT;
  int tid = threadIdx.x;
  {
    const unsigned* wg = (const unsigned*)wtb;
    unsigned* wl = (unsigned*)wsd;
    constexpr int KD2 = KD/2, WP2 = WPAD/2;
    for (int i = tid; i < COUT*KD2; i += 512) {
      int co = i / KD2, c = i % KD2;
      wl[co*WP2 + c] = wg[i];
    }
  }
  {
    const unsigned* xg = (const unsigned*)(xin + (size_t)b*Lin*CIN);
    unsigned* xl = (unsigned*)xs;
    constexpr int C2 = CIN/2, XP2 = XPAD/2;
    for (int i = tid; i < ROWS*C2; i += 512) {
      int r = i / C2, c = i % C2;
      unsigned v = 0;
      if (l0 + r < Lin) v = xg[(size_t)l0*C2 + i];
      xl[r*XP2 + c] = v;
    }
  }
  __syncthreads();
  int lane = tid & 63;
  int w = tid >> 6;
  int mg = w & 3, ng = w >> 2;
  int l15 = lane & 15, l4 = lane >> 4;
  f32x4 acc[4][NT2];
  #pragma unroll
  for (int mi = 0; mi < 4; ++mi)
    #pragma unroll
    for (int nj = 0; nj < NT2; ++nj) acc[mi][nj] = (f32x4){0.f, 0.f, 0.f, 0.f};

  #pragma unroll
  for (int ch = 0; ch < NCH; ++ch) {
    const int kk = (ch*32) / CIN;
    const int cib = (ch*32) % CIN + l4*8;
    bh8 a[4], bb[NT2];
    #pragma unroll
    for (int mi = 0; mi < 4; ++mi) {
      int row = mg*64 + mi*16 + l15 + kk;
      a[mi] = *(const bh8*)&xs[row*XPAD + cib];
    }
    #pragma unroll
    for (int nj = 0; nj < NT2; ++nj) {
      int co = (ng*NT2 + nj)*16 + l15;
      bb[nj] = *(const bh8*)&wsd[co*WPAD + ch*32 + l4*8];
    }
    #pragma unroll
    for (int mi = 0; mi < 4; ++mi)
      #pragma unroll
      for (int nj = 0; nj < NT2; ++nj)
        acc[mi][nj] = __builtin_amdgcn_mfma_f32_16x16x32_bf16(a[mi], bb[nj], acc[mi][nj], 0, 0, 0);
  }

  if (!POOL) {
    #pragma unroll
    for (int nj = 0; nj < NT2; ++nj) {
      int co = (ng*NT2 + nj)*16 + l15;
      float bv = bias[co];
      #pragma unroll
      for (int mi = 0; mi < 4; ++mi)
        #pragma unroll
        for (int r = 0; r < 4; ++r) {
          int m = mg*64 + mi*16 + l4*4 + r;
          if (l0 + m < Lout)
            yout[((size_t)b*Lout + l0 + m)*COUT + co] = f2b(fmaxf(acc[mi][nj][r] + bv, 0.f));
        }
    }
  } else {
    #pragma unroll
    for (int nj = 0; nj < NT2; ++nj) {
      int co = (ng*NT2 + nj)*16 + l15;
      float bv = bias[co];
      float mx = 0.f;
      #pragma unroll
      for (int mi = 0; mi < 4; ++mi)
        #pragma unroll
        for (int r = 0; r < 4; ++r) {
          int m = mg*64 + mi*16 + l4*4 + r;
          if (l0 + m < Lout) mx = fmaxf(mx, fmaxf(acc[mi][nj][r] + bv, 0.f));
        }
      mx = fmaxf(mx, __shfl_xor(mx, 16, 64));
      mx = fmaxf(mx, __shfl_xor(mx, 32, 64));
      if (l4 == 0) atomicMax(&pool[b*COUT + co], __float_as_uint(mx));
    }
  }
}

// =================================================================
// h2 = g1o(bf16 [N,320]) @ g2_w(bf16 [co][k]) -> f32 [N,96] via MFMA.
// 512 thr = 8 waves; M-tile 128: wave w owns m-sub w (16 rows), all 6 n-tiles.
// W fully staged in LDS (96x328 halves, 2-way max bank alias = free);
// A-fragments straight from global (each row read exactly once).
// =================================================================
__global__ __launch_bounds__(512) void k_h2mfma(
    const u16* __restrict__ g1ob, const u16* __restrict__ wb,
    float* __restrict__ h2) {
  constexpr int KD = 320, WPAD = 328, NCH = 10;
  __shared__ u16 wsd[96*WPAD];
  int tid = threadIdx.x;
  {
    const unsigned* wg = (const unsigned*)wb;
    unsigned* wl = (unsigned*)wsd;
    for (int i = tid; i < 96*(KD/2); i += 512) {
      int co = i / (KD/2), c = i % (KD/2);
      wl[co*(WPAD/2) + c] = wg[i];
    }
  }
  __syncthreads();
  int lane = tid & 63;
  int w = tid >> 6;                 // m-sub 0..7
  int l15 = lane & 15, l4 = lane >> 4;
  long m0 = (long)blockIdx.x * 128;
  const u16* xr = g1ob + (m0 + w*16 + l15) * KD;
  f32x4 acc[6];
  #pragma unroll
  for (int nj = 0; nj < 6; ++nj) acc[nj] = (f32x4){0.f, 0.f, 0.f, 0.f};
  #pragma unroll
  for (int ch = 0; ch < NCH; ++ch) {
    bh8 a = *(const bh8*)&xr[ch*32 + l4*8];
    #pragma unroll
    for (int nj = 0; nj < 6; ++nj) {
      bh8 b = *(const bh8*)&wsd[(nj*16 + l15)*WPAD + ch*32 + l4*8];
      acc[nj] = __builtin_amdgcn_mfma_f32_16x16x32_bf16(a, b, acc[nj], 0, 0, 0);
    }
  }
  #pragma unroll
  for (int nj = 0; nj < 6; ++nj) {
    #pragma unroll
    for (int r = 0; r < 4; ++r) {
      long row = m0 + w*16 + l4*4 + r;
      h2[row*96 + nj*16 + l15] = acc[nj][r];
    }
  }
}

// =================================================================
// register-tiled f32 GEMM (h1)
// =================================================================
template<int BM, int BN, int BK, int TM, int TN, bool BIAS, bool RELU>
__global__ void k_gemm(const float* __restrict__ X, const float* __restrict__ W,
                       const float* __restrict__ bias, float* __restrict__ Y,
                       int K, int C) {
  constexpr int NTH = (BM/TM)*(BN/TN);
  static_assert(NTH == 256, "block must be 256 threads");
  __shared__ float xs[BK][BM + 1];
  __shared__ float wsm[BK][BN];
  const int m0 = blockIdx.y * BM;
  const int c0 = blockIdx.x * BN;
  const int tn = threadIdx.x % (BN/TN);
  const int tm = threadIdx.x / (BN/TN);
  float acc[TM][TN];
  #pragma unroll
  for (int i = 0; i < TM; ++i)
    #pragma unroll
    for (int j = 0; j < TN; ++j) acc[i][j] = 0.f;

  for (int k0 = 0; k0 < K; k0 += BK) {
    #pragma unroll
    for (int i = threadIdx.x; i < BM*BK; i += NTH) {
      int m = i / BK, k = i % BK;
      xs[k][m] = X[(long)(m0 + m)*K + k0 + k];
    }
    #pragma unroll
    for (int i = threadIdx.x; i < BK*BN; i += NTH) {
      int k = i / BN, c = i % BN;
      wsm[k][c] = W[(long)(k0 + k)*C + c0 + c];
    }
    __syncthreads();
    #pragma unroll
    for (int k = 0; k < BK; ++k) {
      float xv[TM], wv[TN];
      #pragma unroll
      for (int i = 0; i < TM; ++i) xv[i] = xs[k][tm*TM + i];
      #pragma unroll
      for (int j = 0; j < TN; ++j) wv[j] = wsm[k][tn*TN + j];
      #pragma unroll
      for (int i = 0; i < TM; ++i)
        #pragma unroll
        for (int j = 0; j < TN; ++j) acc[i][j] = fmaf(xv[i], wv[j], acc[i][j]);
    }
    __syncthreads();
  }
  #pragma unroll
  for (int i = 0; i < TM; ++i) {
    float* yr = Y + (long)(m0 + tm*TM + i)*C + c0 + tn*TN;
    #pragma unroll
    for (int j = 0; j < TN; ++j) {
      float v = acc[i][j];
      if (BIAS) v += bias[c0 + tn*TN + j];
      if (RELU) v = fmaxf(v, 0.f);
      yr[j] = v;
    }
  }
}

// =================================================================
// split-K f32 GEMM for skinny-M (M=256) MLP layers.
// =================================================================
template<int BM, int BN, int BK, int TM, int TN>
__global__ void k_gemm_sk(const float* __restrict__ X, const float* __restrict__ W,
                          float* __restrict__ Y, int K, int C, int KS) {
  constexpr int NTH = (BM/TM)*(BN/TN);
  static_assert(NTH == 256, "block must be 256 threads");
  __shared__ float xs[BK][BM + 1];
  __shared__ float wsm[BK][BN];
  const int m0 = blockIdx.y * BM;
  const int c0 = blockIdx.x * BN;
  const int kbeg = blockIdx.z * KS;
  const int kend = min(K, kbeg + KS);
  const int tn = threadIdx.x % (BN/TN);
  const int tm = threadIdx.x / (BN/TN);
  float acc[TM][TN];
  #pragma unroll
  for (int i = 0; i < TM; ++i)
    #pragma unroll
    for (int j = 0; j < TN; ++j) acc[i][j] = 0.f;

  for (int k0 = kbeg; k0 < kend; k0 += BK) {
    #pragma unroll
    for (int i = threadIdx.x; i < BM*BK; i += NTH) {
      int m = i / BK, k = i % BK;
      xs[k][m] = X[(long)(m0 + m)*K + k0 + k];
    }
    #pragma unroll
    for (int i = threadIdx.x; i < BK*BN; i += NTH) {
      int k = i / BN, c = i % BN;
      wsm[k][c] = W[(long)(k0 + k)*C + c0 + c];
    }
    __syncthreads();
    #pragma unroll
    for (int k = 0; k < BK; ++k) {
      float xv[TM], wv[TN];
      #pragma unroll
      for (int i = 0; i < TM; ++i) xv[i] = xs[k][tm*TM + i];
      #pragma unroll
      for (int j = 0; j < TN; ++j) wv[j] = wsm[k][tn*TN + j];
      #pragma unroll
      for (int i = 0; i < TM; ++i)
        #pragma unroll
        for (int j = 0; j < TN; ++j) acc[i][j] = fmaf(xv[i], wv[j], acc[i][j]);
    }
    __syncthreads();
  }
  #pragma unroll
  for (int i = 0; i < TM; ++i) {
    float* yr = Y + (long)(m0 + tm*TM + i)*C + c0 + tn*TN;
    #pragma unroll
    for (int j = 0; j < TN; ++j) atomicAdd(&yr[j], acc[i][j]);
  }
}

// bias + optional relu, in place over [rows*C]
__global__ void k_bias_relu(float* __restrict__ Y, const float* __restrict__ bias,
                            long total, int C, int relu) {
  long o = blockIdx.x*256L + threadIdx.x;
  if (o >= total) return;
  int c = (int)(o % C);
  float v = Y[o] + bias[c];
  if (relu) v = fmaxf(v, 0.f);
  Y[o] = v;
}

// per-node attention terms
__global__ void k_attn_nodeterms(const float* __restrict__ h, const float* __restrict__ a_s,
                                 const float* __restrict__ a_d, float* __restrict__ as_o,
                                 float* __restrict__ ad_o, int H, int CH) {
  long t = blockIdx.x*256L + threadIdx.x;
  if (t >= (long)NN * H) return;
  int n = (int)(t / H), hh = (int)(t % H);
  const float* hr = h + ((long)n*H + hh)*CH;
  float s1 = 0.f, s2 = 0.f;
  for (int c = 0; c < CH; ++c) {
    float v = hr[c];
    s1 = fmaf(v, a_s[hh*CH + c], s1);
    s2 = fmaf(v, a_d[hh*CH + c], s2);
  }
  as_o[t] = s1; ad_o[t] = s2;
}

// per-edge attention logit with leaky_relu(0.2). e >= EE are self loops.
template<int H>
__global__ void k_edge_attn(const int* __restrict__ ei, const float* __restrict__ ea,
                            const float* __restrict__ asb, const float* __restrict__ adb,
                            const float* __restrict__ M, const float* __restrict__ aeself,
                            float* __restrict__ a_out) {
  long e = blockIdx.x*256L + threadIdx.x;
  if (e >= (long)EN) return;
  int s, d;
  float av[H];
  if (e < EE) {
    s = ei[e]; d = ei[EE + e];
    float er[5];
    #pragma unroll
    for (int j = 0; j < 5; ++j) er[j] = ea[e*5 + j];
    #pragma unroll
    for (int h = 0; h < H; ++h) {
      float t = 0.f;
      #pragma unroll
      for (int j = 0; j < 5; ++j) t = fmaf(er[j], M[j*H + h], t);
      av[h] = t;
    }
  } else {
    s = d = (int)(e - EE);
    #pragma unroll
    for (int h = 0; h < H; ++h) av[h] = aeself[h];
  }
  #pragma unroll
  for (int h = 0; h < H; ++h) {
    float v = asb[s*H + h] + adb[d*H + h] + av[h];
    a_out[e*H + h] = (v > 0.f) ? v : 0.2f * v;
  }
}

// gather edge attn into CSR order: ac[p][h] = a[csr_eid[p]][h]
template<int H>
__global__ void k_acsr(const int* __restrict__ csr_eid, const float* __restrict__ a,
                       float* __restrict__ ac) {
  long p = blockIdx.x*256L + threadIdx.x;
  if (p >= (long)EN) return;
  long e = csr_eid[p];
  #pragma unroll
  for (int h = 0; h < H; ++h) ac[p*H + h] = a[e*H + h];
}

// ------------- CSR build -------------
__global__ void k_deg(const int* __restrict__ ei, int* __restrict__ deg) {
  long e = blockIdx.x*256L + threadIdx.x;
  if (e >= (long)EN) return;
  int d = (e < EE) ? ei[EE + e] : (int)(e - EE);
  atomicAdd(&deg[d], 1);
}

__global__ void k_scan(const int* __restrict__ deg, int* __restrict__ rowptr,
                       int* __restrict__ cursor) {
  __shared__ int ps[256];
  int tid = threadIdx.x;
  int base = tid * 128;           // 256*128 = 32768 = NN
  int s = 0;
  for (int i = 0; i < 128; ++i) s += deg[base + i];
  ps[tid] = s;
  __syncthreads();
  for (int off = 1; off < 256; off <<= 1) {
    int v = (tid >= off) ? ps[tid - off] : 0;
    __syncthreads();
    ps[tid] += v;
    __syncthreads();
  }
  int run = ps[tid] - s;          // exclusive prefix
  for (int i = 0; i < 128; ++i) {
    rowptr[base + i] = run;
    cursor[base + i] = run;
    run += deg[base + i];
  }
  if (tid == 255) rowptr[NN] = run;
}

__global__ void k_scatter(const int* __restrict__ ei, int* __restrict__ cursor,
                          int* __restrict__ csr_src, int* __restrict__ csr_eid) {
  long e = blockIdx.x*256L + threadIdx.x;
  if (e >= (long)EN) return;
  int s, d;
  if (e < EE) { s = ei[e]; d = ei[EE + e]; }
  else        { s = d = (int)(e - EE); }
  int p = atomicAdd(&cursor[d], 1);
  csr_src[p] = s;
  csr_eid[p] = (int)e;
}

// =================================================================
// GAT aggregation: wave per destination node, XCD-pinned graph swizzle.
// ac = attn logits in CSR order. ACT: 0=elu, 1=relu. OBF16: bf16 output.
// =================================================================
template<int H, int CH, int ACT, bool OBF16>
__global__ void k_gat_aggr(const int* __restrict__ rowptr, const int* __restrict__ csr_src,
                           const float* __restrict__ ac,
                           const float* __restrict__ hfeat, const float* __restrict__ bias,
                           void* __restrict__ outv) {
  int bid = blockIdx.x;
  int x = bid & 7;
  int r = bid >> 3;
  int s = r & 31;
  int c = r >> 5;
  int g = c*8 + x;
  int wid = g*128 + s*4 + (int)(threadIdx.x >> 6);
  int lane = threadIdx.x & 63;
  int row0 = rowptr[wid], row1 = rowptr[wid + 1];
  constexpr int F = H * CH;
  constexpr int NJ = (F + 63) / 64;
  float amax[H], asum[H], rinv[H];
  #pragma unroll
  for (int h = 0; h < H; ++h) amax[h] = -1e30f;
  for (int p = row0 + lane; p < row1; p += 64) {
    #pragma unroll
    for (int h = 0; h < H; ++h) amax[h] = fmaxf(amax[h], ac[(long)p*H + h]);
  }
  #pragma unroll
  for (int h = 0; h < H; ++h)
    for (int off = 1; off < 64; off <<= 1) amax[h] = fmaxf(amax[h], __shfl_xor(amax[h], off, 64));
  #pragma unroll
  for (int h = 0; h < H; ++h) asum[h] = 0.f;
  for (int p = row0 + lane; p < row1; p += 64) {
    #pragma unroll
    for (int h = 0; h < H; ++h) asum[h] += __expf(ac[(long)p*H + h] - amax[h]);
  }
  #pragma unroll
  for (int h = 0; h < H; ++h) {
    for (int off = 1; off < 64; off <<= 1) asum[h] += __shfl_xor(asum[h], off, 64);
    rinv[h] = 1.f / (asum[h] + 1e-16f);
  }
  float acc[NJ];
  #pragma unroll
  for (int j = 0; j < NJ; ++j) acc[j] = 0.f;
  for (int p = row0; p < row1; ++p) {
    int src = csr_src[p];
    const float* hr = hfeat + (long)src * F;
    #pragma unroll
    for (int j = 0; j < NJ; ++j) {
      int idx = j*64 + lane;
      if ((F % 64 == 0) || idx < F) {
        int h = idx / CH;
        float al = __expf(ac[(long)p*H + h] - amax[h]) * rinv[h];
        acc[j] = fmaf(al, hr[idx], acc[j]);
      }
    }
  }
  #pragma unroll
  for (int j = 0; j < NJ; ++j) {
    int idx = j*64 + lane;
    if ((F % 64 == 0) || idx < F) {
      float v = acc[j] + bias[idx];
      if (ACT == 0) v = (v > 0.f) ? v : expm1f(v);
      else          v = fmaxf(v, 0.f);
      if (OBF16) ((u16*)outv)[(long)wid * F + idx] = f2b(v);
      else       ((float*)outv)[(long)wid * F + idx] = v;
    }
  }
}

// graph max pool (relu'd input >= 0, pooled pre-zeroed)
__global__ void k_pool(const float* __restrict__ g2o, const int* __restrict__ batch,
                       unsigned int* __restrict__ pooled) {
  long o = blockIdx.x*256L + threadIdx.x;
  if (o >= (long)NN * 96) return;
  int n = (int)(o / 96), c = (int)(o % 96);
  atomicMax(&pooled[batch[n]*96 + c], __float_as_uint(g2o[o]));
}

__global__ void k_concat(const float* __restrict__ cd, const float* __restrict__ ct,
                         const float* __restrict__ gfc, float* __restrict__ xc) {
  int t = blockIdx.x*256 + threadIdx.x;
  if (t >= NB*288) return;
  int b = t / 288, c = t % 288;
  float v = (c < 96) ? cd[b*96 + c] : (c < 192) ? ct[b*96 + (c-96)] : gfc[b*96 + (c-192)];
  xc[t] = v;
}

// final 512-dot per row
__global__ void k_final(const float* __restrict__ x, const float* __restrict__ w,
                        const float* __restrict__ b, float* __restrict__ out) {
  int wid = (int)((blockIdx.x*256L + threadIdx.x) >> 6);
  int lane = threadIdx.x & 63;
  if (wid >= NB) return;
  const float* xr = x + (long)wid*512;
  float s = 0.f;
  for (int k = lane; k < 512; k += 64) s = fmaf(xr[k], w[k], s);
  for (int off = 1; off < 64; off <<= 1) s += __shfl_xor(s, off, 64);
  if (lane == 0) out[wid] = s + b[0];
}

// =================================================================
extern "C" void kernel_launch(void* const* d_in, const int* in_sizes, int n_in,
                              void* d_out, int out_size, void* d_ws, size_t ws_size,
                              hipStream_t stream) {
  const int*   xd     = (const int*)  d_in[0];
  const int*   xt     = (const int*)  d_in[1];
  const float* ax     = (const float*)d_in[2];
  const int*   ei     = (const int*)  d_in[3];
  const float* ea     = (const float*)d_in[4];
  const int*   batch  = (const int*)  d_in[5];
  const float* emb_xd = (const float*)d_in[6];
  const float* emb_xt = (const float*)d_in[7];
  const float* wd1 = (const float*)d_in[8];  const float* bd1 = (const float*)d_in[9];
  const float* wd2 = (const float*)d_in[10]; const float* bd2 = (const float*)d_in[11];
  const float* wd3 = (const float*)d_in[12]; const float* bd3 = (const float*)d_in[13];
  const float* wt1 = (const float*)d_in[14]; const float* bt1 = (const float*)d_in[15];
  const float* wt2 = (const float*)d_in[16]; const float* bt2 = (const float*)d_in[17];
  const float* wt3 = (const float*)d_in[18]; const float* bt3 = (const float*)d_in[19];
  const float* g1_w  = (const float*)d_in[20]; const float* g1_as = (const float*)d_in[21];
  const float* g1_ad = (const float*)d_in[22]; const float* g1_we = (const float*)d_in[23];
  const float* g1_ae = (const float*)d_in[24]; const float* g1_b  = (const float*)d_in[25];
  const float* g2_w  = (const float*)d_in[26]; const float* g2_as = (const float*)d_in[27];
  const float* g2_ad = (const float*)d_in[28]; const float* g2_we = (const float*)d_in[29];
  const float* g2_ae = (const float*)d_in[30]; const float* g2_b  = (const float*)d_in[31];
  const float* fc1_w = (const float*)d_in[32]; const float* fc1_b = (const float*)d_in[33];
  const float* c1_w = (const float*)d_in[34]; const float* c1_b = (const float*)d_in[35];
  const float* c2_w = (const float*)d_in[36]; const float* c2_b = (const float*)d_in[37];
  const float* c3_w = (const float*)d_in[38]; const float* c3_b = (const float*)d_in[39];
  const float* c4_w = (const float*)d_in[40]; const float* c4_b = (const float*)d_in[41];
  float* out = (float*)d_out;

  char* ws = (char*)d_ws;
  auto F = [&](size_t off) { return (float*)(ws + off); };
  auto I = [&](size_t off) { return (int*)(ws + off); };
  auto U = [&](size_t off) { return (unsigned int*)(ws + off); };
  auto H = [&](size_t off) { return (u16*)(ws + off); };

  // ---- zero-init the atomically-updated buffers ----
  hipMemsetAsync(ws + OFF_CB,   0, 64*sizeof(float), stream);
  hipMemsetAsync(ws + OFF_DEG,  0, NN*sizeof(int),   stream);
  hipMemsetAsync(ws + OFF_CD,   0, NB*96*sizeof(float), stream);
  hipMemsetAsync(ws + OFF_CT,   0, NB*96*sizeof(float), stream);
  hipMemsetAsync(ws + OFF_POOL, 0, NB*96*sizeof(float), stream);
  // split-K accumulators
  hipMemsetAsync(ws + OFF_GFC,  0, NB*96*sizeof(float),   stream);
  hipMemsetAsync(ws + OFF_M1B,  0, NB*1024*sizeof(float), stream);
  hipMemsetAsync(ws + OFF_M2B,  0, NB*1024*sizeof(float), stream);
  hipMemsetAsync(ws + OFF_M3B,  0, NB*512*sizeof(float),  stream);

  // ---- tables / weight converts ----
  k_tables<<<(8320 + 6656 + 30 + 255)/256, 256, 0, stream>>>(
      wd1, emb_xd, wt1, emb_xt, g1_we, g1_ae, g2_we, g2_ae,
      F(OFF_FD), F(OFF_FT), F(OFF_CB));
  k_wcvt<<<(64*256 + 96*512 + 96*320 + 255)/256, 256, 0, stream>>>(
      wt2, wt3, g2_w, H(OFF_WT2B), H(OFF_WT3B), H(OFF_W2GB));
  k_easum<<<256, 256, 0, stream>>>(ea, F(OFF_CB));
  k_finalize<<<1, 64, 0, stream>>>(F(OFF_CB));

  // ---- drug weight transposes (f32 path) ----
  k_wtrans<<<(8192 + 255)/256, 256, 0, stream>>>(wd2, F(OFF_WD2T), 64, 32, 4);
  k_wtrans<<<(24576 + 255)/256, 256, 0, stream>>>(wd3, F(OFF_WD3T), 96, 64, 4);

  // ---- drug conv branch (f32 direct): L=100 -> 97 -> 94 -> 91 -> maxpool ----
  k_conv1_lut<4,65,32><<<dim3((32*97 + 255)/256, NB), 256, 0, stream>>>(
      xd, F(OFF_FD), bd1, F(OFF_A), 100, 97);
  k_conv<32,4,64,4,16,false><<<dim3((94 + 63)/64, NB), 256, 0, stream>>>(
      F(OFF_A), F(OFF_WD2T), bd2, F(OFF_B), 97, 94);
  k_conv<64,4,96,2,16,true><<<dim3((91 + 31)/32, NB), 192, 0, stream>>>(
      F(OFF_B), F(OFF_WD3T), bd3, F(OFF_CD), 94, 91);

  // ---- target conv branch (bf16 MFMA): 1000 -> 993 -> 986 -> 979 -> maxpool ----
  k_conv1t<<<dim3((993 + 15)/16, NB), 512, 0, stream>>>(
      xt, F(OFF_FT), bt1, H(OFF_A), 1000, 993);
  k_convmfma<32,64,2,false><<<dim3(4, NB), 512, 0, stream>>>(
      H(OFF_A), H(OFF_WT2B), bt2, H(OFF_B), nullptr, 993, 986);
  k_convmfma<64,96,3,true><<<dim3(4, NB), 512, 0, stream>>>(
      H(OFF_B), H(OFF_WT3B), bt3, nullptr, U(OFF_CT), 986, 979);

  // ---- CSR build (independent of h1) ----
  k_deg<<<(EN + 255)/256, 256, 0, stream>>>(ei, I(OFF_DEG));
  k_scan<<<1, 256, 0, stream>>>(I(OFF_DEG), I(OFF_ROWP), I(OFF_CUR));
  k_scatter<<<(EN + 255)/256, 256, 0, stream>>>(ei, I(OFF_CUR), I(OFF_CSRS), I(OFF_CSRE));

  // ---- GAT layer 1 ----
  k_gemm<64,64,24,4,4,false,false><<<dim3(320/64, NN/64), 256, 0, stream>>>(
      ax, g1_w, nullptr, F(OFF_A), 24, 320);
  k_attn_nodeterms<<<(NN*5 + 255)/256, 256, 0, stream>>>(
      F(OFF_A), g1_as, g1_ad, F(OFF_AS1), F(OFF_AD1), 5, 64);
  k_edge_attn<5><<<(EN + 255)/256, 256, 0, stream>>>(
      ei, ea, F(OFF_AS1), F(OFF_AD1), F(OFF_CB), F(OFF_CB) + 35, F(OFF_C));
  k_acsr<5><<<(EN + 255)/256, 256, 0, stream>>>(
      I(OFF_CSRE), F(OFF_C), F(OFF_AC));
  k_gat_aggr<5,64,0,true><<<NN/4, 256, 0, stream>>>(
      I(OFF_ROWP), I(OFF_CSRS), F(OFF_AC), F(OFF_A), g1_b, (void*)H(OFF_B));

  // ---- GAT layer 2 (h2 via MFMA from bf16 g1o) ----
  k_h2mfma<<<NN/128, 512, 0, stream>>>(H(OFF_B), H(OFF_W2GB), F(OFF_C));
  k_attn_nodeterms<<<(NN + 255)/256, 256, 0, stream>>>(
      F(OFF_C), g2_as, g2_ad, F(OFF_AS2), F(OFF_AD2), 1, 96);
  k_edge_attn<1><<<(EN + 255)/256, 256, 0, stream>>>(
      ei, ea, F(OFF_AS2), F(OFF_AD2), F(OFF_CB) + 25, F(OFF_CB) + 40, F(OFF_A2));
  k_acsr<1><<<(EN + 255)/256, 256, 0, stream>>>(
      I(OFF_CSRE), F(OFF_A2), F(OFF_AC));
  k_gat_aggr<1,96,1,false><<<NN/4, 256, 0, stream>>>(
      I(OFF_ROWP), I(OFF_CSRS), F(OFF_AC), F(OFF_C), g2_b, (void*)F(OFF_G2O));

  // ---- graph pool + fc1 (split-K) ----
  k_pool<<<(int)(((long)NN*96 + 255)/256), 256, 0, stream>>>(
      F(OFF_G2O), batch, U(OFF_POOL));
  k_gemm_sk<64,32,32,4,2><<<dim3(96/32, NB/64, 3), 256, 0, stream>>>(
      F(OFF_POOL), fc1_w, F(OFF_GFC), 96, 96, 32);
  k_bias_relu<<<(NB*96 + 255)/256, 256, 0, stream>>>(
      F(OFF_GFC), fc1_b, (long)NB*96, 96, 1);

  // ---- concat + MLP head (split-K GEMMs) ----
  k_concat<<<(NB*288 + 255)/256, 256, 0, stream>>>(
      F(OFF_CD), F(OFF_CT), F(OFF_GFC), F(OFF_XC));

  k_gemm_sk<64,64,32,4,4><<<dim3(1024/64, NB/64, 3), 256, 0, stream>>>(
      F(OFF_XC), c1_w, F(OFF_M1B), 288, 1024, 96);
  k_bias_relu<<<(NB*1024 + 255)/256, 256, 0, stream>>>(
      F(OFF_M1B), c1_b, (long)NB*1024, 1024, 1);

  k_gemm_sk<64,64,32,4,4><<<dim3(1024/64, NB/64, 8), 256, 0, stream>>>(
      F(OFF_M1B), c2_w, F(OFF_M2B), 1024, 1024, 128);
  k_bias_relu<<<(NB*1024 + 255)/256, 256, 0, stream>>>(
      F(OFF_M2B), c2_b, (long)NB*1024, 1024, 1);

  k_gemm_sk<64,64,32,4,4><<<dim3(512/64, NB/64, 8), 256, 0, stream>>>(
      F(OFF_M2B), c3_w, F(OFF_M3B), 1024, 512, 128);
  k_bias_relu<<<(NB*512 + 255)/256, 256, 0, stream>>>(
      F(OFF_M3B), c3_b, (long)NB*512, 512, 1);

  k_final<<<(NB*64 + 255)/256, 256, 0, stream>>>(F(OFF_M3B), c4_w, c4_b, out);
}

// Round 10
// 876.675 us; speedup vs baseline: 2.1519x; 1.0065x over previous
//
#include <hip/hip_runtime.h>

// ---------------- problem constants ----------------
constexpr int NN = 32768;      // nodes
constexpr int EE = 524288;     // edges
constexpr int NB = 256;        // graphs / batch
constexpr int EN = EE + NN;    // edges + self loops

typedef unsigned short u16;
typedef short bh8 __attribute__((ext_vector_type(8)));    // 8 bf16 (4 VGPRs)
typedef float f32x4 __attribute__((ext_vector_type(4)));  // MFMA accumulator

__device__ inline u16 f2b(float f) {   // f32 -> bf16 round-to-nearest-even
  unsigned u = __float_as_uint(f);
  return (u16)((u + 0x7fffu + ((u >> 16) & 1u)) >> 16);
}

// ---------------- workspace layout (bytes) ----------------
constexpr size_t MB = 1ull << 20;
constexpr size_t OFF_A    = 0;        // conv y1 bf16 [b][l][32], later h1 [N,320] f32
constexpr size_t OFF_B    = 48*MB;    // conv y2 bf16, later g1o [N,320] bf16 (21MB)
constexpr size_t OFF_AC   = 100*MB;   // a_csr [EN,5] f32 (11.2MB) -> alpha in place
constexpr size_t OFF_CSRD = 112*MB;   // csr_dst [EN] int (2.2MB)
constexpr size_t OFF_C    = 116*MB;   // a1 [EN,5], later h2 [N,96] f32
constexpr size_t OFF_CSRS = 130*MB;   // csr_src [EN]
constexpr size_t OFF_CSRE = 133*MB;   // csr_eid [EN]
constexpr size_t OFF_ROWP = 136*MB;   // rowptr [N+1]
constexpr size_t OFF_DEG  = 137*MB;   // deg [N]
constexpr size_t OFF_CUR  = 138*MB;   // cursor [N]
constexpr size_t OFF_A2   = 139*MB;   // a2 [EN]
constexpr size_t OFF_G2O  = 142*MB;   // g2o [N,96]
constexpr size_t OFF_AS1  = 155*MB;   // [N,5]: attn src terms, then amax
constexpr size_t OFF_AD1  = 156*MB;   // [N,5]: attn dst terms, then rinv
constexpr size_t OFF_AS2  = 157*MB;   // [N]
constexpr size_t OFF_AD2  = 158*MB;
constexpr size_t OFF_CD   = 159*MB;   // [256,96] pooled drug conv
constexpr size_t OFF_CT   = 160*MB;   // [256,96] pooled target conv
constexpr size_t OFF_POOL = 161*MB;   // [256,96] graph pool
constexpr size_t OFF_GFC  = 162*MB;   // [256,96]
constexpr size_t OFF_XC   = 163*MB;   // [256,288]
constexpr size_t OFF_M1B  = 164*MB;   // [256,1024]
constexpr size_t OFF_M2B  = 165*MB;   // [256,1024]
constexpr size_t OFF_M3B  = 166*MB;   // [256,512]
constexpr size_t OFF_FD   = 167*MB;   // F table drug [4][65][32] f32 (k,v,co)
constexpr size_t OFF_FT   = 168*MB;   // F table target [8][26][32] f32 (k,v,co)
constexpr size_t OFF_WD2B = 169*MB;   // drug w2 bf16 [co][kk*32+ci] (64x128)
constexpr size_t OFF_WD3B = 170*MB;   // drug w3 bf16 [co][kk*64+ci] (96x256)
constexpr size_t OFF_WT2B = 171*MB;   // target w2 bf16 [co][kk*32+ci] (64x256)
constexpr size_t OFF_WT3B = 172*MB;   // target w3 bf16 [co][kk*64+ci] (96x512)
constexpr size_t OFF_W2GB = 174*MB;   // g2_w bf16 [co][k] (96x320)
constexpr size_t OFF_CB   = 173*MB;   // const block: [0:25]=M1, [25:30]=M2, [30:35]=easum,
                                      // [35:40]=aeself1, [40]=ae2self, [41:46]=eamean

// =================================================================
// Tiny precompute tables: F_drug [k][v][co], F_target [k][v][co], M1, M2
// =================================================================
__global__ void k_tables(const float* __restrict__ wd1, const float* __restrict__ emb_xd,
                         const float* __restrict__ wt1, const float* __restrict__ emb_xt,
                         const float* __restrict__ g1we, const float* __restrict__ g1ae,
                         const float* __restrict__ g2we, const float* __restrict__ g2ae,
                         float* __restrict__ Fd, float* __restrict__ Ft,
                         float* __restrict__ CB) {
  int t = blockIdx.x * 256 + threadIdx.x;
  const int NFd = 32*4*65, NFt = 32*8*26;
  if (t < NFd) {                       // Fd stored [k][v][co]
    int v = t % 65; int ck = t / 65; int k = ck & 3; int co = ck >> 2;
    float s = 0.f;
    for (int ci = 0; ci < 128; ++ci)
      s = fmaf(wd1[(co*128 + ci)*4 + k], emb_xd[v*128 + ci], s);
    Fd[(k*65 + v)*32 + co] = s;
  } else if (t < NFd + NFt) {          // Ft stored [k][v][co]
    int u = t - NFd;
    int v = u % 26; int ck = u / 26; int k = ck & 7; int co = ck >> 3;
    float s = 0.f;
    for (int ci = 0; ci < 128; ++ci)
      s = fmaf(wt1[(co*128 + ci)*8 + k], emb_xt[v*128 + ci], s);
    Ft[(k*26 + v)*32 + co] = s;
  } else if (t < NFd + NFt + 25) {     // M1[j][h]
    int u = t - NFd - NFt; int h = u % 5, j = u / 5;
    float s = 0.f;
    for (int c = 0; c < 64; ++c)
      s = fmaf(g1we[j*320 + h*64 + c], g1ae[h*64 + c], s);
    CB[j*5 + h] = s;
  } else if (t < NFd + NFt + 30) {     // M2[j]
    int j = t - NFd - NFt - 25;
    float s = 0.f;
    for (int c = 0; c < 96; ++c)
      s = fmaf(g2we[j*96 + c], g2ae[c], s);
    CB[25 + j] = s;
  }
}

// all conv weights + g2_w -> bf16 [co][kk*CIN+ci] layouts
__global__ void k_wcvt(const float* __restrict__ wd2, const float* __restrict__ wd3,
                       const float* __restrict__ wt2, const float* __restrict__ wt3,
                       const float* __restrict__ g2w,
                       u16* __restrict__ od2, u16* __restrict__ od3,
                       u16* __restrict__ ot2, u16* __restrict__ ot3,
                       u16* __restrict__ og2) {
  int t = blockIdx.x*256 + threadIdx.x;
  if (t < 8192) {                       // drug w2: CIN=32,KK=4,CO=64 (KD=128)
    int co = t >> 7, k = t & 127, kk = k >> 5, ci = k & 31;
    od2[t] = f2b(wd2[(co*32 + ci)*4 + kk]);
  } else if ((t -= 8192) < 24576) {     // drug w3: CIN=64,KK=4,CO=96 (KD=256)
    int co = t >> 8, k = t & 255, kk = k >> 6, ci = k & 63;
    od3[t] = f2b(wd3[(co*64 + ci)*4 + kk]);
  } else if ((t -= 24576) < 16384) {    // target w2: CIN=32,KK=8,CO=64 (KD=256)
    int co = t >> 8, k = t & 255, kk = k >> 5, ci = k & 31;
    ot2[t] = f2b(wt2[(co*32 + ci)*8 + kk]);
  } else if ((t -= 16384) < 49152) {    // target w3: CIN=64,KK=8,CO=96 (KD=512)
    int co = t >> 9, k = t & 511, kk = k >> 6, ci = k & 63;
    ot3[t] = f2b(wt3[(co*64 + ci)*8 + kk]);
  } else if ((t -= 49152) < 30720) {    // g2_w: [co][k], k=0..319
    int co = t / 320, k = t % 320;
    og2[t] = f2b(g2w[k*96 + co]);
  }
}

// sum of ea columns -> CB[30..34] (pre-zeroed)
__global__ void k_easum(const float* __restrict__ ea, float* __restrict__ CB) {
  float acc[5] = {0,0,0,0,0};
  for (long e = blockIdx.x*256L + threadIdx.x; e < EE; e += 256L*gridDim.x) {
    #pragma unroll
    for (int j = 0; j < 5; ++j) acc[j] += ea[e*5 + j];
  }
  #pragma unroll
  for (int j = 0; j < 5; ++j)
    for (int off = 1; off < 64; off <<= 1) acc[j] += __shfl_xor(acc[j], off, 64);
  if ((threadIdx.x & 63) == 0) {
    #pragma unroll
    for (int j = 0; j < 5; ++j) atomicAdd(&CB[30 + j], acc[j]);
  }
}

// eamean, aeself1[h], ae2self
__global__ void k_finalize(float* __restrict__ CB) {
  if (blockIdx.x == 0 && threadIdx.x == 0) {
    float em[5];
    for (int j = 0; j < 5; ++j) { em[j] = CB[30 + j] / (float)EE; CB[41 + j] = em[j]; }
    for (int h = 0; h < 5; ++h) {
      float s = 0.f;
      for (int j = 0; j < 5; ++j) s = fmaf(em[j], CB[j*5 + h], s);
      CB[35 + h] = s;
    }
    float s = 0.f;
    for (int j = 0; j < 5; ++j) s = fmaf(em[j], CB[25 + j], s);
    CB[40] = s;
  }
}

// =================================================================
// conv1 via LUT -> bf16 transposed out y[b][l][32]. LUT layout [k][v][32].
// 512 threads: co = tid&31, p = tid>>5 (16 positions/block)
// =================================================================
template<int K, int V>
__global__ __launch_bounds__(512) void k_conv1t(
    const int* __restrict__ idx, const float* __restrict__ Ftab,
    const float* __restrict__ bias, u16* __restrict__ y, int L, int Lout) {
  constexpr int CO = 32;
  __shared__ float Fs[K*V*CO];
  __shared__ float bs[CO];
  __shared__ int sq[16 + K];
  int b = blockIdx.y, l0 = blockIdx.x * 16;
  for (int i = threadIdx.x; i < K*V*CO; i += 512) Fs[i] = Ftab[i];
  if (threadIdx.x < CO) bs[threadIdx.x] = bias[threadIdx.x];
  if (threadIdx.x < 16 + K - 1) {
    int l = l0 + (int)threadIdx.x;
    sq[threadIdx.x] = (l < L) ? idx[b*L + l] : 0;
  }
  __syncthreads();
  int co = threadIdx.x & 31;
  int p = threadIdx.x >> 5;
  int l = l0 + p;
  if (l >= Lout) return;
  float acc = bs[co];
  #pragma unroll
  for (int k = 0; k < K; ++k) acc += Fs[(k*V + sq[p + k])*CO + co];
  y[((size_t)b*Lout + l)*CO + co] = f2b(fmaxf(acc, 0.f));
}

// =================================================================
// conv2/conv3 (both branches): implicit-GEMM via MFMA bf16.
// x: [B][Lin][CIN] bf16, w: [COUT][KD] bf16 (k = kk*CIN+ci, KD=CIN*KK),
// out y [B][Lout][COUT] bf16 or fused relu+maxpool -> pool[B][COUT].
// =================================================================
template<int CIN, int KK, int COUT, int NT2, bool POOL>
__global__ __launch_bounds__(512) void k_convmfma(
    const u16* __restrict__ xin, const u16* __restrict__ wtb,
    const float* __restrict__ bias, u16* __restrict__ yout,
    unsigned int* __restrict__ pool, int Lin, int Lout) {
  constexpr int KD = CIN*KK;
  constexpr int NCH = KD/32;
  constexpr int MT = 256, ROWS = MT + KK - 1;
  constexpr int XPAD = CIN + 8;
  constexpr int WPAD = KD + 8;
  __shared__ u16 xs[ROWS*XPAD];
  __shared__ u16 wsd[COUT*WPAD];
  int b = blockIdx.y;
  int l0 = blockIdx.x * MT;
  int tid = threadIdx.x;
  {
    const unsigned* wg = (const unsigned*)wtb;
    unsigned* wl = (unsigned*)wsd;
    constexpr int KD2 = KD/2, WP2 = WPAD/2;
    for (int i = tid; i < COUT*KD2; i += 512) {
      int co = i / KD2, c = i % KD2;
      wl[co*WP2 + c] = wg[i];
    }
  }
  {
    const unsigned* xg = (const unsigned*)(xin + (size_t)b*Lin*CIN);
    unsigned* xl = (unsigned*)xs;
    constexpr int C2 = CIN/2, XP2 = XPAD/2;
    for (int i = tid; i < ROWS*C2; i += 512) {
      int r = i / C2, c = i % C2;
      unsigned v = 0;
      if (l0 + r < Lin) v = xg[(size_t)l0*C2 + i];
      xl[r*XP2 + c] = v;
    }
  }
  __syncthreads();
  int lane = tid & 63;
  int w = tid >> 6;
  int mg = w & 3, ng = w >> 2;
  int l15 = lane & 15, l4 = lane >> 4;
  f32x4 acc[4][NT2];
  #pragma unroll
  for (int mi = 0; mi < 4; ++mi)
    #pragma unroll
    for (int nj = 0; nj < NT2; ++nj) acc[mi][nj] = (f32x4){0.f, 0.f, 0.f, 0.f};

  #pragma unroll
  for (int ch = 0; ch < NCH; ++ch) {
    const int kk = (ch*32) / CIN;
    const int cib = (ch*32) % CIN + l4*8;
    bh8 a[4], bb[NT2];
    #pragma unroll
    for (int mi = 0; mi < 4; ++mi) {
      int row = mg*64 + mi*16 + l15 + kk;
      a[mi] = *(const bh8*)&xs[row*XPAD + cib];
    }
    #pragma unroll
    for (int nj = 0; nj < NT2; ++nj) {
      int co = (ng*NT2 + nj)*16 + l15;
      bb[nj] = *(const bh8*)&wsd[co*WPAD + ch*32 + l4*8];
    }
    #pragma unroll
    for (int mi = 0; mi < 4; ++mi)
      #pragma unroll
      for (int nj = 0; nj < NT2; ++nj)
        acc[mi][nj] = __builtin_amdgcn_mfma_f32_16x16x32_bf16(a[mi], bb[nj], acc[mi][nj], 0, 0, 0);
  }

  if (!POOL) {
    #pragma unroll
    for (int nj = 0; nj < NT2; ++nj) {
      int co = (ng*NT2 + nj)*16 + l15;
      float bv = bias[co];
      #pragma unroll
      for (int mi = 0; mi < 4; ++mi)
        #pragma unroll
        for (int r = 0; r < 4; ++r) {
          int m = mg*64 + mi*16 + l4*4 + r;
          if (l0 + m < Lout)
            yout[((size_t)b*Lout + l0 + m)*COUT + co] = f2b(fmaxf(acc[mi][nj][r] + bv, 0.f));
        }
    }
  } else {
    #pragma unroll
    for (int nj = 0; nj < NT2; ++nj) {
      int co = (ng*NT2 + nj)*16 + l15;
      float bv = bias[co];
      float mx = 0.f;
      #pragma unroll
      for (int mi = 0; mi < 4; ++mi)
        #pragma unroll
        for (int r = 0; r < 4; ++r) {
          int m = mg*64 + mi*16 + l4*4 + r;
          if (l0 + m < Lout) mx = fmaxf(mx, fmaxf(acc[mi][nj][r] + bv, 0.f));
        }
      mx = fmaxf(mx, __shfl_xor(mx, 16, 64));
      mx = fmaxf(mx, __shfl_xor(mx, 32, 64));
      if (l4 == 0) atomicMax(&pool[b*COUT + co], __float_as_uint(mx));
    }
  }
}

// =================================================================
// h2 = g1o(bf16 [N,320]) @ g2_w(bf16 [co][k]) -> f32 [N,96] via MFMA.
// =================================================================
__global__ __launch_bounds__(512) void k_h2mfma(
    const u16* __restrict__ g1ob, const u16* __restrict__ wb,
    float* __restrict__ h2) {
  constexpr int KD = 320, WPAD = 328, NCH = 10;
  __shared__ u16 wsd[96*WPAD];
  int tid = threadIdx.x;
  {
    const unsigned* wg = (const unsigned*)wb;
    unsigned* wl = (unsigned*)wsd;
    for (int i = tid; i < 96*(KD/2); i += 512) {
      int co = i / (KD/2), c = i % (KD/2);
      wl[co*(WPAD/2) + c] = wg[i];
    }
  }
  __syncthreads();
  int lane = tid & 63;
  int w = tid >> 6;                 // m-sub 0..7
  int l15 = lane & 15, l4 = lane >> 4;
  long m0 = (long)blockIdx.x * 128;
  const u16* xr = g1ob + (m0 + w*16 + l15) * KD;
  f32x4 acc[6];
  #pragma unroll
  for (int nj = 0; nj < 6; ++nj) acc[nj] = (f32x4){0.f, 0.f, 0.f, 0.f};
  #pragma unroll
  for (int ch = 0; ch < NCH; ++ch) {
    bh8 a = *(const bh8*)&xr[ch*32 + l4*8];
    #pragma unroll
    for (int nj = 0; nj < 6; ++nj) {
      bh8 b = *(const bh8*)&wsd[(nj*16 + l15)*WPAD + ch*32 + l4*8];
      acc[nj] = __builtin_amdgcn_mfma_f32_16x16x32_bf16(a, b, acc[nj], 0, 0, 0);
    }
  }
  #pragma unroll
  for (int nj = 0; nj < 6; ++nj) {
    #pragma unroll
    for (int r = 0; r < 4; ++r) {
      long row = m0 + w*16 + l4*4 + r;
      h2[row*96 + nj*16 + l15] = acc[nj][r];
    }
  }
}

// =================================================================
// register-tiled f32 GEMM (h1)
// =================================================================
template<int BM, int BN, int BK, int TM, int TN, bool BIAS, bool RELU>
__global__ void k_gemm(const float* __restrict__ X, const float* __restrict__ W,
                       const float* __restrict__ bias, float* __restrict__ Y,
                       int K, int C) {
  constexpr int NTH = (BM/TM)*(BN/TN);
  static_assert(NTH == 256, "block must be 256 threads");
  __shared__ float xs[BK][BM + 1];
  __shared__ float wsm[BK][BN];
  const int m0 = blockIdx.y * BM;
  const int c0 = blockIdx.x * BN;
  const int tn = threadIdx.x % (BN/TN);
  const int tm = threadIdx.x / (BN/TN);
  float acc[TM][TN];
  #pragma unroll
  for (int i = 0; i < TM; ++i)
    #pragma unroll
    for (int j = 0; j < TN; ++j) acc[i][j] = 0.f;

  for (int k0 = 0; k0 < K; k0 += BK) {
    #pragma unroll
    for (int i = threadIdx.x; i < BM*BK; i += NTH) {
      int m = i / BK, k = i % BK;
      xs[k][m] = X[(long)(m0 + m)*K + k0 + k];
    }
    #pragma unroll
    for (int i = threadIdx.x; i < BK*BN; i += NTH) {
      int k = i / BN, c = i % BN;
      wsm[k][c] = W[(long)(k0 + k)*C + c0 + c];
    }
    __syncthreads();
    #pragma unroll
    for (int k = 0; k < BK; ++k) {
      float xv[TM], wv[TN];
      #pragma unroll
      for (int i = 0; i < TM; ++i) xv[i] = xs[k][tm*TM + i];
      #pragma unroll
      for (int j = 0; j < TN; ++j) wv[j] = wsm[k][tn*TN + j];
      #pragma unroll
      for (int i = 0; i < TM; ++i)
        #pragma unroll
        for (int j = 0; j < TN; ++j) acc[i][j] = fmaf(xv[i], wv[j], acc[i][j]);
    }
    __syncthreads();
  }
  #pragma unroll
  for (int i = 0; i < TM; ++i) {
    float* yr = Y + (long)(m0 + tm*TM + i)*C + c0 + tn*TN;
    #pragma unroll
    for (int j = 0; j < TN; ++j) {
      float v = acc[i][j];
      if (BIAS) v += bias[c0 + tn*TN + j];
      if (RELU) v = fmaxf(v, 0.f);
      yr[j] = v;
    }
  }
}

// =================================================================
// split-K f32 GEMM for skinny-M (M=256) MLP layers.
// =================================================================
template<int BM, int BN, int BK, int TM, int TN>
__global__ void k_gemm_sk(const float* __restrict__ X, const float* __restrict__ W,
                          float* __restrict__ Y, int K, int C, int KS) {
  constexpr int NTH = (BM/TM)*(BN/TN);
  static_assert(NTH == 256, "block must be 256 threads");
  __shared__ float xs[BK][BM + 1];
  __shared__ float wsm[BK][BN];
  const int m0 = blockIdx.y * BM;
  const int c0 = blockIdx.x * BN;
  const int kbeg = blockIdx.z * KS;
  const int kend = min(K, kbeg + KS);
  const int tn = threadIdx.x % (BN/TN);
  const int tm = threadIdx.x / (BN/TN);
  float acc[TM][TN];
  #pragma unroll
  for (int i = 0; i < TM; ++i)
    #pragma unroll
    for (int j = 0; j < TN; ++j) acc[i][j] = 0.f;

  for (int k0 = kbeg; k0 < kend; k0 += BK) {
    #pragma unroll
    for (int i = threadIdx.x; i < BM*BK; i += NTH) {
      int m = i / BK, k = i % BK;
      xs[k][m] = X[(long)(m0 + m)*K + k0 + k];
    }
    #pragma unroll
    for (int i = threadIdx.x; i < BK*BN; i += NTH) {
      int k = i / BN, c = i % BN;
      wsm[k][c] = W[(long)(k0 + k)*C + c0 + c];
    }
    __syncthreads();
    #pragma unroll
    for (int k = 0; k < BK; ++k) {
      float xv[TM], wv[TN];
      #pragma unroll
      for (int i = 0; i < TM; ++i) xv[i] = xs[k][tm*TM + i];
      #pragma unroll
      for (int j = 0; j < TN; ++j) wv[j] = wsm[k][tn*TN + j];
      #pragma unroll
      for (int i = 0; i < TM; ++i)
        #pragma unroll
        for (int j = 0; j < TN; ++j) acc[i][j] = fmaf(xv[i], wv[j], acc[i][j]);
    }
    __syncthreads();
  }
  #pragma unroll
  for (int i = 0; i < TM; ++i) {
    float* yr = Y + (long)(m0 + tm*TM + i)*C + c0 + tn*TN;
    #pragma unroll
    for (int j = 0; j < TN; ++j) atomicAdd(&yr[j], acc[i][j]);
  }
}

// bias + optional relu, in place over [rows*C]
__global__ void k_bias_relu(float* __restrict__ Y, const float* __restrict__ bias,
                            long total, int C, int relu) {
  long o = blockIdx.x*256L + threadIdx.x;
  if (o >= total) return;
  int c = (int)(o % C);
  float v = Y[o] + bias[c];
  if (relu) v = fmaxf(v, 0.f);
  Y[o] = v;
}

// per-node attention terms
__global__ void k_attn_nodeterms(const float* __restrict__ h, const float* __restrict__ a_s,
                                 const float* __restrict__ a_d, float* __restrict__ as_o,
                                 float* __restrict__ ad_o, int H, int CH) {
  long t = blockIdx.x*256L + threadIdx.x;
  if (t >= (long)NN * H) return;
  int n = (int)(t / H), hh = (int)(t % H);
  const float* hr = h + ((long)n*H + hh)*CH;
  float s1 = 0.f, s2 = 0.f;
  for (int c = 0; c < CH; ++c) {
    float v = hr[c];
    s1 = fmaf(v, a_s[hh*CH + c], s1);
    s2 = fmaf(v, a_d[hh*CH + c], s2);
  }
  as_o[t] = s1; ad_o[t] = s2;
}

// per-edge attention logit with leaky_relu(0.2). e >= EE are self loops.
template<int H>
__global__ void k_edge_attn(const int* __restrict__ ei, const float* __restrict__ ea,
                            const float* __restrict__ asb, const float* __restrict__ adb,
                            const float* __restrict__ M, const float* __restrict__ aeself,
                            float* __restrict__ a_out) {
  long e = blockIdx.x*256L + threadIdx.x;
  if (e >= (long)EN) return;
  int s, d;
  float av[H];
  if (e < EE) {
    s = ei[e]; d = ei[EE + e];
    float er[5];
    #pragma unroll
    for (int j = 0; j < 5; ++j) er[j] = ea[e*5 + j];
    #pragma unroll
    for (int h = 0; h < H; ++h) {
      float t = 0.f;
      #pragma unroll
      for (int j = 0; j < 5; ++j) t = fmaf(er[j], M[j*H + h], t);
      av[h] = t;
    }
  } else {
    s = d = (int)(e - EE);
    #pragma unroll
    for (int h = 0; h < H; ++h) av[h] = aeself[h];
  }
  #pragma unroll
  for (int h = 0; h < H; ++h) {
    float v = asb[s*H + h] + adb[d*H + h] + av[h];
    a_out[e*H + h] = (v > 0.f) ? v : 0.2f * v;
  }
}

// gather edge attn into CSR order: ac[p][h] = a[csr_eid[p]][h]
template<int H>
__global__ void k_acsr(const int* __restrict__ csr_eid, const float* __restrict__ a,
                       float* __restrict__ ac) {
  long p = blockIdx.x*256L + threadIdx.x;
  if (p >= (long)EN) return;
  long e = csr_eid[p];
  #pragma unroll
  for (int h = 0; h < H; ++h) ac[p*H + h] = a[e*H + h];
}

// per-dst softmax stats: amax[h], rinv[h] (one wave per dst)
template<int H>
__global__ void k_stats(const int* __restrict__ rowptr, const float* __restrict__ ac,
                        float* __restrict__ amaxo, float* __restrict__ rinvo) {
  int wid = (int)((blockIdx.x*256L + threadIdx.x) >> 6);
  int lane = threadIdx.x & 63;
  if (wid >= NN) return;
  int row0 = rowptr[wid], row1 = rowptr[wid + 1];
  float amax[H], asum[H];
  #pragma unroll
  for (int h = 0; h < H; ++h) amax[h] = -1e30f;
  for (int p = row0 + lane; p < row1; p += 64) {
    #pragma unroll
    for (int h = 0; h < H; ++h) amax[h] = fmaxf(amax[h], ac[(long)p*H + h]);
  }
  #pragma unroll
  for (int h = 0; h < H; ++h)
    for (int off = 1; off < 64; off <<= 1) amax[h] = fmaxf(amax[h], __shfl_xor(amax[h], off, 64));
  #pragma unroll
  for (int h = 0; h < H; ++h) asum[h] = 0.f;
  for (int p = row0 + lane; p < row1; p += 64) {
    #pragma unroll
    for (int h = 0; h < H; ++h) asum[h] += __expf(ac[(long)p*H + h] - amax[h]);
  }
  #pragma unroll
  for (int h = 0; h < H; ++h)
    for (int off = 1; off < 64; off <<= 1) asum[h] += __shfl_xor(asum[h], off, 64);
  if (lane == 0) {
    #pragma unroll
    for (int h = 0; h < H; ++h) {
      amaxo[(long)wid*H + h] = amax[h];
      rinvo[(long)wid*H + h] = 1.f / (asum[h] + 1e-16f);
    }
  }
}

// normalize logits -> alpha, in place (lane-parallel over CSR slots)
template<int H>
__global__ void k_alpha(const int* __restrict__ csr_dst, const float* __restrict__ amaxb,
                        const float* __restrict__ rinvb, float* __restrict__ ac) {
  long p = blockIdx.x*256L + threadIdx.x;
  if (p >= (long)EN) return;
  int d = csr_dst[p];
  #pragma unroll
  for (int h = 0; h < H; ++h)
    ac[p*H + h] = __expf(ac[p*H + h] - amaxb[(long)d*H + h]) * rinvb[(long)d*H + h];
}

// ------------- CSR build -------------
__global__ void k_deg(const int* __restrict__ ei, int* __restrict__ deg) {
  long e = blockIdx.x*256L + threadIdx.x;
  if (e >= (long)EN) return;
  int d = (e < EE) ? ei[EE + e] : (int)(e - EE);
  atomicAdd(&deg[d], 1);
}

__global__ void k_scan(const int* __restrict__ deg, int* __restrict__ rowptr,
                       int* __restrict__ cursor) {
  __shared__ int ps[256];
  int tid = threadIdx.x;
  int base = tid * 128;           // 256*128 = 32768 = NN
  int s = 0;
  for (int i = 0; i < 128; ++i) s += deg[base + i];
  ps[tid] = s;
  __syncthreads();
  for (int off = 1; off < 256; off <<= 1) {
    int v = (tid >= off) ? ps[tid - off] : 0;
    __syncthreads();
    ps[tid] += v;
    __syncthreads();
  }
  int run = ps[tid] - s;          // exclusive prefix
  for (int i = 0; i < 128; ++i) {
    rowptr[base + i] = run;
    cursor[base + i] = run;
    run += deg[base + i];
  }
  if (tid == 255) rowptr[NN] = run;
}

__global__ void k_scatter(const int* __restrict__ ei, int* __restrict__ cursor,
                          int* __restrict__ csr_src, int* __restrict__ csr_eid,
                          int* __restrict__ csr_dst) {
  long e = blockIdx.x*256L + threadIdx.x;
  if (e >= (long)EN) return;
  int s, d;
  if (e < EE) { s = ei[e]; d = ei[EE + e]; }
  else        { s = d = (int)(e - EE); }
  int p = atomicAdd(&cursor[d], 1);
  csr_src[p] = s;
  csr_eid[p] = (int)e;
  csr_dst[p] = d;
}

// =================================================================
// GAT aggregation (alpha precomputed in ac): wave per dst, XCD-pinned.
// ACT: 0=elu, 1=relu. OBF16: bf16 output.
// =================================================================
template<int H, int CH, int ACT, bool OBF16>
__global__ void k_gat_aggr(const int* __restrict__ rowptr, const int* __restrict__ csr_src,
                           const float* __restrict__ ac,
                           const float* __restrict__ hfeat, const float* __restrict__ bias,
                           void* __restrict__ outv) {
  int bid = blockIdx.x;
  int x = bid & 7;
  int r = bid >> 3;
  int s = r & 31;
  int c = r >> 5;
  int g = c*8 + x;
  int wid = g*128 + s*4 + (int)(threadIdx.x >> 6);
  int lane = threadIdx.x & 63;
  int row0 = rowptr[wid], row1 = rowptr[wid + 1];
  constexpr int F = H * CH;
  constexpr int NJ = (F + 63) / 64;
  float acc[NJ];
  #pragma unroll
  for (int j = 0; j < NJ; ++j) acc[j] = 0.f;
  for (int p = row0; p < row1; ++p) {
    int src = csr_src[p];
    const float* hr = hfeat + (long)src * F;
    #pragma unroll
    for (int j = 0; j < NJ; ++j) {
      int idx = j*64 + lane;
      if ((F % 64 == 0) || idx < F) {
        int h = idx / CH;
        acc[j] = fmaf(ac[(long)p*H + h], hr[idx], acc[j]);
      }
    }
  }
  #pragma unroll
  for (int j = 0; j < NJ; ++j) {
    int idx = j*64 + lane;
    if ((F % 64 == 0) || idx < F) {
      float v = acc[j] + bias[idx];
      if (ACT == 0) v = (v > 0.f) ? v : expm1f(v);
      else          v = fmaxf(v, 0.f);
      if (OBF16) ((u16*)outv)[(long)wid * F + idx] = f2b(v);
      else       ((float*)outv)[(long)wid * F + idx] = v;
    }
  }
}

// graph max pool (relu'd input >= 0, pooled pre-zeroed)
__global__ void k_pool(const float* __restrict__ g2o, const int* __restrict__ batch,
                       unsigned int* __restrict__ pooled) {
  long o = blockIdx.x*256L + threadIdx.x;
  if (o >= (long)NN * 96) return;
  int n = (int)(o / 96), c = (int)(o % 96);
  atomicMax(&pooled[batch[n]*96 + c], __float_as_uint(g2o[o]));
}

__global__ void k_concat(const float* __restrict__ cd, const float* __restrict__ ct,
                         const float* __restrict__ gfc, float* __restrict__ xc) {
  int t = blockIdx.x*256 + threadIdx.x;
  if (t >= NB*288) return;
  int b = t / 288, c = t % 288;
  float v = (c < 96) ? cd[b*96 + c] : (c < 192) ? ct[b*96 + (c-96)] : gfc[b*96 + (c-192)];
  xc[t] = v;
}

// final 512-dot per row
__global__ void k_final(const float* __restrict__ x, const float* __restrict__ w,
                        const float* __restrict__ b, float* __restrict__ out) {
  int wid = (int)((blockIdx.x*256L + threadIdx.x) >> 6);
  int lane = threadIdx.x & 63;
  if (wid >= NB) return;
  const float* xr = x + (long)wid*512;
  float s = 0.f;
  for (int k = lane; k < 512; k += 64) s = fmaf(xr[k], w[k], s);
  for (int off = 1; off < 64; off <<= 1) s += __shfl_xor(s, off, 64);
  if (lane == 0) out[wid] = s + b[0];
}

// =================================================================
extern "C" void kernel_launch(void* const* d_in, const int* in_sizes, int n_in,
                              void* d_out, int out_size, void* d_ws, size_t ws_size,
                              hipStream_t stream) {
  const int*   xd     = (const int*)  d_in[0];
  const int*   xt     = (const int*)  d_in[1];
  const float* ax     = (const float*)d_in[2];
  const int*   ei     = (const int*)  d_in[3];
  const float* ea     = (const float*)d_in[4];
  const int*   batch  = (const int*)  d_in[5];
  const float* emb_xd = (const float*)d_in[6];
  const float* emb_xt = (const float*)d_in[7];
  const float* wd1 = (const float*)d_in[8];  const float* bd1 = (const float*)d_in[9];
  const float* wd2 = (const float*)d_in[10]; const float* bd2 = (const float*)d_in[11];
  const float* wd3 = (const float*)d_in[12]; const float* bd3 = (const float*)d_in[13];
  const float* wt1 = (const float*)d_in[14]; const float* bt1 = (const float*)d_in[15];
  const float* wt2 = (const float*)d_in[16]; const float* bt2 = (const float*)d_in[17];
  const float* wt3 = (const float*)d_in[18]; const float* bt3 = (const float*)d_in[19];
  const float* g1_w  = (const float*)d_in[20]; const float* g1_as = (const float*)d_in[21];
  const float* g1_ad = (const float*)d_in[22]; const float* g1_we = (const float*)d_in[23];
  const float* g1_ae = (const float*)d_in[24]; const float* g1_b  = (const float*)d_in[25];
  const float* g2_w  = (const float*)d_in[26]; const float* g2_as = (const float*)d_in[27];
  const float* g2_ad = (const float*)d_in[28]; const float* g2_we = (const float*)d_in[29];
  const float* g2_ae = (const float*)d_in[30]; const float* g2_b  = (const float*)d_in[31];
  const float* fc1_w = (const float*)d_in[32]; const float* fc1_b = (const float*)d_in[33];
  const float* c1_w = (const float*)d_in[34]; const float* c1_b = (const float*)d_in[35];
  const float* c2_w = (const float*)d_in[36]; const float* c2_b = (const float*)d_in[37];
  const float* c3_w = (const float*)d_in[38]; const float* c3_b = (const float*)d_in[39];
  const float* c4_w = (const float*)d_in[40]; const float* c4_b = (const float*)d_in[41];
  float* out = (float*)d_out;

  char* ws = (char*)d_ws;
  auto F = [&](size_t off) { return (float*)(ws + off); };
  auto I = [&](size_t off) { return (int*)(ws + off); };
  auto U = [&](size_t off) { return (unsigned int*)(ws + off); };
  auto H = [&](size_t off) { return (u16*)(ws + off); };

  // ---- zero-init the atomically-updated buffers ----
  hipMemsetAsync(ws + OFF_CB,   0, 64*sizeof(float), stream);
  hipMemsetAsync(ws + OFF_DEG,  0, NN*sizeof(int),   stream);
  hipMemsetAsync(ws + OFF_CD,   0, NB*96*sizeof(float), stream);
  hipMemsetAsync(ws + OFF_CT,   0, NB*96*sizeof(float), stream);
  hipMemsetAsync(ws + OFF_POOL, 0, NB*96*sizeof(float), stream);
  // split-K accumulators
  hipMemsetAsync(ws + OFF_GFC,  0, NB*96*sizeof(float),   stream);
  hipMemsetAsync(ws + OFF_M1B,  0, NB*1024*sizeof(float), stream);
  hipMemsetAsync(ws + OFF_M2B,  0, NB*1024*sizeof(float), stream);
  hipMemsetAsync(ws + OFF_M3B,  0, NB*512*sizeof(float),  stream);

  // ---- tables / weight converts ----
  k_tables<<<(8320 + 6656 + 30 + 255)/256, 256, 0, stream>>>(
      wd1, emb_xd, wt1, emb_xt, g1_we, g1_ae, g2_we, g2_ae,
      F(OFF_FD), F(OFF_FT), F(OFF_CB));
  k_wcvt<<<(8192 + 24576 + 16384 + 49152 + 30720 + 255)/256, 256, 0, stream>>>(
      wd2, wd3, wt2, wt3, g2_w,
      H(OFF_WD2B), H(OFF_WD3B), H(OFF_WT2B), H(OFF_WT3B), H(OFF_W2GB));
  k_easum<<<256, 256, 0, stream>>>(ea, F(OFF_CB));
  k_finalize<<<1, 64, 0, stream>>>(F(OFF_CB));

  // ---- drug conv branch (bf16 MFMA): 100 -> 97 -> 94 -> 91 -> maxpool ----
  k_conv1t<4,65><<<dim3((97 + 15)/16, NB), 512, 0, stream>>>(
      xd, F(OFF_FD), bd1, H(OFF_A), 100, 97);
  k_convmfma<32,4,64,2,false><<<dim3(1, NB), 512, 0, stream>>>(
      H(OFF_A), H(OFF_WD2B), bd2, H(OFF_B), nullptr, 97, 94);
  k_convmfma<64,4,96,3,true><<<dim3(1, NB), 512, 0, stream>>>(
      H(OFF_B), H(OFF_WD3B), bd3, nullptr, U(OFF_CD), 94, 91);

  // ---- target conv branch (bf16 MFMA): 1000 -> 993 -> 986 -> 979 -> maxpool ----
  k_conv1t<8,26><<<dim3((993 + 15)/16, NB), 512, 0, stream>>>(
      xt, F(OFF_FT), bt1, H(OFF_A), 1000, 993);
  k_convmfma<32,8,64,2,false><<<dim3(4, NB), 512, 0, stream>>>(
      H(OFF_A), H(OFF_WT2B), bt2, H(OFF_B), nullptr, 993, 986);
  k_convmfma<64,8,96,3,true><<<dim3(4, NB), 512, 0, stream>>>(
      H(OFF_B), H(OFF_WT3B), bt3, nullptr, U(OFF_CT), 986, 979);

  // ---- CSR build ----
  k_deg<<<(EN + 255)/256, 256, 0, stream>>>(ei, I(OFF_DEG));
  k_scan<<<1, 256, 0, stream>>>(I(OFF_DEG), I(OFF_ROWP), I(OFF_CUR));
  k_scatter<<<(EN + 255)/256, 256, 0, stream>>>(
      ei, I(OFF_CUR), I(OFF_CSRS), I(OFF_CSRE), I(OFF_CSRD));

  // ---- GAT layer 1 ----
  k_gemm<64,64,24,4,4,false,false><<<dim3(320/64, NN/64), 256, 0, stream>>>(
      ax, g1_w, nullptr, F(OFF_A), 24, 320);
  k_attn_nodeterms<<<(NN*5 + 255)/256, 256, 0, stream>>>(
      F(OFF_A), g1_as, g1_ad, F(OFF_AS1), F(OFF_AD1), 5, 64);
  k_edge_attn<5><<<(EN + 255)/256, 256, 0, stream>>>(
      ei, ea, F(OFF_AS1), F(OFF_AD1), F(OFF_CB), F(OFF_CB) + 35, F(OFF_C));
  k_acsr<5><<<(EN + 255)/256, 256, 0, stream>>>(
      I(OFF_CSRE), F(OFF_C), F(OFF_AC));
  k_stats<5><<<NN/4, 256, 0, stream>>>(
      I(OFF_ROWP), F(OFF_AC), F(OFF_AS1), F(OFF_AD1));   // reuse AS1/AD1 for amax/rinv
  k_alpha<5><<<(EN + 255)/256, 256, 0, stream>>>(
      I(OFF_CSRD), F(OFF_AS1), F(OFF_AD1), F(OFF_AC));
  k_gat_aggr<5,64,0,true><<<NN/4, 256, 0, stream>>>(
      I(OFF_ROWP), I(OFF_CSRS), F(OFF_AC), F(OFF_A), g1_b, (void*)H(OFF_B));

  // ---- GAT layer 2 (h2 via MFMA from bf16 g1o) ----
  k_h2mfma<<<NN/128, 512, 0, stream>>>(H(OFF_B), H(OFF_W2GB), F(OFF_C));
  k_attn_nodeterms<<<(NN + 255)/256, 256, 0, stream>>>(
      F(OFF_C), g2_as, g2_ad, F(OFF_AS2), F(OFF_AD2), 1, 96);
  k_edge_attn<1><<<(EN + 255)/256, 256, 0, stream>>>(
      ei, ea, F(OFF_AS2), F(OFF_AD2), F(OFF_CB) + 25, F(OFF_CB) + 40, F(OFF_A2));
  k_acsr<1><<<(EN + 255)/256, 256, 0, stream>>>(
      I(OFF_CSRE), F(OFF_A2), F(OFF_AC));
  k_stats<1><<<NN/4, 256, 0, stream>>>(
      I(OFF_ROWP), F(OFF_AC), F(OFF_AS2), F(OFF_AD2));
  k_alpha<1><<<(EN + 255)/256, 256, 0, stream>>>(
      I(OFF_CSRD), F(OFF_AS2), F(OFF_AD2), F(OFF_AC));
  k_gat_aggr<1,96,1,false><<<NN/4, 256, 0, stream>>>(
      I(OFF_ROWP), I(OFF_CSRS), F(OFF_AC), F(OFF_C), g2_b, (void*)F(OFF_G2O));

  // ---- graph pool + fc1 (split-K) ----
  k_pool<<<(int)(((long)NN*96 + 255)/256), 256, 0, stream>>>(
      F(OFF_G2O), batch, U(OFF_POOL));
  k_gemm_sk<64,32,32,4,2><<<dim3(96/32, NB/64, 3), 256, 0, stream>>>(
      F(OFF_POOL), fc1_w, F(OFF_GFC), 96, 96, 32);
  k_bias_relu<<<(NB*96 + 255)/256, 256, 0, stream>>>(
      F(OFF_GFC), fc1_b, (long)NB*96, 96, 1);

  // ---- concat + MLP head (split-K GEMMs) ----
  k_concat<<<(NB*288 + 255)/256, 256, 0, stream>>>(
      F(OFF_CD), F(OFF_CT), F(OFF_GFC), F(OFF_XC));

  k_gemm_sk<64,64,32,4,4><<<dim3(1024/64, NB/64, 3), 256, 0, stream>>>(
      F(OFF_XC), c1_w, F(OFF_M1B), 288, 1024, 96);
  k_bias_relu<<<(NB*1024 + 255)/256, 256, 0, stream>>>(
      F(OFF_M1B), c1_b, (long)NB*1024, 1024, 1);

  k_gemm_sk<64,64,32,4,4><<<dim3(1024/64, NB/64, 8), 256, 0, stream>>>(
      F(OFF_M1B), c2_w, F(OFF_M2B), 1024, 1024, 128);
  k_bias_relu<<<(NB*1024 + 255)/256, 256, 0, stream>>>(
      F(OFF_M2B), c2_b, (long)NB*1024, 1024, 1);

  k_gemm_sk<64,64,32,4,4><<<dim3(512/64, NB/64, 8), 256, 0, stream>>>(
      F(OFF_M2B), c3_w, F(OFF_M3B), 1024, 512, 128);
  k_bias_relu<<<(NB*512 + 255)/256, 256, 0, stream>>>(
      F(OFF_M3B), c3_b, (long)NB*512, 512, 1);

  k_final<<<(NB*64 + 255)/256, 256, 0, stream>>>(F(OFF_M3B), c4_w, c4_b, out);
}

// Round 11
// 820.688 us; speedup vs baseline: 2.2987x; 1.0682x over previous
//
#include <hip/hip_runtime.h>

// ---------------- problem constants ----------------
constexpr int NN = 32768;      // nodes
constexpr int EE = 524288;     // edges
constexpr int NB = 256;        // graphs / batch
constexpr int EN = EE + NN;    // edges + self loops

typedef unsigned short u16;
typedef short bh8 __attribute__((ext_vector_type(8)));    // 8 bf16 (4 VGPRs)
typedef float f32x4 __attribute__((ext_vector_type(4)));  // MFMA accumulator

__device__ inline u16 f2b(float f) {   // f32 -> bf16 round-to-nearest-even
  unsigned u = __float_as_uint(f);
  return (u16)((u + 0x7fffu + ((u >> 16) & 1u)) >> 16);
}

// ---------------- workspace layout (bytes) ----------------
constexpr size_t MB = 1ull << 20;
constexpr size_t OFF_A    = 0;        // conv y1 bf16 [b][l][32], later h1 [N,320] f32
constexpr size_t OFF_B    = 48*MB;    // conv y2 bf16, later g1o [N,320] bf16 (21MB)
constexpr size_t OFF_AC   = 100*MB;   // a_csr [EN,5] f32 (11.2MB) -> alpha in place
constexpr size_t OFF_CSRD = 112*MB;   // csr_dst [EN] int (2.2MB)
constexpr size_t OFF_C    = 116*MB;   // a1 [EN,5], later h2 [N,96] f32
constexpr size_t OFF_CSRS = 130*MB;   // csr_src [EN]
constexpr size_t OFF_CSRE = 133*MB;   // csr_eid [EN]
constexpr size_t OFF_ROWP = 136*MB;   // rowptr [N+1]
constexpr size_t OFF_DEG  = 137*MB;   // deg [N]
constexpr size_t OFF_CUR  = 138*MB;   // cursor [N]
constexpr size_t OFF_A2   = 139*MB;   // a2 [EN]
constexpr size_t OFF_G2O  = 142*MB;   // g2o [N,96]
constexpr size_t OFF_AS1  = 155*MB;   // [N,5]: attn src terms, then amax
constexpr size_t OFF_AD1  = 156*MB;   // [N,5]: attn dst terms, then rinv
constexpr size_t OFF_AS2  = 157*MB;   // [N]
constexpr size_t OFF_AD2  = 158*MB;
constexpr size_t OFF_CD   = 159*MB;   // [256,96] pooled drug conv
constexpr size_t OFF_CT   = 160*MB;   // [256,96] pooled target conv
constexpr size_t OFF_POOL = 161*MB;   // [256,96] graph pool
constexpr size_t OFF_GFC  = 162*MB;   // [256,96]
constexpr size_t OFF_XC   = 163*MB;   // [256,288]
constexpr size_t OFF_M1B  = 164*MB;   // [256,1024]
constexpr size_t OFF_M2B  = 165*MB;   // [256,1024]
constexpr size_t OFF_M3B  = 166*MB;   // [256,512]
constexpr size_t OFF_FD   = 167*MB;   // F table drug [4][65][32] f32 (k,v,co)
constexpr size_t OFF_FT   = 168*MB;   // F table target [8][26][32] f32 (k,v,co)
constexpr size_t OFF_WD2B = 169*MB;   // drug w2 bf16 [co][kk*32+ci] (64x128)
constexpr size_t OFF_WD3B = 170*MB;   // drug w3 bf16 [co][kk*64+ci] (96x256)
constexpr size_t OFF_WT2B = 171*MB;   // target w2 bf16 [co][kk*32+ci] (64x256)
constexpr size_t OFF_WT3B = 172*MB;   // target w3 bf16 [co][kk*64+ci] (96x512)
constexpr size_t OFF_W2GB = 174*MB;   // g2_w bf16 [co][k] (96x320)
constexpr size_t OFF_CB   = 173*MB;   // const block: [0:25]=M1, [25:30]=M2, [30:35]=easum,
                                      // [35:40]=aeself1, [40]=ae2self, [41:46]=eamean

// =================================================================
// Tiny precompute tables: F_drug [k][v][co], F_target [k][v][co], M1, M2
// =================================================================
__global__ void k_tables(const float* __restrict__ wd1, const float* __restrict__ emb_xd,
                         const float* __restrict__ wt1, const float* __restrict__ emb_xt,
                         const float* __restrict__ g1we, const float* __restrict__ g1ae,
                         const float* __restrict__ g2we, const float* __restrict__ g2ae,
                         float* __restrict__ Fd, float* __restrict__ Ft,
                         float* __restrict__ CB) {
  int t = blockIdx.x * 256 + threadIdx.x;
  const int NFd = 32*4*65, NFt = 32*8*26;
  if (t < NFd) {                       // Fd stored [k][v][co]
    int v = t % 65; int ck = t / 65; int k = ck & 3; int co = ck >> 2;
    float s = 0.f;
    for (int ci = 0; ci < 128; ++ci)
      s = fmaf(wd1[(co*128 + ci)*4 + k], emb_xd[v*128 + ci], s);
    Fd[(k*65 + v)*32 + co] = s;
  } else if (t < NFd + NFt) {          // Ft stored [k][v][co]
    int u = t - NFd;
    int v = u % 26; int ck = u / 26; int k = ck & 7; int co = ck >> 3;
    float s = 0.f;
    for (int ci = 0; ci < 128; ++ci)
      s = fmaf(wt1[(co*128 + ci)*8 + k], emb_xt[v*128 + ci], s);
    Ft[(k*26 + v)*32 + co] = s;
  } else if (t < NFd + NFt + 25) {     // M1[j][h]
    int u = t - NFd - NFt; int h = u % 5, j = u / 5;
    float s = 0.f;
    for (int c = 0; c < 64; ++c)
      s = fmaf(g1we[j*320 + h*64 + c], g1ae[h*64 + c], s);
    CB[j*5 + h] = s;
  } else if (t < NFd + NFt + 30) {     // M2[j]
    int j = t - NFd - NFt - 25;
    float s = 0.f;
    for (int c = 0; c < 96; ++c)
      s = fmaf(g2we[j*96 + c], g2ae[c], s);
    CB[25 + j] = s;
  }
}

// all conv weights + g2_w -> bf16 [co][kk*CIN+ci] layouts
__global__ void k_wcvt(const float* __restrict__ wd2, const float* __restrict__ wd3,
                       const float* __restrict__ wt2, const float* __restrict__ wt3,
                       const float* __restrict__ g2w,
                       u16* __restrict__ od2, u16* __restrict__ od3,
                       u16* __restrict__ ot2, u16* __restrict__ ot3,
                       u16* __restrict__ og2) {
  int t = blockIdx.x*256 + threadIdx.x;
  if (t < 8192) {                       // drug w2: CIN=32,KK=4,CO=64 (KD=128)
    int co = t >> 7, k = t & 127, kk = k >> 5, ci = k & 31;
    od2[t] = f2b(wd2[(co*32 + ci)*4 + kk]);
  } else if ((t -= 8192) < 24576) {     // drug w3: CIN=64,KK=4,CO=96 (KD=256)
    int co = t >> 8, k = t & 255, kk = k >> 6, ci = k & 63;
    od3[t] = f2b(wd3[(co*64 + ci)*4 + kk]);
  } else if ((t -= 24576) < 16384) {    // target w2: CIN=32,KK=8,CO=64 (KD=256)
    int co = t >> 8, k = t & 255, kk = k >> 5, ci = k & 31;
    ot2[t] = f2b(wt2[(co*32 + ci)*8 + kk]);
  } else if ((t -= 16384) < 49152) {    // target w3: CIN=64,KK=8,CO=96 (KD=512)
    int co = t >> 9, k = t & 511, kk = k >> 6, ci = k & 63;
    ot3[t] = f2b(wt3[(co*64 + ci)*8 + kk]);
  } else if ((t -= 49152) < 30720) {    // g2_w: [co][k], k=0..319
    int co = t / 320, k = t % 320;
    og2[t] = f2b(g2w[k*96 + co]);
  }
}

// sum of ea columns -> CB[30..34] (pre-zeroed)
__global__ void k_easum(const float* __restrict__ ea, float* __restrict__ CB) {
  float acc[5] = {0,0,0,0,0};
  for (long e = blockIdx.x*256L + threadIdx.x; e < EE; e += 256L*gridDim.x) {
    #pragma unroll
    for (int j = 0; j < 5; ++j) acc[j] += ea[e*5 + j];
  }
  #pragma unroll
  for (int j = 0; j < 5; ++j)
    for (int off = 1; off < 64; off <<= 1) acc[j] += __shfl_xor(acc[j], off, 64);
  if ((threadIdx.x & 63) == 0) {
    #pragma unroll
    for (int j = 0; j < 5; ++j) atomicAdd(&CB[30 + j], acc[j]);
  }
}

// eamean, aeself1[h], ae2self
__global__ void k_finalize(float* __restrict__ CB) {
  if (blockIdx.x == 0 && threadIdx.x == 0) {
    float em[5];
    for (int j = 0; j < 5; ++j) { em[j] = CB[30 + j] / (float)EE; CB[41 + j] = em[j]; }
    for (int h = 0; h < 5; ++h) {
      float s = 0.f;
      for (int j = 0; j < 5; ++j) s = fmaf(em[j], CB[j*5 + h], s);
      CB[35 + h] = s;
    }
    float s = 0.f;
    for (int j = 0; j < 5; ++j) s = fmaf(em[j], CB[25 + j], s);
    CB[40] = s;
  }
}

// =================================================================
// conv1 via LUT -> bf16 transposed out y[b][l][32]. LUT layout [k][v][32].
// =================================================================
template<int K, int V>
__global__ __launch_bounds__(512) void k_conv1t(
    const int* __restrict__ idx, const float* __restrict__ Ftab,
    const float* __restrict__ bias, u16* __restrict__ y, int L, int Lout) {
  constexpr int CO = 32;
  __shared__ float Fs[K*V*CO];
  __shared__ float bs[CO];
  __shared__ int sq[16 + K];
  int b = blockIdx.y, l0 = blockIdx.x * 16;
  for (int i = threadIdx.x; i < K*V*CO; i += 512) Fs[i] = Ftab[i];
  if (threadIdx.x < CO) bs[threadIdx.x] = bias[threadIdx.x];
  if (threadIdx.x < 16 + K - 1) {
    int l = l0 + (int)threadIdx.x;
    sq[threadIdx.x] = (l < L) ? idx[b*L + l] : 0;
  }
  __syncthreads();
  int co = threadIdx.x & 31;
  int p = threadIdx.x >> 5;
  int l = l0 + p;
  if (l >= Lout) return;
  float acc = bs[co];
  #pragma unroll
  for (int k = 0; k < K; ++k) acc += Fs[(k*V + sq[p + k])*CO + co];
  y[((size_t)b*Lout + l)*CO + co] = f2b(fmaxf(acc, 0.f));
}

// =================================================================
// conv2/conv3 (both branches): implicit-GEMM via MFMA bf16.
// =================================================================
template<int CIN, int KK, int COUT, int NT2, bool POOL>
__global__ __launch_bounds__(512) void k_convmfma(
    const u16* __restrict__ xin, const u16* __restrict__ wtb,
    const float* __restrict__ bias, u16* __restrict__ yout,
    unsigned int* __restrict__ pool, int Lin, int Lout) {
  constexpr int KD = CIN*KK;
  constexpr int NCH = KD/32;
  constexpr int MT = 256, ROWS = MT + KK - 1;
  constexpr int XPAD = CIN + 8;
  constexpr int WPAD = KD + 8;
  __shared__ u16 xs[ROWS*XPAD];
  __shared__ u16 wsd[COUT*WPAD];
  int b = blockIdx.y;
  int l0 = blockIdx.x * MT;
  int tid = threadIdx.x;
  {
    const unsigned* wg = (const unsigned*)wtb;
    unsigned* wl = (unsigned*)wsd;
    constexpr int KD2 = KD/2, WP2 = WPAD/2;
    for (int i = tid; i < COUT*KD2; i += 512) {
      int co = i / KD2, c = i % KD2;
      wl[co*WP2 + c] = wg[i];
    }
  }
  {
    const unsigned* xg = (const unsigned*)(xin + (size_t)b*Lin*CIN);
    unsigned* xl = (unsigned*)xs;
    constexpr int C2 = CIN/2, XP2 = XPAD/2;
    for (int i = tid; i < ROWS*C2; i += 512) {
      int r = i / C2, c = i % C2;
      unsigned v = 0;
      if (l0 + r < Lin) v = xg[(size_t)l0*C2 + i];
      xl[r*XP2 + c] = v;
    }
  }
  __syncthreads();
  int lane = tid & 63;
  int w = tid >> 6;
  int mg = w & 3, ng = w >> 2;
  int l15 = lane & 15, l4 = lane >> 4;
  f32x4 acc[4][NT2];
  #pragma unroll
  for (int mi = 0; mi < 4; ++mi)
    #pragma unroll
    for (int nj = 0; nj < NT2; ++nj) acc[mi][nj] = (f32x4){0.f, 0.f, 0.f, 0.f};

  #pragma unroll
  for (int ch = 0; ch < NCH; ++ch) {
    const int kk = (ch*32) / CIN;
    const int cib = (ch*32) % CIN + l4*8;
    bh8 a[4], bb[NT2];
    #pragma unroll
    for (int mi = 0; mi < 4; ++mi) {
      int row = mg*64 + mi*16 + l15 + kk;
      a[mi] = *(const bh8*)&xs[row*XPAD + cib];
    }
    #pragma unroll
    for (int nj = 0; nj < NT2; ++nj) {
      int co = (ng*NT2 + nj)*16 + l15;
      bb[nj] = *(const bh8*)&wsd[co*WPAD + ch*32 + l4*8];
    }
    #pragma unroll
    for (int mi = 0; mi < 4; ++mi)
      #pragma unroll
      for (int nj = 0; nj < NT2; ++nj)
        acc[mi][nj] = __builtin_amdgcn_mfma_f32_16x16x32_bf16(a[mi], bb[nj], acc[mi][nj], 0, 0, 0);
  }

  if (!POOL) {
    #pragma unroll
    for (int nj = 0; nj < NT2; ++nj) {
      int co = (ng*NT2 + nj)*16 + l15;
      float bv = bias[co];
      #pragma unroll
      for (int mi = 0; mi < 4; ++mi)
        #pragma unroll
        for (int r = 0; r < 4; ++r) {
          int m = mg*64 + mi*16 + l4*4 + r;
          if (l0 + m < Lout)
            yout[((size_t)b*Lout + l0 + m)*COUT + co] = f2b(fmaxf(acc[mi][nj][r] + bv, 0.f));
        }
    }
  } else {
    #pragma unroll
    for (int nj = 0; nj < NT2; ++nj) {
      int co = (ng*NT2 + nj)*16 + l15;
      float bv = bias[co];
      float mx = 0.f;
      #pragma unroll
      for (int mi = 0; mi < 4; ++mi)
        #pragma unroll
        for (int r = 0; r < 4; ++r) {
          int m = mg*64 + mi*16 + l4*4 + r;
          if (l0 + m < Lout) mx = fmaxf(mx, fmaxf(acc[mi][nj][r] + bv, 0.f));
        }
      mx = fmaxf(mx, __shfl_xor(mx, 16, 64));
      mx = fmaxf(mx, __shfl_xor(mx, 32, 64));
      if (l4 == 0) atomicMax(&pool[b*COUT + co], __float_as_uint(mx));
    }
  }
}

// =================================================================
// h2 = g1o(bf16 [N,320]) @ g2_w(bf16 [co][k]) -> f32 [N,96] via MFMA.
// =================================================================
__global__ __launch_bounds__(512) void k_h2mfma(
    const u16* __restrict__ g1ob, const u16* __restrict__ wb,
    float* __restrict__ h2) {
  constexpr int KD = 320, WPAD = 328, NCH = 10;
  __shared__ u16 wsd[96*WPAD];
  int tid = threadIdx.x;
  {
    const unsigned* wg = (const unsigned*)wb;
    unsigned* wl = (unsigned*)wsd;
    for (int i = tid; i < 96*(KD/2); i += 512) {
      int co = i / (KD/2), c = i % (KD/2);
      wl[co*(WPAD/2) + c] = wg[i];
    }
  }
  __syncthreads();
  int lane = tid & 63;
  int w = tid >> 6;                 // m-sub 0..7
  int l15 = lane & 15, l4 = lane >> 4;
  long m0 = (long)blockIdx.x * 128;
  const u16* xr = g1ob + (m0 + w*16 + l15) * KD;
  f32x4 acc[6];
  #pragma unroll
  for (int nj = 0; nj < 6; ++nj) acc[nj] = (f32x4){0.f, 0.f, 0.f, 0.f};
  #pragma unroll
  for (int ch = 0; ch < NCH; ++ch) {
    bh8 a = *(const bh8*)&xr[ch*32 + l4*8];
    #pragma unroll
    for (int nj = 0; nj < 6; ++nj) {
      bh8 b = *(const bh8*)&wsd[(nj*16 + l15)*WPAD + ch*32 + l4*8];
      acc[nj] = __builtin_amdgcn_mfma_f32_16x16x32_bf16(a, b, acc[nj], 0, 0, 0);
    }
  }
  #pragma unroll
  for (int nj = 0; nj < 6; ++nj) {
    #pragma unroll
    for (int r = 0; r < 4; ++r) {
      long row = m0 + w*16 + l4*4 + r;
      h2[row*96 + nj*16 + l15] = acc[nj][r];
    }
  }
}

// =================================================================
// register-tiled f32 GEMM (h1)
// =================================================================
template<int BM, int BN, int BK, int TM, int TN, bool BIAS, bool RELU>
__global__ void k_gemm(const float* __restrict__ X, const float* __restrict__ W,
                       const float* __restrict__ bias, float* __restrict__ Y,
                       int K, int C) {
  constexpr int NTH = (BM/TM)*(BN/TN);
  static_assert(NTH == 256, "block must be 256 threads");
  __shared__ float xs[BK][BM + 1];
  __shared__ float wsm[BK][BN];
  const int m0 = blockIdx.y * BM;
  const int c0 = blockIdx.x * BN;
  const int tn = threadIdx.x % (BN/TN);
  const int tm = threadIdx.x / (BN/TN);
  float acc[TM][TN];
  #pragma unroll
  for (int i = 0; i < TM; ++i)
    #pragma unroll
    for (int j = 0; j < TN; ++j) acc[i][j] = 0.f;

  for (int k0 = 0; k0 < K; k0 += BK) {
    #pragma unroll
    for (int i = threadIdx.x; i < BM*BK; i += NTH) {
      int m = i / BK, k = i % BK;
      xs[k][m] = X[(long)(m0 + m)*K + k0 + k];
    }
    #pragma unroll
    for (int i = threadIdx.x; i < BK*BN; i += NTH) {
      int k = i / BN, c = i % BN;
      wsm[k][c] = W[(long)(k0 + k)*C + c0 + c];
    }
    __syncthreads();
    #pragma unroll
    for (int k = 0; k < BK; ++k) {
      float xv[TM], wv[TN];
      #pragma unroll
      for (int i = 0; i < TM; ++i) xv[i] = xs[k][tm*TM + i];
      #pragma unroll
      for (int j = 0; j < TN; ++j) wv[j] = wsm[k][tn*TN + j];
      #pragma unroll
      for (int i = 0; i < TM; ++i)
        #pragma unroll
        for (int j = 0; j < TN; ++j) acc[i][j] = fmaf(xv[i], wv[j], acc[i][j]);
    }
    __syncthreads();
  }
  #pragma unroll
  for (int i = 0; i < TM; ++i) {
    float* yr = Y + (long)(m0 + tm*TM + i)*C + c0 + tn*TN;
    #pragma unroll
    for (int j = 0; j < TN; ++j) {
      float v = acc[i][j];
      if (BIAS) v += bias[c0 + tn*TN + j];
      if (RELU) v = fmaxf(v, 0.f);
      yr[j] = v;
    }
  }
}

// =================================================================
// split-K f32 GEMM for skinny-M (M=256) MLP layers.
// =================================================================
template<int BM, int BN, int BK, int TM, int TN>
__global__ void k_gemm_sk(const float* __restrict__ X, const float* __restrict__ W,
                          float* __restrict__ Y, int K, int C, int KS) {
  constexpr int NTH = (BM/TM)*(BN/TN);
  static_assert(NTH == 256, "block must be 256 threads");
  __shared__ float xs[BK][BM + 1];
  __shared__ float wsm[BK][BN];
  const int m0 = blockIdx.y * BM;
  const int c0 = blockIdx.x * BN;
  const int kbeg = blockIdx.z * KS;
  const int kend = min(K, kbeg + KS);
  const int tn = threadIdx.x % (BN/TN);
  const int tm = threadIdx.x / (BN/TN);
  float acc[TM][TN];
  #pragma unroll
  for (int i = 0; i < TM; ++i)
    #pragma unroll
    for (int j = 0; j < TN; ++j) acc[i][j] = 0.f;

  for (int k0 = kbeg; k0 < kend; k0 += BK) {
    #pragma unroll
    for (int i = threadIdx.x; i < BM*BK; i += NTH) {
      int m = i / BK, k = i % BK;
      xs[k][m] = X[(long)(m0 + m)*K + k0 + k];
    }
    #pragma unroll
    for (int i = threadIdx.x; i < BK*BN; i += NTH) {
      int k = i / BN, c = i % BN;
      wsm[k][c] = W[(long)(k0 + k)*C + c0 + c];
    }
    __syncthreads();
    #pragma unroll
    for (int k = 0; k < BK; ++k) {
      float xv[TM], wv[TN];
      #pragma unroll
      for (int i = 0; i < TM; ++i) xv[i] = xs[k][tm*TM + i];
      #pragma unroll
      for (int j = 0; j < TN; ++j) wv[j] = wsm[k][tn*TN + j];
      #pragma unroll
      for (int i = 0; i < TM; ++i)
        #pragma unroll
        for (int j = 0; j < TN; ++j) acc[i][j] = fmaf(xv[i], wv[j], acc[i][j]);
    }
    __syncthreads();
  }
  #pragma unroll
  for (int i = 0; i < TM; ++i) {
    float* yr = Y + (long)(m0 + tm*TM + i)*C + c0 + tn*TN;
    #pragma unroll
    for (int j = 0; j < TN; ++j) atomicAdd(&yr[j], acc[i][j]);
  }
}

// bias + optional relu, in place over [rows*C]
__global__ void k_bias_relu(float* __restrict__ Y, const float* __restrict__ bias,
                            long total, int C, int relu) {
  long o = blockIdx.x*256L + threadIdx.x;
  if (o >= total) return;
  int c = (int)(o % C);
  float v = Y[o] + bias[c];
  if (relu) v = fmaxf(v, 0.f);
  Y[o] = v;
}

// =================================================================
// per-node attention terms, wave-per-node (coalesced loads + shfl reduce)
// as[n,h] = sum_c h[n,h*CH+c]*a_s[h*CH+c]; same for ad.
// =================================================================
template<int H, int CH>
__global__ void k_nodeterms_w(const float* __restrict__ hf, const float* __restrict__ a_s,
                              const float* __restrict__ a_d, float* __restrict__ as_o,
                              float* __restrict__ ad_o) {
  constexpr int F = H * CH;
  constexpr int NJ = (F + 63) / 64;
  int wid = (int)((blockIdx.x*256L + threadIdx.x) >> 6);
  int lane = threadIdx.x & 63;
  if (wid >= NN) return;
  const float* hr = hf + (long)wid * F;
  float s1[H], s2[H];
  #pragma unroll
  for (int h = 0; h < H; ++h) { s1[h] = 0.f; s2[h] = 0.f; }
  #pragma unroll
  for (int j = 0; j < NJ; ++j) {
    int c = j*64 + lane;
    if ((F % 64 == 0) || c < F) {
      int h = c / CH;            // compile-time-constant per j when CH==64
      float v = hr[c];
      s1[h] = fmaf(v, a_s[c], s1[h]);
      s2[h] = fmaf(v, a_d[c], s2[h]);
    }
  }
  #pragma unroll
  for (int h = 0; h < H; ++h) {
    #pragma unroll
    for (int off = 1; off < 64; off <<= 1) {
      s1[h] += __shfl_xor(s1[h], off, 64);
      s2[h] += __shfl_xor(s2[h], off, 64);
    }
  }
  if (lane == 0) {
    #pragma unroll
    for (int h = 0; h < H; ++h) {
      as_o[(long)wid*H + h] = s1[h];
      ad_o[(long)wid*H + h] = s2[h];
    }
  }
}

// per-edge attention logit with leaky_relu(0.2). e >= EE are self loops.
template<int H>
__global__ void k_edge_attn(const int* __restrict__ ei, const float* __restrict__ ea,
                            const float* __restrict__ asb, const float* __restrict__ adb,
                            const float* __restrict__ M, const float* __restrict__ aeself,
                            float* __restrict__ a_out) {
  long e = blockIdx.x*256L + threadIdx.x;
  if (e >= (long)EN) return;
  int s, d;
  float av[H];
  if (e < EE) {
    s = ei[e]; d = ei[EE + e];
    float er[5];
    #pragma unroll
    for (int j = 0; j < 5; ++j) er[j] = ea[e*5 + j];
    #pragma unroll
    for (int h = 0; h < H; ++h) {
      float t = 0.f;
      #pragma unroll
      for (int j = 0; j < 5; ++j) t = fmaf(er[j], M[j*H + h], t);
      av[h] = t;
    }
  } else {
    s = d = (int)(e - EE);
    #pragma unroll
    for (int h = 0; h < H; ++h) av[h] = aeself[h];
  }
  #pragma unroll
  for (int h = 0; h < H; ++h) {
    float v = asb[s*H + h] + adb[d*H + h] + av[h];
    a_out[e*H + h] = (v > 0.f) ? v : 0.2f * v;
  }
}

// gather edge attn into CSR order: ac[p][h] = a[csr_eid[p]][h]
template<int H>
__global__ void k_acsr(const int* __restrict__ csr_eid, const float* __restrict__ a,
                       float* __restrict__ ac) {
  long p = blockIdx.x*256L + threadIdx.x;
  if (p >= (long)EN) return;
  long e = csr_eid[p];
  #pragma unroll
  for (int h = 0; h < H; ++h) ac[p*H + h] = a[e*H + h];
}

// per-dst softmax stats: amax[h], rinv[h] (one wave per dst)
template<int H>
__global__ void k_stats(const int* __restrict__ rowptr, const float* __restrict__ ac,
                        float* __restrict__ amaxo, float* __restrict__ rinvo) {
  int wid = (int)((blockIdx.x*256L + threadIdx.x) >> 6);
  int lane = threadIdx.x & 63;
  if (wid >= NN) return;
  int row0 = rowptr[wid], row1 = rowptr[wid + 1];
  float amax[H], asum[H];
  #pragma unroll
  for (int h = 0; h < H; ++h) amax[h] = -1e30f;
  for (int p = row0 + lane; p < row1; p += 64) {
    #pragma unroll
    for (int h = 0; h < H; ++h) amax[h] = fmaxf(amax[h], ac[(long)p*H + h]);
  }
  #pragma unroll
  for (int h = 0; h < H; ++h)
    for (int off = 1; off < 64; off <<= 1) amax[h] = fmaxf(amax[h], __shfl_xor(amax[h], off, 64));
  #pragma unroll
  for (int h = 0; h < H; ++h) asum[h] = 0.f;
  for (int p = row0 + lane; p < row1; p += 64) {
    #pragma unroll
    for (int h = 0; h < H; ++h) asum[h] += __expf(ac[(long)p*H + h] - amax[h]);
  }
  #pragma unroll
  for (int h = 0; h < H; ++h)
    for (int off = 1; off < 64; off <<= 1) asum[h] += __shfl_xor(asum[h], off, 64);
  if (lane == 0) {
    #pragma unroll
    for (int h = 0; h < H; ++h) {
      amaxo[(long)wid*H + h] = amax[h];
      rinvo[(long)wid*H + h] = 1.f / (asum[h] + 1e-16f);
    }
  }
}

// normalize logits -> alpha, in place (lane-parallel over CSR slots)
template<int H>
__global__ void k_alpha(const int* __restrict__ csr_dst, const float* __restrict__ amaxb,
                        const float* __restrict__ rinvb, float* __restrict__ ac) {
  long p = blockIdx.x*256L + threadIdx.x;
  if (p >= (long)EN) return;
  int d = csr_dst[p];
  #pragma unroll
  for (int h = 0; h < H; ++h)
    ac[p*H + h] = __expf(ac[p*H + h] - amaxb[(long)d*H + h]) * rinvb[(long)d*H + h];
}

// ------------- CSR build -------------
__global__ void k_deg(const int* __restrict__ ei, int* __restrict__ deg) {
  long e = blockIdx.x*256L + threadIdx.x;
  if (e >= (long)EN) return;
  int d = (e < EE) ? ei[EE + e] : (int)(e - EE);
  atomicAdd(&deg[d], 1);
}

__global__ void k_scan(const int* __restrict__ deg, int* __restrict__ rowptr,
                       int* __restrict__ cursor) {
  __shared__ int ps[256];
  int tid = threadIdx.x;
  int base = tid * 128;           // 256*128 = 32768 = NN
  int s = 0;
  for (int i = 0; i < 128; ++i) s += deg[base + i];
  ps[tid] = s;
  __syncthreads();
  for (int off = 1; off < 256; off <<= 1) {
    int v = (tid >= off) ? ps[tid - off] : 0;
    __syncthreads();
    ps[tid] += v;
    __syncthreads();
  }
  int run = ps[tid] - s;          // exclusive prefix
  for (int i = 0; i < 128; ++i) {
    rowptr[base + i] = run;
    cursor[base + i] = run;
    run += deg[base + i];
  }
  if (tid == 255) rowptr[NN] = run;
}

__global__ void k_scatter(const int* __restrict__ ei, int* __restrict__ cursor,
                          int* __restrict__ csr_src, int* __restrict__ csr_eid,
                          int* __restrict__ csr_dst) {
  long e = blockIdx.x*256L + threadIdx.x;
  if (e >= (long)EN) return;
  int s, d;
  if (e < EE) { s = ei[e]; d = ei[EE + e]; }
  else        { s = d = (int)(e - EE); }
  int p = atomicAdd(&cursor[d], 1);
  csr_src[p] = s;
  csr_eid[p] = (int)e;
  csr_dst[p] = d;
}

// =================================================================
// GAT aggregation (alpha precomputed in ac): wave per dst, XCD-pinned.
// ACT: 0=elu, 1=relu. OBF16: bf16 output.
// =================================================================
template<int H, int CH, int ACT, bool OBF16>
__global__ void k_gat_aggr(const int* __restrict__ rowptr, const int* __restrict__ csr_src,
                           const float* __restrict__ ac,
                           const float* __restrict__ hfeat, const float* __restrict__ bias,
                           void* __restrict__ outv) {
  int bid = blockIdx.x;
  int x = bid & 7;
  int r = bid >> 3;
  int s = r & 31;
  int c = r >> 5;
  int g = c*8 + x;
  int wid = g*128 + s*4 + (int)(threadIdx.x >> 6);
  int lane = threadIdx.x & 63;
  int row0 = rowptr[wid], row1 = rowptr[wid + 1];
  constexpr int F = H * CH;
  constexpr int NJ = (F + 63) / 64;
  float acc[NJ];
  #pragma unroll
  for (int j = 0; j < NJ; ++j) acc[j] = 0.f;
  for (int p = row0; p < row1; ++p) {
    int src = csr_src[p];
    const float* hr = hfeat + (long)src * F;
    #pragma unroll
    for (int j = 0; j < NJ; ++j) {
      int idx = j*64 + lane;
      if ((F % 64 == 0) || idx < F) {
        int h = idx / CH;
        acc[j] = fmaf(ac[(long)p*H + h], hr[idx], acc[j]);
      }
    }
  }
  #pragma unroll
  for (int j = 0; j < NJ; ++j) {
    int idx = j*64 + lane;
    if ((F % 64 == 0) || idx < F) {
      float v = acc[j] + bias[idx];
      if (ACT == 0) v = (v > 0.f) ? v : expm1f(v);
      else          v = fmaxf(v, 0.f);
      if (OBF16) ((u16*)outv)[(long)wid * F + idx] = f2b(v);
      else       ((float*)outv)[(long)wid * F + idx] = v;
    }
  }
}

// graph max pool (relu'd input >= 0, pooled pre-zeroed)
__global__ void k_pool(const float* __restrict__ g2o, const int* __restrict__ batch,
                       unsigned int* __restrict__ pooled) {
  long o = blockIdx.x*256L + threadIdx.x;
  if (o >= (long)NN * 96) return;
  int n = (int)(o / 96), c = (int)(o % 96);
  atomicMax(&pooled[batch[n]*96 + c], __float_as_uint(g2o[o]));
}

__global__ void k_concat(const float* __restrict__ cd, const float* __restrict__ ct,
                         const float* __restrict__ gfc, float* __restrict__ xc) {
  int t = blockIdx.x*256 + threadIdx.x;
  if (t >= NB*288) return;
  int b = t / 288, c = t % 288;
  float v = (c < 96) ? cd[b*96 + c] : (c < 192) ? ct[b*96 + (c-96)] : gfc[b*96 + (c-192)];
  xc[t] = v;
}

// final 512-dot per row
__global__ void k_final(const float* __restrict__ x, const float* __restrict__ w,
                        const float* __restrict__ b, float* __restrict__ out) {
  int wid = (int)((blockIdx.x*256L + threadIdx.x) >> 6);
  int lane = threadIdx.x & 63;
  if (wid >= NB) return;
  const float* xr = x + (long)wid*512;
  float s = 0.f;
  for (int k = lane; k < 512; k += 64) s = fmaf(xr[k], w[k], s);
  for (int off = 1; off < 64; off <<= 1) s += __shfl_xor(s, off, 64);
  if (lane == 0) out[wid] = s + b[0];
}

// =================================================================
extern "C" void kernel_launch(void* const* d_in, const int* in_sizes, int n_in,
                              void* d_out, int out_size, void* d_ws, size_t ws_size,
                              hipStream_t stream) {
  const int*   xd     = (const int*)  d_in[0];
  const int*   xt     = (const int*)  d_in[1];
  const float* ax     = (const float*)d_in[2];
  const int*   ei     = (const int*)  d_in[3];
  const float* ea     = (const float*)d_in[4];
  const int*   batch  = (const int*)  d_in[5];
  const float* emb_xd = (const float*)d_in[6];
  const float* emb_xt = (const float*)d_in[7];
  const float* wd1 = (const float*)d_in[8];  const float* bd1 = (const float*)d_in[9];
  const float* wd2 = (const float*)d_in[10]; const float* bd2 = (const float*)d_in[11];
  const float* wd3 = (const float*)d_in[12]; const float* bd3 = (const float*)d_in[13];
  const float* wt1 = (const float*)d_in[14]; const float* bt1 = (const float*)d_in[15];
  const float* wt2 = (const float*)d_in[16]; const float* bt2 = (const float*)d_in[17];
  const float* wt3 = (const float*)d_in[18]; const float* bt3 = (const float*)d_in[19];
  const float* g1_w  = (const float*)d_in[20]; const float* g1_as = (const float*)d_in[21];
  const float* g1_ad = (const float*)d_in[22]; const float* g1_we = (const float*)d_in[23];
  const float* g1_ae = (const float*)d_in[24]; const float* g1_b  = (const float*)d_in[25];
  const float* g2_w  = (const float*)d_in[26]; const float* g2_as = (const float*)d_in[27];
  const float* g2_ad = (const float*)d_in[28]; const float* g2_we = (const float*)d_in[29];
  const float* g2_ae = (const float*)d_in[30]; const float* g2_b  = (const float*)d_in[31];
  const float* fc1_w = (const float*)d_in[32]; const float* fc1_b = (const float*)d_in[33];
  const float* c1_w = (const float*)d_in[34]; const float* c1_b = (const float*)d_in[35];
  const float* c2_w = (const float*)d_in[36]; const float* c2_b = (const float*)d_in[37];
  const float* c3_w = (const float*)d_in[38]; const float* c3_b = (const float*)d_in[39];
  const float* c4_w = (const float*)d_in[40]; const float* c4_b = (const float*)d_in[41];
  float* out = (float*)d_out;

  char* ws = (char*)d_ws;
  auto F = [&](size_t off) { return (float*)(ws + off); };
  auto I = [&](size_t off) { return (int*)(ws + off); };
  auto U = [&](size_t off) { return (unsigned int*)(ws + off); };
  auto H = [&](size_t off) { return (u16*)(ws + off); };

  // ---- zero-init the atomically-updated buffers ----
  hipMemsetAsync(ws + OFF_CB,   0, 64*sizeof(float), stream);
  hipMemsetAsync(ws + OFF_DEG,  0, NN*sizeof(int),   stream);
  hipMemsetAsync(ws + OFF_CD,   0, NB*96*sizeof(float), stream);
  hipMemsetAsync(ws + OFF_CT,   0, NB*96*sizeof(float), stream);
  hipMemsetAsync(ws + OFF_POOL, 0, NB*96*sizeof(float), stream);
  // split-K accumulators
  hipMemsetAsync(ws + OFF_GFC,  0, NB*96*sizeof(float),   stream);
  hipMemsetAsync(ws + OFF_M1B,  0, NB*1024*sizeof(float), stream);
  hipMemsetAsync(ws + OFF_M2B,  0, NB*1024*sizeof(float), stream);
  hipMemsetAsync(ws + OFF_M3B,  0, NB*512*sizeof(float),  stream);

  // ---- tables / weight converts ----
  k_tables<<<(8320 + 6656 + 30 + 255)/256, 256, 0, stream>>>(
      wd1, emb_xd, wt1, emb_xt, g1_we, g1_ae, g2_we, g2_ae,
      F(OFF_FD), F(OFF_FT), F(OFF_CB));
  k_wcvt<<<(8192 + 24576 + 16384 + 49152 + 30720 + 255)/256, 256, 0, stream>>>(
      wd2, wd3, wt2, wt3, g2_w,
      H(OFF_WD2B), H(OFF_WD3B), H(OFF_WT2B), H(OFF_WT3B), H(OFF_W2GB));
  k_easum<<<256, 256, 0, stream>>>(ea, F(OFF_CB));
  k_finalize<<<1, 64, 0, stream>>>(F(OFF_CB));

  // ---- drug conv branch (bf16 MFMA): 100 -> 97 -> 94 -> 91 -> maxpool ----
  k_conv1t<4,65><<<dim3((97 + 15)/16, NB), 512, 0, stream>>>(
      xd, F(OFF_FD), bd1, H(OFF_A), 100, 97);
  k_convmfma<32,4,64,2,false><<<dim3(1, NB), 512, 0, stream>>>(
      H(OFF_A), H(OFF_WD2B), bd2, H(OFF_B), nullptr, 97, 94);
  k_convmfma<64,4,96,3,true><<<dim3(1, NB), 512, 0, stream>>>(
      H(OFF_B), H(OFF_WD3B), bd3, nullptr, U(OFF_CD), 94, 91);

  // ---- target conv branch (bf16 MFMA): 1000 -> 993 -> 986 -> 979 -> maxpool ----
  k_conv1t<8,26><<<dim3((993 + 15)/16, NB), 512, 0, stream>>>(
      xt, F(OFF_FT), bt1, H(OFF_A), 1000, 993);
  k_convmfma<32,8,64,2,false><<<dim3(4, NB), 512, 0, stream>>>(
      H(OFF_A), H(OFF_WT2B), bt2, H(OFF_B), nullptr, 993, 986);
  k_convmfma<64,8,96,3,true><<<dim3(4, NB), 512, 0, stream>>>(
      H(OFF_B), H(OFF_WT3B), bt3, nullptr, U(OFF_CT), 986, 979);

  // ---- CSR build ----
  k_deg<<<(EN + 255)/256, 256, 0, stream>>>(ei, I(OFF_DEG));
  k_scan<<<1, 256, 0, stream>>>(I(OFF_DEG), I(OFF_ROWP), I(OFF_CUR));
  k_scatter<<<(EN + 255)/256, 256, 0, stream>>>(
      ei, I(OFF_CUR), I(OFF_CSRS), I(OFF_CSRE), I(OFF_CSRD));

  // ---- GAT layer 1 ----
  k_gemm<64,64,24,4,4,false,false><<<dim3(320/64, NN/64), 256, 0, stream>>>(
      ax, g1_w, nullptr, F(OFF_A), 24, 320);
  k_nodeterms_w<5,64><<<NN/4, 256, 0, stream>>>(
      F(OFF_A), g1_as, g1_ad, F(OFF_AS1), F(OFF_AD1));
  k_edge_attn<5><<<(EN + 255)/256, 256, 0, stream>>>(
      ei, ea, F(OFF_AS1), F(OFF_AD1), F(OFF_CB), F(OFF_CB) + 35, F(OFF_C));
  k_acsr<5><<<(EN + 255)/256, 256, 0, stream>>>(
      I(OFF_CSRE), F(OFF_C), F(OFF_AC));
  k_stats<5><<<NN/4, 256, 0, stream>>>(
      I(OFF_ROWP), F(OFF_AC), F(OFF_AS1), F(OFF_AD1));   // reuse AS1/AD1 for amax/rinv
  k_alpha<5><<<(EN + 255)/256, 256, 0, stream>>>(
      I(OFF_CSRD), F(OFF_AS1), F(OFF_AD1), F(OFF_AC));
  k_gat_aggr<5,64,0,true><<<NN/4, 256, 0, stream>>>(
      I(OFF_ROWP), I(OFF_CSRS), F(OFF_AC), F(OFF_A), g1_b, (void*)H(OFF_B));

  // ---- GAT layer 2 (h2 via MFMA from bf16 g1o) ----
  k_h2mfma<<<NN/128, 512, 0, stream>>>(H(OFF_B), H(OFF_W2GB), F(OFF_C));
  k_nodeterms_w<1,96><<<NN/4, 256, 0, stream>>>(
      F(OFF_C), g2_as, g2_ad, F(OFF_AS2), F(OFF_AD2));
  k_edge_attn<1><<<(EN + 255)/256, 256, 0, stream>>>(
      ei, ea, F(OFF_AS2), F(OFF_AD2), F(OFF_CB) + 25, F(OFF_CB) + 40, F(OFF_A2));
  k_acsr<1><<<(EN + 255)/256, 256, 0, stream>>>(
      I(OFF_CSRE), F(OFF_A2), F(OFF_AC));
  k_stats<1><<<NN/4, 256, 0, stream>>>(
      I(OFF_ROWP), F(OFF_AC), F(OFF_AS2), F(OFF_AD2));
  k_alpha<1><<<(EN + 255)/256, 256, 0, stream>>>(
      I(OFF_CSRD), F(OFF_AS2), F(OFF_AD2), F(OFF_AC));
  k_gat_aggr<1,96,1,false><<<NN/4, 256, 0, stream>>>(
      I(OFF_ROWP), I(OFF_CSRS), F(OFF_AC), F(OFF_C), g2_b, (void*)F(OFF_G2O));

  // ---- graph pool + fc1 (split-K) ----
  k_pool<<<(int)(((long)NN*96 + 255)/256), 256, 0, stream>>>(
      F(OFF_G2O), batch, U(OFF_POOL));
  k_gemm_sk<64,32,32,4,2><<<dim3(96/32, NB/64, 3), 256, 0, stream>>>(
      F(OFF_POOL), fc1_w, F(OFF_GFC), 96, 96, 32);
  k_bias_relu<<<(NB*96 + 255)/256, 256, 0, stream>>>(
      F(OFF_GFC), fc1_b, (long)NB*96, 96, 1);

  // ---- concat + MLP head (split-K GEMMs) ----
  k_concat<<<(NB*288 + 255)/256, 256, 0, stream>>>(
      F(OFF_CD), F(OFF_CT), F(OFF_GFC), F(OFF_XC));

  k_gemm_sk<64,64,32,4,4><<<dim3(1024/64, NB/64, 3), 256, 0, stream>>>(
      F(OFF_XC), c1_w, F(OFF_M1B), 288, 1024, 96);
  k_bias_relu<<<(NB*1024 + 255)/256, 256, 0, stream>>>(
      F(OFF_M1B), c1_b, (long)NB*1024, 1024, 1);

  k_gemm_sk<64,64,32,4,4><<<dim3(1024/64, NB/64, 8), 256, 0, stream>>>(
      F(OFF_M1B), c2_w, F(OFF_M2B), 1024, 1024, 128);
  k_bias_relu<<<(NB*1024 + 255)/256, 256, 0, stream>>>(
      F(OFF_M2B), c2_b, (long)NB*1024, 1024, 1);

  k_gemm_sk<64,64,32,4,4><<<dim3(512/64, NB/64, 8), 256, 0, stream>>>(
      F(OFF_M2B), c3_w, F(OFF_M3B), 1024, 512, 128);
  k_bias_relu<<<(NB*512 + 255)/256, 256, 0, stream>>>(
      F(OFF_M3B), c3_b, (long)NB*512, 512, 1);

  k_final<<<(NB*64 + 255)/256, 256, 0, stream>>>(F(OFF_M3B), c4_w, c4_b, out);
}

// Round 12
// 795.782 us; speedup vs baseline: 2.3707x; 1.0313x over previous
//
#include <hip/hip_runtime.h>

// ---------------- problem constants ----------------
constexpr int NN = 32768;      // nodes
constexpr int EE = 524288;     // edges
constexpr int NB = 256;        // graphs / batch
constexpr int EN = EE + NN;    // edges + self loops

typedef unsigned short u16;
typedef short bh8 __attribute__((ext_vector_type(8)));    // 8 bf16 (4 VGPRs)
typedef float f32x4 __attribute__((ext_vector_type(4)));  // MFMA accumulator

__device__ inline u16 f2b(float f) {   // f32 -> bf16 round-to-nearest-even
  unsigned u = __float_as_uint(f);
  return (u16)((u + 0x7fffu + ((u >> 16) & 1u)) >> 16);
}

// ---------------- workspace layout (bytes) ----------------
constexpr size_t MB = 1ull << 20;
constexpr size_t OFF_A    = 0;        // conv y1 bf16 [b][l][32], later h1 [N,320] f32
constexpr size_t OFF_B    = 48*MB;    // conv y2 bf16, later g1o [N,320] bf16 (21MB)
constexpr size_t OFF_AC   = 100*MB;   // alpha/logits in CSR order [EN,5] f32 (11.2MB)
constexpr size_t OFF_CSRD = 112*MB;   // csr_dst [EN] int (2.2MB)
constexpr size_t OFF_C    = 116*MB;   // h2 [N,96] f32
constexpr size_t OFF_CSRS = 130*MB;   // csr_src [EN]
constexpr size_t OFF_CSRP = 133*MB;   // csr_pos [EN] (edge e -> CSR slot p)
constexpr size_t OFF_ROWP = 136*MB;   // rowptr [N+1]
constexpr size_t OFF_DEG  = 137*MB;   // deg [N]
constexpr size_t OFF_CUR  = 138*MB;   // cursor [N]
constexpr size_t OFF_G2O  = 142*MB;   // g2o [N,96]
constexpr size_t OFF_AS1  = 155*MB;   // [N,5]: attn src terms, then amax
constexpr size_t OFF_AD1  = 156*MB;   // [N,5]: attn dst terms, then rinv
constexpr size_t OFF_AS2  = 157*MB;   // [N]
constexpr size_t OFF_AD2  = 158*MB;
constexpr size_t OFF_CD   = 159*MB;   // [256,96] pooled drug conv
constexpr size_t OFF_CT   = 160*MB;   // [256,96] pooled target conv
constexpr size_t OFF_POOL = 161*MB;   // [256,96] graph pool
constexpr size_t OFF_GFC  = 162*MB;   // [256,96]
constexpr size_t OFF_XC   = 163*MB;   // [256,288]
constexpr size_t OFF_M1B  = 164*MB;   // [256,1024]
constexpr size_t OFF_M2B  = 165*MB;   // [256,1024]
constexpr size_t OFF_M3B  = 166*MB;   // [256,512]
constexpr size_t OFF_FD   = 167*MB;   // F table drug [4][65][32] f32 (k,v,co)
constexpr size_t OFF_FT   = 168*MB;   // F table target [8][26][32] f32 (k,v,co)
constexpr size_t OFF_WD2B = 169*MB;   // drug w2 bf16 [co][kk*32+ci] (64x128)
constexpr size_t OFF_WD3B = 170*MB;   // drug w3 bf16 [co][kk*64+ci] (96x256)
constexpr size_t OFF_WT2B = 171*MB;   // target w2 bf16 [co][kk*32+ci] (64x256)
constexpr size_t OFF_WT3B = 172*MB;   // target w3 bf16 [co][kk*64+ci] (96x512)
constexpr size_t OFF_W2GB = 174*MB;   // g2_w bf16 [co][k] (96x320)
constexpr size_t OFF_CB   = 173*MB;   // const block: [0:25]=M1, [25:30]=M2, [30:35]=easum,
                                      // [35:40]=aeself1, [40]=ae2self, [41:46]=eamean

// =================================================================
// Tiny precompute tables: F_drug [k][v][co], F_target [k][v][co], M1, M2
// =================================================================
__global__ void k_tables(const float* __restrict__ wd1, const float* __restrict__ emb_xd,
                         const float* __restrict__ wt1, const float* __restrict__ emb_xt,
                         const float* __restrict__ g1we, const float* __restrict__ g1ae,
                         const float* __restrict__ g2we, const float* __restrict__ g2ae,
                         float* __restrict__ Fd, float* __restrict__ Ft,
                         float* __restrict__ CB) {
  int t = blockIdx.x * 256 + threadIdx.x;
  const int NFd = 32*4*65, NFt = 32*8*26;
  if (t < NFd) {                       // Fd stored [k][v][co]
    int v = t % 65; int ck = t / 65; int k = ck & 3; int co = ck >> 2;
    float s = 0.f;
    for (int ci = 0; ci < 128; ++ci)
      s = fmaf(wd1[(co*128 + ci)*4 + k], emb_xd[v*128 + ci], s);
    Fd[(k*65 + v)*32 + co] = s;
  } else if (t < NFd + NFt) {          // Ft stored [k][v][co]
    int u = t - NFd;
    int v = u % 26; int ck = u / 26; int k = ck & 7; int co = ck >> 3;
    float s = 0.f;
    for (int ci = 0; ci < 128; ++ci)
      s = fmaf(wt1[(co*128 + ci)*8 + k], emb_xt[v*128 + ci], s);
    Ft[(k*26 + v)*32 + co] = s;
  } else if (t < NFd + NFt + 25) {     // M1[j][h]
    int u = t - NFd - NFt; int h = u % 5, j = u / 5;
    float s = 0.f;
    for (int c = 0; c < 64; ++c)
      s = fmaf(g1we[j*320 + h*64 + c], g1ae[h*64 + c], s);
    CB[j*5 + h] = s;
  } else if (t < NFd + NFt + 30) {     // M2[j]
    int j = t - NFd - NFt - 25;
    float s = 0.f;
    for (int c = 0; c < 96; ++c)
      s = fmaf(g2we[j*96 + c], g2ae[c], s);
    CB[25 + j] = s;
  }
}

// all conv weights + g2_w -> bf16 [co][kk*CIN+ci] layouts
__global__ void k_wcvt(const float* __restrict__ wd2, const float* __restrict__ wd3,
                       const float* __restrict__ wt2, const float* __restrict__ wt3,
                       const float* __restrict__ g2w,
                       u16* __restrict__ od2, u16* __restrict__ od3,
                       u16* __restrict__ ot2, u16* __restrict__ ot3,
                       u16* __restrict__ og2) {
  int t = blockIdx.x*256 + threadIdx.x;
  if (t < 8192) {                       // drug w2: CIN=32,KK=4,CO=64 (KD=128)
    int co = t >> 7, k = t & 127, kk = k >> 5, ci = k & 31;
    od2[t] = f2b(wd2[(co*32 + ci)*4 + kk]);
  } else if ((t -= 8192) < 24576) {     // drug w3: CIN=64,KK=4,CO=96 (KD=256)
    int co = t >> 8, k = t & 255, kk = k >> 6, ci = k & 63;
    od3[t] = f2b(wd3[(co*64 + ci)*4 + kk]);
  } else if ((t -= 24576) < 16384) {    // target w2: CIN=32,KK=8,CO=64 (KD=256)
    int co = t >> 8, k = t & 255, kk = k >> 5, ci = k & 31;
    ot2[t] = f2b(wt2[(co*32 + ci)*8 + kk]);
  } else if ((t -= 16384) < 49152) {    // target w3: CIN=64,KK=8,CO=96 (KD=512)
    int co = t >> 9, k = t & 511, kk = k >> 6, ci = k & 63;
    ot3[t] = f2b(wt3[(co*64 + ci)*8 + kk]);
  } else if ((t -= 49152) < 30720) {    // g2_w: [co][k], k=0..319
    int co = t / 320, k = t % 320;
    og2[t] = f2b(g2w[k*96 + co]);
  }
}

// sum of ea columns -> CB[30..34] (pre-zeroed)
__global__ void k_easum(const float* __restrict__ ea, float* __restrict__ CB) {
  float acc[5] = {0,0,0,0,0};
  for (long e = blockIdx.x*256L + threadIdx.x; e < EE; e += 256L*gridDim.x) {
    #pragma unroll
    for (int j = 0; j < 5; ++j) acc[j] += ea[e*5 + j];
  }
  #pragma unroll
  for (int j = 0; j < 5; ++j)
    for (int off = 1; off < 64; off <<= 1) acc[j] += __shfl_xor(acc[j], off, 64);
  if ((threadIdx.x & 63) == 0) {
    #pragma unroll
    for (int j = 0; j < 5; ++j) atomicAdd(&CB[30 + j], acc[j]);
  }
}

// eamean, aeself1[h], ae2self
__global__ void k_finalize(float* __restrict__ CB) {
  if (blockIdx.x == 0 && threadIdx.x == 0) {
    float em[5];
    for (int j = 0; j < 5; ++j) { em[j] = CB[30 + j] / (float)EE; CB[41 + j] = em[j]; }
    for (int h = 0; h < 5; ++h) {
      float s = 0.f;
      for (int j = 0; j < 5; ++j) s = fmaf(em[j], CB[j*5 + h], s);
      CB[35 + h] = s;
    }
    float s = 0.f;
    for (int j = 0; j < 5; ++j) s = fmaf(em[j], CB[25 + j], s);
    CB[40] = s;
  }
}

// =================================================================
// conv1 via LUT -> bf16 transposed out y[b][l][32]. LUT layout [k][v][32].
// =================================================================
template<int K, int V>
__global__ __launch_bounds__(512) void k_conv1t(
    const int* __restrict__ idx, const float* __restrict__ Ftab,
    const float* __restrict__ bias, u16* __restrict__ y, int L, int Lout) {
  constexpr int CO = 32;
  __shared__ float Fs[K*V*CO];
  __shared__ float bs[CO];
  __shared__ int sq[16 + K];
  int b = blockIdx.y, l0 = blockIdx.x * 16;
  for (int i = threadIdx.x; i < K*V*CO; i += 512) Fs[i] = Ftab[i];
  if (threadIdx.x < CO) bs[threadIdx.x] = bias[threadIdx.x];
  if (threadIdx.x < 16 + K - 1) {
    int l = l0 + (int)threadIdx.x;
    sq[threadIdx.x] = (l < L) ? idx[b*L + l] : 0;
  }
  __syncthreads();
  int co = threadIdx.x & 31;
  int p = threadIdx.x >> 5;
  int l = l0 + p;
  if (l >= Lout) return;
  float acc = bs[co];
  #pragma unroll
  for (int k = 0; k < K; ++k) acc += Fs[(k*V + sq[p + k])*CO + co];
  y[((size_t)b*Lout + l)*CO + co] = f2b(fmaxf(acc, 0.f));
}

// =================================================================
// conv2/conv3 (both branches): implicit-GEMM via MFMA bf16.
// =================================================================
template<int CIN, int KK, int COUT, int NT2, bool POOL>
__global__ __launch_bounds__(512) void k_convmfma(
    const u16* __restrict__ xin, const u16* __restrict__ wtb,
    const float* __restrict__ bias, u16* __restrict__ yout,
    unsigned int* __restrict__ pool, int Lin, int Lout) {
  constexpr int KD = CIN*KK;
  constexpr int NCH = KD/32;
  constexpr int MT = 256, ROWS = MT + KK - 1;
  constexpr int XPAD = CIN + 8;
  constexpr int WPAD = KD + 8;
  __shared__ u16 xs[ROWS*XPAD];
  __shared__ u16 wsd[COUT*WPAD];
  int b = blockIdx.y;
  int l0 = blockIdx.x * MT;
  int tid = threadIdx.x;
  {
    const unsigned* wg = (const unsigned*)wtb;
    unsigned* wl = (unsigned*)wsd;
    constexpr int KD2 = KD/2, WP2 = WPAD/2;
    for (int i = tid; i < COUT*KD2; i += 512) {
      int co = i / KD2, c = i % KD2;
      wl[co*WP2 + c] = wg[i];
    }
  }
  {
    const unsigned* xg = (const unsigned*)(xin + (size_t)b*Lin*CIN);
    unsigned* xl = (unsigned*)xs;
    constexpr int C2 = CIN/2, XP2 = XPAD/2;
    for (int i = tid; i < ROWS*C2; i += 512) {
      int r = i / C2, c = i % C2;
      unsigned v = 0;
      if (l0 + r < Lin) v = xg[(size_t)l0*C2 + i];
      xl[r*XP2 + c] = v;
    }
  }
  __syncthreads();
  int lane = tid & 63;
  int w = tid >> 6;
  int mg = w & 3, ng = w >> 2;
  int l15 = lane & 15, l4 = lane >> 4;
  f32x4 acc[4][NT2];
  #pragma unroll
  for (int mi = 0; mi < 4; ++mi)
    #pragma unroll
    for (int nj = 0; nj < NT2; ++nj) acc[mi][nj] = (f32x4){0.f, 0.f, 0.f, 0.f};

  #pragma unroll
  for (int ch = 0; ch < NCH; ++ch) {
    const int kk = (ch*32) / CIN;
    const int cib = (ch*32) % CIN + l4*8;
    bh8 a[4], bb[NT2];
    #pragma unroll
    for (int mi = 0; mi < 4; ++mi) {
      int row = mg*64 + mi*16 + l15 + kk;
      a[mi] = *(const bh8*)&xs[row*XPAD + cib];
    }
    #pragma unroll
    for (int nj = 0; nj < NT2; ++nj) {
      int co = (ng*NT2 + nj)*16 + l15;
      bb[nj] = *(const bh8*)&wsd[co*WPAD + ch*32 + l4*8];
    }
    #pragma unroll
    for (int mi = 0; mi < 4; ++mi)
      #pragma unroll
      for (int nj = 0; nj < NT2; ++nj)
        acc[mi][nj] = __builtin_amdgcn_mfma_f32_16x16x32_bf16(a[mi], bb[nj], acc[mi][nj], 0, 0, 0);
  }

  if (!POOL) {
    #pragma unroll
    for (int nj = 0; nj < NT2; ++nj) {
      int co = (ng*NT2 + nj)*16 + l15;
      float bv = bias[co];
      #pragma unroll
      for (int mi = 0; mi < 4; ++mi)
        #pragma unroll
        for (int r = 0; r < 4; ++r) {
          int m = mg*64 + mi*16 + l4*4 + r;
          if (l0 + m < Lout)
            yout[((size_t)b*Lout + l0 + m)*COUT + co] = f2b(fmaxf(acc[mi][nj][r] + bv, 0.f));
        }
    }
  } else {
    #pragma unroll
    for (int nj = 0; nj < NT2; ++nj) {
      int co = (ng*NT2 + nj)*16 + l15;
      float bv = bias[co];
      float mx = 0.f;
      #pragma unroll
      for (int mi = 0; mi < 4; ++mi)
        #pragma unroll
        for (int r = 0; r < 4; ++r) {
          int m = mg*64 + mi*16 + l4*4 + r;
          if (l0 + m < Lout) mx = fmaxf(mx, fmaxf(acc[mi][nj][r] + bv, 0.f));
        }
      mx = fmaxf(mx, __shfl_xor(mx, 16, 64));
      mx = fmaxf(mx, __shfl_xor(mx, 32, 64));
      if (l4 == 0) atomicMax(&pool[b*COUT + co], __float_as_uint(mx));
    }
  }
}

// =================================================================
// h2 = g1o(bf16 [N,320]) @ g2_w(bf16 [co][k]) -> f32 [N,96] via MFMA.
// =================================================================
__global__ __launch_bounds__(512) void k_h2mfma(
    const u16* __restrict__ g1ob, const u16* __restrict__ wb,
    float* __restrict__ h2) {
  constexpr int KD = 320, WPAD = 328, NCH = 10;
  __shared__ u16 wsd[96*WPAD];
  int tid = threadIdx.x;
  {
    const unsigned* wg = (const unsigned*)wb;
    unsigned* wl = (unsigned*)wsd;
    for (int i = tid; i < 96*(KD/2); i += 512) {
      int co = i / (KD/2), c = i % (KD/2);
      wl[co*(WPAD/2) + c] = wg[i];
    }
  }
  __syncthreads();
  int lane = tid & 63;
  int w = tid >> 6;                 // m-sub 0..7
  int l15 = lane & 15, l4 = lane >> 4;
  long m0 = (long)blockIdx.x * 128;
  const u16* xr = g1ob + (m0 + w*16 + l15) * KD;
  f32x4 acc[6];
  #pragma unroll
  for (int nj = 0; nj < 6; ++nj) acc[nj] = (f32x4){0.f, 0.f, 0.f, 0.f};
  #pragma unroll
  for (int ch = 0; ch < NCH; ++ch) {
    bh8 a = *(const bh8*)&xr[ch*32 + l4*8];
    #pragma unroll
    for (int nj = 0; nj < 6; ++nj) {
      bh8 b = *(const bh8*)&wsd[(nj*16 + l15)*WPAD + ch*32 + l4*8];
      acc[nj] = __builtin_amdgcn_mfma_f32_16x16x32_bf16(a, b, acc[nj], 0, 0, 0);
    }
  }
  #pragma unroll
  for (int nj = 0; nj < 6; ++nj) {
    #pragma unroll
    for (int r = 0; r < 4; ++r) {
      long row = m0 + w*16 + l4*4 + r;
      h2[row*96 + nj*16 + l15] = acc[nj][r];
    }
  }
}

// =================================================================
// register-tiled f32 GEMM (h1)
// =================================================================
template<int BM, int BN, int BK, int TM, int TN, bool BIAS, bool RELU>
__global__ void k_gemm(const float* __restrict__ X, const float* __restrict__ W,
                       const float* __restrict__ bias, float* __restrict__ Y,
                       int K, int C) {
  constexpr int NTH = (BM/TM)*(BN/TN);
  static_assert(NTH == 256, "block must be 256 threads");
  __shared__ float xs[BK][BM + 1];
  __shared__ float wsm[BK][BN];
  const int m0 = blockIdx.y * BM;
  const int c0 = blockIdx.x * BN;
  const int tn = threadIdx.x % (BN/TN);
  const int tm = threadIdx.x / (BN/TN);
  float acc[TM][TN];
  #pragma unroll
  for (int i = 0; i < TM; ++i)
    #pragma unroll
    for (int j = 0; j < TN; ++j) acc[i][j] = 0.f;

  for (int k0 = 0; k0 < K; k0 += BK) {
    #pragma unroll
    for (int i = threadIdx.x; i < BM*BK; i += NTH) {
      int m = i / BK, k = i % BK;
      xs[k][m] = X[(long)(m0 + m)*K + k0 + k];
    }
    #pragma unroll
    for (int i = threadIdx.x; i < BK*BN; i += NTH) {
      int k = i / BN, c = i % BN;
      wsm[k][c] = W[(long)(k0 + k)*C + c0 + c];
    }
    __syncthreads();
    #pragma unroll
    for (int k = 0; k < BK; ++k) {
      float xv[TM], wv[TN];
      #pragma unroll
      for (int i = 0; i < TM; ++i) xv[i] = xs[k][tm*TM + i];
      #pragma unroll
      for (int j = 0; j < TN; ++j) wv[j] = wsm[k][tn*TN + j];
      #pragma unroll
      for (int i = 0; i < TM; ++i)
        #pragma unroll
        for (int j = 0; j < TN; ++j) acc[i][j] = fmaf(xv[i], wv[j], acc[i][j]);
    }
    __syncthreads();
  }
  #pragma unroll
  for (int i = 0; i < TM; ++i) {
    float* yr = Y + (long)(m0 + tm*TM + i)*C + c0 + tn*TN;
    #pragma unroll
    for (int j = 0; j < TN; ++j) {
      float v = acc[i][j];
      if (BIAS) v += bias[c0 + tn*TN + j];
      if (RELU) v = fmaxf(v, 0.f);
      yr[j] = v;
    }
  }
}

// =================================================================
// split-K f32 GEMM for skinny-M (M=256) MLP layers.
// =================================================================
template<int BM, int BN, int BK, int TM, int TN>
__global__ void k_gemm_sk(const float* __restrict__ X, const float* __restrict__ W,
                          float* __restrict__ Y, int K, int C, int KS) {
  constexpr int NTH = (BM/TM)*(BN/TN);
  static_assert(NTH == 256, "block must be 256 threads");
  __shared__ float xs[BK][BM + 1];
  __shared__ float wsm[BK][BN];
  const int m0 = blockIdx.y * BM;
  const int c0 = blockIdx.x * BN;
  const int kbeg = blockIdx.z * KS;
  const int kend = min(K, kbeg + KS);
  const int tn = threadIdx.x % (BN/TN);
  const int tm = threadIdx.x / (BN/TN);
  float acc[TM][TN];
  #pragma unroll
  for (int i = 0; i < TM; ++i)
    #pragma unroll
    for (int j = 0; j < TN; ++j) acc[i][j] = 0.f;

  for (int k0 = kbeg; k0 < kend; k0 += BK) {
    #pragma unroll
    for (int i = threadIdx.x; i < BM*BK; i += NTH) {
      int m = i / BK, k = i % BK;
      xs[k][m] = X[(long)(m0 + m)*K + k0 + k];
    }
    #pragma unroll
    for (int i = threadIdx.x; i < BK*BN; i += NTH) {
      int k = i / BN, c = i % BN;
      wsm[k][c] = W[(long)(k0 + k)*C + c0 + c];
    }
    __syncthreads();
    #pragma unroll
    for (int k = 0; k < BK; ++k) {
      float xv[TM], wv[TN];
      #pragma unroll
      for (int i = 0; i < TM; ++i) xv[i] = xs[k][tm*TM + i];
      #pragma unroll
      for (int j = 0; j < TN; ++j) wv[j] = wsm[k][tn*TN + j];
      #pragma unroll
      for (int i = 0; i < TM; ++i)
        #pragma unroll
        for (int j = 0; j < TN; ++j) acc[i][j] = fmaf(xv[i], wv[j], acc[i][j]);
    }
    __syncthreads();
  }
  #pragma unroll
  for (int i = 0; i < TM; ++i) {
    float* yr = Y + (long)(m0 + tm*TM + i)*C + c0 + tn*TN;
    #pragma unroll
    for (int j = 0; j < TN; ++j) atomicAdd(&yr[j], acc[i][j]);
  }
}

// bias + optional relu, in place over [rows*C]
__global__ void k_bias_relu(float* __restrict__ Y, const float* __restrict__ bias,
                            long total, int C, int relu) {
  long o = blockIdx.x*256L + threadIdx.x;
  if (o >= total) return;
  int c = (int)(o % C);
  float v = Y[o] + bias[c];
  if (relu) v = fmaxf(v, 0.f);
  Y[o] = v;
}

// =================================================================
// per-node attention terms, wave-per-node (coalesced loads + shfl reduce)
// =================================================================
template<int H, int CH>
__global__ void k_nodeterms_w(const float* __restrict__ hf, const float* __restrict__ a_s,
                              const float* __restrict__ a_d, float* __restrict__ as_o,
                              float* __restrict__ ad_o) {
  constexpr int F = H * CH;
  constexpr int NJ = (F + 63) / 64;
  int wid = (int)((blockIdx.x*256L + threadIdx.x) >> 6);
  int lane = threadIdx.x & 63;
  if (wid >= NN) return;
  const float* hr = hf + (long)wid * F;
  float s1[H], s2[H];
  #pragma unroll
  for (int h = 0; h < H; ++h) { s1[h] = 0.f; s2[h] = 0.f; }
  #pragma unroll
  for (int j = 0; j < NJ; ++j) {
    int c = j*64 + lane;
    if ((F % 64 == 0) || c < F) {
      int h = c / CH;
      float v = hr[c];
      s1[h] = fmaf(v, a_s[c], s1[h]);
      s2[h] = fmaf(v, a_d[c], s2[h]);
    }
  }
  #pragma unroll
  for (int h = 0; h < H; ++h) {
    #pragma unroll
    for (int off = 1; off < 64; off <<= 1) {
      s1[h] += __shfl_xor(s1[h], off, 64);
      s2[h] += __shfl_xor(s2[h], off, 64);
    }
  }
  if (lane == 0) {
    #pragma unroll
    for (int h = 0; h < H; ++h) {
      as_o[(long)wid*H + h] = s1[h];
      ad_o[(long)wid*H + h] = s2[h];
    }
  }
}

// per-edge attention logit with leaky_relu(0.2), written directly in CSR
// order via csr_pos. e >= EE are self loops.
template<int H>
__global__ void k_edge_attn(const int* __restrict__ ei, const float* __restrict__ ea,
                            const int* __restrict__ csr_pos,
                            const float* __restrict__ asb, const float* __restrict__ adb,
                            const float* __restrict__ M, const float* __restrict__ aeself,
                            float* __restrict__ ac) {
  long e = blockIdx.x*256L + threadIdx.x;
  if (e >= (long)EN) return;
  int s, d;
  float av[H];
  if (e < EE) {
    s = ei[e]; d = ei[EE + e];
    float er[5];
    #pragma unroll
    for (int j = 0; j < 5; ++j) er[j] = ea[e*5 + j];
    #pragma unroll
    for (int h = 0; h < H; ++h) {
      float t = 0.f;
      #pragma unroll
      for (int j = 0; j < 5; ++j) t = fmaf(er[j], M[j*H + h], t);
      av[h] = t;
    }
  } else {
    s = d = (int)(e - EE);
    #pragma unroll
    for (int h = 0; h < H; ++h) av[h] = aeself[h];
  }
  long p = csr_pos[e];
  #pragma unroll
  for (int h = 0; h < H; ++h) {
    float v = asb[s*H + h] + adb[d*H + h] + av[h];
    ac[p*H + h] = (v > 0.f) ? v : 0.2f * v;
  }
}

// per-dst softmax stats: amax[h], rinv[h] (one wave per dst)
template<int H>
__global__ void k_stats(const int* __restrict__ rowptr, const float* __restrict__ ac,
                        float* __restrict__ amaxo, float* __restrict__ rinvo) {
  int wid = (int)((blockIdx.x*256L + threadIdx.x) >> 6);
  int lane = threadIdx.x & 63;
  if (wid >= NN) return;
  int row0 = rowptr[wid], row1 = rowptr[wid + 1];
  float amax[H], asum[H];
  #pragma unroll
  for (int h = 0; h < H; ++h) amax[h] = -1e30f;
  for (int p = row0 + lane; p < row1; p += 64) {
    #pragma unroll
    for (int h = 0; h < H; ++h) amax[h] = fmaxf(amax[h], ac[(long)p*H + h]);
  }
  #pragma unroll
  for (int h = 0; h < H; ++h)
    for (int off = 1; off < 64; off <<= 1) amax[h] = fmaxf(amax[h], __shfl_xor(amax[h], off, 64));
  #pragma unroll
  for (int h = 0; h < H; ++h) asum[h] = 0.f;
  for (int p = row0 + lane; p < row1; p += 64) {
    #pragma unroll
    for (int h = 0; h < H; ++h) asum[h] += __expf(ac[(long)p*H + h] - amax[h]);
  }
  #pragma unroll
  for (int h = 0; h < H; ++h)
    for (int off = 1; off < 64; off <<= 1) asum[h] += __shfl_xor(asum[h], off, 64);
  if (lane == 0) {
    #pragma unroll
    for (int h = 0; h < H; ++h) {
      amaxo[(long)wid*H + h] = amax[h];
      rinvo[(long)wid*H + h] = 1.f / (asum[h] + 1e-16f);
    }
  }
}

// normalize logits -> alpha, in place (lane-parallel over CSR slots)
template<int H>
__global__ void k_alpha(const int* __restrict__ csr_dst, const float* __restrict__ amaxb,
                        const float* __restrict__ rinvb, float* __restrict__ ac) {
  long p = blockIdx.x*256L + threadIdx.x;
  if (p >= (long)EN) return;
  int d = csr_dst[p];
  #pragma unroll
  for (int h = 0; h < H; ++h)
    ac[p*H + h] = __expf(ac[p*H + h] - amaxb[(long)d*H + h]) * rinvb[(long)d*H + h];
}

// ------------- CSR build -------------
__global__ void k_deg(const int* __restrict__ ei, int* __restrict__ deg) {
  long e = blockIdx.x*256L + threadIdx.x;
  if (e >= (long)EN) return;
  int d = (e < EE) ? ei[EE + e] : (int)(e - EE);
  atomicAdd(&deg[d], 1);
}

__global__ void k_scan(const int* __restrict__ deg, int* __restrict__ rowptr,
                       int* __restrict__ cursor) {
  __shared__ int ps[256];
  int tid = threadIdx.x;
  int base = tid * 128;           // 256*128 = 32768 = NN
  int s = 0;
  for (int i = 0; i < 128; ++i) s += deg[base + i];
  ps[tid] = s;
  __syncthreads();
  for (int off = 1; off < 256; off <<= 1) {
    int v = (tid >= off) ? ps[tid - off] : 0;
    __syncthreads();
    ps[tid] += v;
    __syncthreads();
  }
  int run = ps[tid] - s;          // exclusive prefix
  for (int i = 0; i < 128; ++i) {
    rowptr[base + i] = run;
    cursor[base + i] = run;
    run += deg[base + i];
  }
  if (tid == 255) rowptr[NN] = run;
}

__global__ void k_scatter(const int* __restrict__ ei, int* __restrict__ cursor,
                          int* __restrict__ csr_src, int* __restrict__ csr_pos,
                          int* __restrict__ csr_dst) {
  long e = blockIdx.x*256L + threadIdx.x;
  if (e >= (long)EN) return;
  int s, d;
  if (e < EE) { s = ei[e]; d = ei[EE + e]; }
  else        { s = d = (int)(e - EE); }
  int p = atomicAdd(&cursor[d], 1);
  csr_src[p] = s;
  csr_dst[p] = d;
  csr_pos[e] = p;
}

// =================================================================
// GAT aggregation (alpha precomputed in ac): wave per dst, XCD-pinned,
// edge loop unrolled x4 for memory-level parallelism.
// ACT: 0=elu, 1=relu. OBF16: bf16 output.
// =================================================================
template<int H, int CH, int ACT, bool OBF16>
__global__ void k_gat_aggr(const int* __restrict__ rowptr, const int* __restrict__ csr_src,
                           const float* __restrict__ ac,
                           const float* __restrict__ hfeat, const float* __restrict__ bias,
                           void* __restrict__ outv) {
  int bid = blockIdx.x;
  int x = bid & 7;
  int r = bid >> 3;
  int s = r & 31;
  int c = r >> 5;
  int g = c*8 + x;
  int wid = g*128 + s*4 + (int)(threadIdx.x >> 6);
  int lane = threadIdx.x & 63;
  int row0 = rowptr[wid], row1 = rowptr[wid + 1];
  constexpr int F = H * CH;
  constexpr int NJ = (F + 63) / 64;
  float acc[NJ];
  #pragma unroll
  for (int j = 0; j < NJ; ++j) acc[j] = 0.f;
  int p = row0;
  for (; p + 4 <= row1; p += 4) {
    int sidx[4];
    float al[4][H];
    #pragma unroll
    for (int u = 0; u < 4; ++u) sidx[u] = csr_src[p + u];
    #pragma unroll
    for (int u = 0; u < 4; ++u)
      #pragma unroll
      for (int h = 0; h < H; ++h) al[u][h] = ac[(long)(p + u)*H + h];
    #pragma unroll
    for (int j = 0; j < NJ; ++j) {
      int idx = j*64 + lane;
      if ((F % 64 == 0) || idx < F) {
        int h = idx / CH;
        float v0 = hfeat[(long)sidx[0]*F + idx];
        float v1 = hfeat[(long)sidx[1]*F + idx];
        float v2 = hfeat[(long)sidx[2]*F + idx];
        float v3 = hfeat[(long)sidx[3]*F + idx];
        acc[j] = fmaf(al[0][h], v0, acc[j]);
        acc[j] = fmaf(al[1][h], v1, acc[j]);
        acc[j] = fmaf(al[2][h], v2, acc[j]);
        acc[j] = fmaf(al[3][h], v3, acc[j]);
      }
    }
  }
  for (; p < row1; ++p) {
    int src = csr_src[p];
    const float* hr = hfeat + (long)src * F;
    #pragma unroll
    for (int j = 0; j < NJ; ++j) {
      int idx = j*64 + lane;
      if ((F % 64 == 0) || idx < F) {
        int h = idx / CH;
        acc[j] = fmaf(ac[(long)p*H + h], hr[idx], acc[j]);
      }
    }
  }
  #pragma unroll
  for (int j = 0; j < NJ; ++j) {
    int idx = j*64 + lane;
    if ((F % 64 == 0) || idx < F) {
      float v = acc[j] + bias[idx];
      if (ACT == 0) v = (v > 0.f) ? v : expm1f(v);
      else          v = fmaxf(v, 0.f);
      if (OBF16) ((u16*)outv)[(long)wid * F + idx] = f2b(v);
      else       ((float*)outv)[(long)wid * F + idx] = v;
    }
  }
}

// graph max pool (relu'd input >= 0, pooled pre-zeroed)
__global__ void k_pool(const float* __restrict__ g2o, const int* __restrict__ batch,
                       unsigned int* __restrict__ pooled) {
  long o = blockIdx.x*256L + threadIdx.x;
  if (o >= (long)NN * 96) return;
  int n = (int)(o / 96), c = (int)(o % 96);
  atomicMax(&pooled[batch[n]*96 + c], __float_as_uint(g2o[o]));
}

__global__ void k_concat(const float* __restrict__ cd, const float* __restrict__ ct,
                         const float* __restrict__ gfc, float* __restrict__ xc) {
  int t = blockIdx.x*256 + threadIdx.x;
  if (t >= NB*288) return;
  int b = t / 288, c = t % 288;
  float v = (c < 96) ? cd[b*96 + c] : (c < 192) ? ct[b*96 + (c-96)] : gfc[b*96 + (c-192)];
  xc[t] = v;
}

// final 512-dot per row
__global__ void k_final(const float* __restrict__ x, const float* __restrict__ w,
                        const float* __restrict__ b, float* __restrict__ out) {
  int wid = (int)((blockIdx.x*256L + threadIdx.x) >> 6);
  int lane = threadIdx.x & 63;
  if (wid >= NB) return;
  const float* xr = x + (long)wid*512;
  float s = 0.f;
  for (int k = lane; k < 512; k += 64) s = fmaf(xr[k], w[k], s);
  for (int off = 1; off < 64; off <<= 1) s += __shfl_xor(s, off, 64);
  if (lane == 0) out[wid] = s + b[0];
}

// =================================================================
extern "C" void kernel_launch(void* const* d_in, const int* in_sizes, int n_in,
                              void* d_out, int out_size, void* d_ws, size_t ws_size,
                              hipStream_t stream) {
  const int*   xd     = (const int*)  d_in[0];
  const int*   xt     = (const int*)  d_in[1];
  const float* ax     = (const float*)d_in[2];
  const int*   ei     = (const int*)  d_in[3];
  const float* ea     = (const float*)d_in[4];
  const int*   batch  = (const int*)  d_in[5];
  const float* emb_xd = (const float*)d_in[6];
  const float* emb_xt = (const float*)d_in[7];
  const float* wd1 = (const float*)d_in[8];  const float* bd1 = (const float*)d_in[9];
  const float* wd2 = (const float*)d_in[10]; const float* bd2 = (const float*)d_in[11];
  const float* wd3 = (const float*)d_in[12]; const float* bd3 = (const float*)d_in[13];
  const float* wt1 = (const float*)d_in[14]; const float* bt1 = (const float*)d_in[15];
  const float* wt2 = (const float*)d_in[16]; const float* bt2 = (const float*)d_in[17];
  const float* wt3 = (const float*)d_in[18]; const float* bt3 = (const float*)d_in[19];
  const float* g1_w  = (const float*)d_in[20]; const float* g1_as = (const float*)d_in[21];
  const float* g1_ad = (const float*)d_in[22]; const float* g1_we = (const float*)d_in[23];
  const float* g1_ae = (const float*)d_in[24]; const float* g1_b  = (const float*)d_in[25];
  const float* g2_w  = (const float*)d_in[26]; const float* g2_as = (const float*)d_in[27];
  const float* g2_ad = (const float*)d_in[28]; const float* g2_we = (const float*)d_in[29];
  const float* g2_ae = (const float*)d_in[30]; const float* g2_b  = (const float*)d_in[31];
  const float* fc1_w = (const float*)d_in[32]; const float* fc1_b = (const float*)d_in[33];
  const float* c1_w = (const float*)d_in[34]; const float* c1_b = (const float*)d_in[35];
  const float* c2_w = (const float*)d_in[36]; const float* c2_b = (const float*)d_in[37];
  const float* c3_w = (const float*)d_in[38]; const float* c3_b = (const float*)d_in[39];
  const float* c4_w = (const float*)d_in[40]; const float* c4_b = (const float*)d_in[41];
  float* out = (float*)d_out;

  char* ws = (char*)d_ws;
  auto F = [&](size_t off) { return (float*)(ws + off); };
  auto I = [&](size_t off) { return (int*)(ws + off); };
  auto U = [&](size_t off) { return (unsigned int*)(ws + off); };
  auto H = [&](size_t off) { return (u16*)(ws + off); };

  // ---- zero-init the atomically-updated buffers ----
  hipMemsetAsync(ws + OFF_CB,   0, 64*sizeof(float), stream);
  hipMemsetAsync(ws + OFF_DEG,  0, NN*sizeof(int),   stream);
  hipMemsetAsync(ws + OFF_CD,   0, NB*96*sizeof(float), stream);
  hipMemsetAsync(ws + OFF_CT,   0, NB*96*sizeof(float), stream);
  hipMemsetAsync(ws + OFF_POOL, 0, NB*96*sizeof(float), stream);
  // split-K accumulators
  hipMemsetAsync(ws + OFF_GFC,  0, NB*96*sizeof(float),   stream);
  hipMemsetAsync(ws + OFF_M1B,  0, NB*1024*sizeof(float), stream);
  hipMemsetAsync(ws + OFF_M2B,  0, NB*1024*sizeof(float), stream);
  hipMemsetAsync(ws + OFF_M3B,  0, NB*512*sizeof(float),  stream);

  // ---- tables / weight converts ----
  k_tables<<<(8320 + 6656 + 30 + 255)/256, 256, 0, stream>>>(
      wd1, emb_xd, wt1, emb_xt, g1_we, g1_ae, g2_we, g2_ae,
      F(OFF_FD), F(OFF_FT), F(OFF_CB));
  k_wcvt<<<(8192 + 24576 + 16384 + 49152 + 30720 + 255)/256, 256, 0, stream>>>(
      wd2, wd3, wt2, wt3, g2_w,
      H(OFF_WD2B), H(OFF_WD3B), H(OFF_WT2B), H(OFF_WT3B), H(OFF_W2GB));
  k_easum<<<256, 256, 0, stream>>>(ea, F(OFF_CB));
  k_finalize<<<1, 64, 0, stream>>>(F(OFF_CB));

  // ---- drug conv branch (bf16 MFMA): 100 -> 97 -> 94 -> 91 -> maxpool ----
  k_conv1t<4,65><<<dim3((97 + 15)/16, NB), 512, 0, stream>>>(
      xd, F(OFF_FD), bd1, H(OFF_A), 100, 97);
  k_convmfma<32,4,64,2,false><<<dim3(1, NB), 512, 0, stream>>>(
      H(OFF_A), H(OFF_WD2B), bd2, H(OFF_B), nullptr, 97, 94);
  k_convmfma<64,4,96,3,true><<<dim3(1, NB), 512, 0, stream>>>(
      H(OFF_B), H(OFF_WD3B), bd3, nullptr, U(OFF_CD), 94, 91);

  // ---- target conv branch (bf16 MFMA): 1000 -> 993 -> 986 -> 979 -> maxpool ----
  k_conv1t<8,26><<<dim3((993 + 15)/16, NB), 512, 0, stream>>>(
      xt, F(OFF_FT), bt1, H(OFF_A), 1000, 993);
  k_convmfma<32,8,64,2,false><<<dim3(4, NB), 512, 0, stream>>>(
      H(OFF_A), H(OFF_WT2B), bt2, H(OFF_B), nullptr, 993, 986);
  k_convmfma<64,8,96,3,true><<<dim3(4, NB), 512, 0, stream>>>(
      H(OFF_B), H(OFF_WT3B), bt3, nullptr, U(OFF_CT), 986, 979);

  // ---- CSR build ----
  k_deg<<<(EN + 255)/256, 256, 0, stream>>>(ei, I(OFF_DEG));
  k_scan<<<1, 256, 0, stream>>>(I(OFF_DEG), I(OFF_ROWP), I(OFF_CUR));
  k_scatter<<<(EN + 255)/256, 256, 0, stream>>>(
      ei, I(OFF_CUR), I(OFF_CSRS), I(OFF_CSRP), I(OFF_CSRD));

  // ---- GAT layer 1 ----
  k_gemm<64,64,24,4,4,false,false><<<dim3(320/64, NN/64), 256, 0, stream>>>(
      ax, g1_w, nullptr, F(OFF_A), 24, 320);
  k_nodeterms_w<5,64><<<NN/4, 256, 0, stream>>>(
      F(OFF_A), g1_as, g1_ad, F(OFF_AS1), F(OFF_AD1));
  k_edge_attn<5><<<(EN + 255)/256, 256, 0, stream>>>(
      ei, ea, I(OFF_CSRP), F(OFF_AS1), F(OFF_AD1), F(OFF_CB), F(OFF_CB) + 35, F(OFF_AC));
  k_stats<5><<<NN/4, 256, 0, stream>>>(
      I(OFF_ROWP), F(OFF_AC), F(OFF_AS1), F(OFF_AD1));   // reuse AS1/AD1 for amax/rinv
  k_alpha<5><<<(EN + 255)/256, 256, 0, stream>>>(
      I(OFF_CSRD), F(OFF_AS1), F(OFF_AD1), F(OFF_AC));
  k_gat_aggr<5,64,0,true><<<NN/4, 256, 0, stream>>>(
      I(OFF_ROWP), I(OFF_CSRS), F(OFF_AC), F(OFF_A), g1_b, (void*)H(OFF_B));

  // ---- GAT layer 2 (h2 via MFMA from bf16 g1o) ----
  k_h2mfma<<<NN/128, 512, 0, stream>>>(H(OFF_B), H(OFF_W2GB), F(OFF_C));
  k_nodeterms_w<1,96><<<NN/4, 256, 0, stream>>>(
      F(OFF_C), g2_as, g2_ad, F(OFF_AS2), F(OFF_AD2));
  k_edge_attn<1><<<(EN + 255)/256, 256, 0, stream>>>(
      ei, ea, I(OFF_CSRP), F(OFF_AS2), F(OFF_AD2), F(OFF_CB) + 25, F(OFF_CB) + 40, F(OFF_AC));
  k_stats<1><<<NN/4, 256, 0, stream>>>(
      I(OFF_ROWP), F(OFF_AC), F(OFF_AS2), F(OFF_AD2));
  k_alpha<1><<<(EN + 255)/256, 256, 0, stream>>>(
      I(OFF_CSRD), F(OFF_AS2), F(OFF_AD2), F(OFF_AC));
  k_gat_aggr<1,96,1,false><<<NN/4, 256, 0, stream>>>(
      I(OFF_ROWP), I(OFF_CSRS), F(OFF_AC), F(OFF_C), g2_b, (void*)F(OFF_G2O));

  // ---- graph pool + fc1 (split-K) ----
  k_pool<<<(int)(((long)NN*96 + 255)/256), 256, 0, stream>>>(
      F(OFF_G2O), batch, U(OFF_POOL));
  k_gemm_sk<64,32,32,4,2><<<dim3(96/32, NB/64, 3), 256, 0, stream>>>(
      F(OFF_POOL), fc1_w, F(OFF_GFC), 96, 96, 32);
  k_bias_relu<<<(NB*96 + 255)/256, 256, 0, stream>>>(
      F(OFF_GFC), fc1_b, (long)NB*96, 96, 1);

  // ---- concat + MLP head (split-K GEMMs) ----
  k_concat<<<(NB*288 + 255)/256, 256, 0, stream>>>(
      F(OFF_CD), F(OFF_CT), F(OFF_GFC), F(OFF_XC));

  k_gemm_sk<64,64,32,4,4><<<dim3(1024/64, NB/64, 3), 256, 0, stream>>>(
      F(OFF_XC), c1_w, F(OFF_M1B), 288, 1024, 96);
  k_bias_relu<<<(NB*1024 + 255)/256, 256, 0, stream>>>(
      F(OFF_M1B), c1_b, (long)NB*1024, 1024, 1);

  k_gemm_sk<64,64,32,4,4><<<dim3(1024/64, NB/64, 8), 256, 0, stream>>>(
      F(OFF_M1B), c2_w, F(OFF_M2B), 1024, 1024, 128);
  k_bias_relu<<<(NB*1024 + 255)/256, 256, 0, stream>>>(
      F(OFF_M2B), c2_b, (long)NB*1024, 1024, 1);

  k_gemm_sk<64,64,32,4,4><<<dim3(512/64, NB/64, 8), 256, 0, stream>>>(
      F(OFF_M2B), c3_w, F(OFF_M3B), 1024, 512, 128);
  k_bias_relu<<<(NB*512 + 255)/256, 256, 0, stream>>>(
      F(OFF_M3B), c3_b, (long)NB*512, 512, 1);

  k_final<<<(NB*64 + 255)/256, 256, 0, stream>>>(F(OFF_M3B), c4_w, c4_b, out);
}

// Round 13
// 744.507 us; speedup vs baseline: 2.5339x; 1.0689x over previous
//
#include <hip/hip_runtime.h>

// ---------------- problem constants ----------------
constexpr int NN = 32768;      // nodes
constexpr int EE = 524288;     // edges
constexpr int NB = 256;        // graphs / batch
constexpr int EN = EE + NN;    // edges + self loops

typedef unsigned short u16;
typedef short bh8 __attribute__((ext_vector_type(8)));    // 8 bf16 (4 VGPRs)
typedef float f32x4 __attribute__((ext_vector_type(4)));  // MFMA accumulator

__device__ inline u16 f2b(float f) {   // f32 -> bf16 round-to-nearest-even
  unsigned u = __float_as_uint(f);
  return (u16)((u + 0x7fffu + ((u >> 16) & 1u)) >> 16);
}

// ---------------- workspace layout (bytes) ----------------
constexpr size_t MB = 1ull << 20;
constexpr size_t OFF_A    = 0;        // conv y1 bf16 / h1 [N,320] f32; later MLP partials
constexpr size_t OFF_M1P  = 0;        // c1 partials [3][256*1024] f32 (3MB)  (aliases OFF_A, dead then)
constexpr size_t OFF_M2P  = 4*MB;     // c2 partials [8][256*1024] f32 (8MB)
constexpr size_t OFF_M3P  = 12*MB;    // c3 partials [8][256*512] f32 (4MB)
constexpr size_t OFF_B    = 48*MB;    // conv y2 bf16, later g1o [N,320] bf16 (21MB)
constexpr size_t OFF_AC   = 100*MB;   // alpha/logits in CSR order [EN,5] f32 (11.2MB)
constexpr size_t OFF_CSRD = 112*MB;   // csr_dst [EN] int (2.2MB)
constexpr size_t OFF_C    = 116*MB;   // h2 [N,96] f32
constexpr size_t OFF_CSRS = 130*MB;   // csr_src [EN]
constexpr size_t OFF_CSRP = 133*MB;   // csr_pos [EN] (edge e -> CSR slot p)
constexpr size_t OFF_ROWP = 136*MB;   // rowptr [N+1]
constexpr size_t OFF_DEG  = 137*MB;   // deg [N]
constexpr size_t OFF_CUR  = 138*MB;   // cursor [N]
constexpr size_t OFF_G2O  = 142*MB;   // g2o [N,96]
constexpr size_t OFF_AS1  = 155*MB;   // [N,5]: attn src terms, then amax
constexpr size_t OFF_AD1  = 156*MB;   // [N,5]: attn dst terms, then rinv
constexpr size_t OFF_AS2  = 157*MB;   // [N]
constexpr size_t OFF_AD2  = 158*MB;
constexpr size_t OFF_CD   = 159*MB;   // [256,96] pooled drug conv
constexpr size_t OFF_CT   = 160*MB;   // [256,96] pooled target conv
constexpr size_t OFF_POOL = 161*MB;   // [256,96] graph pool
constexpr size_t OFF_GFC  = 162*MB;   // [256,96]
constexpr size_t OFF_XC   = 163*MB;   // [256,288]
constexpr size_t OFF_M1B  = 164*MB;   // [256,1024]
constexpr size_t OFF_M2B  = 165*MB;   // [256,1024]
constexpr size_t OFF_M3B  = 166*MB;   // [256,512]
constexpr size_t OFF_FD   = 167*MB;   // F table drug [4][65][32] f32 (k,v,co)
constexpr size_t OFF_FT   = 168*MB;   // F table target [8][26][32] f32 (k,v,co)
constexpr size_t OFF_WD2B = 169*MB;   // drug w2 bf16 [co][kk*32+ci] (64x128)
constexpr size_t OFF_WD3B = 170*MB;   // drug w3 bf16 [co][kk*64+ci] (96x256)
constexpr size_t OFF_WT2B = 171*MB;   // target w2 bf16 [co][kk*32+ci] (64x256)
constexpr size_t OFF_WT3B = 172*MB;   // target w3 bf16 [co][kk*64+ci] (96x512)
constexpr size_t OFF_W2GB = 174*MB;   // g2_w bf16 [co][k] (96x320)
constexpr size_t OFF_CB   = 173*MB;   // const block: [0:25]=M1, [25:30]=M2, [30:35]=easum,
                                      // [35:40]=aeself1, [40]=ae2self, [41:46]=eamean

// =================================================================
// Tiny precompute tables: F_drug [k][v][co], F_target [k][v][co], M1, M2
// =================================================================
__global__ void k_tables(const float* __restrict__ wd1, const float* __restrict__ emb_xd,
                         const float* __restrict__ wt1, const float* __restrict__ emb_xt,
                         const float* __restrict__ g1we, const float* __restrict__ g1ae,
                         const float* __restrict__ g2we, const float* __restrict__ g2ae,
                         float* __restrict__ Fd, float* __restrict__ Ft,
                         float* __restrict__ CB) {
  int t = blockIdx.x * 256 + threadIdx.x;
  const int NFd = 32*4*65, NFt = 32*8*26;
  if (t < NFd) {                       // Fd stored [k][v][co]
    int v = t % 65; int ck = t / 65; int k = ck & 3; int co = ck >> 2;
    float s = 0.f;
    for (int ci = 0; ci < 128; ++ci)
      s = fmaf(wd1[(co*128 + ci)*4 + k], emb_xd[v*128 + ci], s);
    Fd[(k*65 + v)*32 + co] = s;
  } else if (t < NFd + NFt) {          // Ft stored [k][v][co]
    int u = t - NFd;
    int v = u % 26; int ck = u / 26; int k = ck & 7; int co = ck >> 3;
    float s = 0.f;
    for (int ci = 0; ci < 128; ++ci)
      s = fmaf(wt1[(co*128 + ci)*8 + k], emb_xt[v*128 + ci], s);
    Ft[(k*26 + v)*32 + co] = s;
  } else if (t < NFd + NFt + 25) {     // M1[j][h]
    int u = t - NFd - NFt; int h = u % 5, j = u / 5;
    float s = 0.f;
    for (int c = 0; c < 64; ++c)
      s = fmaf(g1we[j*320 + h*64 + c], g1ae[h*64 + c], s);
    CB[j*5 + h] = s;
  } else if (t < NFd + NFt + 30) {     // M2[j]
    int j = t - NFd - NFt - 25;
    float s = 0.f;
    for (int c = 0; c < 96; ++c)
      s = fmaf(g2we[j*96 + c], g2ae[c], s);
    CB[25 + j] = s;
  }
}

// all conv weights + g2_w -> bf16 [co][kk*CIN+ci] layouts
__global__ void k_wcvt(const float* __restrict__ wd2, const float* __restrict__ wd3,
                       const float* __restrict__ wt2, const float* __restrict__ wt3,
                       const float* __restrict__ g2w,
                       u16* __restrict__ od2, u16* __restrict__ od3,
                       u16* __restrict__ ot2, u16* __restrict__ ot3,
                       u16* __restrict__ og2) {
  int t = blockIdx.x*256 + threadIdx.x;
  if (t < 8192) {                       // drug w2: CIN=32,KK=4,CO=64 (KD=128)
    int co = t >> 7, k = t & 127, kk = k >> 5, ci = k & 31;
    od2[t] = f2b(wd2[(co*32 + ci)*4 + kk]);
  } else if ((t -= 8192) < 24576) {     // drug w3: CIN=64,KK=4,CO=96 (KD=256)
    int co = t >> 8, k = t & 255, kk = k >> 6, ci = k & 63;
    od3[t] = f2b(wd3[(co*64 + ci)*4 + kk]);
  } else if ((t -= 24576) < 16384) {    // target w2: CIN=32,KK=8,CO=64 (KD=256)
    int co = t >> 8, k = t & 255, kk = k >> 5, ci = k & 31;
    ot2[t] = f2b(wt2[(co*32 + ci)*8 + kk]);
  } else if ((t -= 16384) < 49152) {    // target w3: CIN=64,KK=8,CO=96 (KD=512)
    int co = t >> 9, k = t & 511, kk = k >> 6, ci = k & 63;
    ot3[t] = f2b(wt3[(co*64 + ci)*8 + kk]);
  } else if ((t -= 49152) < 30720) {    // g2_w: [co][k], k=0..319
    int co = t / 320, k = t % 320;
    og2[t] = f2b(g2w[k*96 + co]);
  }
}

// sum of ea columns -> CB[30..34] (pre-zeroed)
__global__ void k_easum(const float* __restrict__ ea, float* __restrict__ CB) {
  float acc[5] = {0,0,0,0,0};
  for (long e = blockIdx.x*256L + threadIdx.x; e < EE; e += 256L*gridDim.x) {
    #pragma unroll
    for (int j = 0; j < 5; ++j) acc[j] += ea[e*5 + j];
  }
  #pragma unroll
  for (int j = 0; j < 5; ++j)
    for (int off = 1; off < 64; off <<= 1) acc[j] += __shfl_xor(acc[j], off, 64);
  if ((threadIdx.x & 63) == 0) {
    #pragma unroll
    for (int j = 0; j < 5; ++j) atomicAdd(&CB[30 + j], acc[j]);
  }
}

// eamean, aeself1[h], ae2self
__global__ void k_finalize(float* __restrict__ CB) {
  if (blockIdx.x == 0 && threadIdx.x == 0) {
    float em[5];
    for (int j = 0; j < 5; ++j) { em[j] = CB[30 + j] / (float)EE; CB[41 + j] = em[j]; }
    for (int h = 0; h < 5; ++h) {
      float s = 0.f;
      for (int j = 0; j < 5; ++j) s = fmaf(em[j], CB[j*5 + h], s);
      CB[35 + h] = s;
    }
    float s = 0.f;
    for (int j = 0; j < 5; ++j) s = fmaf(em[j], CB[25 + j], s);
    CB[40] = s;
  }
}

// =================================================================
// conv1 via LUT -> bf16 transposed out y[b][l][32]. LUT layout [k][v][32].
// =================================================================
template<int K, int V>
__global__ __launch_bounds__(512) void k_conv1t(
    const int* __restrict__ idx, const float* __restrict__ Ftab,
    const float* __restrict__ bias, u16* __restrict__ y, int L, int Lout) {
  constexpr int CO = 32;
  __shared__ float Fs[K*V*CO];
  __shared__ float bs[CO];
  __shared__ int sq[16 + K];
  int b = blockIdx.y, l0 = blockIdx.x * 16;
  for (int i = threadIdx.x; i < K*V*CO; i += 512) Fs[i] = Ftab[i];
  if (threadIdx.x < CO) bs[threadIdx.x] = bias[threadIdx.x];
  if (threadIdx.x < 16 + K - 1) {
    int l = l0 + (int)threadIdx.x;
    sq[threadIdx.x] = (l < L) ? idx[b*L + l] : 0;
  }
  __syncthreads();
  int co = threadIdx.x & 31;
  int p = threadIdx.x >> 5;
  int l = l0 + p;
  if (l >= Lout) return;
  float acc = bs[co];
  #pragma unroll
  for (int k = 0; k < K; ++k) acc += Fs[(k*V + sq[p + k])*CO + co];
  y[((size_t)b*Lout + l)*CO + co] = f2b(fmaxf(acc, 0.f));
}

// =================================================================
// conv2/conv3 (both branches): implicit-GEMM via MFMA bf16.
// =================================================================
template<int CIN, int KK, int COUT, int NT2, bool POOL>
__global__ __launch_bounds__(512) void k_convmfma(
    const u16* __restrict__ xin, const u16* __restrict__ wtb,
    const float* __restrict__ bias, u16* __restrict__ yout,
    unsigned int* __restrict__ pool, int Lin, int Lout) {
  constexpr int KD = CIN*KK;
  constexpr int NCH = KD/32;
  constexpr int MT = 256, ROWS = MT + KK - 1;
  constexpr int XPAD = CIN + 8;
  constexpr int WPAD = KD + 8;
  __shared__ u16 xs[ROWS*XPAD];
  __shared__ u16 wsd[COUT*WPAD];
  int b = blockIdx.y;
  int l0 = blockIdx.x * MT;
  int tid = threadIdx.x;
  {
    const unsigned* wg = (const unsigned*)wtb;
    unsigned* wl = (unsigned*)wsd;
    constexpr int KD2 = KD/2, WP2 = WPAD/2;
    for (int i = tid; i < COUT*KD2; i += 512) {
      int co = i / KD2, c = i % KD2;
      wl[co*WP2 + c] = wg[i];
    }
  }
  {
    const unsigned* xg = (const unsigned*)(xin + (size_t)b*Lin*CIN);
    unsigned* xl = (unsigned*)xs;
    constexpr int C2 = CIN/2, XP2 = XPAD/2;
    for (int i = tid; i < ROWS*C2; i += 512) {
      int r = i / C2, c = i % C2;
      unsigned v = 0;
      if (l0 + r < Lin) v = xg[(size_t)l0*C2 + i];
      xl[r*XP2 + c] = v;
    }
  }
  __syncthreads();
  int lane = tid & 63;
  int w = tid >> 6;
  int mg = w & 3, ng = w >> 2;
  int l15 = lane & 15, l4 = lane >> 4;
  f32x4 acc[4][NT2];
  #pragma unroll
  for (int mi = 0; mi < 4; ++mi)
    #pragma unroll
    for (int nj = 0; nj < NT2; ++nj) acc[mi][nj] = (f32x4){0.f, 0.f, 0.f, 0.f};

  #pragma unroll
  for (int ch = 0; ch < NCH; ++ch) {
    const int kk = (ch*32) / CIN;
    const int cib = (ch*32) % CIN + l4*8;
    bh8 a[4], bb[NT2];
    #pragma unroll
    for (int mi = 0; mi < 4; ++mi) {
      int row = mg*64 + mi*16 + l15 + kk;
      a[mi] = *(const bh8*)&xs[row*XPAD + cib];
    }
    #pragma unroll
    for (int nj = 0; nj < NT2; ++nj) {
      int co = (ng*NT2 + nj)*16 + l15;
      bb[nj] = *(const bh8*)&wsd[co*WPAD + ch*32 + l4*8];
    }
    #pragma unroll
    for (int mi = 0; mi < 4; ++mi)
      #pragma unroll
      for (int nj = 0; nj < NT2; ++nj)
        acc[mi][nj] = __builtin_amdgcn_mfma_f32_16x16x32_bf16(a[mi], bb[nj], acc[mi][nj], 0, 0, 0);
  }

  if (!POOL) {
    #pragma unroll
    for (int nj = 0; nj < NT2; ++nj) {
      int co = (ng*NT2 + nj)*16 + l15;
      float bv = bias[co];
      #pragma unroll
      for (int mi = 0; mi < 4; ++mi)
        #pragma unroll
        for (int r = 0; r < 4; ++r) {
          int m = mg*64 + mi*16 + l4*4 + r;
          if (l0 + m < Lout)
            yout[((size_t)b*Lout + l0 + m)*COUT + co] = f2b(fmaxf(acc[mi][nj][r] + bv, 0.f));
        }
    }
  } else {
    #pragma unroll
    for (int nj = 0; nj < NT2; ++nj) {
      int co = (ng*NT2 + nj)*16 + l15;
      float bv = bias[co];
      float mx = 0.f;
      #pragma unroll
      for (int mi = 0; mi < 4; ++mi)
        #pragma unroll
        for (int r = 0; r < 4; ++r) {
          int m = mg*64 + mi*16 + l4*4 + r;
          if (l0 + m < Lout) mx = fmaxf(mx, fmaxf(acc[mi][nj][r] + bv, 0.f));
        }
      mx = fmaxf(mx, __shfl_xor(mx, 16, 64));
      mx = fmaxf(mx, __shfl_xor(mx, 32, 64));
      if (l4 == 0) atomicMax(&pool[b*COUT + co], __float_as_uint(mx));
    }
  }
}

// =================================================================
// h2 = g1o(bf16 [N,320]) @ g2_w(bf16 [co][k]) -> f32 [N,96] via MFMA.
// =================================================================
__global__ __launch_bounds__(512) void k_h2mfma(
    const u16* __restrict__ g1ob, const u16* __restrict__ wb,
    float* __restrict__ h2) {
  constexpr int KD = 320, WPAD = 328, NCH = 10;
  __shared__ u16 wsd[96*WPAD];
  int tid = threadIdx.x;
  {
    const unsigned* wg = (const unsigned*)wb;
    unsigned* wl = (unsigned*)wsd;
    for (int i = tid; i < 96*(KD/2); i += 512) {
      int co = i / (KD/2), c = i % (KD/2);
      wl[co*(WPAD/2) + c] = wg[i];
    }
  }
  __syncthreads();
  int lane = tid & 63;
  int w = tid >> 6;                 // m-sub 0..7
  int l15 = lane & 15, l4 = lane >> 4;
  long m0 = (long)blockIdx.x * 128;
  const u16* xr = g1ob + (m0 + w*16 + l15) * KD;
  f32x4 acc[6];
  #pragma unroll
  for (int nj = 0; nj < 6; ++nj) acc[nj] = (f32x4){0.f, 0.f, 0.f, 0.f};
  #pragma unroll
  for (int ch = 0; ch < NCH; ++ch) {
    bh8 a = *(const bh8*)&xr[ch*32 + l4*8];
    #pragma unroll
    for (int nj = 0; nj < 6; ++nj) {
      bh8 b = *(const bh8*)&wsd[(nj*16 + l15)*WPAD + ch*32 + l4*8];
      acc[nj] = __builtin_amdgcn_mfma_f32_16x16x32_bf16(a, b, acc[nj], 0, 0, 0);
    }
  }
  #pragma unroll
  for (int nj = 0; nj < 6; ++nj) {
    #pragma unroll
    for (int r = 0; r < 4; ++r) {
      long row = m0 + w*16 + l4*4 + r;
      h2[row*96 + nj*16 + l15] = acc[nj][r];
    }
  }
}

// =================================================================
// register-tiled f32 GEMM (h1)
// =================================================================
template<int BM, int BN, int BK, int TM, int TN, bool BIAS, bool RELU>
__global__ void k_gemm(const float* __restrict__ X, const float* __restrict__ W,
                       const float* __restrict__ bias, float* __restrict__ Y,
                       int K, int C) {
  constexpr int NTH = (BM/TM)*(BN/TN);
  static_assert(NTH == 256, "block must be 256 threads");
  __shared__ float xs[BK][BM + 1];
  __shared__ float wsm[BK][BN];
  const int m0 = blockIdx.y * BM;
  const int c0 = blockIdx.x * BN;
  const int tn = threadIdx.x % (BN/TN);
  const int tm = threadIdx.x / (BN/TN);
  float acc[TM][TN];
  #pragma unroll
  for (int i = 0; i < TM; ++i)
    #pragma unroll
    for (int j = 0; j < TN; ++j) acc[i][j] = 0.f;

  for (int k0 = 0; k0 < K; k0 += BK) {
    #pragma unroll
    for (int i = threadIdx.x; i < BM*BK; i += NTH) {
      int m = i / BK, k = i % BK;
      xs[k][m] = X[(long)(m0 + m)*K + k0 + k];
    }
    #pragma unroll
    for (int i = threadIdx.x; i < BK*BN; i += NTH) {
      int k = i / BN, c = i % BN;
      wsm[k][c] = W[(long)(k0 + k)*C + c0 + c];
    }
    __syncthreads();
    #pragma unroll
    for (int k = 0; k < BK; ++k) {
      float xv[TM], wv[TN];
      #pragma unroll
      for (int i = 0; i < TM; ++i) xv[i] = xs[k][tm*TM + i];
      #pragma unroll
      for (int j = 0; j < TN; ++j) wv[j] = wsm[k][tn*TN + j];
      #pragma unroll
      for (int i = 0; i < TM; ++i)
        #pragma unroll
        for (int j = 0; j < TN; ++j) acc[i][j] = fmaf(xv[i], wv[j], acc[i][j]);
    }
    __syncthreads();
  }
  #pragma unroll
  for (int i = 0; i < TM; ++i) {
    float* yr = Y + (long)(m0 + tm*TM + i)*C + c0 + tn*TN;
    #pragma unroll
    for (int j = 0; j < TN; ++j) {
      float v = acc[i][j];
      if (BIAS) v += bias[c0 + tn*TN + j];
      if (RELU) v = fmaxf(v, 0.f);
      yr[j] = v;
    }
  }
}

// =================================================================
// split-K f32 GEMM writing PRIVATE per-z partials (no atomics).
// P[z][m][c], z = blockIdx.z. MR = total rows (256).
// =================================================================
template<int BM, int BN, int BK, int TM, int TN>
__global__ void k_gemm_skp(const float* __restrict__ X, const float* __restrict__ W,
                           float* __restrict__ P, int K, int C, int KS, int MR) {
  constexpr int NTH = (BM/TM)*(BN/TN);
  static_assert(NTH == 256, "block must be 256 threads");
  __shared__ float xs[BK][BM + 1];
  __shared__ float wsm[BK][BN];
  const int m0 = blockIdx.y * BM;
  const int c0 = blockIdx.x * BN;
  const int kbeg = blockIdx.z * KS;
  const int kend = min(K, kbeg + KS);
  const int tn = threadIdx.x % (BN/TN);
  const int tm = threadIdx.x / (BN/TN);
  float acc[TM][TN];
  #pragma unroll
  for (int i = 0; i < TM; ++i)
    #pragma unroll
    for (int j = 0; j < TN; ++j) acc[i][j] = 0.f;

  for (int k0 = kbeg; k0 < kend; k0 += BK) {
    #pragma unroll
    for (int i = threadIdx.x; i < BM*BK; i += NTH) {
      int m = i / BK, k = i % BK;
      xs[k][m] = X[(long)(m0 + m)*K + k0 + k];
    }
    #pragma unroll
    for (int i = threadIdx.x; i < BK*BN; i += NTH) {
      int k = i / BN, c = i % BN;
      wsm[k][c] = W[(long)(k0 + k)*C + c0 + c];
    }
    __syncthreads();
    #pragma unroll
    for (int k = 0; k < BK; ++k) {
      float xv[TM], wv[TN];
      #pragma unroll
      for (int i = 0; i < TM; ++i) xv[i] = xs[k][tm*TM + i];
      #pragma unroll
      for (int j = 0; j < TN; ++j) wv[j] = wsm[k][tn*TN + j];
      #pragma unroll
      for (int i = 0; i < TM; ++i)
        #pragma unroll
        for (int j = 0; j < TN; ++j) acc[i][j] = fmaf(xv[i], wv[j], acc[i][j]);
    }
    __syncthreads();
  }
  float* pz = P + (size_t)blockIdx.z * MR * C;
  #pragma unroll
  for (int i = 0; i < TM; ++i) {
    float* yr = pz + (long)(m0 + tm*TM + i)*C + c0 + tn*TN;
    #pragma unroll
    for (int j = 0; j < TN; ++j) yr[j] = acc[i][j];
  }
}

// reduce NZ partials + bias + optional relu: Y[o] = act(bias[c] + sum_z P[z][o])
__global__ void k_redux(const float* __restrict__ P, const float* __restrict__ bias,
                        float* __restrict__ Y, long total, int C, int NZ, int relu) {
  long o = blockIdx.x*256L + threadIdx.x;
  if (o >= total) return;
  float v = bias[(int)(o % C)];
  for (int z = 0; z < NZ; ++z) v += P[(size_t)z*total + o];
  if (relu) v = fmaxf(v, 0.f);
  Y[o] = v;
}

// =================================================================
// split-K f32 GEMM with atomics (kept for tiny fc1)
// =================================================================
template<int BM, int BN, int BK, int TM, int TN>
__global__ void k_gemm_sk(const float* __restrict__ X, const float* __restrict__ W,
                          float* __restrict__ Y, int K, int C, int KS) {
  constexpr int NTH = (BM/TM)*(BN/TN);
  static_assert(NTH == 256, "block must be 256 threads");
  __shared__ float xs[BK][BM + 1];
  __shared__ float wsm[BK][BN];
  const int m0 = blockIdx.y * BM;
  const int c0 = blockIdx.x * BN;
  const int kbeg = blockIdx.z * KS;
  const int kend = min(K, kbeg + KS);
  const int tn = threadIdx.x % (BN/TN);
  const int tm = threadIdx.x / (BN/TN);
  float acc[TM][TN];
  #pragma unroll
  for (int i = 0; i < TM; ++i)
    #pragma unroll
    for (int j = 0; j < TN; ++j) acc[i][j] = 0.f;

  for (int k0 = kbeg; k0 < kend; k0 += BK) {
    #pragma unroll
    for (int i = threadIdx.x; i < BM*BK; i += NTH) {
      int m = i / BK, k = i % BK;
      xs[k][m] = X[(long)(m0 + m)*K + k0 + k];
    }
    #pragma unroll
    for (int i = threadIdx.x; i < BK*BN; i += NTH) {
      int k = i / BN, c = i % BN;
      wsm[k][c] = W[(long)(k0 + k)*C + c0 + c];
    }
    __syncthreads();
    #pragma unroll
    for (int k = 0; k < BK; ++k) {
      float xv[TM], wv[TN];
      #pragma unroll
      for (int i = 0; i < TM; ++i) xv[i] = xs[k][tm*TM + i];
      #pragma unroll
      for (int j = 0; j < TN; ++j) wv[j] = wsm[k][tn*TN + j];
      #pragma unroll
      for (int i = 0; i < TM; ++i)
        #pragma unroll
        for (int j = 0; j < TN; ++j) acc[i][j] = fmaf(xv[i], wv[j], acc[i][j]);
    }
    __syncthreads();
  }
  #pragma unroll
  for (int i = 0; i < TM; ++i) {
    float* yr = Y + (long)(m0 + tm*TM + i)*C + c0 + tn*TN;
    #pragma unroll
    for (int j = 0; j < TN; ++j) atomicAdd(&yr[j], acc[i][j]);
  }
}

// bias + optional relu, in place over [rows*C]
__global__ void k_bias_relu(float* __restrict__ Y, const float* __restrict__ bias,
                            long total, int C, int relu) {
  long o = blockIdx.x*256L + threadIdx.x;
  if (o >= total) return;
  int c = (int)(o % C);
  float v = Y[o] + bias[c];
  if (relu) v = fmaxf(v, 0.f);
  Y[o] = v;
}

// =================================================================
// per-node attention terms, wave-per-node (coalesced loads + shfl reduce)
// =================================================================
template<int H, int CH>
__global__ void k_nodeterms_w(const float* __restrict__ hf, const float* __restrict__ a_s,
                              const float* __restrict__ a_d, float* __restrict__ as_o,
                              float* __restrict__ ad_o) {
  constexpr int F = H * CH;
  constexpr int NJ = (F + 63) / 64;
  int wid = (int)((blockIdx.x*256L + threadIdx.x) >> 6);
  int lane = threadIdx.x & 63;
  if (wid >= NN) return;
  const float* hr = hf + (long)wid * F;
  float s1[H], s2[H];
  #pragma unroll
  for (int h = 0; h < H; ++h) { s1[h] = 0.f; s2[h] = 0.f; }
  #pragma unroll
  for (int j = 0; j < NJ; ++j) {
    int c = j*64 + lane;
    if ((F % 64 == 0) || c < F) {
      int h = c / CH;
      float v = hr[c];
      s1[h] = fmaf(v, a_s[c], s1[h]);
      s2[h] = fmaf(v, a_d[c], s2[h]);
    }
  }
  #pragma unroll
  for (int h = 0; h < H; ++h) {
    #pragma unroll
    for (int off = 1; off < 64; off <<= 1) {
      s1[h] += __shfl_xor(s1[h], off, 64);
      s2[h] += __shfl_xor(s2[h], off, 64);
    }
  }
  if (lane == 0) {
    #pragma unroll
    for (int h = 0; h < H; ++h) {
      as_o[(long)wid*H + h] = s1[h];
      ad_o[(long)wid*H + h] = s2[h];
    }
  }
}

// per-edge attention logit with leaky_relu(0.2), written directly in CSR
// order via csr_pos. e >= EE are self loops.
template<int H>
__global__ void k_edge_attn(const int* __restrict__ ei, const float* __restrict__ ea,
                            const int* __restrict__ csr_pos,
                            const float* __restrict__ asb, const float* __restrict__ adb,
                            const float* __restrict__ M, const float* __restrict__ aeself,
                            float* __restrict__ ac) {
  long e = blockIdx.x*256L + threadIdx.x;
  if (e >= (long)EN) return;
  int s, d;
  float av[H];
  if (e < EE) {
    s = ei[e]; d = ei[EE + e];
    float er[5];
    #pragma unroll
    for (int j = 0; j < 5; ++j) er[j] = ea[e*5 + j];
    #pragma unroll
    for (int h = 0; h < H; ++h) {
      float t = 0.f;
      #pragma unroll
      for (int j = 0; j < 5; ++j) t = fmaf(er[j], M[j*H + h], t);
      av[h] = t;
    }
  } else {
    s = d = (int)(e - EE);
    #pragma unroll
    for (int h = 0; h < H; ++h) av[h] = aeself[h];
  }
  long p = csr_pos[e];
  #pragma unroll
  for (int h = 0; h < H; ++h) {
    float v = asb[s*H + h] + adb[d*H + h] + av[h];
    ac[p*H + h] = (v > 0.f) ? v : 0.2f * v;
  }
}

// per-dst softmax stats: amax[h], rinv[h] (one wave per dst)
template<int H>
__global__ void k_stats(const int* __restrict__ rowptr, const float* __restrict__ ac,
                        float* __restrict__ amaxo, float* __restrict__ rinvo) {
  int wid = (int)((blockIdx.x*256L + threadIdx.x) >> 6);
  int lane = threadIdx.x & 63;
  if (wid >= NN) return;
  int row0 = rowptr[wid], row1 = rowptr[wid + 1];
  float amax[H], asum[H];
  #pragma unroll
  for (int h = 0; h < H; ++h) amax[h] = -1e30f;
  for (int p = row0 + lane; p < row1; p += 64) {
    #pragma unroll
    for (int h = 0; h < H; ++h) amax[h] = fmaxf(amax[h], ac[(long)p*H + h]);
  }
  #pragma unroll
  for (int h = 0; h < H; ++h)
    for (int off = 1; off < 64; off <<= 1) amax[h] = fmaxf(amax[h], __shfl_xor(amax[h], off, 64));
  #pragma unroll
  for (int h = 0; h < H; ++h) asum[h] = 0.f;
  for (int p = row0 + lane; p < row1; p += 64) {
    #pragma unroll
    for (int h = 0; h < H; ++h) asum[h] += __expf(ac[(long)p*H + h] - amax[h]);
  }
  #pragma unroll
  for (int h = 0; h < H; ++h)
    for (int off = 1; off < 64; off <<= 1) asum[h] += __shfl_xor(asum[h], off, 64);
  if (lane == 0) {
    #pragma unroll
    for (int h = 0; h < H; ++h) {
      amaxo[(long)wid*H + h] = amax[h];
      rinvo[(long)wid*H + h] = 1.f / (asum[h] + 1e-16f);
    }
  }
}

// normalize logits -> alpha, in place (lane-parallel over CSR slots)
template<int H>
__global__ void k_alpha(const int* __restrict__ csr_dst, const float* __restrict__ amaxb,
                        const float* __restrict__ rinvb, float* __restrict__ ac) {
  long p = blockIdx.x*256L + threadIdx.x;
  if (p >= (long)EN) return;
  int d = csr_dst[p];
  #pragma unroll
  for (int h = 0; h < H; ++h)
    ac[p*H + h] = __expf(ac[p*H + h] - amaxb[(long)d*H + h]) * rinvb[(long)d*H + h];
}

// ------------- CSR build -------------
__global__ void k_deg(const int* __restrict__ ei, int* __restrict__ deg) {
  long e = blockIdx.x*256L + threadIdx.x;
  if (e >= (long)EN) return;
  int d = (e < EE) ? ei[EE + e] : (int)(e - EE);
  atomicAdd(&deg[d], 1);
}

__global__ void k_scan(const int* __restrict__ deg, int* __restrict__ rowptr,
                       int* __restrict__ cursor) {
  __shared__ int ps[256];
  int tid = threadIdx.x;
  int base = tid * 128;           // 256*128 = 32768 = NN
  int s = 0;
  for (int i = 0; i < 128; ++i) s += deg[base + i];
  ps[tid] = s;
  __syncthreads();
  for (int off = 1; off < 256; off <<= 1) {
    int v = (tid >= off) ? ps[tid - off] : 0;
    __syncthreads();
    ps[tid] += v;
    __syncthreads();
  }
  int run = ps[tid] - s;          // exclusive prefix
  for (int i = 0; i < 128; ++i) {
    rowptr[base + i] = run;
    cursor[base + i] = run;
    run += deg[base + i];
  }
  if (tid == 255) rowptr[NN] = run;
}

__global__ void k_scatter(const int* __restrict__ ei, int* __restrict__ cursor,
                          int* __restrict__ csr_src, int* __restrict__ csr_pos,
                          int* __restrict__ csr_dst) {
  long e = blockIdx.x*256L + threadIdx.x;
  if (e >= (long)EN) return;
  int s, d;
  if (e < EE) { s = ei[e]; d = ei[EE + e]; }
  else        { s = d = (int)(e - EE); }
  int p = atomicAdd(&cursor[d], 1);
  csr_src[p] = s;
  csr_dst[p] = d;
  csr_pos[e] = p;
}

// =================================================================
// GAT aggregation (alpha precomputed in ac): wave per dst, XCD-pinned,
// edge loop unrolled x4 for memory-level parallelism.
// =================================================================
template<int H, int CH, int ACT, bool OBF16>
__global__ void k_gat_aggr(const int* __restrict__ rowptr, const int* __restrict__ csr_src,
                           const float* __restrict__ ac,
                           const float* __restrict__ hfeat, const float* __restrict__ bias,
                           void* __restrict__ outv) {
  int bid = blockIdx.x;
  int x = bid & 7;
  int r = bid >> 3;
  int s = r & 31;
  int c = r >> 5;
  int g = c*8 + x;
  int wid = g*128 + s*4 + (int)(threadIdx.x >> 6);
  int lane = threadIdx.x & 63;
  int row0 = rowptr[wid], row1 = rowptr[wid + 1];
  constexpr int F = H * CH;
  constexpr int NJ = (F + 63) / 64;
  float acc[NJ];
  #pragma unroll
  for (int j = 0; j < NJ; ++j) acc[j] = 0.f;
  int p = row0;
  for (; p + 4 <= row1; p += 4) {
    int sidx[4];
    float al[4][H];
    #pragma unroll
    for (int u = 0; u < 4; ++u) sidx[u] = csr_src[p + u];
    #pragma unroll
    for (int u = 0; u < 4; ++u)
      #pragma unroll
      for (int h = 0; h < H; ++h) al[u][h] = ac[(long)(p + u)*H + h];
    #pragma unroll
    for (int j = 0; j < NJ; ++j) {
      int idx = j*64 + lane;
      if ((F % 64 == 0) || idx < F) {
        int h = idx / CH;
        float v0 = hfeat[(long)sidx[0]*F + idx];
        float v1 = hfeat[(long)sidx[1]*F + idx];
        float v2 = hfeat[(long)sidx[2]*F + idx];
        float v3 = hfeat[(long)sidx[3]*F + idx];
        acc[j] = fmaf(al[0][h], v0, acc[j]);
        acc[j] = fmaf(al[1][h], v1, acc[j]);
        acc[j] = fmaf(al[2][h], v2, acc[j]);
        acc[j] = fmaf(al[3][h], v3, acc[j]);
      }
    }
  }
  for (; p < row1; ++p) {
    int src = csr_src[p];
    const float* hr = hfeat + (long)src * F;
    #pragma unroll
    for (int j = 0; j < NJ; ++j) {
      int idx = j*64 + lane;
      if ((F % 64 == 0) || idx < F) {
        int h = idx / CH;
        acc[j] = fmaf(ac[(long)p*H + h], hr[idx], acc[j]);
      }
    }
  }
  #pragma unroll
  for (int j = 0; j < NJ; ++j) {
    int idx = j*64 + lane;
    if ((F % 64 == 0) || idx < F) {
      float v = acc[j] + bias[idx];
      if (ACT == 0) v = (v > 0.f) ? v : expm1f(v);
      else          v = fmaxf(v, 0.f);
      if (OBF16) ((u16*)outv)[(long)wid * F + idx] = f2b(v);
      else       ((float*)outv)[(long)wid * F + idx] = v;
    }
  }
}

// graph max pool (relu'd input >= 0, pooled pre-zeroed)
__global__ void k_pool(const float* __restrict__ g2o, const int* __restrict__ batch,
                       unsigned int* __restrict__ pooled) {
  long o = blockIdx.x*256L + threadIdx.x;
  if (o >= (long)NN * 96) return;
  int n = (int)(o / 96), c = (int)(o % 96);
  atomicMax(&pooled[batch[n]*96 + c], __float_as_uint(g2o[o]));
}

__global__ void k_concat(const float* __restrict__ cd, const float* __restrict__ ct,
                         const float* __restrict__ gfc, float* __restrict__ xc) {
  int t = blockIdx.x*256 + threadIdx.x;
  if (t >= NB*288) return;
  int b = t / 288, c = t % 288;
  float v = (c < 96) ? cd[b*96 + c] : (c < 192) ? ct[b*96 + (c-96)] : gfc[b*96 + (c-192)];
  xc[t] = v;
}

// final 512-dot per row
__global__ void k_final(const float* __restrict__ x, const float* __restrict__ w,
                        const float* __restrict__ b, float* __restrict__ out) {
  int wid = (int)((blockIdx.x*256L + threadIdx.x) >> 6);
  int lane = threadIdx.x & 63;
  if (wid >= NB) return;
  const float* xr = x + (long)wid*512;
  float s = 0.f;
  for (int k = lane; k < 512; k += 64) s = fmaf(xr[k], w[k], s);
  for (int off = 1; off < 64; off <<= 1) s += __shfl_xor(s, off, 64);
  if (lane == 0) out[wid] = s + b[0];
}

// =================================================================
extern "C" void kernel_launch(void* const* d_in, const int* in_sizes, int n_in,
                              void* d_out, int out_size, void* d_ws, size_t ws_size,
                              hipStream_t stream) {
  const int*   xd     = (const int*)  d_in[0];
  const int*   xt     = (const int*)  d_in[1];
  const float* ax     = (const float*)d_in[2];
  const int*   ei     = (const int*)  d_in[3];
  const float* ea     = (const float*)d_in[4];
  const int*   batch  = (const int*)  d_in[5];
  const float* emb_xd = (const float*)d_in[6];
  const float* emb_xt = (const float*)d_in[7];
  const float* wd1 = (const float*)d_in[8];  const float* bd1 = (const float*)d_in[9];
  const float* wd2 = (const float*)d_in[10]; const float* bd2 = (const float*)d_in[11];
  const float* wd3 = (const float*)d_in[12]; const float* bd3 = (const float*)d_in[13];
  const float* wt1 = (const float*)d_in[14]; const float* bt1 = (const float*)d_in[15];
  const float* wt2 = (const float*)d_in[16]; const float* bt2 = (const float*)d_in[17];
  const float* wt3 = (const float*)d_in[18]; const float* bt3 = (const float*)d_in[19];
  const float* g1_w  = (const float*)d_in[20]; const float* g1_as = (const float*)d_in[21];
  const float* g1_ad = (const float*)d_in[22]; const float* g1_we = (const float*)d_in[23];
  const float* g1_ae = (const float*)d_in[24]; const float* g1_b  = (const float*)d_in[25];
  const float* g2_w  = (const float*)d_in[26]; const float* g2_as = (const float*)d_in[27];
  const float* g2_ad = (const float*)d_in[28]; const float* g2_we = (const float*)d_in[29];
  const float* g2_ae = (const float*)d_in[30]; const float* g2_b  = (const float*)d_in[31];
  const float* fc1_w = (const float*)d_in[32]; const float* fc1_b = (const float*)d_in[33];
  const float* c1_w = (const float*)d_in[34]; const float* c1_b = (const float*)d_in[35];
  const float* c2_w = (const float*)d_in[36]; const float* c2_b = (const float*)d_in[37];
  const float* c3_w = (const float*)d_in[38]; const float* c3_b = (const float*)d_in[39];
  const float* c4_w = (const float*)d_in[40]; const float* c4_b = (const float*)d_in[41];
  float* out = (float*)d_out;

  char* ws = (char*)d_ws;
  auto F = [&](size_t off) { return (float*)(ws + off); };
  auto I = [&](size_t off) { return (int*)(ws + off); };
  auto U = [&](size_t off) { return (unsigned int*)(ws + off); };
  auto H = [&](size_t off) { return (u16*)(ws + off); };

  // ---- zero-init the atomically-updated buffers ----
  hipMemsetAsync(ws + OFF_CB,   0, 64*sizeof(float), stream);
  hipMemsetAsync(ws + OFF_DEG,  0, NN*sizeof(int),   stream);
  hipMemsetAsync(ws + OFF_CD,   0, NB*96*sizeof(float), stream);
  hipMemsetAsync(ws + OFF_CT,   0, NB*96*sizeof(float), stream);
  hipMemsetAsync(ws + OFF_POOL, 0, NB*96*sizeof(float), stream);
  hipMemsetAsync(ws + OFF_GFC,  0, NB*96*sizeof(float), stream);

  // ---- tables / weight converts ----
  k_tables<<<(8320 + 6656 + 30 + 255)/256, 256, 0, stream>>>(
      wd1, emb_xd, wt1, emb_xt, g1_we, g1_ae, g2_we, g2_ae,
      F(OFF_FD), F(OFF_FT), F(OFF_CB));
  k_wcvt<<<(8192 + 24576 + 16384 + 49152 + 30720 + 255)/256, 256, 0, stream>>>(
      wd2, wd3, wt2, wt3, g2_w,
      H(OFF_WD2B), H(OFF_WD3B), H(OFF_WT2B), H(OFF_WT3B), H(OFF_W2GB));
  k_easum<<<256, 256, 0, stream>>>(ea, F(OFF_CB));
  k_finalize<<<1, 64, 0, stream>>>(F(OFF_CB));

  // ---- drug conv branch (bf16 MFMA): 100 -> 97 -> 94 -> 91 -> maxpool ----
  k_conv1t<4,65><<<dim3((97 + 15)/16, NB), 512, 0, stream>>>(
      xd, F(OFF_FD), bd1, H(OFF_A), 100, 97);
  k_convmfma<32,4,64,2,false><<<dim3(1, NB), 512, 0, stream>>>(
      H(OFF_A), H(OFF_WD2B), bd2, H(OFF_B), nullptr, 97, 94);
  k_convmfma<64,4,96,3,true><<<dim3(1, NB), 512, 0, stream>>>(
      H(OFF_B), H(OFF_WD3B), bd3, nullptr, U(OFF_CD), 94, 91);

  // ---- target conv branch (bf16 MFMA): 1000 -> 993 -> 986 -> 979 -> maxpool ----
  k_conv1t<8,26><<<dim3((993 + 15)/16, NB), 512, 0, stream>>>(
      xt, F(OFF_FT), bt1, H(OFF_A), 1000, 993);
  k_convmfma<32,8,64,2,false><<<dim3(4, NB), 512, 0, stream>>>(
      H(OFF_A), H(OFF_WT2B), bt2, H(OFF_B), nullptr, 993, 986);
  k_convmfma<64,8,96,3,true><<<dim3(4, NB), 512, 0, stream>>>(
      H(OFF_B), H(OFF_WT3B), bt3, nullptr, U(OFF_CT), 986, 979);

  // ---- CSR build ----
  k_deg<<<(EN + 255)/256, 256, 0, stream>>>(ei, I(OFF_DEG));
  k_scan<<<1, 256, 0, stream>>>(I(OFF_DEG), I(OFF_ROWP), I(OFF_CUR));
  k_scatter<<<(EN + 255)/256, 256, 0, stream>>>(
      ei, I(OFF_CUR), I(OFF_CSRS), I(OFF_CSRP), I(OFF_CSRD));

  // ---- GAT layer 1 ----
  k_gemm<64,64,24,4,4,false,false><<<dim3(320/64, NN/64), 256, 0, stream>>>(
      ax, g1_w, nullptr, F(OFF_A), 24, 320);
  k_nodeterms_w<5,64><<<NN/4, 256, 0, stream>>>(
      F(OFF_A), g1_as, g1_ad, F(OFF_AS1), F(OFF_AD1));
  k_edge_attn<5><<<(EN + 255)/256, 256, 0, stream>>>(
      ei, ea, I(OFF_CSRP), F(OFF_AS1), F(OFF_AD1), F(OFF_CB), F(OFF_CB) + 35, F(OFF_AC));
  k_stats<5><<<NN/4, 256, 0, stream>>>(
      I(OFF_ROWP), F(OFF_AC), F(OFF_AS1), F(OFF_AD1));   // reuse AS1/AD1 for amax/rinv
  k_alpha<5><<<(EN + 255)/256, 256, 0, stream>>>(
      I(OFF_CSRD), F(OFF_AS1), F(OFF_AD1), F(OFF_AC));
  k_gat_aggr<5,64,0,true><<<NN/4, 256, 0, stream>>>(
      I(OFF_ROWP), I(OFF_CSRS), F(OFF_AC), F(OFF_A), g1_b, (void*)H(OFF_B));

  // ---- GAT layer 2 (h2 via MFMA from bf16 g1o) ----
  k_h2mfma<<<NN/128, 512, 0, stream>>>(H(OFF_B), H(OFF_W2GB), F(OFF_C));
  k_nodeterms_w<1,96><<<NN/4, 256, 0, stream>>>(
      F(OFF_C), g2_as, g2_ad, F(OFF_AS2), F(OFF_AD2));
  k_edge_attn<1><<<(EN + 255)/256, 256, 0, stream>>>(
      ei, ea, I(OFF_CSRP), F(OFF_AS2), F(OFF_AD2), F(OFF_CB) + 25, F(OFF_CB) + 40, F(OFF_AC));
  k_stats<1><<<NN/4, 256, 0, stream>>>(
      I(OFF_ROWP), F(OFF_AC), F(OFF_AS2), F(OFF_AD2));
  k_alpha<1><<<(EN + 255)/256, 256, 0, stream>>>(
      I(OFF_CSRD), F(OFF_AS2), F(OFF_AD2), F(OFF_AC));
  k_gat_aggr<1,96,1,false><<<NN/4, 256, 0, stream>>>(
      I(OFF_ROWP), I(OFF_CSRS), F(OFF_AC), F(OFF_C), g2_b, (void*)F(OFF_G2O));

  // ---- graph pool + fc1 (tiny split-K w/ atomics) ----
  k_pool<<<(int)(((long)NN*96 + 255)/256), 256, 0, stream>>>(
      F(OFF_G2O), batch, U(OFF_POOL));
  k_gemm_sk<64,32,32,4,2><<<dim3(96/32, NB/64, 3), 256, 0, stream>>>(
      F(OFF_POOL), fc1_w, F(OFF_GFC), 96, 96, 32);
  k_bias_relu<<<(NB*96 + 255)/256, 256, 0, stream>>>(
      F(OFF_GFC), fc1_b, (long)NB*96, 96, 1);

  // ---- concat + MLP head (split-K private partials + fused reduce) ----
  k_concat<<<(NB*288 + 255)/256, 256, 0, stream>>>(
      F(OFF_CD), F(OFF_CT), F(OFF_GFC), F(OFF_XC));

  k_gemm_skp<64,64,32,4,4><<<dim3(1024/64, NB/64, 3), 256, 0, stream>>>(
      F(OFF_XC), c1_w, F(OFF_M1P), 288, 1024, 96, NB);
  k_redux<<<(NB*1024 + 255)/256, 256, 0, stream>>>(
      F(OFF_M1P), c1_b, F(OFF_M1B), (long)NB*1024, 1024, 3, 1);

  k_gemm_skp<64,64,32,4,4><<<dim3(1024/64, NB/64, 8), 256, 0, stream>>>(
      F(OFF_M1B), c2_w, F(OFF_M2P), 1024, 1024, 128, NB);
  k_redux<<<(NB*1024 + 255)/256, 256, 0, stream>>>(
      F(OFF_M2P), c2_b, F(OFF_M2B), (long)NB*1024, 1024, 8, 1);

  k_gemm_skp<64,64,32,4,4><<<dim3(512/64, NB/64, 8), 256, 0, stream>>>(
      F(OFF_M2B), c3_w, F(OFF_M3P), 1024, 512, 128, NB);
  k_redux<<<(NB*512 + 255)/256, 256, 0, stream>>>(
      F(OFF_M3P), c3_b, F(OFF_M3B), (long)NB*512, 512, 8, 1);

  k_final<<<(NB*64 + 255)/256, 256, 0, stream>>>(F(OFF_M3B), c4_w, c4_b, out);
}